// Round 4
// baseline (54992.761 us; speedup 1.0000x reference)
//
#include <hip/hip_runtime.h>

#define LL 6
#define BB 8
#define TT 1024
#define CC 1024
#define HH 16
#define HS 64
#define VV 4096
#define BT (BB*TT)

// ---------------- embedding: x = tok_emb[idx] + pos_emb ----------------
__global__ __launch_bounds__(256) void embed_kernel(
    const int* __restrict__ idx, const float* __restrict__ tok,
    const float* __restrict__ pos, float* __restrict__ x) {
  int bt = blockIdx.x;
  int t = bt & (TT - 1);
  int id = idx[bt];
  float4 te = reinterpret_cast<const float4*>(tok)[(size_t)id * (CC/4) + threadIdx.x];
  float4 pe = reinterpret_cast<const float4*>(pos)[(size_t)t * (CC/4) + threadIdx.x];
  float4 r; r.x = te.x+pe.x; r.y = te.y+pe.y; r.z = te.z+pe.z; r.w = te.w+pe.w;
  reinterpret_cast<float4*>(x)[(size_t)bt * (CC/4) + threadIdx.x] = r;
}

// ---------------- layernorm: fp32 in -> fp32 out ----------------
__global__ __launch_bounds__(256) void ln32_kernel(
    const float* __restrict__ x, const float* __restrict__ g,
    const float* __restrict__ b, float* __restrict__ out) {
  __shared__ float red[8];
  int row = blockIdx.x, tid = threadIdx.x;
  float4 v = reinterpret_cast<const float4*>(x)[(size_t)row * (CC/4) + tid];
  float s  = v.x+v.y+v.z+v.w;
  float ss = v.x*v.x+v.y*v.y+v.z*v.z+v.w*v.w;
  #pragma unroll
  for (int off = 32; off; off >>= 1) { s += __shfl_xor(s, off); ss += __shfl_xor(ss, off); }
  if ((tid & 63) == 0) { red[tid>>6] = s; red[4+(tid>>6)] = ss; }
  __syncthreads();
  s  = red[0]+red[1]+red[2]+red[3];
  ss = red[4]+red[5]+red[6]+red[7];
  float mu = s * (1.f/CC);
  float rs = rsqrtf(ss*(1.f/CC) - mu*mu + 1e-5f);
  float4 gg = reinterpret_cast<const float4*>(g)[tid];
  float4 bb = reinterpret_cast<const float4*>(b)[tid];
  float4 o;
  o.x = (v.x-mu)*rs*gg.x + bb.x;
  o.y = (v.y-mu)*rs*gg.y + bb.y;
  o.z = (v.z-mu)*rs*gg.z + bb.z;
  o.w = (v.w-mu)*rs*gg.w + bb.w;
  reinterpret_cast<float4*>(out)[(size_t)row * (CC/4) + tid] = o;
}

// ---------------- dumb-but-correct fp32 SIMT GEMM ----------------
// C[M x N] = A[M x K] (lda=K) @ B[K x N] (ldb) ; 64x64 tile, 256 threads,
// each thread 4x4 outputs (strided 16). No MFMA, no bf16 -- bisection build.
__global__ __launch_bounds__(256) void gemm32_kernel(
    const float* __restrict__ A, const float* __restrict__ B,
    const float* __restrict__ bias, const float* __restrict__ res,
    float* __restrict__ outf, int K, int ldb, int ldc, int relu) {
  __shared__ float As[64][17];
  __shared__ float Bs[16][65];
  int tid = threadIdx.x;
  int m0 = blockIdx.y * 64, n0 = blockIdx.x * 64;
  int tx = tid & 15, ty = tid >> 4;      // 16x16 thread grid
  int bcol = tid & 63, brow = tid >> 6;  // B staging decomposition
  float acc[4][4] = {};
  for (int k0 = 0; k0 < K; k0 += 16) {
    #pragma unroll
    for (int i = 0; i < 4; ++i)
      As[ty + 16*i][tx] = A[(size_t)(m0 + ty + 16*i) * K + k0 + tx];
    #pragma unroll
    for (int i = 0; i < 4; ++i)
      Bs[brow + 4*i][bcol] = B[(size_t)(k0 + brow + 4*i) * ldb + n0 + bcol];
    __syncthreads();
    #pragma unroll
    for (int kk = 0; kk < 16; ++kk) {
      float a[4], bb[4];
      #pragma unroll
      for (int i = 0; i < 4; ++i) a[i] = As[ty + 16*i][kk];
      #pragma unroll
      for (int j = 0; j < 4; ++j) bb[j] = Bs[kk][tx + 16*j];
      #pragma unroll
      for (int i = 0; i < 4; ++i)
        #pragma unroll
        for (int j = 0; j < 4; ++j)
          acc[i][j] += a[i] * bb[j];
    }
    __syncthreads();
  }
  #pragma unroll
  for (int i = 0; i < 4; ++i) {
    int row = m0 + ty + 16*i;
    #pragma unroll
    for (int j = 0; j < 4; ++j) {
      int col = n0 + tx + 16*j;
      float vv = acc[i][j] + (bias ? bias[col] : 0.f);
      if (relu) vv = fmaxf(vv, 0.f);
      size_t off = (size_t)row * ldc + col;
      if (res) vv += res[off];
      outf[off] = vv;
    }
  }
}

// ---------------- dumb-but-correct attention: one block per (b,h,t) row ----
// fp32 q/k/v/o, barriers between every phase, serial thread-0 reductions.
__global__ __launch_bounds__(256) void attn32_kernel(
    const float* __restrict__ q, const float* __restrict__ k,
    const float* __restrict__ v, float* __restrict__ o) {
  __shared__ float s_lds[TT];
  __shared__ float q_lds[HS];
  __shared__ float stat[2];
  int tid = threadIdx.x;
  int rid = blockIdx.x;                 // (b, hh, t)
  int t  = rid & (TT - 1);
  int hh = (rid >> 10) & (HH - 1);
  int b  = rid >> 14;
  size_t rowbase = ((size_t)(b*TT + t)) * CC + hh*HS;
  if (tid < HS) q_lds[tid] = q[rowbase + tid];
  __syncthreads();
  // scores for keys 0..t, MULTIPLIED by sqrt(HS)=8 (faithful to reference)
  for (int kk = tid; kk <= t; kk += 256) {
    const float* kr = k + ((size_t)(b*TT + kk)) * CC + hh*HS;
    float s = 0.f;
    for (int d = 0; d < HS; ++d) s += q_lds[d] * kr[d];
    s_lds[kk] = s * 8.0f;
  }
  __syncthreads();
  if (tid == 0) {
    float mx = s_lds[0];
    for (int kk = 1; kk <= t; ++kk) mx = fmaxf(mx, s_lds[kk]);
    stat[0] = mx;
  }
  __syncthreads();
  float mx = stat[0];
  for (int kk = tid; kk <= t; kk += 256) s_lds[kk] = expf(s_lds[kk] - mx);
  __syncthreads();
  if (tid == 0) {
    float sum = 0.f;
    for (int kk = 0; kk <= t; ++kk) sum += s_lds[kk];
    stat[1] = 1.0f / sum;
  }
  __syncthreads();
  float inv = stat[1];
  if (tid < HS) {
    float acc = 0.f;
    const float* vcol = v + (size_t)b*TT*CC + hh*HS + tid;
    for (int kk = 0; kk <= t; ++kk) acc += s_lds[kk] * vcol[(size_t)kk*CC];
    o[rowbase + tid] = acc * inv;
  }
}

extern "C" void kernel_launch(void* const* d_in, const int* in_sizes, int n_in,
                              void* d_out, int out_size, void* d_ws, size_t ws_size,
                              hipStream_t stream) {
  const int*   idx  = (const int*)d_in[0];
  const float* tok  = (const float*)d_in[1];
  const float* pos  = (const float*)d_in[2];
  const float* Wq   = (const float*)d_in[3];
  const float* Wk   = (const float*)d_in[4];
  const float* Wv   = (const float*)d_in[5];
  const float* Wo   = (const float*)d_in[6];
  const float* bo   = (const float*)d_in[7];
  const float* ln1g = (const float*)d_in[8];
  const float* ln1b = (const float*)d_in[9];
  const float* ln2g = (const float*)d_in[10];
  const float* ln2b = (const float*)d_in[11];
  const float* W1   = (const float*)d_in[12];
  const float* b1   = (const float*)d_in[13];
  const float* W2   = (const float*)d_in[14];
  const float* b2   = (const float*)d_in[15];
  const float* lnfg = (const float*)d_in[16];
  const float* lnfb = (const float*)d_in[17];
  const float* lmw  = (const float*)d_in[18];
  const float* lmb  = (const float*)d_in[19];
  float* out = (float*)d_out;

  // d_out (128 MiB) layout, liveness-checked:
  //   x  fp32 [  0, 32M)  residual (dead only at final logits gemm)
  //   h  fp32 [ 32M,64M)  ln1-out -> attn-out -> ln2-out
  //   qf fp32 [ 64M,96M)  \ dead after attn; region reused as a1 (BTx2048 fp32)
  //   kf fp32 [ 96M,128M) /
  // ws: v fp32 [0,32M) during layers; hf fp32 [0,32M) for final LN (v dead).
  char* ob = (char*)d_out;
  float* x  = (float*)ob;
  float* h  = (float*)(ob + ((size_t)32<<20));
  float* qf = (float*)(ob + ((size_t)64<<20));
  float* kf = (float*)(ob + ((size_t)96<<20));
  float* a1 = (float*)(ob + ((size_t)64<<20));  // BTx2048 fp32 = 64 MiB
  float* vf = (float*)d_ws;                      // 32 MiB
  float* hf = (float*)d_ws;                      // reuse after v dead

  dim3 blk(256);
  dim3 g1(CC/64,   BT/64);   // (16, 128) N=1024
  dim3 gh(2048/64, BT/64);   // (32, 128) N=2048 (MLP column chunk)
  dim3 gl(VV/64,   BT/64);   // (64, 128) N=4096

  embed_kernel<<<BT, blk, 0, stream>>>(idx, tok, pos, x);
  for (int l = 0; l < LL; ++l) {
    const float* Wq_l = Wq + (size_t)l*CC*CC;
    const float* Wk_l = Wk + (size_t)l*CC*CC;
    const float* Wv_l = Wv + (size_t)l*CC*CC;
    const float* Wo_l = Wo + (size_t)l*CC*CC;
    const float* W1_l = W1 + (size_t)l*CC*4*CC;
    const float* W2_l = W2 + (size_t)l*4*CC*CC;
    ln32_kernel<<<BT, blk, 0, stream>>>(x, ln1g + (size_t)l*CC, ln1b + (size_t)l*CC, h);
    gemm32_kernel<<<g1, blk, 0, stream>>>(h, Wq_l, nullptr, nullptr, qf, CC, CC, CC, 0);
    gemm32_kernel<<<g1, blk, 0, stream>>>(h, Wk_l, nullptr, nullptr, kf, CC, CC, CC, 0);
    gemm32_kernel<<<g1, blk, 0, stream>>>(h, Wv_l, nullptr, nullptr, vf, CC, CC, CC, 0);
    attn32_kernel<<<BB*HH*TT, blk, 0, stream>>>(qf, kf, vf, h);  // o -> h (ln1-out dead)
    gemm32_kernel<<<g1, blk, 0, stream>>>(h, Wo_l, bo + (size_t)l*CC, x, x, CC, CC, CC, 0);
    ln32_kernel<<<BT, blk, 0, stream>>>(x, ln2g + (size_t)l*CC, ln2b + (size_t)l*CC, h);
    // MLP in two 2048-column chunks (a1 reuses qf/kf region)
    gemm32_kernel<<<gh, blk, 0, stream>>>(h,  W1_l,           b1 + (size_t)l*4*CC,        nullptr, a1, CC,   4*CC, 2048, 1);
    gemm32_kernel<<<g1, blk, 0, stream>>>(a1, W2_l,           b2 + (size_t)l*CC,          x, x,        2048, CC,   CC,   0);
    gemm32_kernel<<<gh, blk, 0, stream>>>(h,  W1_l + 2048,    b1 + (size_t)l*4*CC + 2048, nullptr, a1, CC,   4*CC, 2048, 1);
    gemm32_kernel<<<g1, blk, 0, stream>>>(a1, W2_l + 2048*CC, nullptr,                    x, x,        2048, CC,   CC,   0);
  }
  ln32_kernel<<<BT, blk, 0, stream>>>(x, lnfg, lnfb, hf);
  gemm32_kernel<<<gl, blk, 0, stream>>>(hf, lmw, lmb, nullptr, out, CC, VV, VV, 0);
}

// Round 7
// 29992.728 us; speedup vs baseline: 1.8335x; 1.8335x over previous
//
#include <hip/hip_runtime.h>

#define LL 6
#define BB 8
#define TT 1024
#define CC 1024
#define HH 16
#define HS 64
#define VV 4096
#define BT (BB*TT)

typedef __attribute__((ext_vector_type(4))) float f32x4;
typedef __attribute__((ext_vector_type(8))) short bf16x8;

// ---------------- embedding: x = tok_emb[idx] + pos_emb ----------------
__global__ __launch_bounds__(256) void embed_kernel(
    const int* __restrict__ idx, const float* __restrict__ tok,
    const float* __restrict__ pos, float* __restrict__ x) {
  int bt = blockIdx.x;
  int t = bt & (TT - 1);
  int id = idx[bt];
  float4 te = reinterpret_cast<const float4*>(tok)[(size_t)id * (CC/4) + threadIdx.x];
  float4 pe = reinterpret_cast<const float4*>(pos)[(size_t)t * (CC/4) + threadIdx.x];
  float4 r; r.x = te.x+pe.x; r.y = te.y+pe.y; r.z = te.z+pe.z; r.w = te.w+pe.w;
  reinterpret_cast<float4*>(x)[(size_t)bt * (CC/4) + threadIdx.x] = r;
}

// ---------------- layernorm: fp32 in -> fp32 out (R4-proven) ----------------
__global__ __launch_bounds__(256) void ln32_kernel(
    const float* __restrict__ x, const float* __restrict__ g,
    const float* __restrict__ b, float* __restrict__ out) {
  __shared__ float red[8];
  int row = blockIdx.x, tid = threadIdx.x;
  float4 v = reinterpret_cast<const float4*>(x)[(size_t)row * (CC/4) + tid];
  float s  = v.x+v.y+v.z+v.w;
  float ss = v.x*v.x+v.y*v.y+v.z*v.z+v.w*v.w;
  #pragma unroll
  for (int off = 32; off; off >>= 1) { s += __shfl_xor(s, off); ss += __shfl_xor(ss, off); }
  if ((tid & 63) == 0) { red[tid>>6] = s; red[4+(tid>>6)] = ss; }
  __syncthreads();
  s  = red[0]+red[1]+red[2]+red[3];
  ss = red[4]+red[5]+red[6]+red[7];
  float mu = s * (1.f/CC);
  float rs = rsqrtf(ss*(1.f/CC) - mu*mu + 1e-5f);
  float4 gg = reinterpret_cast<const float4*>(g)[tid];
  float4 bb = reinterpret_cast<const float4*>(b)[tid];
  float4 o;
  o.x = (v.x-mu)*rs*gg.x + bb.x;
  o.y = (v.y-mu)*rs*gg.y + bb.y;
  o.z = (v.z-mu)*rs*gg.z + bb.z;
  o.w = (v.w-mu)*rs*gg.w + bb.w;
  reinterpret_cast<float4*>(out)[(size_t)row * (CC/4) + tid] = o;
}

// ---- split 8 fp32 into 3 truncated-bf16 planes, packed as uint4 each ----
// f = p0 + p1 + p2 + eps, |eps| <= 2^-21 |f| (trunc planes are exact subtractions).
struct Oct3 { uint4 p0, p1, p2; };
__device__ __forceinline__ unsigned pk2(unsigned lo, unsigned hi) {
  return (lo >> 16) | (hi & 0xffff0000u);
}
__device__ __forceinline__ Oct3 split8(const float* f) {
  unsigned a0[8], a1[8], a2[8];
  #pragma unroll
  for (int e = 0; e < 8; ++e) {
    float v = f[e];
    unsigned u = __float_as_uint(v);
    a0[e] = u;
    float r = v - __uint_as_float(u & 0xffff0000u);
    unsigned ur = __float_as_uint(r);
    a1[e] = ur;
    float r2 = r - __uint_as_float(ur & 0xffff0000u);
    a2[e] = __float_as_uint(r2);
  }
  Oct3 o;
  o.p0 = make_uint4(pk2(a0[0],a0[1]), pk2(a0[2],a0[3]), pk2(a0[4],a0[5]), pk2(a0[6],a0[7]));
  o.p1 = make_uint4(pk2(a1[0],a1[1]), pk2(a1[2],a1[3]), pk2(a1[4],a1[5]), pk2(a1[6],a1[7]));
  o.p2 = make_uint4(pk2(a2[0],a2[1]), pk2(a2[2],a2[3]), pk2(a2[4],a2[5]), pk2(a2[6],a2[7]));
  return o;
}

// ---------------- fp32-emulation MFMA GEMM (3-plane bf16, 6 MFMA) ----------------
// C[M x N] = A[M x K fp32] @ B[K x N fp32, ldb] (+bias,+res,relu) -> fp32, ldc.
// 64x128 tile, BK=64, 256 threads (4 waves 2x2; wave = 32x64 via 2x4 16x16x32 frags).
// NP=3: planes give ~fp32 accuracy. NP=1: plain bf16 (final logits only).
// Staging/swizzle/fragment/epilogue structure is the R6-exonerated one.
template<int NP>
__global__ __launch_bounds__(256) void gemm_kernel(
    const float* __restrict__ A, const float* __restrict__ Bw,
    const float* __restrict__ bias, const float* __restrict__ res,
    float* __restrict__ outf, int K, int ldb, int ldc, int relu) {
  __shared__ uint4 lds_a[NP][64*8];   // 8 KB per plane
  __shared__ uint4 lds_b[NP][8*128];  // 16 KB per plane
  int tid = threadIdx.x;
  int m0 = blockIdx.y * 64;
  int n0 = blockIdx.x * 128;
  int lane = tid & 63, wid = tid >> 6;
  int wm = wid >> 1, wn = wid & 1;
  int lr = lane & 15, lk = lane >> 4;
  int bcol = tid & 127, bkcg = tid >> 7;

  f32x4 acc[2][4];
  #pragma unroll
  for (int m = 0; m < 2; ++m)
    #pragma unroll
    for (int n = 0; n < 4; ++n)
      acc[m][n] = (f32x4){0.f, 0.f, 0.f, 0.f};

  for (int k0 = 0; k0 < K; k0 += 64) {
    // stage A: 64 rows x 64 k fp32 -> 3 planes; octet (row,sl), slot XOR-swizzled
    #pragma unroll
    for (int i = 0; i < 2; ++i) {
      int c = tid + i * 256;            // 0..511
      int row = c >> 3, sl = c & 7;
      const float4* ap = reinterpret_cast<const float4*>(A + (size_t)(m0+row)*K + k0 + sl*8);
      float4 x0 = ap[0], x1 = ap[1];
      float f[8] = {x0.x,x0.y,x0.z,x0.w,x1.x,x1.y,x1.z,x1.w};
      Oct3 o = split8(f);
      int di = row*8 + (sl ^ (row & 7));
      lds_a[0][di] = o.p0;
      if (NP == 3) { lds_a[1][di] = o.p1; lds_a[2][di] = o.p2; }
    }
    // stage B: 64 k x 128 n fp32 -> 3 planes; [kc][col][8 along k]
    #pragma unroll
    for (int g = 0; g < 4; ++g) {
      int kc = bkcg * 4 + g;
      float f[8];
      #pragma unroll
      for (int j = 0; j < 8; ++j)
        f[j] = Bw[(size_t)(k0 + kc*8 + j) * ldb + n0 + bcol];
      Oct3 o = split8(f);
      int di = kc*128 + bcol;
      lds_b[0][di] = o.p0;
      if (NP == 3) { lds_b[1][di] = o.p1; lds_b[2][di] = o.p2; }
    }
    __syncthreads();
    #pragma unroll
    for (int ks = 0; ks < 2; ++ks) {
      int kc = ks*4 + lk;
      bf16x8 af[NP][2], bfr[NP][4];
      #pragma unroll
      for (int m = 0; m < 2; ++m) {
        int row = wm*32 + m*16 + lr;
        int si = row*8 + (kc ^ (row & 7));
        #pragma unroll
        for (int p = 0; p < NP; ++p)
          af[p][m] = reinterpret_cast<const bf16x8*>(lds_a[p])[si];
      }
      #pragma unroll
      for (int n = 0; n < 4; ++n) {
        int si = kc*128 + wn*64 + n*16 + lr;
        #pragma unroll
        for (int p = 0; p < NP; ++p)
          bfr[p][n] = reinterpret_cast<const bf16x8*>(lds_b[p])[si];
      }
      #pragma unroll
      for (int m = 0; m < 2; ++m)
        #pragma unroll
        for (int n = 0; n < 4; ++n) {
          acc[m][n] = __builtin_amdgcn_mfma_f32_16x16x32_bf16(af[0][m], bfr[0][n], acc[m][n], 0, 0, 0);
          if (NP == 3) {
            acc[m][n] = __builtin_amdgcn_mfma_f32_16x16x32_bf16(af[0][m], bfr[1][n], acc[m][n], 0, 0, 0);
            acc[m][n] = __builtin_amdgcn_mfma_f32_16x16x32_bf16(af[1][m], bfr[0][n], acc[m][n], 0, 0, 0);
            acc[m][n] = __builtin_amdgcn_mfma_f32_16x16x32_bf16(af[1][m], bfr[1][n], acc[m][n], 0, 0, 0);
            acc[m][n] = __builtin_amdgcn_mfma_f32_16x16x32_bf16(af[2][m], bfr[0][n], acc[m][n], 0, 0, 0);
            acc[m][n] = __builtin_amdgcn_mfma_f32_16x16x32_bf16(af[0][m], bfr[2][n], acc[m][n], 0, 0, 0);
          }
        }
    }
    __syncthreads();
  }

  // epilogue: D layout col=lane&15, row=(lane>>4)*4+j  (R6-exonerated)
  #pragma unroll
  for (int m = 0; m < 2; ++m) {
    #pragma unroll
    for (int n = 0; n < 4; ++n) {
      int col = n0 + wn*64 + n*16 + lr;
      float bv = bias ? bias[col] : 0.f;
      #pragma unroll
      for (int j = 0; j < 4; ++j) {
        int row = m0 + wm*32 + m*16 + lk*4 + j;
        float vv = acc[m][n][j] + bv;
        if (relu) vv = fmaxf(vv, 0.f);
        size_t off = (size_t)row * ldc + col;
        if (res) vv += res[off];
        outf[off] = vv;
      }
    }
  }
}

// ---------------- attention: block per (b,h,t) row, fp32 everywhere ----------
__global__ __launch_bounds__(256) void attn32_kernel(
    const float* __restrict__ q, const float* __restrict__ k,
    const float* __restrict__ v, float* __restrict__ o) {
  __shared__ float s_lds[TT];
  __shared__ float q_lds[HS];
  __shared__ float red[4];
  __shared__ float part[4][HS];
  int tid = threadIdx.x, lane = tid & 63, w = tid >> 6;
  int rid = blockIdx.x;                 // (b, hh, t)
  int t  = rid & (TT - 1);
  int hh = (rid >> 10) & (HH - 1);
  int b  = rid >> 14;
  size_t rowbase = ((size_t)(b*TT + t)) * CC + hh*HS;
  if (tid < HS) q_lds[tid] = q[rowbase + tid];
  __syncthreads();
  // scores for keys 0..t, MULTIPLIED by sqrt(HS)=8 (faithful to reference)
  for (int kk = tid; kk <= t; kk += 256) {
    const float* kr = k + ((size_t)(b*TT + kk)) * CC + hh*HS;
    float s = 0.f;
    #pragma unroll
    for (int d = 0; d < HS; d += 4)
      s += q_lds[d]*kr[d] + q_lds[d+1]*kr[d+1] + q_lds[d+2]*kr[d+2] + q_lds[d+3]*kr[d+3];
    s_lds[kk] = s * 8.0f;
  }
  __syncthreads();
  float mx = -3.0e38f;
  for (int kk = tid; kk <= t; kk += 256) mx = fmaxf(mx, s_lds[kk]);
  #pragma unroll
  for (int off = 32; off; off >>= 1) mx = fmaxf(mx, __shfl_xor(mx, off));
  if (lane == 0) red[w] = mx;
  __syncthreads();
  mx = fmaxf(fmaxf(red[0], red[1]), fmaxf(red[2], red[3]));
  float sum = 0.f;
  for (int kk = tid; kk <= t; kk += 256) {
    float e = expf(s_lds[kk] - mx);
    s_lds[kk] = e; sum += e;
  }
  #pragma unroll
  for (int off = 32; off; off >>= 1) sum += __shfl_xor(sum, off);
  __syncthreads();
  if (lane == 0) red[w] = sum;
  __syncthreads();
  float inv = 1.0f / (red[0]+red[1]+red[2]+red[3]);
  float acc = 0.f;
  const float* vcol = v + (size_t)b*TT*CC + hh*HS + lane;
  for (int kk = w; kk <= t; kk += 4)
    acc += s_lds[kk] * vcol[(size_t)kk*CC];
  part[w][lane] = acc;
  __syncthreads();
  if (tid < HS) {
    float r = (part[0][tid]+part[1][tid]+part[2][tid]+part[3][tid]) * inv;
    o[rowbase + tid] = r;
  }
}

extern "C" void kernel_launch(void* const* d_in, const int* in_sizes, int n_in,
                              void* d_out, int out_size, void* d_ws, size_t ws_size,
                              hipStream_t stream) {
  const int*   idx  = (const int*)d_in[0];
  const float* tok  = (const float*)d_in[1];
  const float* pos  = (const float*)d_in[2];
  const float* Wq   = (const float*)d_in[3];
  const float* Wk   = (const float*)d_in[4];
  const float* Wv   = (const float*)d_in[5];
  const float* Wo   = (const float*)d_in[6];
  const float* bo   = (const float*)d_in[7];
  const float* ln1g = (const float*)d_in[8];
  const float* ln1b = (const float*)d_in[9];
  const float* ln2g = (const float*)d_in[10];
  const float* ln2b = (const float*)d_in[11];
  const float* W1   = (const float*)d_in[12];
  const float* b1   = (const float*)d_in[13];
  const float* W2   = (const float*)d_in[14];
  const float* b2   = (const float*)d_in[15];
  const float* lnfg = (const float*)d_in[16];
  const float* lnfb = (const float*)d_in[17];
  const float* lmw  = (const float*)d_in[18];
  const float* lmb  = (const float*)d_in[19];
  float* out = (float*)d_out;

  // R4-PROVEN all-fp32 scratch layout:
  //   d_out: x[0,32M) | h[32,64M) | qf[64,96M) | kf[96,128M); a1=[64,128M) (MLP)
  //   ws:    vf[0,32M) during layers; hf[0,32M) for final LN (vf dead).
  char* ob = (char*)d_out;
  float* x  = (float*)ob;
  float* h  = (float*)(ob + ((size_t)32<<20));
  float* qf = (float*)(ob + ((size_t)64<<20));
  float* kf = (float*)(ob + ((size_t)96<<20));
  float* a1 = (float*)(ob + ((size_t)64<<20));  // BTx2048 fp32 = 64 MiB
  float* vf = (float*)d_ws;                      // 32 MiB
  float* hf = (float*)d_ws;                      // reuse after vf dead

  dim3 blk(256);
  dim3 g1(CC/128,   BT/64);   // (8, 128)  N=1024
  dim3 gh(2048/128, BT/64);   // (16, 128) N=2048 (MLP column chunk)
  dim3 gl(VV/128,   BT/64);   // (32, 128) N=4096

  embed_kernel<<<BT, blk, 0, stream>>>(idx, tok, pos, x);
  for (int l = 0; l < LL; ++l) {
    const float* Wq_l = Wq + (size_t)l*CC*CC;
    const float* Wk_l = Wk + (size_t)l*CC*CC;
    const float* Wv_l = Wv + (size_t)l*CC*CC;
    const float* Wo_l = Wo + (size_t)l*CC*CC;
    const float* W1_l = W1 + (size_t)l*CC*4*CC;
    const float* W2_l = W2 + (size_t)l*4*CC*CC;
    ln32_kernel<<<BT, blk, 0, stream>>>(x, ln1g + (size_t)l*CC, ln1b + (size_t)l*CC, h);
    gemm_kernel<3><<<g1, blk, 0, stream>>>(h, Wq_l, nullptr, nullptr, qf, CC, CC, CC, 0);
    gemm_kernel<3><<<g1, blk, 0, stream>>>(h, Wk_l, nullptr, nullptr, kf, CC, CC, CC, 0);
    gemm_kernel<3><<<g1, blk, 0, stream>>>(h, Wv_l, nullptr, nullptr, vf, CC, CC, CC, 0);
    attn32_kernel<<<BB*HH*TT, blk, 0, stream>>>(qf, kf, vf, h);  // o -> h (ln1-out dead)
    gemm_kernel<3><<<g1, blk, 0, stream>>>(h, Wo_l, bo + (size_t)l*CC, x, x, CC, CC, CC, 0);
    ln32_kernel<<<BT, blk, 0, stream>>>(x, ln2g + (size_t)l*CC, ln2b + (size_t)l*CC, h);
    // MLP in two 2048-column chunks (a1 reuses qf/kf region)
    gemm_kernel<3><<<gh, blk, 0, stream>>>(h,  W1_l,           b1 + (size_t)l*4*CC,        nullptr, a1, CC,   4*CC, 2048, 1);
    gemm_kernel<3><<<g1, blk, 0, stream>>>(a1, W2_l,           b2 + (size_t)l*CC,          x, x,        2048, CC,   CC,   0);
    gemm_kernel<3><<<gh, blk, 0, stream>>>(h,  W1_l + 2048,    b1 + (size_t)l*4*CC + 2048, nullptr, a1, CC,   4*CC, 2048, 1);
    gemm_kernel<3><<<g1, blk, 0, stream>>>(a1, W2_l + 2048*CC, nullptr,                    x, x,        2048, CC,   CC,   0);
  }
  ln32_kernel<<<BT, blk, 0, stream>>>(x, lnfg, lnfb, hf);
  // final logits: plain bf16 MFMA (no downstream amplification -> bf16 error ok)
  gemm_kernel<1><<<gl, blk, 0, stream>>>(hf, lmw, lmb, nullptr, out, CC, VV, VV, 0);
}

// Round 8
// 19706.688 us; speedup vs baseline: 2.7906x; 1.5220x over previous
//
#include <hip/hip_runtime.h>

#define LL 6
#define BB 8
#define TT 1024
#define CC 1024
#define HH 16
#define HS 64
#define VV 4096
#define BT (BB*TT)

typedef __attribute__((ext_vector_type(4))) float f32x4;
typedef __attribute__((ext_vector_type(8))) short bf16x8;

// ---------------- embedding: x = tok_emb[idx] + pos_emb ----------------
__global__ __launch_bounds__(256) void embed_kernel(
    const int* __restrict__ idx, const float* __restrict__ tok,
    const float* __restrict__ pos, float* __restrict__ x) {
  int bt = blockIdx.x;
  int t = bt & (TT - 1);
  int id = idx[bt];
  float4 te = reinterpret_cast<const float4*>(tok)[(size_t)id * (CC/4) + threadIdx.x];
  float4 pe = reinterpret_cast<const float4*>(pos)[(size_t)t * (CC/4) + threadIdx.x];
  float4 r; r.x = te.x+pe.x; r.y = te.y+pe.y; r.z = te.z+pe.z; r.w = te.w+pe.w;
  reinterpret_cast<float4*>(x)[(size_t)bt * (CC/4) + threadIdx.x] = r;
}

// ---------------- layernorm: fp32 in -> fp32 out (R4-proven) ----------------
__global__ __launch_bounds__(256) void ln32_kernel(
    const float* __restrict__ x, const float* __restrict__ g,
    const float* __restrict__ b, float* __restrict__ out) {
  __shared__ float red[8];
  int row = blockIdx.x, tid = threadIdx.x;
  float4 v = reinterpret_cast<const float4*>(x)[(size_t)row * (CC/4) + tid];
  float s  = v.x+v.y+v.z+v.w;
  float ss = v.x*v.x+v.y*v.y+v.z*v.z+v.w*v.w;
  #pragma unroll
  for (int off = 32; off; off >>= 1) { s += __shfl_xor(s, off); ss += __shfl_xor(ss, off); }
  if ((tid & 63) == 0) { red[tid>>6] = s; red[4+(tid>>6)] = ss; }
  __syncthreads();
  s  = red[0]+red[1]+red[2]+red[3];
  ss = red[4]+red[5]+red[6]+red[7];
  float mu = s * (1.f/CC);
  float rs = rsqrtf(ss*(1.f/CC) - mu*mu + 1e-5f);
  float4 gg = reinterpret_cast<const float4*>(g)[tid];
  float4 bb = reinterpret_cast<const float4*>(b)[tid];
  float4 o;
  o.x = (v.x-mu)*rs*gg.x + bb.x;
  o.y = (v.y-mu)*rs*gg.y + bb.y;
  o.z = (v.z-mu)*rs*gg.z + bb.z;
  o.w = (v.w-mu)*rs*gg.w + bb.w;
  reinterpret_cast<float4*>(out)[(size_t)row * (CC/4) + tid] = o;
}

// ---- split 8 fp32 into 3 truncated-bf16 planes, packed as uint4 each ----
struct Oct3 { uint4 p0, p1, p2; };
__device__ __forceinline__ unsigned pk2(unsigned lo, unsigned hi) {
  return (lo >> 16) | (hi & 0xffff0000u);
}
__device__ __forceinline__ Oct3 split8(const float* f) {
  unsigned a0[8], a1[8], a2[8];
  #pragma unroll
  for (int e = 0; e < 8; ++e) {
    float v = f[e];
    unsigned u = __float_as_uint(v);
    a0[e] = u;
    float r = v - __uint_as_float(u & 0xffff0000u);
    unsigned ur = __float_as_uint(r);
    a1[e] = ur;
    float r2 = r - __uint_as_float(ur & 0xffff0000u);
    a2[e] = __float_as_uint(r2);
  }
  Oct3 o;
  o.p0 = make_uint4(pk2(a0[0],a0[1]), pk2(a0[2],a0[3]), pk2(a0[4],a0[5]), pk2(a0[6],a0[7]));
  o.p1 = make_uint4(pk2(a1[0],a1[1]), pk2(a1[2],a1[3]), pk2(a1[4],a1[5]), pk2(a1[6],a1[7]));
  o.p2 = make_uint4(pk2(a2[0],a2[1]), pk2(a2[2],a2[3]), pk2(a2[4],a2[5]), pk2(a2[6],a2[7]));
  return o;
}

// ---------------- fp32-emulation MFMA GEMM (3-plane bf16, 6 MFMA) ----------------
// (R7-proven, unchanged)
template<int NP>
__global__ __launch_bounds__(256) void gemm_kernel(
    const float* __restrict__ A, const float* __restrict__ Bw,
    const float* __restrict__ bias, const float* __restrict__ res,
    float* __restrict__ outf, int K, int ldb, int ldc, int relu) {
  __shared__ uint4 lds_a[NP][64*8];
  __shared__ uint4 lds_b[NP][8*128];
  int tid = threadIdx.x;
  int m0 = blockIdx.y * 64;
  int n0 = blockIdx.x * 128;
  int lane = tid & 63, wid = tid >> 6;
  int wm = wid >> 1, wn = wid & 1;
  int lr = lane & 15, lk = lane >> 4;
  int bcol = tid & 127, bkcg = tid >> 7;

  f32x4 acc[2][4];
  #pragma unroll
  for (int m = 0; m < 2; ++m)
    #pragma unroll
    for (int n = 0; n < 4; ++n)
      acc[m][n] = (f32x4){0.f, 0.f, 0.f, 0.f};

  for (int k0 = 0; k0 < K; k0 += 64) {
    #pragma unroll
    for (int i = 0; i < 2; ++i) {
      int c = tid + i * 256;
      int row = c >> 3, sl = c & 7;
      const float4* ap = reinterpret_cast<const float4*>(A + (size_t)(m0+row)*K + k0 + sl*8);
      float4 x0 = ap[0], x1 = ap[1];
      float f[8] = {x0.x,x0.y,x0.z,x0.w,x1.x,x1.y,x1.z,x1.w};
      Oct3 o = split8(f);
      int di = row*8 + (sl ^ (row & 7));
      lds_a[0][di] = o.p0;
      if (NP == 3) { lds_a[1][di] = o.p1; lds_a[2][di] = o.p2; }
    }
    #pragma unroll
    for (int g = 0; g < 4; ++g) {
      int kc = bkcg * 4 + g;
      float f[8];
      #pragma unroll
      for (int j = 0; j < 8; ++j)
        f[j] = Bw[(size_t)(k0 + kc*8 + j) * ldb + n0 + bcol];
      Oct3 o = split8(f);
      int di = kc*128 + bcol;
      lds_b[0][di] = o.p0;
      if (NP == 3) { lds_b[1][di] = o.p1; lds_b[2][di] = o.p2; }
    }
    __syncthreads();
    #pragma unroll
    for (int ks = 0; ks < 2; ++ks) {
      int kc = ks*4 + lk;
      bf16x8 af[NP][2], bfr[NP][4];
      #pragma unroll
      for (int m = 0; m < 2; ++m) {
        int row = wm*32 + m*16 + lr;
        int si = row*8 + (kc ^ (row & 7));
        #pragma unroll
        for (int p = 0; p < NP; ++p)
          af[p][m] = reinterpret_cast<const bf16x8*>(lds_a[p])[si];
      }
      #pragma unroll
      for (int n = 0; n < 4; ++n) {
        int si = kc*128 + wn*64 + n*16 + lr;
        #pragma unroll
        for (int p = 0; p < NP; ++p)
          bfr[p][n] = reinterpret_cast<const bf16x8*>(lds_b[p])[si];
      }
      #pragma unroll
      for (int m = 0; m < 2; ++m)
        #pragma unroll
        for (int n = 0; n < 4; ++n) {
          acc[m][n] = __builtin_amdgcn_mfma_f32_16x16x32_bf16(af[0][m], bfr[0][n], acc[m][n], 0, 0, 0);
          if (NP == 3) {
            acc[m][n] = __builtin_amdgcn_mfma_f32_16x16x32_bf16(af[0][m], bfr[1][n], acc[m][n], 0, 0, 0);
            acc[m][n] = __builtin_amdgcn_mfma_f32_16x16x32_bf16(af[1][m], bfr[0][n], acc[m][n], 0, 0, 0);
            acc[m][n] = __builtin_amdgcn_mfma_f32_16x16x32_bf16(af[1][m], bfr[1][n], acc[m][n], 0, 0, 0);
            acc[m][n] = __builtin_amdgcn_mfma_f32_16x16x32_bf16(af[2][m], bfr[0][n], acc[m][n], 0, 0, 0);
            acc[m][n] = __builtin_amdgcn_mfma_f32_16x16x32_bf16(af[0][m], bfr[2][n], acc[m][n], 0, 0, 0);
          }
        }
    }
    __syncthreads();
  }

  #pragma unroll
  for (int m = 0; m < 2; ++m) {
    #pragma unroll
    for (int n = 0; n < 4; ++n) {
      int col = n0 + wn*64 + n*16 + lr;
      float bv = bias ? bias[col] : 0.f;
      #pragma unroll
      for (int j = 0; j < 4; ++j) {
        int row = m0 + wm*32 + m*16 + lk*4 + j;
        float vv = acc[m][n][j] + bv;
        if (relu) vv = fmaxf(vv, 0.f);
        size_t off = (size_t)row * ldc + col;
        if (res) vv += res[off];
        outf[off] = vv;
      }
    }
  }
}

// ---------------- flash attention (all fp32 VALU, LDS-tiled K/V) ----------------
// Grid: b*HH*16 blocks; block = (b, h, q-tile of 64). 4 waves x 16 queries.
// Per lane: q = w*16 + (lane&15); key-subrange group g = lane>>4.
// Online softmax; K/V staged [64][68] with XOR float4-slot swizzle (2-way max).
__global__ __launch_bounds__(256) void attn_flash_kernel(
    const float* __restrict__ q, const float* __restrict__ k,
    const float* __restrict__ v, float* __restrict__ o) {
  __shared__ float K_lds[64][68];
  __shared__ float V_lds[64][68];
  int tid = threadIdx.x, lane = tid & 63, w = tid >> 6;
  int rid = blockIdx.x;
  int qt = rid & 15;
  int hh = (rid >> 4) & (HH - 1);
  int b  = rid >> 8;
  const size_t headoff = (size_t)b*TT*CC + (size_t)hh*HS;
  int lq = lane & 15;           // query-in-wave
  int g  = lane >> 4;           // key/dim group
  int qglob = qt*64 + w*16 + lq;

  // Q row -> registers (64 floats)
  float4 qreg[16];
  const float4* qrow = reinterpret_cast<const float4*>(q + headoff + (size_t)qglob*CC);
  #pragma unroll
  for (int j = 0; j < 16; ++j) qreg[j] = qrow[j];

  float m = -3.0e38f, l = 0.f;
  float oacc[16];
  #pragma unroll
  for (int j = 0; j < 16; ++j) oacc[j] = 0.f;

  for (int kt = 0; kt <= qt; ++kt) {
    __syncthreads();   // previous tile's reads done before overwrite
    // stage K,V tile (64 rows x 64 fp32), coalesced; float4 slot ^= (row>>2)&15
    #pragma unroll
    for (int pp = 0; pp < 4; ++pp) {
      int c = tid + pp*256;             // 0..1023
      int row = c >> 4, sl = c & 15;
      int psl = sl ^ ((row >> 2) & 15);
      const float4* kg = reinterpret_cast<const float4*>(k + headoff + (size_t)(kt*64+row)*CC);
      const float4* vg = reinterpret_cast<const float4*>(v + headoff + (size_t)(kt*64+row)*CC);
      reinterpret_cast<float4*>(&K_lds[row][0])[psl] = kg[sl];
      reinterpret_cast<float4*>(&V_lds[row][0])[psl] = vg[sl];
    }
    __syncthreads();

    // scores: lane computes s[i] for keys kt*64 + g*16 + i, i=0..15
    float s[16];
    int kbase = kt*64 + g*16;
    #pragma unroll
    for (int i = 0; i < 16; ++i) {
      int kk = g*16 + i;
      const float4* kr = reinterpret_cast<const float4*>(&K_lds[kk][0]);
      int sw = (kk >> 2) & 15;
      float acc = 0.f;
      #pragma unroll
      for (int d0 = 0; d0 < 16; ++d0) {
        float4 kv = kr[d0 ^ sw];
        float4 qv = qreg[d0];
        acc += qv.x*kv.x + qv.y*kv.y + qv.z*kv.z + qv.w*kv.w;
      }
      s[i] = (kbase + i > qglob) ? -3.0e38f : acc * 8.0f;  // scale by sqrt(HS)=8
    }

    // online softmax (row = query; row-reduce across groups via shfl 16/32)
    float tmax = s[0];
    #pragma unroll
    for (int i = 1; i < 16; ++i) tmax = fmaxf(tmax, s[i]);
    tmax = fmaxf(tmax, __shfl_xor(tmax, 16));
    tmax = fmaxf(tmax, __shfl_xor(tmax, 32));
    float mnew = fmaxf(m, tmax);
    float alpha = __expf(m - mnew);
    float tsum = 0.f;
    #pragma unroll
    for (int i = 0; i < 16; ++i) { s[i] = __expf(s[i] - mnew); tsum += s[i]; }
    tsum += __shfl_xor(tsum, 16);
    tsum += __shfl_xor(tsum, 32);
    l = l * alpha + tsum;
    m = mnew;
    #pragma unroll
    for (int j = 0; j < 16; ++j) oacc[j] *= alpha;

    // PV: oacc[d - g*16] += p[q][k'] * V[k'][d], d in [g*16, g*16+16)
    #pragma unroll
    for (int kq = 0; kq < 4; ++kq) {
      #pragma unroll
      for (int i = 0; i < 16; ++i) {
        float pk = __shfl(s[i], kq*16 + lq, 64);
        int kk = kq*16 + i;
        const float4* vr = reinterpret_cast<const float4*>(&V_lds[kk][0]);
        int sw = (kk >> 2) & 15;
        float4 v0 = vr[(g*4+0) ^ sw];
        float4 v1 = vr[(g*4+1) ^ sw];
        float4 v2 = vr[(g*4+2) ^ sw];
        float4 v3 = vr[(g*4+3) ^ sw];
        oacc[0]  += pk*v0.x; oacc[1]  += pk*v0.y; oacc[2]  += pk*v0.z; oacc[3]  += pk*v0.w;
        oacc[4]  += pk*v1.x; oacc[5]  += pk*v1.y; oacc[6]  += pk*v1.z; oacc[7]  += pk*v1.w;
        oacc[8]  += pk*v2.x; oacc[9]  += pk*v2.y; oacc[10] += pk*v2.z; oacc[11] += pk*v2.w;
        oacc[12] += pk*v3.x; oacc[13] += pk*v3.y; oacc[14] += pk*v3.z; oacc[15] += pk*v3.w;
      }
    }
  }

  float invl = 1.0f / l;
  float4* orow = reinterpret_cast<float4*>(o + headoff + (size_t)qglob*CC + g*16);
  #pragma unroll
  for (int j4 = 0; j4 < 4; ++j4) {
    float4 ov;
    ov.x = oacc[j4*4+0]*invl; ov.y = oacc[j4*4+1]*invl;
    ov.z = oacc[j4*4+2]*invl; ov.w = oacc[j4*4+3]*invl;
    orow[j4] = ov;
  }
}

extern "C" void kernel_launch(void* const* d_in, const int* in_sizes, int n_in,
                              void* d_out, int out_size, void* d_ws, size_t ws_size,
                              hipStream_t stream) {
  const int*   idx  = (const int*)d_in[0];
  const float* tok  = (const float*)d_in[1];
  const float* pos  = (const float*)d_in[2];
  const float* Wq   = (const float*)d_in[3];
  const float* Wk   = (const float*)d_in[4];
  const float* Wv   = (const float*)d_in[5];
  const float* Wo   = (const float*)d_in[6];
  const float* bo   = (const float*)d_in[7];
  const float* ln1g = (const float*)d_in[8];
  const float* ln1b = (const float*)d_in[9];
  const float* ln2g = (const float*)d_in[10];
  const float* ln2b = (const float*)d_in[11];
  const float* W1   = (const float*)d_in[12];
  const float* b1   = (const float*)d_in[13];
  const float* W2   = (const float*)d_in[14];
  const float* b2   = (const float*)d_in[15];
  const float* lnfg = (const float*)d_in[16];
  const float* lnfb = (const float*)d_in[17];
  const float* lmw  = (const float*)d_in[18];
  const float* lmb  = (const float*)d_in[19];
  float* out = (float*)d_out;

  // R4-proven all-fp32 scratch layout:
  //   d_out: x[0,32M) | h[32,64M) | qf[64,96M) | kf[96,128M); a1=[64,128M) (MLP)
  //   ws:    vf[0,32M) during layers; hf[0,32M) for final LN (vf dead).
  char* ob = (char*)d_out;
  float* x  = (float*)ob;
  float* h  = (float*)(ob + ((size_t)32<<20));
  float* qf = (float*)(ob + ((size_t)64<<20));
  float* kf = (float*)(ob + ((size_t)96<<20));
  float* a1 = (float*)(ob + ((size_t)64<<20));
  float* vf = (float*)d_ws;
  float* hf = (float*)d_ws;

  dim3 blk(256);
  dim3 g1(CC/128,   BT/64);   // (8, 128)  N=1024
  dim3 gh(2048/128, BT/64);   // (16, 128) N=2048 (MLP column chunk)
  dim3 gl(VV/128,   BT/64);   // (32, 128) N=4096

  embed_kernel<<<BT, blk, 0, stream>>>(idx, tok, pos, x);
  for (int l = 0; l < LL; ++l) {
    const float* Wq_l = Wq + (size_t)l*CC*CC;
    const float* Wk_l = Wk + (size_t)l*CC*CC;
    const float* Wv_l = Wv + (size_t)l*CC*CC;
    const float* Wo_l = Wo + (size_t)l*CC*CC;
    const float* W1_l = W1 + (size_t)l*CC*4*CC;
    const float* W2_l = W2 + (size_t)l*4*CC*CC;
    ln32_kernel<<<BT, blk, 0, stream>>>(x, ln1g + (size_t)l*CC, ln1b + (size_t)l*CC, h);
    gemm_kernel<3><<<g1, blk, 0, stream>>>(h, Wq_l, nullptr, nullptr, qf, CC, CC, CC, 0);
    gemm_kernel<3><<<g1, blk, 0, stream>>>(h, Wk_l, nullptr, nullptr, kf, CC, CC, CC, 0);
    gemm_kernel<3><<<g1, blk, 0, stream>>>(h, Wv_l, nullptr, nullptr, vf, CC, CC, CC, 0);
    attn_flash_kernel<<<BB*HH*16, blk, 0, stream>>>(qf, kf, vf, h);  // o -> h
    gemm_kernel<3><<<g1, blk, 0, stream>>>(h, Wo_l, bo + (size_t)l*CC, x, x, CC, CC, CC, 0);
    ln32_kernel<<<BT, blk, 0, stream>>>(x, ln2g + (size_t)l*CC, ln2b + (size_t)l*CC, h);
    gemm_kernel<3><<<gh, blk, 0, stream>>>(h,  W1_l,           b1 + (size_t)l*4*CC,        nullptr, a1, CC,   4*CC, 2048, 1);
    gemm_kernel<3><<<g1, blk, 0, stream>>>(a1, W2_l,           b2 + (size_t)l*CC,          x, x,        2048, CC,   CC,   0);
    gemm_kernel<3><<<gh, blk, 0, stream>>>(h,  W1_l + 2048,    b1 + (size_t)l*4*CC + 2048, nullptr, a1, CC,   4*CC, 2048, 1);
    gemm_kernel<3><<<g1, blk, 0, stream>>>(a1, W2_l + 2048*CC, nullptr,                    x, x,        2048, CC,   CC,   0);
  }
  ln32_kernel<<<BT, blk, 0, stream>>>(x, lnfg, lnfb, hf);
  gemm_kernel<1><<<gl, blk, 0, stream>>>(hf, lmw, lmb, nullptr, out, CC, VV, VV, 0);
}

// Round 9
// 9419.888 us; speedup vs baseline: 5.8379x; 2.0920x over previous
//
#include <hip/hip_runtime.h>

#define LL 6
#define BB 8
#define TT 1024
#define CC 1024
#define HH 16
#define HS 64
#define VV 4096
#define BT (BB*TT)

typedef __attribute__((ext_vector_type(4))) float f32x4;
typedef __attribute__((ext_vector_type(8))) short bf16x8;

// ---------------- embedding ----------------
__global__ __launch_bounds__(256) void embed_kernel(
    const int* __restrict__ idx, const float* __restrict__ tok,
    const float* __restrict__ pos, float* __restrict__ x) {
  int bt = blockIdx.x;
  int t = bt & (TT - 1);
  int id = idx[bt];
  float4 te = reinterpret_cast<const float4*>(tok)[(size_t)id * (CC/4) + threadIdx.x];
  float4 pe = reinterpret_cast<const float4*>(pos)[(size_t)t * (CC/4) + threadIdx.x];
  float4 r; r.x = te.x+pe.x; r.y = te.y+pe.y; r.z = te.z+pe.z; r.w = te.w+pe.w;
  reinterpret_cast<float4*>(x)[(size_t)bt * (CC/4) + threadIdx.x] = r;
}

// ---------------- layernorm fp32->fp32 (R4-proven) ----------------
__global__ __launch_bounds__(256) void ln32_kernel(
    const float* __restrict__ x, const float* __restrict__ g,
    const float* __restrict__ b, float* __restrict__ out) {
  __shared__ float red[8];
  int row = blockIdx.x, tid = threadIdx.x;
  float4 v = reinterpret_cast<const float4*>(x)[(size_t)row * (CC/4) + tid];
  float s  = v.x+v.y+v.z+v.w;
  float ss = v.x*v.x+v.y*v.y+v.z*v.z+v.w*v.w;
  #pragma unroll
  for (int off = 32; off; off >>= 1) { s += __shfl_xor(s, off); ss += __shfl_xor(ss, off); }
  if ((tid & 63) == 0) { red[tid>>6] = s; red[4+(tid>>6)] = ss; }
  __syncthreads();
  s  = red[0]+red[1]+red[2]+red[3];
  ss = red[4]+red[5]+red[6]+red[7];
  float mu = s * (1.f/CC);
  float rs = rsqrtf(ss*(1.f/CC) - mu*mu + 1e-5f);
  float4 gg = reinterpret_cast<const float4*>(g)[tid];
  float4 bb = reinterpret_cast<const float4*>(b)[tid];
  float4 o;
  o.x = (v.x-mu)*rs*gg.x + bb.x;
  o.y = (v.y-mu)*rs*gg.y + bb.y;
  o.z = (v.z-mu)*rs*gg.z + bb.z;
  o.w = (v.w-mu)*rs*gg.w + bb.w;
  reinterpret_cast<float4*>(out)[(size_t)row * (CC/4) + tid] = o;
}

// ---- split 8 fp32 into 3 truncated-bf16 planes (R7-proven) ----
struct Oct3 { uint4 p0, p1, p2; };
__device__ __forceinline__ unsigned pk2(unsigned lo, unsigned hi) {
  return (lo >> 16) | (hi & 0xffff0000u);
}
__device__ __forceinline__ Oct3 split8(const float* f) {
  unsigned a0[8], a1[8], a2[8];
  #pragma unroll
  for (int e = 0; e < 8; ++e) {
    float v = f[e];
    unsigned u = __float_as_uint(v);
    a0[e] = u;
    float r = v - __uint_as_float(u & 0xffff0000u);
    unsigned ur = __float_as_uint(r);
    a1[e] = ur;
    float r2 = r - __uint_as_float(ur & 0xffff0000u);
    a2[e] = __float_as_uint(r2);
  }
  Oct3 o;
  o.p0 = make_uint4(pk2(a0[0],a0[1]), pk2(a0[2],a0[3]), pk2(a0[4],a0[5]), pk2(a0[6],a0[7]));
  o.p1 = make_uint4(pk2(a1[0],a1[1]), pk2(a1[2],a1[3]), pk2(a1[4],a1[5]), pk2(a1[6],a1[7]));
  o.p2 = make_uint4(pk2(a2[0],a2[1]), pk2(a2[2],a2[3]), pk2(a2[4],a2[5]), pk2(a2[6],a2[7]));
  return o;
}

// ---------------- fp32-emulation MFMA GEMM (R7-proven, unchanged) ----------------
template<int NP>
__global__ __launch_bounds__(256) void gemm_kernel(
    const float* __restrict__ A, const float* __restrict__ Bw,
    const float* __restrict__ bias, const float* __restrict__ res,
    float* __restrict__ outf, int K, int ldb, int ldc, int relu) {
  __shared__ uint4 lds_a[NP][64*8];
  __shared__ uint4 lds_b[NP][8*128];
  int tid = threadIdx.x;
  int m0 = blockIdx.y * 64;
  int n0 = blockIdx.x * 128;
  int lane = tid & 63, wid = tid >> 6;
  int wm = wid >> 1, wn = wid & 1;
  int lr = lane & 15, lk = lane >> 4;
  int bcol = tid & 127, bkcg = tid >> 7;

  f32x4 acc[2][4];
  #pragma unroll
  for (int m = 0; m < 2; ++m)
    #pragma unroll
    for (int n = 0; n < 4; ++n)
      acc[m][n] = (f32x4){0.f, 0.f, 0.f, 0.f};

  for (int k0 = 0; k0 < K; k0 += 64) {
    #pragma unroll
    for (int i = 0; i < 2; ++i) {
      int c = tid + i * 256;
      int row = c >> 3, sl = c & 7;
      const float4* ap = reinterpret_cast<const float4*>(A + (size_t)(m0+row)*K + k0 + sl*8);
      float4 x0 = ap[0], x1 = ap[1];
      float f[8] = {x0.x,x0.y,x0.z,x0.w,x1.x,x1.y,x1.z,x1.w};
      Oct3 o = split8(f);
      int di = row*8 + (sl ^ (row & 7));
      lds_a[0][di] = o.p0;
      if (NP == 3) { lds_a[1][di] = o.p1; lds_a[2][di] = o.p2; }
    }
    #pragma unroll
    for (int g = 0; g < 4; ++g) {
      int kc = bkcg * 4 + g;
      float f[8];
      #pragma unroll
      for (int j = 0; j < 8; ++j)
        f[j] = Bw[(size_t)(k0 + kc*8 + j) * ldb + n0 + bcol];
      Oct3 o = split8(f);
      int di = kc*128 + bcol;
      lds_b[0][di] = o.p0;
      if (NP == 3) { lds_b[1][di] = o.p1; lds_b[2][di] = o.p2; }
    }
    __syncthreads();
    #pragma unroll
    for (int ks = 0; ks < 2; ++ks) {
      int kc = ks*4 + lk;
      bf16x8 af[NP][2], bfr[NP][4];
      #pragma unroll
      for (int m = 0; m < 2; ++m) {
        int row = wm*32 + m*16 + lr;
        int si = row*8 + (kc ^ (row & 7));
        #pragma unroll
        for (int p = 0; p < NP; ++p)
          af[p][m] = reinterpret_cast<const bf16x8*>(lds_a[p])[si];
      }
      #pragma unroll
      for (int n = 0; n < 4; ++n) {
        int si = kc*128 + wn*64 + n*16 + lr;
        #pragma unroll
        for (int p = 0; p < NP; ++p)
          bfr[p][n] = reinterpret_cast<const bf16x8*>(lds_b[p])[si];
      }
      #pragma unroll
      for (int m = 0; m < 2; ++m)
        #pragma unroll
        for (int n = 0; n < 4; ++n) {
          acc[m][n] = __builtin_amdgcn_mfma_f32_16x16x32_bf16(af[0][m], bfr[0][n], acc[m][n], 0, 0, 0);
          if (NP == 3) {
            acc[m][n] = __builtin_amdgcn_mfma_f32_16x16x32_bf16(af[0][m], bfr[1][n], acc[m][n], 0, 0, 0);
            acc[m][n] = __builtin_amdgcn_mfma_f32_16x16x32_bf16(af[1][m], bfr[0][n], acc[m][n], 0, 0, 0);
            acc[m][n] = __builtin_amdgcn_mfma_f32_16x16x32_bf16(af[1][m], bfr[1][n], acc[m][n], 0, 0, 0);
            acc[m][n] = __builtin_amdgcn_mfma_f32_16x16x32_bf16(af[2][m], bfr[0][n], acc[m][n], 0, 0, 0);
            acc[m][n] = __builtin_amdgcn_mfma_f32_16x16x32_bf16(af[0][m], bfr[2][n], acc[m][n], 0, 0, 0);
          }
        }
    }
    __syncthreads();
  }

  #pragma unroll
  for (int m = 0; m < 2; ++m) {
    #pragma unroll
    for (int n = 0; n < 4; ++n) {
      int col = n0 + wn*64 + n*16 + lr;
      float bv = bias ? bias[col] : 0.f;
      #pragma unroll
      for (int j = 0; j < 4; ++j) {
        int row = m0 + wm*32 + m*16 + lk*4 + j;
        float vv = acc[m][n][j] + bv;
        if (relu) vv = fmaxf(vv, 0.f);
        size_t off = (size_t)row * ldc + col;
        if (res) vv += res[off];
        outf[off] = vv;
      }
    }
  }
}

// ---------------- V transpose: v[token][h*64+d] -> vt[b][h][d][t] ----------------
__global__ __launch_bounds__(256) void vtrans_kernel(
    const float* __restrict__ v, float* __restrict__ vt) {
  __shared__ float T[64][69];
  int rid = blockIdx.x;
  int tc = rid & 15, hh = (rid >> 4) & 15, b = rid >> 8;
  int tid = threadIdx.x;
  #pragma unroll
  for (int pp = 0; pp < 4; ++pp) {
    int c = tid + pp*256;
    int r = c >> 4, c4 = c & 15;
    float4 x = *reinterpret_cast<const float4*>(
        v + ((size_t)(b*TT + tc*64 + r))*CC + hh*HS + c4*4);
    T[c4*4+0][r] = x.x; T[c4*4+1][r] = x.y; T[c4*4+2][r] = x.z; T[c4*4+3][r] = x.w;
  }
  __syncthreads();
  #pragma unroll
  for (int pp = 0; pp < 4; ++pp) {
    int c = tid + pp*256;
    int d = c >> 4, t4 = c & 15;
    float4 y;
    y.x = T[d][t4*4+0]; y.y = T[d][t4*4+1]; y.z = T[d][t4*4+2]; y.w = T[d][t4*4+3];
    *reinterpret_cast<float4*>(
        vt + (((size_t)(b*HH+hh)*HS + d))*TT + tc*64 + t4*4) = y;
  }
}

// ---------------- MFMA flash attention ----------------
// Block = (b, h, q-tile 64). 4 waves x 16 queries. K 3-plane, QK 6-MFMA combo
// (score precision); P packed hi|lo u32 in LDS; V transposed 2-plane, PV 3-MFMA.
__global__ __launch_bounds__(256) void attn_mfma_kernel(
    const float* __restrict__ q, const float* __restrict__ k,
    const float* __restrict__ vt, float* __restrict__ o) {
  __shared__ uint4 K_lds[3][64*8];     // 24 KB: row=key, 8 dim-octets, slot^(row&7)
  __shared__ uint4 V_lds[2][8*66];     // 16.9 KB: [key-octet^(d&7)]*66 + d
  __shared__ unsigned P_lds[64*68];    // 17 KB: [q][68], key-octet^(q&7), hi|lo
  int tid = threadIdx.x, lane = tid & 63, w = tid >> 6;
  int rid = blockIdx.x;
  int qt = rid & 15, hh = (rid >> 4) & 15, b = rid >> 8;
  int lr = lane & 15, lk = lane >> 4;
  const size_t tok0 = (size_t)b * TT;

  // Q -> 3-plane A-frags in registers (row = lr within wave's 16 queries)
  bf16x8 qa[2][3];
  {
    const float* qp = q + (tok0 + qt*64 + w*16 + lr) * CC + hh*HS;
    #pragma unroll
    for (int ks = 0; ks < 2; ++ks) {
      const float4* p4 = reinterpret_cast<const float4*>(qp + ks*32 + lk*8);
      float4 a = p4[0], c = p4[1];
      float f[8] = {a.x,a.y,a.z,a.w,c.x,c.y,c.z,c.w};
      Oct3 ot = split8(f);
      qa[ks][0] = *reinterpret_cast<bf16x8*>(&ot.p0);
      qa[ks][1] = *reinterpret_cast<bf16x8*>(&ot.p1);
      qa[ks][2] = *reinterpret_cast<bf16x8*>(&ot.p2);
    }
  }

  float mrow[4] = {-3.0e38f,-3.0e38f,-3.0e38f,-3.0e38f};
  float lrow[4] = {0.f,0.f,0.f,0.f};
  f32x4 oac[4];
  #pragma unroll
  for (int n = 0; n < 4; ++n) oac[n] = (f32x4){0.f,0.f,0.f,0.f};

  for (int kt = 0; kt <= qt; ++kt) {
    __syncthreads();                       // prev tile's P/V reads done
    // stage K (3 planes, gemm lds_a pattern)
    #pragma unroll
    for (int pp = 0; pp < 2; ++pp) {
      int c = tid + pp*256;
      int r = c >> 3, sl = c & 7;
      const float4* kp = reinterpret_cast<const float4*>(
          k + (tok0 + kt*64 + r) * CC + hh*HS + sl*8);
      float4 x0 = kp[0], x1 = kp[1];
      float f[8] = {x0.x,x0.y,x0.z,x0.w,x1.x,x1.y,x1.z,x1.w};
      Oct3 ot = split8(f);
      int di = r*8 + (sl ^ (r & 7));
      K_lds[0][di] = ot.p0; K_lds[1][di] = ot.p1; K_lds[2][di] = ot.p2;
    }
    // stage Vt (2 planes)
    #pragma unroll
    for (int pp = 0; pp < 2; ++pp) {
      int c = tid + pp*256;
      int kc = c & 7, d = c >> 3;
      const float4* vp = reinterpret_cast<const float4*>(
          vt + (((size_t)(b*HH+hh)*HS + d))*TT + kt*64 + kc*8);
      float4 x0 = vp[0], x1 = vp[1];
      float f[8] = {x0.x,x0.y,x0.z,x0.w,x1.x,x1.y,x1.z,x1.w};
      Oct3 ot = split8(f);
      int di = (kc ^ (d & 7))*66 + d;
      V_lds[0][di] = ot.p0; V_lds[1][di] = ot.p1;
    }
    __syncthreads();

    // S = Q K^T (3x3 planes, 6-combo) — B-frag col=key=nf*16+lr
    f32x4 sfr[4];
    #pragma unroll
    for (int nf = 0; nf < 4; ++nf) sfr[nf] = (f32x4){0.f,0.f,0.f,0.f};
    #pragma unroll
    for (int ks = 0; ks < 2; ++ks) {
      int kc = ks*4 + lk;
      #pragma unroll
      for (int nf = 0; nf < 4; ++nf) {
        int row = nf*16 + lr;
        int si = row*8 + (kc ^ (row & 7));
        bf16x8 k0 = *reinterpret_cast<const bf16x8*>(&K_lds[0][si]);
        bf16x8 k1 = *reinterpret_cast<const bf16x8*>(&K_lds[1][si]);
        bf16x8 k2 = *reinterpret_cast<const bf16x8*>(&K_lds[2][si]);
        sfr[nf] = __builtin_amdgcn_mfma_f32_16x16x32_bf16(qa[ks][0], k0, sfr[nf], 0,0,0);
        sfr[nf] = __builtin_amdgcn_mfma_f32_16x16x32_bf16(qa[ks][0], k1, sfr[nf], 0,0,0);
        sfr[nf] = __builtin_amdgcn_mfma_f32_16x16x32_bf16(qa[ks][1], k0, sfr[nf], 0,0,0);
        sfr[nf] = __builtin_amdgcn_mfma_f32_16x16x32_bf16(qa[ks][1], k1, sfr[nf], 0,0,0);
        sfr[nf] = __builtin_amdgcn_mfma_f32_16x16x32_bf16(qa[ks][2], k0, sfr[nf], 0,0,0);
        sfr[nf] = __builtin_amdgcn_mfma_f32_16x16x32_bf16(qa[ks][0], k2, sfr[nf], 0,0,0);
      }
    }
    // scale *8 (faithful), causal mask on diagonal tile
    #pragma unroll
    for (int nf = 0; nf < 4; ++nf)
      #pragma unroll
      for (int j = 0; j < 4; ++j) {
        float s = sfr[nf][j] * 8.0f;
        if (kt == qt && (nf*16 + lr) > (w*16 + lk*4 + j)) s = -3.0e38f;
        sfr[nf][j] = s;
      }
    // online softmax: per query j, values spread over 4 nf x 16 lanes (lr group)
    float alpha[4], tsum[4];
    #pragma unroll
    for (int j = 0; j < 4; ++j) {
      float mx = fmaxf(fmaxf(sfr[0][j], sfr[1][j]), fmaxf(sfr[2][j], sfr[3][j]));
      mx = fmaxf(mx, __shfl_xor(mx, 1));
      mx = fmaxf(mx, __shfl_xor(mx, 2));
      mx = fmaxf(mx, __shfl_xor(mx, 4));
      mx = fmaxf(mx, __shfl_xor(mx, 8));
      float mnew = fmaxf(mrow[j], mx);
      alpha[j] = __expf(mrow[j] - mnew);
      mrow[j] = mnew;
      tsum[j] = 0.f;
    }
    #pragma unroll
    for (int nf = 0; nf < 4; ++nf)
      #pragma unroll
      for (int j = 0; j < 4; ++j) {
        float p = __expf(sfr[nf][j] - mrow[j]);
        tsum[j] += p;
        unsigned u = __float_as_uint(p);
        float r = p - __uint_as_float(u & 0xffff0000u);
        unsigned pw = (u & 0xffff0000u) | (__float_as_uint(r) >> 16);
        int qrow = w*16 + lk*4 + j;
        int kcol = nf*16 + lr;
        P_lds[qrow*68 + (((kcol>>3) ^ (qrow & 7)))*8 + (kcol & 7)] = pw;
      }
    #pragma unroll
    for (int j = 0; j < 4; ++j) {
      float ts = tsum[j];
      ts += __shfl_xor(ts, 1);
      ts += __shfl_xor(ts, 2);
      ts += __shfl_xor(ts, 4);
      ts += __shfl_xor(ts, 8);
      lrow[j] = lrow[j]*alpha[j] + ts;
      oac[0][j] *= alpha[j]; oac[1][j] *= alpha[j];
      oac[2][j] *= alpha[j]; oac[3][j] *= alpha[j];
    }
    __syncthreads();                      // P visible

    // O += P V  (A = P hi/lo, B = Vt hi/lo, 3-combo)
    #pragma unroll
    for (int ks = 0; ks < 2; ++ks) {
      int kc = ks*4 + lk;
      int prow = w*16 + lr;
      const uint4* pp4 = reinterpret_cast<const uint4*>(
          &P_lds[prow*68 + ((kc ^ (prow & 7)))*8]);
      uint4 pw0 = pp4[0], pw1 = pp4[1];
      uint4 phu, plu;
      phu.x = (pw0.x>>16) | (pw0.y & 0xffff0000u);
      phu.y = (pw0.z>>16) | (pw0.w & 0xffff0000u);
      phu.z = (pw1.x>>16) | (pw1.y & 0xffff0000u);
      phu.w = (pw1.z>>16) | (pw1.w & 0xffff0000u);
      plu.x = (pw0.x & 0xffffu) | (pw0.y << 16);
      plu.y = (pw0.z & 0xffffu) | (pw0.w << 16);
      plu.z = (pw1.x & 0xffffu) | (pw1.y << 16);
      plu.w = (pw1.z & 0xffffu) | (pw1.w << 16);
      bf16x8 ph = *reinterpret_cast<bf16x8*>(&phu);
      bf16x8 pl = *reinterpret_cast<bf16x8*>(&plu);
      #pragma unroll
      for (int nf2 = 0; nf2 < 4; ++nf2) {
        int d = nf2*16 + lr;
        int di = (kc ^ (d & 7))*66 + d;
        bf16x8 vh = *reinterpret_cast<const bf16x8*>(&V_lds[0][di]);
        bf16x8 vl = *reinterpret_cast<const bf16x8*>(&V_lds[1][di]);
        oac[nf2] = __builtin_amdgcn_mfma_f32_16x16x32_bf16(ph, vh, oac[nf2], 0,0,0);
        oac[nf2] = __builtin_amdgcn_mfma_f32_16x16x32_bf16(ph, vl, oac[nf2], 0,0,0);
        oac[nf2] = __builtin_amdgcn_mfma_f32_16x16x32_bf16(pl, vh, oac[nf2], 0,0,0);
      }
    }
  }

  // write O (D layout: row = query lk*4+j, col = d = nf2*16+lr)
  #pragma unroll
  for (int j = 0; j < 4; ++j) {
    float inv = 1.0f / lrow[j];
    float* op = o + (tok0 + qt*64 + w*16 + lk*4 + j) * CC + hh*HS;
    #pragma unroll
    for (int nf2 = 0; nf2 < 4; ++nf2)
      op[nf2*16 + lr] = oac[nf2][j] * inv;
  }
}

extern "C" void kernel_launch(void* const* d_in, const int* in_sizes, int n_in,
                              void* d_out, int out_size, void* d_ws, size_t ws_size,
                              hipStream_t stream) {
  const int*   idx  = (const int*)d_in[0];
  const float* tok  = (const float*)d_in[1];
  const float* pos  = (const float*)d_in[2];
  const float* Wq   = (const float*)d_in[3];
  const float* Wk   = (const float*)d_in[4];
  const float* Wv   = (const float*)d_in[5];
  const float* Wo   = (const float*)d_in[6];
  const float* bo   = (const float*)d_in[7];
  const float* ln1g = (const float*)d_in[8];
  const float* ln1b = (const float*)d_in[9];
  const float* ln2g = (const float*)d_in[10];
  const float* ln2b = (const float*)d_in[11];
  const float* W1   = (const float*)d_in[12];
  const float* b1   = (const float*)d_in[13];
  const float* W2   = (const float*)d_in[14];
  const float* b2   = (const float*)d_in[15];
  const float* lnfg = (const float*)d_in[16];
  const float* lnfb = (const float*)d_in[17];
  const float* lmw  = (const float*)d_in[18];
  const float* lmb  = (const float*)d_in[19];
  float* out = (float*)d_out;

  // d_out: x[0,32M) | h[32,64M) | qf[64,96M) | kf[96,128M); a1=[64,128M) (MLP)
  // ws:    vf[0,32M) | vt[32,64M); hf reuses [0,32M) for final LN.
  char* ob = (char*)d_out;
  float* x  = (float*)ob;
  float* h  = (float*)(ob + ((size_t)32<<20));
  float* qf = (float*)(ob + ((size_t)64<<20));
  float* kf = (float*)(ob + ((size_t)96<<20));
  float* a1 = (float*)(ob + ((size_t)64<<20));
  float* vf = (float*)d_ws;
  float* vtf = (float*)((char*)d_ws + ((size_t)32<<20));
  float* hf = (float*)d_ws;

  dim3 blk(256);
  dim3 g1(CC/128,   BT/64);
  dim3 gh(2048/128, BT/64);
  dim3 gl(VV/128,   BT/64);

  embed_kernel<<<BT, blk, 0, stream>>>(idx, tok, pos, x);
  for (int l = 0; l < LL; ++l) {
    const float* Wq_l = Wq + (size_t)l*CC*CC;
    const float* Wk_l = Wk + (size_t)l*CC*CC;
    const float* Wv_l = Wv + (size_t)l*CC*CC;
    const float* Wo_l = Wo + (size_t)l*CC*CC;
    const float* W1_l = W1 + (size_t)l*CC*4*CC;
    const float* W2_l = W2 + (size_t)l*4*CC*CC;
    ln32_kernel<<<BT, blk, 0, stream>>>(x, ln1g + (size_t)l*CC, ln1b + (size_t)l*CC, h);
    gemm_kernel<3><<<g1, blk, 0, stream>>>(h, Wq_l, nullptr, nullptr, qf, CC, CC, CC, 0);
    gemm_kernel<3><<<g1, blk, 0, stream>>>(h, Wk_l, nullptr, nullptr, kf, CC, CC, CC, 0);
    gemm_kernel<3><<<g1, blk, 0, stream>>>(h, Wv_l, nullptr, nullptr, vf, CC, CC, CC, 0);
    vtrans_kernel<<<BB*HH*16, blk, 0, stream>>>(vf, vtf);
    attn_mfma_kernel<<<BB*HH*16, blk, 0, stream>>>(qf, kf, vtf, h);
    gemm_kernel<3><<<g1, blk, 0, stream>>>(h, Wo_l, bo + (size_t)l*CC, x, x, CC, CC, CC, 0);
    ln32_kernel<<<BT, blk, 0, stream>>>(x, ln2g + (size_t)l*CC, ln2b + (size_t)l*CC, h);
    gemm_kernel<3><<<gh, blk, 0, stream>>>(h,  W1_l,           b1 + (size_t)l*4*CC,        nullptr, a1, CC,   4*CC, 2048, 1);
    gemm_kernel<3><<<g1, blk, 0, stream>>>(a1, W2_l,           b2 + (size_t)l*CC,          x, x,        2048, CC,   CC,   0);
    gemm_kernel<3><<<gh, blk, 0, stream>>>(h,  W1_l + 2048,    b1 + (size_t)l*4*CC + 2048, nullptr, a1, CC,   4*CC, 2048, 1);
    gemm_kernel<3><<<g1, blk, 0, stream>>>(a1, W2_l + 2048*CC, nullptr,                    x, x,        2048, CC,   CC,   0);
  }
  ln32_kernel<<<BT, blk, 0, stream>>>(x, lnfg, lnfb, hf);
  gemm_kernel<1><<<gl, blk, 0, stream>>>(hf, lmw, lmb, nullptr, out, CC, VV, VV, 0);
}

// Round 10
// 8325.039 us; speedup vs baseline: 6.6057x; 1.1315x over previous
//
#include <hip/hip_runtime.h>

#define LL 6
#define BB 8
#define TT 1024
#define CC 1024
#define HH 16
#define HS 64
#define VV 4096
#define BT (BB*TT)

typedef __attribute__((ext_vector_type(4))) float f32x4;
typedef __attribute__((ext_vector_type(8))) short bf16x8;

__device__ __forceinline__ float bf2f(unsigned short u) {
  union { unsigned int u; float f; } v; v.u = ((unsigned int)u) << 16; return v.f;
}
__device__ __forceinline__ unsigned short rne16(float f) {
  unsigned u = __float_as_uint(f);
  return (unsigned short)((u + 0x7fffu + ((u >> 16) & 1u)) >> 16);
}

// ---------------- embedding ----------------
__global__ __launch_bounds__(256) void embed_kernel(
    const int* __restrict__ idx, const float* __restrict__ tok,
    const float* __restrict__ pos, float* __restrict__ x) {
  int bt = blockIdx.x;
  int t = bt & (TT - 1);
  int id = idx[bt];
  float4 te = reinterpret_cast<const float4*>(tok)[(size_t)id * (CC/4) + threadIdx.x];
  float4 pe = reinterpret_cast<const float4*>(pos)[(size_t)t * (CC/4) + threadIdx.x];
  float4 r; r.x = te.x+pe.x; r.y = te.y+pe.y; r.z = te.z+pe.z; r.w = te.w+pe.w;
  reinterpret_cast<float4*>(x)[(size_t)bt * (CC/4) + threadIdx.x] = r;
}

// ---------------- layernorm fp32->fp32 (R4-proven) ----------------
__global__ __launch_bounds__(256) void ln32_kernel(
    const float* __restrict__ x, const float* __restrict__ g,
    const float* __restrict__ b, float* __restrict__ out) {
  __shared__ float red[8];
  int row = blockIdx.x, tid = threadIdx.x;
  float4 v = reinterpret_cast<const float4*>(x)[(size_t)row * (CC/4) + tid];
  float s  = v.x+v.y+v.z+v.w;
  float ss = v.x*v.x+v.y*v.y+v.z*v.z+v.w*v.w;
  #pragma unroll
  for (int off = 32; off; off >>= 1) { s += __shfl_xor(s, off); ss += __shfl_xor(ss, off); }
  if ((tid & 63) == 0) { red[tid>>6] = s; red[4+(tid>>6)] = ss; }
  __syncthreads();
  s  = red[0]+red[1]+red[2]+red[3];
  ss = red[4]+red[5]+red[6]+red[7];
  float mu = s * (1.f/CC);
  float rs = rsqrtf(ss*(1.f/CC) - mu*mu + 1e-5f);
  float4 gg = reinterpret_cast<const float4*>(g)[tid];
  float4 bb = reinterpret_cast<const float4*>(b)[tid];
  float4 o;
  o.x = (v.x-mu)*rs*gg.x + bb.x;
  o.y = (v.y-mu)*rs*gg.y + bb.y;
  o.z = (v.z-mu)*rs*gg.z + bb.z;
  o.w = (v.w-mu)*rs*gg.w + bb.w;
  reinterpret_cast<float4*>(out)[(size_t)row * (CC/4) + tid] = o;
}

// ---- split 8 fp32 into 3 truncated-bf16 planes (R7-proven, for NP=3) ----
struct Oct3 { uint4 p0, p1, p2; };
__device__ __forceinline__ unsigned pk2(unsigned lo, unsigned hi) {
  return (lo >> 16) | (hi & 0xffff0000u);
}
__device__ __forceinline__ Oct3 split8(const float* f) {
  unsigned a0[8], a1[8], a2[8];
  #pragma unroll
  for (int e = 0; e < 8; ++e) {
    float v = f[e];
    unsigned u = __float_as_uint(v);
    a0[e] = u;
    float r = v - __uint_as_float(u & 0xffff0000u);
    unsigned ur = __float_as_uint(r);
    a1[e] = ur;
    float r2 = r - __uint_as_float(ur & 0xffff0000u);
    a2[e] = __float_as_uint(r2);
  }
  Oct3 o;
  o.p0 = make_uint4(pk2(a0[0],a0[1]), pk2(a0[2],a0[3]), pk2(a0[4],a0[5]), pk2(a0[6],a0[7]));
  o.p1 = make_uint4(pk2(a1[0],a1[1]), pk2(a1[2],a1[3]), pk2(a1[4],a1[5]), pk2(a1[6],a1[7]));
  o.p2 = make_uint4(pk2(a2[0],a2[1]), pk2(a2[2],a2[3]), pk2(a2[4],a2[5]), pk2(a2[6],a2[7]));
  return o;
}

// ---- split 8 fp32 into 2 RNE bf16 planes (NP=2; zero-mean residual <= 2^-18) ----
struct Oct2 { uint4 p0, p1; };
__device__ __forceinline__ Oct2 split8_rne2(const float* f) {
  unsigned h0[8], h1[8];
  #pragma unroll
  for (int e = 0; e < 8; ++e) {
    h0[e] = rne16(f[e]);
    float r = f[e] - bf2f((unsigned short)h0[e]);
    h1[e] = rne16(r);
  }
  Oct2 o;
  o.p0 = make_uint4(h0[0]|(h0[1]<<16), h0[2]|(h0[3]<<16), h0[4]|(h0[5]<<16), h0[6]|(h0[7]<<16));
  o.p1 = make_uint4(h1[0]|(h1[1]<<16), h1[2]|(h1[3]<<16), h1[4]|(h1[5]<<16), h1[6]|(h1[7]<<16));
  return o;
}
__device__ __forceinline__ uint4 pack8_rne(const float* f) {
  unsigned h[8];
  #pragma unroll
  for (int e = 0; e < 8; ++e) h[e] = rne16(f[e]);
  return make_uint4(h[0]|(h[1]<<16), h[2]|(h[3]<<16), h[4]|(h[5]<<16), h[6]|(h[7]<<16));
}

// ---------------- fp32-emulation MFMA GEMM ----------------
// NP=3: trunc 3-plane, 6-MFMA (score-critical Q/K; R7-proven numerics).
// NP=2: RNE 2-plane, 4-MFMA (residual-stream paths).
// NP=1: RNE 1-plane (logits).
template<int NP>
__global__ __launch_bounds__(256) void gemm_kernel(
    const float* __restrict__ A, const float* __restrict__ Bw,
    const float* __restrict__ bias, const float* __restrict__ res,
    float* __restrict__ outf, int K, int ldb, int ldc, int relu) {
  __shared__ uint4 lds_a[NP][64*8];
  __shared__ uint4 lds_b[NP][8*128];
  int tid = threadIdx.x;
  int m0 = blockIdx.y * 64;
  int n0 = blockIdx.x * 128;
  int lane = tid & 63, wid = tid >> 6;
  int wm = wid >> 1, wn = wid & 1;
  int lr = lane & 15, lk = lane >> 4;
  int bcol = tid & 127, bkcg = tid >> 7;

  f32x4 acc[2][4];
  #pragma unroll
  for (int m = 0; m < 2; ++m)
    #pragma unroll
    for (int n = 0; n < 4; ++n)
      acc[m][n] = (f32x4){0.f, 0.f, 0.f, 0.f};

  for (int k0 = 0; k0 < K; k0 += 64) {
    #pragma unroll
    for (int i = 0; i < 2; ++i) {
      int c = tid + i * 256;
      int row = c >> 3, sl = c & 7;
      const float4* ap = reinterpret_cast<const float4*>(A + (size_t)(m0+row)*K + k0 + sl*8);
      float4 x0 = ap[0], x1 = ap[1];
      float f[8] = {x0.x,x0.y,x0.z,x0.w,x1.x,x1.y,x1.z,x1.w};
      int di = row*8 + (sl ^ (row & 7));
      if (NP == 3) {
        Oct3 o = split8(f);
        lds_a[0][di] = o.p0; lds_a[1][di] = o.p1; lds_a[2][di] = o.p2;
      } else if (NP == 2) {
        Oct2 o = split8_rne2(f);
        lds_a[0][di] = o.p0; lds_a[1][di] = o.p1;
      } else {
        lds_a[0][di] = pack8_rne(f);
      }
    }
    #pragma unroll
    for (int g = 0; g < 4; ++g) {
      int kc = bkcg * 4 + g;
      float f[8];
      #pragma unroll
      for (int j = 0; j < 8; ++j)
        f[j] = Bw[(size_t)(k0 + kc*8 + j) * ldb + n0 + bcol];
      int di = kc*128 + bcol;
      if (NP == 3) {
        Oct3 o = split8(f);
        lds_b[0][di] = o.p0; lds_b[1][di] = o.p1; lds_b[2][di] = o.p2;
      } else if (NP == 2) {
        Oct2 o = split8_rne2(f);
        lds_b[0][di] = o.p0; lds_b[1][di] = o.p1;
      } else {
        lds_b[0][di] = pack8_rne(f);
      }
    }
    __syncthreads();
    #pragma unroll
    for (int ks = 0; ks < 2; ++ks) {
      int kc = ks*4 + lk;
      bf16x8 af[NP][2], bfr[NP][4];
      #pragma unroll
      for (int m = 0; m < 2; ++m) {
        int row = wm*32 + m*16 + lr;
        int si = row*8 + (kc ^ (row & 7));
        #pragma unroll
        for (int p = 0; p < NP; ++p)
          af[p][m] = reinterpret_cast<const bf16x8*>(lds_a[p])[si];
      }
      #pragma unroll
      for (int n = 0; n < 4; ++n) {
        int si = kc*128 + wn*64 + n*16 + lr;
        #pragma unroll
        for (int p = 0; p < NP; ++p)
          bfr[p][n] = reinterpret_cast<const bf16x8*>(lds_b[p])[si];
      }
      #pragma unroll
      for (int m = 0; m < 2; ++m)
        #pragma unroll
        for (int n = 0; n < 4; ++n) {
          acc[m][n] = __builtin_amdgcn_mfma_f32_16x16x32_bf16(af[0][m], bfr[0][n], acc[m][n], 0, 0, 0);
          if (NP >= 2) {
            acc[m][n] = __builtin_amdgcn_mfma_f32_16x16x32_bf16(af[0][m], bfr[1][n], acc[m][n], 0, 0, 0);
            acc[m][n] = __builtin_amdgcn_mfma_f32_16x16x32_bf16(af[1][m], bfr[0][n], acc[m][n], 0, 0, 0);
            acc[m][n] = __builtin_amdgcn_mfma_f32_16x16x32_bf16(af[1][m], bfr[1][n], acc[m][n], 0, 0, 0);
          }
          if (NP == 3) {
            acc[m][n] = __builtin_amdgcn_mfma_f32_16x16x32_bf16(af[2][m], bfr[0][n], acc[m][n], 0, 0, 0);
            acc[m][n] = __builtin_amdgcn_mfma_f32_16x16x32_bf16(af[0][m], bfr[2][n], acc[m][n], 0, 0, 0);
          }
        }
    }
    __syncthreads();
  }

  #pragma unroll
  for (int m = 0; m < 2; ++m) {
    #pragma unroll
    for (int n = 0; n < 4; ++n) {
      int col = n0 + wn*64 + n*16 + lr;
      float bv = bias ? bias[col] : 0.f;
      #pragma unroll
      for (int j = 0; j < 4; ++j) {
        int row = m0 + wm*32 + m*16 + lk*4 + j;
        float vv = acc[m][n][j] + bv;
        if (relu) vv = fmaxf(vv, 0.f);
        size_t off = (size_t)row * ldc + col;
        if (res) vv += res[off];
        outf[off] = vv;
      }
    }
  }
}

// ---------------- V transpose: v[token][h*64+d] -> vt[b][h][d][t] ----------------
__global__ __launch_bounds__(256) void vtrans_kernel(
    const float* __restrict__ v, float* __restrict__ vt) {
  __shared__ float T[64][69];
  int rid = blockIdx.x;
  int tc = rid & 15, hh = (rid >> 4) & 15, b = rid >> 8;
  int tid = threadIdx.x;
  #pragma unroll
  for (int pp = 0; pp < 4; ++pp) {
    int c = tid + pp*256;
    int r = c >> 4, c4 = c & 15;
    float4 x = *reinterpret_cast<const float4*>(
        v + ((size_t)(b*TT + tc*64 + r))*CC + hh*HS + c4*4);
    T[c4*4+0][r] = x.x; T[c4*4+1][r] = x.y; T[c4*4+2][r] = x.z; T[c4*4+3][r] = x.w;
  }
  __syncthreads();
  #pragma unroll
  for (int pp = 0; pp < 4; ++pp) {
    int c = tid + pp*256;
    int d = c >> 4, t4 = c & 15;
    float4 y;
    y.x = T[d][t4*4+0]; y.y = T[d][t4*4+1]; y.z = T[d][t4*4+2]; y.w = T[d][t4*4+3];
    *reinterpret_cast<float4*>(
        vt + (((size_t)(b*HH+hh)*HS + d))*TT + tc*64 + t4*4) = y;
  }
}

// ---------------- MFMA flash attention (R9-proven, unchanged) ----------------
__global__ __launch_bounds__(256) void attn_mfma_kernel(
    const float* __restrict__ q, const float* __restrict__ k,
    const float* __restrict__ vt, float* __restrict__ o) {
  __shared__ uint4 K_lds[3][64*8];
  __shared__ uint4 V_lds[2][8*66];
  __shared__ unsigned P_lds[64*68];
  int tid = threadIdx.x, lane = tid & 63, w = tid >> 6;
  int rid = blockIdx.x;
  int qt = rid & 15, hh = (rid >> 4) & 15, b = rid >> 8;
  int lr = lane & 15, lk = lane >> 4;
  const size_t tok0 = (size_t)b * TT;

  bf16x8 qa[2][3];
  {
    const float* qp = q + (tok0 + qt*64 + w*16 + lr) * CC + hh*HS;
    #pragma unroll
    for (int ks = 0; ks < 2; ++ks) {
      const float4* p4 = reinterpret_cast<const float4*>(qp + ks*32 + lk*8);
      float4 a = p4[0], c = p4[1];
      float f[8] = {a.x,a.y,a.z,a.w,c.x,c.y,c.z,c.w};
      Oct3 ot = split8(f);
      qa[ks][0] = *reinterpret_cast<bf16x8*>(&ot.p0);
      qa[ks][1] = *reinterpret_cast<bf16x8*>(&ot.p1);
      qa[ks][2] = *reinterpret_cast<bf16x8*>(&ot.p2);
    }
  }

  float mrow[4] = {-3.0e38f,-3.0e38f,-3.0e38f,-3.0e38f};
  float lrow[4] = {0.f,0.f,0.f,0.f};
  f32x4 oac[4];
  #pragma unroll
  for (int n = 0; n < 4; ++n) oac[n] = (f32x4){0.f,0.f,0.f,0.f};

  for (int kt = 0; kt <= qt; ++kt) {
    __syncthreads();
    #pragma unroll
    for (int pp = 0; pp < 2; ++pp) {
      int c = tid + pp*256;
      int r = c >> 3, sl = c & 7;
      const float4* kp = reinterpret_cast<const float4*>(
          k + (tok0 + kt*64 + r) * CC + hh*HS + sl*8);
      float4 x0 = kp[0], x1 = kp[1];
      float f[8] = {x0.x,x0.y,x0.z,x0.w,x1.x,x1.y,x1.z,x1.w};
      Oct3 ot = split8(f);
      int di = r*8 + (sl ^ (r & 7));
      K_lds[0][di] = ot.p0; K_lds[1][di] = ot.p1; K_lds[2][di] = ot.p2;
    }
    #pragma unroll
    for (int pp = 0; pp < 2; ++pp) {
      int c = tid + pp*256;
      int kc = c & 7, d = c >> 3;
      const float4* vp = reinterpret_cast<const float4*>(
          vt + (((size_t)(b*HH+hh)*HS + d))*TT + kt*64 + kc*8);
      float4 x0 = vp[0], x1 = vp[1];
      float f[8] = {x0.x,x0.y,x0.z,x0.w,x1.x,x1.y,x1.z,x1.w};
      Oct3 ot = split8(f);
      int di = (kc ^ (d & 7))*66 + d;
      V_lds[0][di] = ot.p0; V_lds[1][di] = ot.p1;
    }
    __syncthreads();

    f32x4 sfr[4];
    #pragma unroll
    for (int nf = 0; nf < 4; ++nf) sfr[nf] = (f32x4){0.f,0.f,0.f,0.f};
    #pragma unroll
    for (int ks = 0; ks < 2; ++ks) {
      int kc = ks*4 + lk;
      #pragma unroll
      for (int nf = 0; nf < 4; ++nf) {
        int row = nf*16 + lr;
        int si = row*8 + (kc ^ (row & 7));
        bf16x8 k0 = *reinterpret_cast<const bf16x8*>(&K_lds[0][si]);
        bf16x8 k1 = *reinterpret_cast<const bf16x8*>(&K_lds[1][si]);
        bf16x8 k2 = *reinterpret_cast<const bf16x8*>(&K_lds[2][si]);
        sfr[nf] = __builtin_amdgcn_mfma_f32_16x16x32_bf16(qa[ks][0], k0, sfr[nf], 0,0,0);
        sfr[nf] = __builtin_amdgcn_mfma_f32_16x16x32_bf16(qa[ks][0], k1, sfr[nf], 0,0,0);
        sfr[nf] = __builtin_amdgcn_mfma_f32_16x16x32_bf16(qa[ks][1], k0, sfr[nf], 0,0,0);
        sfr[nf] = __builtin_amdgcn_mfma_f32_16x16x32_bf16(qa[ks][1], k1, sfr[nf], 0,0,0);
        sfr[nf] = __builtin_amdgcn_mfma_f32_16x16x32_bf16(qa[ks][2], k0, sfr[nf], 0,0,0);
        sfr[nf] = __builtin_amdgcn_mfma_f32_16x16x32_bf16(qa[ks][0], k2, sfr[nf], 0,0,0);
      }
    }
    #pragma unroll
    for (int nf = 0; nf < 4; ++nf)
      #pragma unroll
      for (int j = 0; j < 4; ++j) {
        float s = sfr[nf][j] * 8.0f;
        if (kt == qt && (nf*16 + lr) > (w*16 + lk*4 + j)) s = -3.0e38f;
        sfr[nf][j] = s;
      }
    float alpha[4], tsum[4];
    #pragma unroll
    for (int j = 0; j < 4; ++j) {
      float mx = fmaxf(fmaxf(sfr[0][j], sfr[1][j]), fmaxf(sfr[2][j], sfr[3][j]));
      mx = fmaxf(mx, __shfl_xor(mx, 1));
      mx = fmaxf(mx, __shfl_xor(mx, 2));
      mx = fmaxf(mx, __shfl_xor(mx, 4));
      mx = fmaxf(mx, __shfl_xor(mx, 8));
      float mnew = fmaxf(mrow[j], mx);
      alpha[j] = __expf(mrow[j] - mnew);
      mrow[j] = mnew;
      tsum[j] = 0.f;
    }
    #pragma unroll
    for (int nf = 0; nf < 4; ++nf)
      #pragma unroll
      for (int j = 0; j < 4; ++j) {
        float p = __expf(sfr[nf][j] - mrow[j]);
        tsum[j] += p;
        unsigned u = __float_as_uint(p);
        float r = p - __uint_as_float(u & 0xffff0000u);
        unsigned pw = (u & 0xffff0000u) | (__float_as_uint(r) >> 16);
        int qrow = w*16 + lk*4 + j;
        int kcol = nf*16 + lr;
        P_lds[qrow*68 + (((kcol>>3) ^ (qrow & 7)))*8 + (kcol & 7)] = pw;
      }
    #pragma unroll
    for (int j = 0; j < 4; ++j) {
      float ts = tsum[j];
      ts += __shfl_xor(ts, 1);
      ts += __shfl_xor(ts, 2);
      ts += __shfl_xor(ts, 4);
      ts += __shfl_xor(ts, 8);
      lrow[j] = lrow[j]*alpha[j] + ts;
      oac[0][j] *= alpha[j]; oac[1][j] *= alpha[j];
      oac[2][j] *= alpha[j]; oac[3][j] *= alpha[j];
    }
    __syncthreads();

    #pragma unroll
    for (int ks = 0; ks < 2; ++ks) {
      int kc = ks*4 + lk;
      int prow = w*16 + lr;
      const uint4* pp4 = reinterpret_cast<const uint4*>(
          &P_lds[prow*68 + ((kc ^ (prow & 7)))*8]);
      uint4 pw0 = pp4[0], pw1 = pp4[1];
      uint4 phu, plu;
      phu.x = (pw0.x>>16) | (pw0.y & 0xffff0000u);
      phu.y = (pw0.z>>16) | (pw0.w & 0xffff0000u);
      phu.z = (pw1.x>>16) | (pw1.y & 0xffff0000u);
      phu.w = (pw1.z>>16) | (pw1.w & 0xffff0000u);
      plu.x = (pw0.x & 0xffffu) | (pw0.y << 16);
      plu.y = (pw0.z & 0xffffu) | (pw0.w << 16);
      plu.z = (pw1.x & 0xffffu) | (pw1.y << 16);
      plu.w = (pw1.z & 0xffffu) | (pw1.w << 16);
      bf16x8 ph = *reinterpret_cast<bf16x8*>(&phu);
      bf16x8 pl = *reinterpret_cast<bf16x8*>(&plu);
      #pragma unroll
      for (int nf2 = 0; nf2 < 4; ++nf2) {
        int d = nf2*16 + lr;
        int di = (kc ^ (d & 7))*66 + d;
        bf16x8 vh = *reinterpret_cast<const bf16x8*>(&V_lds[0][di]);
        bf16x8 vl = *reinterpret_cast<const bf16x8*>(&V_lds[1][di]);
        oac[nf2] = __builtin_amdgcn_mfma_f32_16x16x32_bf16(ph, vh, oac[nf2], 0,0,0);
        oac[nf2] = __builtin_amdgcn_mfma_f32_16x16x32_bf16(ph, vl, oac[nf2], 0,0,0);
        oac[nf2] = __builtin_amdgcn_mfma_f32_16x16x32_bf16(pl, vh, oac[nf2], 0,0,0);
      }
    }
  }

  #pragma unroll
  for (int j = 0; j < 4; ++j) {
    float inv = 1.0f / lrow[j];
    float* op = o + (tok0 + qt*64 + w*16 + lk*4 + j) * CC + hh*HS;
    #pragma unroll
    for (int nf2 = 0; nf2 < 4; ++nf2)
      op[nf2*16 + lr] = oac[nf2][j] * inv;
  }
}

extern "C" void kernel_launch(void* const* d_in, const int* in_sizes, int n_in,
                              void* d_out, int out_size, void* d_ws, size_t ws_size,
                              hipStream_t stream) {
  const int*   idx  = (const int*)d_in[0];
  const float* tok  = (const float*)d_in[1];
  const float* pos  = (const float*)d_in[2];
  const float* Wq   = (const float*)d_in[3];
  const float* Wk   = (const float*)d_in[4];
  const float* Wv   = (const float*)d_in[5];
  const float* Wo   = (const float*)d_in[6];
  const float* bo   = (const float*)d_in[7];
  const float* ln1g = (const float*)d_in[8];
  const float* ln1b = (const float*)d_in[9];
  const float* ln2g = (const float*)d_in[10];
  const float* ln2b = (const float*)d_in[11];
  const float* W1   = (const float*)d_in[12];
  const float* b1   = (const float*)d_in[13];
  const float* W2   = (const float*)d_in[14];
  const float* b2   = (const float*)d_in[15];
  const float* lnfg = (const float*)d_in[16];
  const float* lnfb = (const float*)d_in[17];
  const float* lmw  = (const float*)d_in[18];
  const float* lmb  = (const float*)d_in[19];
  float* out = (float*)d_out;

  // d_out: x[0,32M) | h[32,64M) | qf[64,96M) | kf[96,128M); a1=[64,128M) (MLP)
  // ws:    vf[0,32M) | vt[32,64M); hf reuses [0,32M) for final LN.
  char* ob = (char*)d_out;
  float* x  = (float*)ob;
  float* h  = (float*)(ob + ((size_t)32<<20));
  float* qf = (float*)(ob + ((size_t)64<<20));
  float* kf = (float*)(ob + ((size_t)96<<20));
  float* a1 = (float*)(ob + ((size_t)64<<20));
  float* vf = (float*)d_ws;
  float* vtf = (float*)((char*)d_ws + ((size_t)32<<20));
  float* hf = (float*)d_ws;

  dim3 blk(256);
  dim3 g1(CC/128,   BT/64);
  dim3 gh(2048/128, BT/64);
  dim3 gl(VV/128,   BT/64);

  embed_kernel<<<BT, blk, 0, stream>>>(idx, tok, pos, x);
  for (int l = 0; l < LL; ++l) {
    const float* Wq_l = Wq + (size_t)l*CC*CC;
    const float* Wk_l = Wk + (size_t)l*CC*CC;
    const float* Wv_l = Wv + (size_t)l*CC*CC;
    const float* Wo_l = Wo + (size_t)l*CC*CC;
    const float* W1_l = W1 + (size_t)l*CC*4*CC;
    const float* W2_l = W2 + (size_t)l*4*CC*CC;
    ln32_kernel<<<BT, blk, 0, stream>>>(x, ln1g + (size_t)l*CC, ln1b + (size_t)l*CC, h);
    gemm_kernel<3><<<g1, blk, 0, stream>>>(h, Wq_l, nullptr, nullptr, qf, CC, CC, CC, 0);
    gemm_kernel<3><<<g1, blk, 0, stream>>>(h, Wk_l, nullptr, nullptr, kf, CC, CC, CC, 0);
    gemm_kernel<2><<<g1, blk, 0, stream>>>(h, Wv_l, nullptr, nullptr, vf, CC, CC, CC, 0);
    vtrans_kernel<<<BB*HH*16, blk, 0, stream>>>(vf, vtf);
    attn_mfma_kernel<<<BB*HH*16, blk, 0, stream>>>(qf, kf, vtf, h);
    gemm_kernel<2><<<g1, blk, 0, stream>>>(h, Wo_l, bo + (size_t)l*CC, x, x, CC, CC, CC, 0);
    ln32_kernel<<<BT, blk, 0, stream>>>(x, ln2g + (size_t)l*CC, ln2b + (size_t)l*CC, h);
    gemm_kernel<2><<<gh, blk, 0, stream>>>(h,  W1_l,           b1 + (size_t)l*4*CC,        nullptr, a1, CC,   4*CC, 2048, 1);
    gemm_kernel<2><<<g1, blk, 0, stream>>>(a1, W2_l,           b2 + (size_t)l*CC,          x, x,        2048, CC,   CC,   0);
    gemm_kernel<2><<<gh, blk, 0, stream>>>(h,  W1_l + 2048,    b1 + (size_t)l*4*CC + 2048, nullptr, a1, CC,   4*CC, 2048, 1);
    gemm_kernel<2><<<g1, blk, 0, stream>>>(a1, W2_l + 2048*CC, nullptr,                    x, x,        2048, CC,   CC,   0);
  }
  ln32_kernel<<<BT, blk, 0, stream>>>(x, lnfg, lnfb, hf);
  gemm_kernel<1><<<gl, blk, 0, stream>>>(hf, lmw, lmb, nullptr, out, CC, VV, VV, 0);
}

// Round 11
// 7426.513 us; speedup vs baseline: 7.4049x; 1.1210x over previous
//
#include <hip/hip_runtime.h>

#define LL 6
#define BB 8
#define TT 1024
#define CC 1024
#define HH 16
#define HS 64
#define VV 4096
#define BT (BB*TT)

typedef __attribute__((ext_vector_type(4))) float f32x4;
typedef __attribute__((ext_vector_type(8))) short bf16x8;

__device__ __forceinline__ float bf2f(unsigned short u) {
  union { unsigned int u; float f; } v; v.u = ((unsigned int)u) << 16; return v.f;
}
__device__ __forceinline__ unsigned short rne16(float f) {
  unsigned u = __float_as_uint(f);
  return (unsigned short)((u + 0x7fffu + ((u >> 16) & 1u)) >> 16);
}

// ---------------- embedding ----------------
__global__ __launch_bounds__(256) void embed_kernel(
    const int* __restrict__ idx, const float* __restrict__ tok,
    const float* __restrict__ pos, float* __restrict__ x) {
  int bt = blockIdx.x;
  int t = bt & (TT - 1);
  int id = idx[bt];
  float4 te = reinterpret_cast<const float4*>(tok)[(size_t)id * (CC/4) + threadIdx.x];
  float4 pe = reinterpret_cast<const float4*>(pos)[(size_t)t * (CC/4) + threadIdx.x];
  float4 r; r.x = te.x+pe.x; r.y = te.y+pe.y; r.z = te.z+pe.z; r.w = te.w+pe.w;
  reinterpret_cast<float4*>(x)[(size_t)bt * (CC/4) + threadIdx.x] = r;
}

// ---------------- layernorm fp32->fp32 (R4-proven) ----------------
__global__ __launch_bounds__(256) void ln32_kernel(
    const float* __restrict__ x, const float* __restrict__ g,
    const float* __restrict__ b, float* __restrict__ out) {
  __shared__ float red[8];
  int row = blockIdx.x, tid = threadIdx.x;
  float4 v = reinterpret_cast<const float4*>(x)[(size_t)row * (CC/4) + tid];
  float s  = v.x+v.y+v.z+v.w;
  float ss = v.x*v.x+v.y*v.y+v.z*v.z+v.w*v.w;
  #pragma unroll
  for (int off = 32; off; off >>= 1) { s += __shfl_xor(s, off); ss += __shfl_xor(ss, off); }
  if ((tid & 63) == 0) { red[tid>>6] = s; red[4+(tid>>6)] = ss; }
  __syncthreads();
  s  = red[0]+red[1]+red[2]+red[3];
  ss = red[4]+red[5]+red[6]+red[7];
  float mu = s * (1.f/CC);
  float rs = rsqrtf(ss*(1.f/CC) - mu*mu + 1e-5f);
  float4 gg = reinterpret_cast<const float4*>(g)[tid];
  float4 bb = reinterpret_cast<const float4*>(b)[tid];
  float4 o;
  o.x = (v.x-mu)*rs*gg.x + bb.x;
  o.y = (v.y-mu)*rs*gg.y + bb.y;
  o.z = (v.z-mu)*rs*gg.z + bb.z;
  o.w = (v.w-mu)*rs*gg.w + bb.w;
  reinterpret_cast<float4*>(out)[(size_t)row * (CC/4) + tid] = o;
}

// ---- split 8 fp32 into 3 truncated-bf16 planes (R7-proven) ----
struct Oct3 { uint4 p0, p1, p2; };
__device__ __forceinline__ unsigned pk2(unsigned lo, unsigned hi) {
  return (lo >> 16) | (hi & 0xffff0000u);
}
__device__ __forceinline__ Oct3 split8(const float* f) {
  unsigned a0[8], a1[8], a2[8];
  #pragma unroll
  for (int e = 0; e < 8; ++e) {
    float v = f[e];
    unsigned u = __float_as_uint(v);
    a0[e] = u;
    float r = v - __uint_as_float(u & 0xffff0000u);
    unsigned ur = __float_as_uint(r);
    a1[e] = ur;
    float r2 = r - __uint_as_float(ur & 0xffff0000u);
    a2[e] = __float_as_uint(r2);
  }
  Oct3 o;
  o.p0 = make_uint4(pk2(a0[0],a0[1]), pk2(a0[2],a0[3]), pk2(a0[4],a0[5]), pk2(a0[6],a0[7]));
  o.p1 = make_uint4(pk2(a1[0],a1[1]), pk2(a1[2],a1[3]), pk2(a1[4],a1[5]), pk2(a1[6],a1[7]));
  o.p2 = make_uint4(pk2(a2[0],a2[1]), pk2(a2[2],a2[3]), pk2(a2[4],a2[5]), pk2(a2[6],a2[7]));
  return o;
}

// ---- split 8 fp32 into 2 RNE bf16 planes (R10-proven) ----
struct Oct2 { uint4 p0, p1; };
__device__ __forceinline__ Oct2 split8_rne2(const float* f) {
  unsigned h0[8], h1[8];
  #pragma unroll
  for (int e = 0; e < 8; ++e) {
    h0[e] = rne16(f[e]);
    float r = f[e] - bf2f((unsigned short)h0[e]);
    h1[e] = rne16(r);
  }
  Oct2 o;
  o.p0 = make_uint4(h0[0]|(h0[1]<<16), h0[2]|(h0[3]<<16), h0[4]|(h0[5]<<16), h0[6]|(h0[7]<<16));
  o.p1 = make_uint4(h1[0]|(h1[1]<<16), h1[2]|(h1[3]<<16), h1[4]|(h1[5]<<16), h1[6]|(h1[7]<<16));
  return o;
}
__device__ __forceinline__ uint4 pack8_rne(const float* f) {
  unsigned h[8];
  #pragma unroll
  for (int e = 0; e < 8; ++e) h[e] = rne16(f[e]);
  return make_uint4(h[0]|(h[1]<<16), h[2]|(h[3]<<16), h[4]|(h[5]<<16), h[6]|(h[7]<<16));
}

// ---------------- B pre-split: write planes in LDS-tile format ----------------
// out[plane][ntile][kt][kc][col] as uint4 (8 k-consecutive bf16, pair-packed).
// grid = (ntTotal, ktTotal); plane stride = ntTotal*ktTotal*1024 uint4.
template<int NP>
__global__ __launch_bounds__(256) void bsplit_kernel(
    const float* __restrict__ Bw, uint4* __restrict__ outp, int ldb) {
  int ntile = blockIdx.x, kt = blockIdx.y;
  size_t planeStride = (size_t)gridDim.x * gridDim.y * 1024;
  int tid = threadIdx.x;
  int bcol = tid & 127, bkcg = tid >> 7;
  #pragma unroll
  for (int g = 0; g < 4; ++g) {
    int kc = bkcg*4 + g;
    float f[8];
    #pragma unroll
    for (int j = 0; j < 8; ++j)
      f[j] = Bw[(size_t)(kt*64 + kc*8 + j) * ldb + ntile*128 + bcol];
    size_t di = (((size_t)ntile * gridDim.y + kt) * 8 + kc) * 128 + bcol;
    if (NP == 3) {
      Oct3 o = split8(f);
      outp[di] = o.p0; outp[planeStride+di] = o.p1; outp[2*planeStride+di] = o.p2;
    } else if (NP == 2) {
      Oct2 o = split8_rne2(f);
      outp[di] = o.p0; outp[planeStride+di] = o.p1;
    } else {
      outp[di] = pack8_rne(f);
    }
  }
}

// ---------------- fp32-emulation MFMA GEMM, pre-split B ----------------
// NP=3: 6-MFMA (Q/K); NP=2: 4-MFMA (residual paths); NP=1: plain bf16 (logits).
// B-staging = NP coalesced uint4 copies from the pre-split buffer.
// vtmode=1: write output transposed as vt[b][h][d][t] (V projection).
template<int NP>
__global__ __launch_bounds__(256) void gemm_kernel(
    const float* __restrict__ A, const uint4* __restrict__ Bs,
    const float* __restrict__ bias, const float* __restrict__ res,
    float* __restrict__ outf, int K, int ldc, int relu,
    int ntile0, int ntTotal, int kt0, int ktTotal, int vtmode) {
  __shared__ uint4 lds_a[NP][64*8];
  __shared__ uint4 lds_b[NP][8*128];
  int tid = threadIdx.x;
  int m0 = blockIdx.y * 64;
  int n0 = blockIdx.x * 128;            // local output col base
  int ntg = ntile0 + blockIdx.x;        // global B tile index
  size_t planeStride = (size_t)ntTotal * ktTotal * 1024;
  int lane = tid & 63, wid = tid >> 6;
  int wm = wid >> 1, wn = wid & 1;
  int lr = lane & 15, lk = lane >> 4;
  int bcol = tid & 127, bkcg = tid >> 7;

  f32x4 acc[2][4];
  #pragma unroll
  for (int m = 0; m < 2; ++m)
    #pragma unroll
    for (int n = 0; n < 4; ++n)
      acc[m][n] = (f32x4){0.f, 0.f, 0.f, 0.f};

  for (int k0 = 0; k0 < K; k0 += 64) {
    // stage A: fp32 -> planes (split on the fly; redundancy only ntiles-wide)
    #pragma unroll
    for (int i = 0; i < 2; ++i) {
      int c = tid + i * 256;
      int row = c >> 3, sl = c & 7;
      const float4* ap = reinterpret_cast<const float4*>(A + (size_t)(m0+row)*K + k0 + sl*8);
      float4 x0 = ap[0], x1 = ap[1];
      float f[8] = {x0.x,x0.y,x0.z,x0.w,x1.x,x1.y,x1.z,x1.w};
      int di = row*8 + (sl ^ (row & 7));
      if (NP == 3) {
        Oct3 o = split8(f);
        lds_a[0][di] = o.p0; lds_a[1][di] = o.p1; lds_a[2][di] = o.p2;
      } else if (NP == 2) {
        Oct2 o = split8_rne2(f);
        lds_a[0][di] = o.p0; lds_a[1][di] = o.p1;
      } else {
        lds_a[0][di] = pack8_rne(f);
      }
    }
    // stage B: straight coalesced copies from pre-split buffer
    {
      int ktg = kt0 + (k0 >> 6);
      #pragma unroll
      for (int g = 0; g < 4; ++g) {
        int kc = bkcg*4 + g;
        size_t di = (((size_t)ntg * ktTotal + ktg) * 8 + kc) * 128 + bcol;
        lds_b[0][kc*128 + bcol] = Bs[di];
        if (NP >= 2) lds_b[1][kc*128 + bcol] = Bs[planeStride + di];
        if (NP == 3) lds_b[2][kc*128 + bcol] = Bs[2*planeStride + di];
      }
    }
    __syncthreads();
    #pragma unroll
    for (int ks = 0; ks < 2; ++ks) {
      int kc = ks*4 + lk;
      bf16x8 af[NP][2], bfr[NP][4];
      #pragma unroll
      for (int m = 0; m < 2; ++m) {
        int row = wm*32 + m*16 + lr;
        int si = row*8 + (kc ^ (row & 7));
        #pragma unroll
        for (int p = 0; p < NP; ++p)
          af[p][m] = reinterpret_cast<const bf16x8*>(lds_a[p])[si];
      }
      #pragma unroll
      for (int n = 0; n < 4; ++n) {
        int si = kc*128 + wn*64 + n*16 + lr;
        #pragma unroll
        for (int p = 0; p < NP; ++p)
          bfr[p][n] = reinterpret_cast<const bf16x8*>(lds_b[p])[si];
      }
      #pragma unroll
      for (int m = 0; m < 2; ++m)
        #pragma unroll
        for (int n = 0; n < 4; ++n) {
          acc[m][n] = __builtin_amdgcn_mfma_f32_16x16x32_bf16(af[0][m], bfr[0][n], acc[m][n], 0, 0, 0);
          if (NP >= 2) {
            acc[m][n] = __builtin_amdgcn_mfma_f32_16x16x32_bf16(af[0][m], bfr[1][n], acc[m][n], 0, 0, 0);
            acc[m][n] = __builtin_amdgcn_mfma_f32_16x16x32_bf16(af[1][m], bfr[0][n], acc[m][n], 0, 0, 0);
            acc[m][n] = __builtin_amdgcn_mfma_f32_16x16x32_bf16(af[1][m], bfr[1][n], acc[m][n], 0, 0, 0);
          }
          if (NP == 3) {
            acc[m][n] = __builtin_amdgcn_mfma_f32_16x16x32_bf16(af[2][m], bfr[0][n], acc[m][n], 0, 0, 0);
            acc[m][n] = __builtin_amdgcn_mfma_f32_16x16x32_bf16(af[0][m], bfr[2][n], acc[m][n], 0, 0, 0);
          }
        }
    }
    __syncthreads();
  }

  if (vtmode) {
    // write transposed: vt[((b*HH+h)*HS+d)*TT + t]; lane's 4 j = 4 consecutive t
    #pragma unroll
    for (int m = 0; m < 2; ++m) {
      int t0 = m0 + wm*32 + m*16 + lk*4;
      int bq = t0 >> 10, tb = t0 & (TT-1);
      #pragma unroll
      for (int n = 0; n < 4; ++n) {
        int col = n0 + wn*64 + n*16 + lr;   // h*64 + d
        float4 val;
        val.x = acc[m][n][0]; val.y = acc[m][n][1];
        val.z = acc[m][n][2]; val.w = acc[m][n][3];
        *reinterpret_cast<float4*>(
            outf + (((size_t)(bq*HH + (col>>6)))*HS + (col&63))*TT + tb) = val;
      }
    }
  } else {
    #pragma unroll
    for (int m = 0; m < 2; ++m) {
      #pragma unroll
      for (int n = 0; n < 4; ++n) {
        int col = n0 + wn*64 + n*16 + lr;
        float bv = bias ? bias[col] : 0.f;
        #pragma unroll
        for (int j = 0; j < 4; ++j) {
          int row = m0 + wm*32 + m*16 + lk*4 + j;
          float vv = acc[m][n][j] + bv;
          if (relu) vv = fmaxf(vv, 0.f);
          size_t off = (size_t)row * ldc + col;
          if (res) vv += res[off];
          outf[off] = vv;
        }
      }
    }
  }
}

// ---------------- MFMA flash attention (R9-proven, unchanged) ----------------
__global__ __launch_bounds__(256) void attn_mfma_kernel(
    const float* __restrict__ q, const float* __restrict__ k,
    const float* __restrict__ vt, float* __restrict__ o) {
  __shared__ uint4 K_lds[3][64*8];
  __shared__ uint4 V_lds[2][8*66];
  __shared__ unsigned P_lds[64*68];
  int tid = threadIdx.x, lane = tid & 63, w = tid >> 6;
  int rid = blockIdx.x;
  int qt = rid & 15, hh = (rid >> 4) & 15, b = rid >> 8;
  int lr = lane & 15, lk = lane >> 4;
  const size_t tok0 = (size_t)b * TT;

  bf16x8 qa[2][3];
  {
    const float* qp = q + (tok0 + qt*64 + w*16 + lr) * CC + hh*HS;
    #pragma unroll
    for (int ks = 0; ks < 2; ++ks) {
      const float4* p4 = reinterpret_cast<const float4*>(qp + ks*32 + lk*8);
      float4 a = p4[0], c = p4[1];
      float f[8] = {a.x,a.y,a.z,a.w,c.x,c.y,c.z,c.w};
      Oct3 ot = split8(f);
      qa[ks][0] = *reinterpret_cast<bf16x8*>(&ot.p0);
      qa[ks][1] = *reinterpret_cast<bf16x8*>(&ot.p1);
      qa[ks][2] = *reinterpret_cast<bf16x8*>(&ot.p2);
    }
  }

  float mrow[4] = {-3.0e38f,-3.0e38f,-3.0e38f,-3.0e38f};
  float lrow[4] = {0.f,0.f,0.f,0.f};
  f32x4 oac[4];
  #pragma unroll
  for (int n = 0; n < 4; ++n) oac[n] = (f32x4){0.f,0.f,0.f,0.f};

  for (int kt = 0; kt <= qt; ++kt) {
    __syncthreads();
    #pragma unroll
    for (int pp = 0; pp < 2; ++pp) {
      int c = tid + pp*256;
      int r = c >> 3, sl = c & 7;
      const float4* kp = reinterpret_cast<const float4*>(
          k + (tok0 + kt*64 + r) * CC + hh*HS + sl*8);
      float4 x0 = kp[0], x1 = kp[1];
      float f[8] = {x0.x,x0.y,x0.z,x0.w,x1.x,x1.y,x1.z,x1.w};
      Oct3 ot = split8(f);
      int di = r*8 + (sl ^ (r & 7));
      K_lds[0][di] = ot.p0; K_lds[1][di] = ot.p1; K_lds[2][di] = ot.p2;
    }
    #pragma unroll
    for (int pp = 0; pp < 2; ++pp) {
      int c = tid + pp*256;
      int kc = c & 7, d = c >> 3;
      const float4* vp = reinterpret_cast<const float4*>(
          vt + (((size_t)(b*HH+hh)*HS + d))*TT + kt*64 + kc*8);
      float4 x0 = vp[0], x1 = vp[1];
      float f[8] = {x0.x,x0.y,x0.z,x0.w,x1.x,x1.y,x1.z,x1.w};
      Oct2 ot = split8_rne2(f);
      int di = (kc ^ (d & 7))*66 + d;
      V_lds[0][di] = ot.p0; V_lds[1][di] = ot.p1;
    }
    __syncthreads();

    f32x4 sfr[4];
    #pragma unroll
    for (int nf = 0; nf < 4; ++nf) sfr[nf] = (f32x4){0.f,0.f,0.f,0.f};
    #pragma unroll
    for (int ks = 0; ks < 2; ++ks) {
      int kc = ks*4 + lk;
      #pragma unroll
      for (int nf = 0; nf < 4; ++nf) {
        int row = nf*16 + lr;
        int si = row*8 + (kc ^ (row & 7));
        bf16x8 k0 = *reinterpret_cast<const bf16x8*>(&K_lds[0][si]);
        bf16x8 k1 = *reinterpret_cast<const bf16x8*>(&K_lds[1][si]);
        bf16x8 k2 = *reinterpret_cast<const bf16x8*>(&K_lds[2][si]);
        sfr[nf] = __builtin_amdgcn_mfma_f32_16x16x32_bf16(qa[ks][0], k0, sfr[nf], 0,0,0);
        sfr[nf] = __builtin_amdgcn_mfma_f32_16x16x32_bf16(qa[ks][0], k1, sfr[nf], 0,0,0);
        sfr[nf] = __builtin_amdgcn_mfma_f32_16x16x32_bf16(qa[ks][1], k0, sfr[nf], 0,0,0);
        sfr[nf] = __builtin_amdgcn_mfma_f32_16x16x32_bf16(qa[ks][1], k1, sfr[nf], 0,0,0);
        sfr[nf] = __builtin_amdgcn_mfma_f32_16x16x32_bf16(qa[ks][2], k0, sfr[nf], 0,0,0);
        sfr[nf] = __builtin_amdgcn_mfma_f32_16x16x32_bf16(qa[ks][0], k2, sfr[nf], 0,0,0);
      }
    }
    #pragma unroll
    for (int nf = 0; nf < 4; ++nf)
      #pragma unroll
      for (int j = 0; j < 4; ++j) {
        float s = sfr[nf][j] * 8.0f;
        if (kt == qt && (nf*16 + lr) > (w*16 + lk*4 + j)) s = -3.0e38f;
        sfr[nf][j] = s;
      }
    float alpha[4], tsum[4];
    #pragma unroll
    for (int j = 0; j < 4; ++j) {
      float mx = fmaxf(fmaxf(sfr[0][j], sfr[1][j]), fmaxf(sfr[2][j], sfr[3][j]));
      mx = fmaxf(mx, __shfl_xor(mx, 1));
      mx = fmaxf(mx, __shfl_xor(mx, 2));
      mx = fmaxf(mx, __shfl_xor(mx, 4));
      mx = fmaxf(mx, __shfl_xor(mx, 8));
      float mnew = fmaxf(mrow[j], mx);
      alpha[j] = __expf(mrow[j] - mnew);
      mrow[j] = mnew;
      tsum[j] = 0.f;
    }
    #pragma unroll
    for (int nf = 0; nf < 4; ++nf)
      #pragma unroll
      for (int j = 0; j < 4; ++j) {
        float p = __expf(sfr[nf][j] - mrow[j]);
        tsum[j] += p;
        unsigned u = __float_as_uint(p);
        float r = p - __uint_as_float(u & 0xffff0000u);
        unsigned pw = (u & 0xffff0000u) | (__float_as_uint(r) >> 16);
        int qrow = w*16 + lk*4 + j;
        int kcol = nf*16 + lr;
        P_lds[qrow*68 + (((kcol>>3) ^ (qrow & 7)))*8 + (kcol & 7)] = pw;
      }
    #pragma unroll
    for (int j = 0; j < 4; ++j) {
      float ts = tsum[j];
      ts += __shfl_xor(ts, 1);
      ts += __shfl_xor(ts, 2);
      ts += __shfl_xor(ts, 4);
      ts += __shfl_xor(ts, 8);
      lrow[j] = lrow[j]*alpha[j] + ts;
      oac[0][j] *= alpha[j]; oac[1][j] *= alpha[j];
      oac[2][j] *= alpha[j]; oac[3][j] *= alpha[j];
    }
    __syncthreads();

    #pragma unroll
    for (int ks = 0; ks < 2; ++ks) {
      int kc = ks*4 + lk;
      int prow = w*16 + lr;
      const uint4* pp4 = reinterpret_cast<const uint4*>(
          &P_lds[prow*68 + ((kc ^ (prow & 7)))*8]);
      uint4 pw0 = pp4[0], pw1 = pp4[1];
      uint4 phu, plu;
      phu.x = (pw0.x>>16) | (pw0.y & 0xffff0000u);
      phu.y = (pw0.z>>16) | (pw0.w & 0xffff0000u);
      phu.z = (pw1.x>>16) | (pw1.y & 0xffff0000u);
      phu.w = (pw1.z>>16) | (pw1.w & 0xffff0000u);
      plu.x = (pw0.x & 0xffffu) | (pw0.y << 16);
      plu.y = (pw0.z & 0xffffu) | (pw0.w << 16);
      plu.z = (pw1.x & 0xffffu) | (pw1.y << 16);
      plu.w = (pw1.z & 0xffffu) | (pw1.w << 16);
      bf16x8 ph = *reinterpret_cast<bf16x8*>(&phu);
      bf16x8 pl = *reinterpret_cast<bf16x8*>(&plu);
      #pragma unroll
      for (int nf2 = 0; nf2 < 4; ++nf2) {
        int d = nf2*16 + lr;
        int di = (kc ^ (d & 7))*66 + d;
        bf16x8 vh = *reinterpret_cast<const bf16x8*>(&V_lds[0][di]);
        bf16x8 vl = *reinterpret_cast<const bf16x8*>(&V_lds[1][di]);
        oac[nf2] = __builtin_amdgcn_mfma_f32_16x16x32_bf16(ph, vh, oac[nf2], 0,0,0);
        oac[nf2] = __builtin_amdgcn_mfma_f32_16x16x32_bf16(ph, vl, oac[nf2], 0,0,0);
        oac[nf2] = __builtin_amdgcn_mfma_f32_16x16x32_bf16(pl, vh, oac[nf2], 0,0,0);
      }
    }
  }

  #pragma unroll
  for (int j = 0; j < 4; ++j) {
    float inv = 1.0f / lrow[j];
    float* op = o + (tok0 + qt*64 + w*16 + lk*4 + j) * CC + hh*HS;
    #pragma unroll
    for (int nf2 = 0; nf2 < 4; ++nf2)
      op[nf2*16 + lr] = oac[nf2][j] * inv;
  }
}

extern "C" void kernel_launch(void* const* d_in, const int* in_sizes, int n_in,
                              void* d_out, int out_size, void* d_ws, size_t ws_size,
                              hipStream_t stream) {
  const int*   idx  = (const int*)d_in[0];
  const float* tok  = (const float*)d_in[1];
  const float* pos  = (const float*)d_in[2];
  const float* Wq   = (const float*)d_in[3];
  const float* Wk   = (const float*)d_in[4];
  const float* Wv   = (const float*)d_in[5];
  const float* Wo   = (const float*)d_in[6];
  const float* bo   = (const float*)d_in[7];
  const float* ln1g = (const float*)d_in[8];
  const float* ln1b = (const float*)d_in[9];
  const float* ln2g = (const float*)d_in[10];
  const float* ln2b = (const float*)d_in[11];
  const float* W1   = (const float*)d_in[12];
  const float* b1   = (const float*)d_in[13];
  const float* W2   = (const float*)d_in[14];
  const float* b2   = (const float*)d_in[15];
  const float* lnfg = (const float*)d_in[16];
  const float* lnfb = (const float*)d_in[17];
  const float* lmw  = (const float*)d_in[18];
  const float* lmb  = (const float*)d_in[19];
  float* out = (float*)d_out;

  // d_out: x[0,32M) | h[32,64M) | qf[64,96M) | kf[96,128M); a1=[64,128M) (MLP)
  // ws (64 MB, liveness time-shared):
  //   [0,6M) bsQ | [6,12M) bsK | [12,16M) bsV          (phase A; dead after QKV gemms)
  //   [32,64M) vt (V gemm out, read by attn)
  //   after attn: [32,36M) bsO -> [32,48M) bsW1 | [48,64M) bsW2
  //   final: hf [0,32M); bsL [32,40M)
  char* ob = (char*)d_out;
  float* x  = (float*)ob;
  float* h  = (float*)(ob + ((size_t)32<<20));
  float* qf = (float*)(ob + ((size_t)64<<20));
  float* kf = (float*)(ob + ((size_t)96<<20));
  float* a1 = (float*)(ob + ((size_t)64<<20));
  char* wsb = (char*)d_ws;
  uint4* bsQ  = (uint4*)wsb;
  uint4* bsK  = (uint4*)(wsb + ((size_t) 6<<20));
  uint4* bsV  = (uint4*)(wsb + ((size_t)12<<20));
  float* vtf  = (float*)(wsb + ((size_t)32<<20));
  uint4* bsO  = (uint4*)(wsb + ((size_t)32<<20));
  uint4* bsW1 = (uint4*)(wsb + ((size_t)32<<20));
  uint4* bsW2 = (uint4*)(wsb + ((size_t)48<<20));
  uint4* bsL  = (uint4*)(wsb + ((size_t)32<<20));
  float* hf   = (float*)wsb;

  dim3 blk(256);
  dim3 g1(8,  BT/64);
  dim3 gh(16, BT/64);
  dim3 gl(32, BT/64);
  dim3 sQKV(8, 16), sW1(32, 16), sW2(8, 64), sLM(32, 16);

  embed_kernel<<<BT, blk, 0, stream>>>(idx, tok, pos, x);
  for (int l = 0; l < LL; ++l) {
    const float* Wq_l = Wq + (size_t)l*CC*CC;
    const float* Wk_l = Wk + (size_t)l*CC*CC;
    const float* Wv_l = Wv + (size_t)l*CC*CC;
    const float* Wo_l = Wo + (size_t)l*CC*CC;
    const float* W1_l = W1 + (size_t)l*CC*4*CC;
    const float* W2_l = W2 + (size_t)l*4*CC*CC;
    ln32_kernel<<<BT, blk, 0, stream>>>(x, ln1g + (size_t)l*CC, ln1b + (size_t)l*CC, h);
    bsplit_kernel<3><<<sQKV, blk, 0, stream>>>(Wq_l, bsQ, CC);
    bsplit_kernel<3><<<sQKV, blk, 0, stream>>>(Wk_l, bsK, CC);
    bsplit_kernel<2><<<sQKV, blk, 0, stream>>>(Wv_l, bsV, CC);
    gemm_kernel<3><<<g1, blk, 0, stream>>>(h, bsQ, nullptr, nullptr, qf, CC, CC, 0, 0, 8, 0, 16, 0);
    gemm_kernel<3><<<g1, blk, 0, stream>>>(h, bsK, nullptr, nullptr, kf, CC, CC, 0, 0, 8, 0, 16, 0);
    gemm_kernel<2><<<g1, blk, 0, stream>>>(h, bsV, nullptr, nullptr, vtf, CC, CC, 0, 0, 8, 0, 16, 1);
    attn_mfma_kernel<<<BB*HH*16, blk, 0, stream>>>(qf, kf, vtf, h);
    bsplit_kernel<2><<<sQKV, blk, 0, stream>>>(Wo_l, bsO, CC);
    gemm_kernel<2><<<g1, blk, 0, stream>>>(h, bsO, bo + (size_t)l*CC, x, x, CC, CC, 0, 0, 8, 0, 16, 0);
    ln32_kernel<<<BT, blk, 0, stream>>>(x, ln2g + (size_t)l*CC, ln2b + (size_t)l*CC, h);
    bsplit_kernel<2><<<sW1, blk, 0, stream>>>(W1_l, bsW1, 4*CC);
    bsplit_kernel<2><<<sW2, blk, 0, stream>>>(W2_l, bsW2, CC);
    gemm_kernel<2><<<gh, blk, 0, stream>>>(h,  bsW1, b1 + (size_t)l*4*CC,        nullptr, a1, CC,   2048, 1,  0, 32,  0, 16, 0);
    gemm_kernel<2><<<g1, blk, 0, stream>>>(a1, bsW2, b2 + (size_t)l*CC,          x, x,        2048, CC,   0,  0,  8,  0, 64, 0);
    gemm_kernel<2><<<gh, blk, 0, stream>>>(h,  bsW1, b1 + (size_t)l*4*CC + 2048, nullptr, a1, CC,   2048, 1, 16, 32,  0, 16, 0);
    gemm_kernel<2><<<g1, blk, 0, stream>>>(a1, bsW2, nullptr,                    x, x,        2048, CC,   0,  0,  8, 32, 64, 0);
  }
  ln32_kernel<<<BT, blk, 0, stream>>>(x, lnfg, lnfb, hf);
  bsplit_kernel<1><<<sLM, blk, 0, stream>>>(lmw, bsL, VV);
  gemm_kernel<1><<<gl, blk, 0, stream>>>(hf, bsL, lmb, nullptr, out, CC, VV, 0, 0, 32, 0, 16, 0);
}

// Round 12
// 7412.749 us; speedup vs baseline: 7.4187x; 1.0019x over previous
//
#include <hip/hip_runtime.h>

#define LL 6
#define BB 8
#define TT 1024
#define CC 1024
#define HH 16
#define HS 64
#define VV 4096
#define BT (BB*TT)

typedef __attribute__((ext_vector_type(4))) float f32x4;
typedef __attribute__((ext_vector_type(8))) short bf16x8;

__device__ __forceinline__ float bf2f(unsigned short u) {
  union { unsigned int u; float f; } v; v.u = ((unsigned int)u) << 16; return v.f;
}
__device__ __forceinline__ unsigned short rne16(float f) {
  unsigned u = __float_as_uint(f);
  return (unsigned short)((u + 0x7fffu + ((u >> 16) & 1u)) >> 16);
}

// ---------------- embedding ----------------
__global__ __launch_bounds__(256) void embed_kernel(
    const int* __restrict__ idx, const float* __restrict__ tok,
    const float* __restrict__ pos, float* __restrict__ x) {
  int bt = blockIdx.x;
  int t = bt & (TT - 1);
  int id = idx[bt];
  float4 te = reinterpret_cast<const float4*>(tok)[(size_t)id * (CC/4) + threadIdx.x];
  float4 pe = reinterpret_cast<const float4*>(pos)[(size_t)t * (CC/4) + threadIdx.x];
  float4 r; r.x = te.x+pe.x; r.y = te.y+pe.y; r.z = te.z+pe.z; r.w = te.w+pe.w;
  reinterpret_cast<float4*>(x)[(size_t)bt * (CC/4) + threadIdx.x] = r;
}

// ---------------- layernorm fp32->fp32 (R4-proven) ----------------
__global__ __launch_bounds__(256) void ln32_kernel(
    const float* __restrict__ x, const float* __restrict__ g,
    const float* __restrict__ b, float* __restrict__ out) {
  __shared__ float red[8];
  int row = blockIdx.x, tid = threadIdx.x;
  float4 v = reinterpret_cast<const float4*>(x)[(size_t)row * (CC/4) + tid];
  float s  = v.x+v.y+v.z+v.w;
  float ss = v.x*v.x+v.y*v.y+v.z*v.z+v.w*v.w;
  #pragma unroll
  for (int off = 32; off; off >>= 1) { s += __shfl_xor(s, off); ss += __shfl_xor(ss, off); }
  if ((tid & 63) == 0) { red[tid>>6] = s; red[4+(tid>>6)] = ss; }
  __syncthreads();
  s  = red[0]+red[1]+red[2]+red[3];
  ss = red[4]+red[5]+red[6]+red[7];
  float mu = s * (1.f/CC);
  float rs = rsqrtf(ss*(1.f/CC) - mu*mu + 1e-5f);
  float4 gg = reinterpret_cast<const float4*>(g)[tid];
  float4 bb = reinterpret_cast<const float4*>(b)[tid];
  float4 o;
  o.x = (v.x-mu)*rs*gg.x + bb.x;
  o.y = (v.y-mu)*rs*gg.y + bb.y;
  o.z = (v.z-mu)*rs*gg.z + bb.z;
  o.w = (v.w-mu)*rs*gg.w + bb.w;
  reinterpret_cast<float4*>(out)[(size_t)row * (CC/4) + tid] = o;
}

// ---- split 8 fp32 into 3 truncated-bf16 planes (R7-proven) ----
struct Oct3 { uint4 p0, p1, p2; };
__device__ __forceinline__ unsigned pk2(unsigned lo, unsigned hi) {
  return (lo >> 16) | (hi & 0xffff0000u);
}
__device__ __forceinline__ Oct3 split8(const float* f) {
  unsigned a0[8], a1[8], a2[8];
  #pragma unroll
  for (int e = 0; e < 8; ++e) {
    float v = f[e];
    unsigned u = __float_as_uint(v);
    a0[e] = u;
    float r = v - __uint_as_float(u & 0xffff0000u);
    unsigned ur = __float_as_uint(r);
    a1[e] = ur;
    float r2 = r - __uint_as_float(ur & 0xffff0000u);
    a2[e] = __float_as_uint(r2);
  }
  Oct3 o;
  o.p0 = make_uint4(pk2(a0[0],a0[1]), pk2(a0[2],a0[3]), pk2(a0[4],a0[5]), pk2(a0[6],a0[7]));
  o.p1 = make_uint4(pk2(a1[0],a1[1]), pk2(a1[2],a1[3]), pk2(a1[4],a1[5]), pk2(a1[6],a1[7]));
  o.p2 = make_uint4(pk2(a2[0],a2[1]), pk2(a2[2],a2[3]), pk2(a2[4],a2[5]), pk2(a2[6],a2[7]));
  return o;
}

// ---- split 8 fp32 into 2 RNE bf16 planes (R10-proven) ----
struct Oct2 { uint4 p0, p1; };
__device__ __forceinline__ Oct2 split8_rne2(const float* f) {
  unsigned h0[8], h1[8];
  #pragma unroll
  for (int e = 0; e < 8; ++e) {
    h0[e] = rne16(f[e]);
    float r = f[e] - bf2f((unsigned short)h0[e]);
    h1[e] = rne16(r);
  }
  Oct2 o;
  o.p0 = make_uint4(h0[0]|(h0[1]<<16), h0[2]|(h0[3]<<16), h0[4]|(h0[5]<<16), h0[6]|(h0[7]<<16));
  o.p1 = make_uint4(h1[0]|(h1[1]<<16), h1[2]|(h1[3]<<16), h1[4]|(h1[5]<<16), h1[6]|(h1[7]<<16));
  return o;
}
__device__ __forceinline__ uint4 pack8_rne(const float* f) {
  unsigned h[8];
  #pragma unroll
  for (int e = 0; e < 8; ++e) h[e] = rne16(f[e]);
  return make_uint4(h[0]|(h[1]<<16), h[2]|(h[3]<<16), h[4]|(h[5]<<16), h[6]|(h[7]<<16));
}

// ---------------- A pre-split: fp32 [M x lda] -> NP planes, linear tile layout ----
// out[plane][(mt*ktT + kt)*512 + c] where c = row*8 + sl (NO swizzle; gemm applies
// the XOR swizzle at its LDS write). Grid (mtiles, ktTotal).
template<int NP>
__global__ __launch_bounds__(256) void asplit_kernel(
    const float* __restrict__ A, int lda, uint4* __restrict__ outp) {
  int mt = blockIdx.x, kt = blockIdx.y;
  size_t aPS = (size_t)gridDim.x * gridDim.y * 512;
  int tid = threadIdx.x;
  #pragma unroll
  for (int i = 0; i < 2; ++i) {
    int c = tid + i * 256;
    int row = c >> 3, sl = c & 7;
    const float4* ap = reinterpret_cast<const float4*>(
        A + (size_t)(mt*64 + row) * lda + kt*64 + sl*8);
    float4 x0 = ap[0], x1 = ap[1];
    float f[8] = {x0.x,x0.y,x0.z,x0.w,x1.x,x1.y,x1.z,x1.w};
    size_t di = ((size_t)(mt * gridDim.y + kt)) * 512 + c;
    if (NP == 3) {
      Oct3 o = split8(f);
      outp[di] = o.p0; outp[aPS+di] = o.p1; outp[2*aPS+di] = o.p2;
    } else {
      Oct2 o = split8_rne2(f);
      outp[di] = o.p0; outp[aPS+di] = o.p1;
    }
  }
}

// ---------------- B pre-split (R11-proven; + ntile0/ntTotal) ----------------
template<int NP>
__global__ __launch_bounds__(256) void bsplit_kernel(
    const float* __restrict__ Bw, uint4* __restrict__ outp, int ldb,
    int ntile0, int ntTotal) {
  int ntile = ntile0 + blockIdx.x, kt = blockIdx.y;
  size_t planeStride = (size_t)ntTotal * gridDim.y * 1024;
  int tid = threadIdx.x;
  int bcol = tid & 127, bkcg = tid >> 7;
  #pragma unroll
  for (int g = 0; g < 4; ++g) {
    int kc = bkcg*4 + g;
    float f[8];
    #pragma unroll
    for (int j = 0; j < 8; ++j)
      f[j] = Bw[(size_t)(kt*64 + kc*8 + j) * ldb + blockIdx.x*128 + bcol];
    size_t di = (((size_t)ntile * gridDim.y + kt) * 8 + kc) * 128 + bcol;
    if (NP == 3) {
      Oct3 o = split8(f);
      outp[di] = o.p0; outp[planeStride+di] = o.p1; outp[2*planeStride+di] = o.p2;
    } else if (NP == 2) {
      Oct2 o = split8_rne2(f);
      outp[di] = o.p0; outp[planeStride+di] = o.p1;
    } else {
      outp[di] = pack8_rne(f);
    }
  }
}

// ---------------- fp32-emulation MFMA GEMM, pre-split A and B ----------------
// ASP=true: A staged by pure copies from asplit buffer (swizzle at LDS write).
// ASP=false: A fp32, split on the fly (W2 / logits).
// vtmode=1: write output transposed as vt[b][h][d][t].
template<int NP, bool ASP>
__global__ __launch_bounds__(256) void gemm_kernel(
    const float* __restrict__ A, int lda,
    const uint4* __restrict__ Asp, size_t aPS,
    const uint4* __restrict__ Bs,
    const float* __restrict__ bias, const float* __restrict__ res,
    float* __restrict__ outf, int K, int ldc, int relu,
    int ntile0, int ntTotal, int kt0, int ktTotal, int vtmode) {
  __shared__ uint4 lds_a[NP][64*8];
  __shared__ uint4 lds_b[NP][8*128];
  int tid = threadIdx.x;
  int m0 = blockIdx.y * 64;
  int n0 = blockIdx.x * 128;
  int ntg = ntile0 + blockIdx.x;
  size_t planeStride = (size_t)ntTotal * ktTotal * 1024;
  int lane = tid & 63, wid = tid >> 6;
  int wm = wid >> 1, wn = wid & 1;
  int lr = lane & 15, lk = lane >> 4;
  int bcol = tid & 127, bkcg = tid >> 7;

  f32x4 acc[2][4];
  #pragma unroll
  for (int m = 0; m < 2; ++m)
    #pragma unroll
    for (int n = 0; n < 4; ++n)
      acc[m][n] = (f32x4){0.f, 0.f, 0.f, 0.f};

  for (int k0 = 0; k0 < K; k0 += 64) {
    if (ASP) {
      size_t abase = ((size_t)blockIdx.y * (unsigned)(K >> 6) + (k0 >> 6)) * 512;
      #pragma unroll
      for (int p = 0; p < NP; ++p)
        #pragma unroll
        for (int i = 0; i < 2; ++i) {
          int c = tid + i*256;
          int sw = (c & ~7) | ((c & 7) ^ ((c >> 3) & 7));
          lds_a[p][sw] = Asp[p*aPS + abase + c];
        }
    } else {
      #pragma unroll
      for (int i = 0; i < 2; ++i) {
        int c = tid + i * 256;
        int row = c >> 3, sl = c & 7;
        const float4* ap = reinterpret_cast<const float4*>(
            A + (size_t)(m0+row)*lda + k0 + sl*8);
        float4 x0 = ap[0], x1 = ap[1];
        float f[8] = {x0.x,x0.y,x0.z,x0.w,x1.x,x1.y,x1.z,x1.w};
        int di = row*8 + (sl ^ (row & 7));
        if (NP == 3) {
          Oct3 o = split8(f);
          lds_a[0][di] = o.p0; lds_a[1][di] = o.p1; lds_a[2][di] = o.p2;
        } else if (NP == 2) {
          Oct2 o = split8_rne2(f);
          lds_a[0][di] = o.p0; lds_a[1][di] = o.p1;
        } else {
          lds_a[0][di] = pack8_rne(f);
        }
      }
    }
    {
      int ktg = kt0 + (k0 >> 6);
      #pragma unroll
      for (int g = 0; g < 4; ++g) {
        int kc = bkcg*4 + g;
        size_t di = (((size_t)ntg * ktTotal + ktg) * 8 + kc) * 128 + bcol;
        lds_b[0][kc*128 + bcol] = Bs[di];
        if (NP >= 2) lds_b[1][kc*128 + bcol] = Bs[planeStride + di];
        if (NP == 3) lds_b[2][kc*128 + bcol] = Bs[2*planeStride + di];
      }
    }
    __syncthreads();
    #pragma unroll
    for (int ks = 0; ks < 2; ++ks) {
      int kc = ks*4 + lk;
      bf16x8 af[NP][2], bfr[NP][4];
      #pragma unroll
      for (int m = 0; m < 2; ++m) {
        int row = wm*32 + m*16 + lr;
        int si = row*8 + (kc ^ (row & 7));
        #pragma unroll
        for (int p = 0; p < NP; ++p)
          af[p][m] = reinterpret_cast<const bf16x8*>(lds_a[p])[si];
      }
      #pragma unroll
      for (int n = 0; n < 4; ++n) {
        int si = kc*128 + wn*64 + n*16 + lr;
        #pragma unroll
        for (int p = 0; p < NP; ++p)
          bfr[p][n] = reinterpret_cast<const bf16x8*>(lds_b[p])[si];
      }
      #pragma unroll
      for (int m = 0; m < 2; ++m)
        #pragma unroll
        for (int n = 0; n < 4; ++n) {
          acc[m][n] = __builtin_amdgcn_mfma_f32_16x16x32_bf16(af[0][m], bfr[0][n], acc[m][n], 0, 0, 0);
          if (NP >= 2) {
            acc[m][n] = __builtin_amdgcn_mfma_f32_16x16x32_bf16(af[0][m], bfr[1][n], acc[m][n], 0, 0, 0);
            acc[m][n] = __builtin_amdgcn_mfma_f32_16x16x32_bf16(af[1][m], bfr[0][n], acc[m][n], 0, 0, 0);
            acc[m][n] = __builtin_amdgcn_mfma_f32_16x16x32_bf16(af[1][m], bfr[1][n], acc[m][n], 0, 0, 0);
          }
          if (NP == 3) {
            acc[m][n] = __builtin_amdgcn_mfma_f32_16x16x32_bf16(af[2][m], bfr[0][n], acc[m][n], 0, 0, 0);
            acc[m][n] = __builtin_amdgcn_mfma_f32_16x16x32_bf16(af[0][m], bfr[2][n], acc[m][n], 0, 0, 0);
          }
        }
    }
    __syncthreads();
  }

  if (vtmode) {
    #pragma unroll
    for (int m = 0; m < 2; ++m) {
      int t0 = m0 + wm*32 + m*16 + lk*4;
      int bq = t0 >> 10, tb = t0 & (TT-1);
      #pragma unroll
      for (int n = 0; n < 4; ++n) {
        int col = n0 + wn*64 + n*16 + lr;
        float4 val;
        val.x = acc[m][n][0]; val.y = acc[m][n][1];
        val.z = acc[m][n][2]; val.w = acc[m][n][3];
        *reinterpret_cast<float4*>(
            outf + (((size_t)(bq*HH + (col>>6)))*HS + (col&63))*TT + tb) = val;
      }
    }
  } else {
    #pragma unroll
    for (int m = 0; m < 2; ++m) {
      #pragma unroll
      for (int n = 0; n < 4; ++n) {
        int col = n0 + wn*64 + n*16 + lr;
        float bv = bias ? bias[col] : 0.f;
        #pragma unroll
        for (int j = 0; j < 4; ++j) {
          int row = m0 + wm*32 + m*16 + lk*4 + j;
          float vv = acc[m][n][j] + bv;
          if (relu) vv = fmaxf(vv, 0.f);
          size_t off = (size_t)row * ldc + col;
          if (res) vv += res[off];
          outf[off] = vv;
        }
      }
    }
  }
}

// ---------------- MFMA flash attention (R9-proven; qk-combined addressing) ------
// q = qk cols [0,1024), k = qk cols [1024,2048), row stride 2048.
// Output written into the q-half (safe: each block reads its own Q before writing).
__global__ __launch_bounds__(256) void attn_mfma_kernel(
    float* __restrict__ qk, const float* __restrict__ vt) {
  __shared__ uint4 K_lds[3][64*8];
  __shared__ uint4 V_lds[2][8*66];
  __shared__ unsigned P_lds[64*68];
  int tid = threadIdx.x, lane = tid & 63, w = tid >> 6;
  int rid = blockIdx.x;
  int qt = rid & 15, hh = (rid >> 4) & 15, b = rid >> 8;
  int lr = lane & 15, lk = lane >> 4;
  const size_t tok0 = (size_t)b * TT;

  bf16x8 qa[2][3];
  {
    const float* qp = qk + (tok0 + qt*64 + w*16 + lr) * 2048 + hh*HS;
    #pragma unroll
    for (int ks = 0; ks < 2; ++ks) {
      const float4* p4 = reinterpret_cast<const float4*>(qp + ks*32 + lk*8);
      float4 a = p4[0], c = p4[1];
      float f[8] = {a.x,a.y,a.z,a.w,c.x,c.y,c.z,c.w};
      Oct3 ot = split8(f);
      qa[ks][0] = *reinterpret_cast<bf16x8*>(&ot.p0);
      qa[ks][1] = *reinterpret_cast<bf16x8*>(&ot.p1);
      qa[ks][2] = *reinterpret_cast<bf16x8*>(&ot.p2);
    }
  }

  float mrow[4] = {-3.0e38f,-3.0e38f,-3.0e38f,-3.0e38f};
  float lrow[4] = {0.f,0.f,0.f,0.f};
  f32x4 oac[4];
  #pragma unroll
  for (int n = 0; n < 4; ++n) oac[n] = (f32x4){0.f,0.f,0.f,0.f};

  for (int kt = 0; kt <= qt; ++kt) {
    __syncthreads();
    #pragma unroll
    for (int pp = 0; pp < 2; ++pp) {
      int c = tid + pp*256;
      int r = c >> 3, sl = c & 7;
      const float4* kp = reinterpret_cast<const float4*>(
          qk + (tok0 + kt*64 + r) * 2048 + 1024 + hh*HS + sl*8);
      float4 x0 = kp[0], x1 = kp[1];
      float f[8] = {x0.x,x0.y,x0.z,x0.w,x1.x,x1.y,x1.z,x1.w};
      Oct3 ot = split8(f);
      int di = r*8 + (sl ^ (r & 7));
      K_lds[0][di] = ot.p0; K_lds[1][di] = ot.p1; K_lds[2][di] = ot.p2;
    }
    #pragma unroll
    for (int pp = 0; pp < 2; ++pp) {
      int c = tid + pp*256;
      int kc = c & 7, d = c >> 3;
      const float4* vp = reinterpret_cast<const float4*>(
          vt + (((size_t)(b*HH+hh)*HS + d))*TT + kt*64 + kc*8);
      float4 x0 = vp[0], x1 = vp[1];
      float f[8] = {x0.x,x0.y,x0.z,x0.w,x1.x,x1.y,x1.z,x1.w};
      Oct2 ot = split8_rne2(f);
      int di = (kc ^ (d & 7))*66 + d;
      V_lds[0][di] = ot.p0; V_lds[1][di] = ot.p1;
    }
    __syncthreads();

    f32x4 sfr[4];
    #pragma unroll
    for (int nf = 0; nf < 4; ++nf) sfr[nf] = (f32x4){0.f,0.f,0.f,0.f};
    #pragma unroll
    for (int ks = 0; ks < 2; ++ks) {
      int kc = ks*4 + lk;
      #pragma unroll
      for (int nf = 0; nf < 4; ++nf) {
        int row = nf*16 + lr;
        int si = row*8 + (kc ^ (row & 7));
        bf16x8 k0 = *reinterpret_cast<const bf16x8*>(&K_lds[0][si]);
        bf16x8 k1 = *reinterpret_cast<const bf16x8*>(&K_lds[1][si]);
        bf16x8 k2 = *reinterpret_cast<const bf16x8*>(&K_lds[2][si]);
        sfr[nf] = __builtin_amdgcn_mfma_f32_16x16x32_bf16(qa[ks][0], k0, sfr[nf], 0,0,0);
        sfr[nf] = __builtin_amdgcn_mfma_f32_16x16x32_bf16(qa[ks][0], k1, sfr[nf], 0,0,0);
        sfr[nf] = __builtin_amdgcn_mfma_f32_16x16x32_bf16(qa[ks][1], k0, sfr[nf], 0,0,0);
        sfr[nf] = __builtin_amdgcn_mfma_f32_16x16x32_bf16(qa[ks][1], k1, sfr[nf], 0,0,0);
        sfr[nf] = __builtin_amdgcn_mfma_f32_16x16x32_bf16(qa[ks][2], k0, sfr[nf], 0,0,0);
        sfr[nf] = __builtin_amdgcn_mfma_f32_16x16x32_bf16(qa[ks][0], k2, sfr[nf], 0,0,0);
      }
    }
    #pragma unroll
    for (int nf = 0; nf < 4; ++nf)
      #pragma unroll
      for (int j = 0; j < 4; ++j) {
        float s = sfr[nf][j] * 8.0f;
        if (kt == qt && (nf*16 + lr) > (w*16 + lk*4 + j)) s = -3.0e38f;
        sfr[nf][j] = s;
      }
    float alpha[4], tsum[4];
    #pragma unroll
    for (int j = 0; j < 4; ++j) {
      float mx = fmaxf(fmaxf(sfr[0][j], sfr[1][j]), fmaxf(sfr[2][j], sfr[3][j]));
      mx = fmaxf(mx, __shfl_xor(mx, 1));
      mx = fmaxf(mx, __shfl_xor(mx, 2));
      mx = fmaxf(mx, __shfl_xor(mx, 4));
      mx = fmaxf(mx, __shfl_xor(mx, 8));
      float mnew = fmaxf(mrow[j], mx);
      alpha[j] = __expf(mrow[j] - mnew);
      mrow[j] = mnew;
      tsum[j] = 0.f;
    }
    #pragma unroll
    for (int nf = 0; nf < 4; ++nf)
      #pragma unroll
      for (int j = 0; j < 4; ++j) {
        float p = __expf(sfr[nf][j] - mrow[j]);
        tsum[j] += p;
        unsigned u = __float_as_uint(p);
        float r = p - __uint_as_float(u & 0xffff0000u);
        unsigned pw = (u & 0xffff0000u) | (__float_as_uint(r) >> 16);
        int qrow = w*16 + lk*4 + j;
        int kcol = nf*16 + lr;
        P_lds[qrow*68 + (((kcol>>3) ^ (qrow & 7)))*8 + (kcol & 7)] = pw;
      }
    #pragma unroll
    for (int j = 0; j < 4; ++j) {
      float ts = tsum[j];
      ts += __shfl_xor(ts, 1);
      ts += __shfl_xor(ts, 2);
      ts += __shfl_xor(ts, 4);
      ts += __shfl_xor(ts, 8);
      lrow[j] = lrow[j]*alpha[j] + ts;
      oac[0][j] *= alpha[j]; oac[1][j] *= alpha[j];
      oac[2][j] *= alpha[j]; oac[3][j] *= alpha[j];
    }
    __syncthreads();

    #pragma unroll
    for (int ks = 0; ks < 2; ++ks) {
      int kc = ks*4 + lk;
      int prow = w*16 + lr;
      const uint4* pp4 = reinterpret_cast<const uint4*>(
          &P_lds[prow*68 + ((kc ^ (prow & 7)))*8]);
      uint4 pw0 = pp4[0], pw1 = pp4[1];
      uint4 phu, plu;
      phu.x = (pw0.x>>16) | (pw0.y & 0xffff0000u);
      phu.y = (pw0.z>>16) | (pw0.w & 0xffff0000u);
      phu.z = (pw1.x>>16) | (pw1.y & 0xffff0000u);
      phu.w = (pw1.z>>16) | (pw1.w & 0xffff0000u);
      plu.x = (pw0.x & 0xffffu) | (pw0.y << 16);
      plu.y = (pw0.z & 0xffffu) | (pw0.w << 16);
      plu.z = (pw1.x & 0xffffu) | (pw1.y << 16);
      plu.w = (pw1.z & 0xffffu) | (pw1.w << 16);
      bf16x8 ph = *reinterpret_cast<bf16x8*>(&phu);
      bf16x8 pl = *reinterpret_cast<bf16x8*>(&plu);
      #pragma unroll
      for (int nf2 = 0; nf2 < 4; ++nf2) {
        int d = nf2*16 + lr;
        int di = (kc ^ (d & 7))*66 + d;
        bf16x8 vh = *reinterpret_cast<const bf16x8*>(&V_lds[0][di]);
        bf16x8 vl = *reinterpret_cast<const bf16x8*>(&V_lds[1][di]);
        oac[nf2] = __builtin_amdgcn_mfma_f32_16x16x32_bf16(ph, vh, oac[nf2], 0,0,0);
        oac[nf2] = __builtin_amdgcn_mfma_f32_16x16x32_bf16(ph, vl, oac[nf2], 0,0,0);
        oac[nf2] = __builtin_amdgcn_mfma_f32_16x16x32_bf16(pl, vh, oac[nf2], 0,0,0);
      }
    }
  }

  #pragma unroll
  for (int j = 0; j < 4; ++j) {
    float inv = 1.0f / lrow[j];
    float* op = qk + (tok0 + qt*64 + w*16 + lk*4 + j) * 2048 + hh*HS;
    #pragma unroll
    for (int nf2 = 0; nf2 < 4; ++nf2)
      op[nf2*16 + lr] = oac[nf2][j] * inv;
  }
}

extern "C" void kernel_launch(void* const* d_in, const int* in_sizes, int n_in,
                              void* d_out, int out_size, void* d_ws, size_t ws_size,
                              hipStream_t stream) {
  const int*   idx  = (const int*)d_in[0];
  const float* tok  = (const float*)d_in[1];
  const float* pos  = (const float*)d_in[2];
  const float* Wq   = (const float*)d_in[3];
  const float* Wk   = (const float*)d_in[4];
  const float* Wv   = (const float*)d_in[5];
  const float* Wo   = (const float*)d_in[6];
  const float* bo   = (const float*)d_in[7];
  const float* ln1g = (const float*)d_in[8];
  const float* ln1b = (const float*)d_in[9];
  const float* ln2g = (const float*)d_in[10];
  const float* ln2b = (const float*)d_in[11];
  const float* W1   = (const float*)d_in[12];
  const float* b1   = (const float*)d_in[13];
  const float* W2   = (const float*)d_in[14];
  const float* b2   = (const float*)d_in[15];
  const float* lnfg = (const float*)d_in[16];
  const float* lnfb = (const float*)d_in[17];
  const float* lmw  = (const float*)d_in[18];
  const float* lmb  = (const float*)d_in[19];
  float* out = (float*)d_out;

  // d_out: x[0,32M) | h/vt[32,64M) | qk (8192x2048) / a1 [64,128M)
  // ws (64 MB, time-shared; liveness checked):
  //  phase A: aspH (3pl, 48M) [0,48) | bsQK (12M) [48,60) | bsV (4M) [60,64)
  //  phase B: aspH2 (2pl, 32M) [0,32) | bsO (4M) [32,36)
  //  phase C: aspH3 (2pl, 32M) [0,32) | bsW1 (16M) [32,48) | bsW2 (16M) [48,64)
  //  final:   hf [0,32) | bsL (8M) [32,40)
  char* ob = (char*)d_out;
  float* x  = (float*)ob;
  float* h  = (float*)(ob + ((size_t)32<<20));
  float* vt = h;
  float* qk = (float*)(ob + ((size_t)64<<20));
  float* a1 = (float*)(ob + ((size_t)64<<20));
  char* wsb = (char*)d_ws;
  uint4* aspH  = (uint4*)wsb;
  uint4* bsQK  = (uint4*)(wsb + ((size_t)48<<20));
  uint4* bsV   = (uint4*)(wsb + ((size_t)60<<20));
  uint4* aspH2 = (uint4*)wsb;
  uint4* bsO   = (uint4*)(wsb + ((size_t)32<<20));
  uint4* aspH3 = (uint4*)wsb;
  uint4* bsW1  = (uint4*)(wsb + ((size_t)32<<20));
  uint4* bsW2  = (uint4*)(wsb + ((size_t)48<<20));
  float* hf    = (float*)wsb;
  uint4* bsL   = (uint4*)(wsb + ((size_t)32<<20));
  const size_t aPSh = (size_t)128 * 16 * 512;   // uint4 per A plane (16 MB)

  dim3 blk(256);
  dim3 gQK(16, BT/64), g1(8, BT/64), gh(16, BT/64), gl(32, BT/64);
  dim3 sA(128, 16), s8(8, 16), sW1(32, 16), sW2(8, 64), sLM(32, 16);

  embed_kernel<<<BT, blk, 0, stream>>>(idx, tok, pos, x);
  for (int l = 0; l < LL; ++l) {
    const float* Wq_l = Wq + (size_t)l*CC*CC;
    const float* Wk_l = Wk + (size_t)l*CC*CC;
    const float* Wv_l = Wv + (size_t)l*CC*CC;
    const float* Wo_l = Wo + (size_t)l*CC*CC;
    const float* W1_l = W1 + (size_t)l*CC*4*CC;
    const float* W2_l = W2 + (size_t)l*4*CC*CC;
    ln32_kernel<<<BT, blk, 0, stream>>>(x, ln1g + (size_t)l*CC, ln1b + (size_t)l*CC, h);
    asplit_kernel<3><<<sA, blk, 0, stream>>>(h, CC, aspH);
    bsplit_kernel<3><<<s8, blk, 0, stream>>>(Wq_l, bsQK, CC, 0, 16);
    bsplit_kernel<3><<<s8, blk, 0, stream>>>(Wk_l, bsQK, CC, 8, 16);
    bsplit_kernel<2><<<s8, blk, 0, stream>>>(Wv_l, bsV, CC, 0, 8);
    gemm_kernel<3,true><<<gQK, blk, 0, stream>>>(nullptr, 0, aspH, aPSh, bsQK,
        nullptr, nullptr, qk, CC, 2048, 0, 0, 16, 0, 16, 0);
    gemm_kernel<2,true><<<g1, blk, 0, stream>>>(nullptr, 0, aspH, aPSh, bsV,
        nullptr, nullptr, vt, CC, CC, 0, 0, 8, 0, 16, 1);
    attn_mfma_kernel<<<BB*HH*16, blk, 0, stream>>>(qk, vt);
    asplit_kernel<2><<<sA, blk, 0, stream>>>(qk, 2048, aspH2);
    bsplit_kernel<2><<<s8, blk, 0, stream>>>(Wo_l, bsO, CC, 0, 8);
    gemm_kernel<2,true><<<g1, blk, 0, stream>>>(nullptr, 0, aspH2, aPSh, bsO,
        bo + (size_t)l*CC, x, x, CC, CC, 0, 0, 8, 0, 16, 0);
    ln32_kernel<<<BT, blk, 0, stream>>>(x, ln2g + (size_t)l*CC, ln2b + (size_t)l*CC, h);
    asplit_kernel<2><<<sA, blk, 0, stream>>>(h, CC, aspH3);
    bsplit_kernel<2><<<sW1, blk, 0, stream>>>(W1_l, bsW1, 4*CC, 0, 32);
    bsplit_kernel<2><<<sW2, blk, 0, stream>>>(W2_l, bsW2, CC, 0, 8);
    gemm_kernel<2,true><<<gh, blk, 0, stream>>>(nullptr, 0, aspH3, aPSh, bsW1,
        b1 + (size_t)l*4*CC, nullptr, a1, CC, 2048, 1, 0, 32, 0, 16, 0);
    gemm_kernel<2,false><<<g1, blk, 0, stream>>>(a1, 2048, nullptr, 0, bsW2,
        b2 + (size_t)l*CC, x, x, 2048, CC, 0, 0, 8, 0, 64, 0);
    gemm_kernel<2,true><<<gh, blk, 0, stream>>>(nullptr, 0, aspH3, aPSh, bsW1,
        b1 + (size_t)l*4*CC + 2048, nullptr, a1, CC, 2048, 1, 16, 32, 0, 16, 0);
    gemm_kernel<2,false><<<g1, blk, 0, stream>>>(a1, 2048, nullptr, 0, bsW2,
        nullptr, x, x, 2048, CC, 0, 0, 8, 32, 64, 0);
  }
  ln32_kernel<<<BT, blk, 0, stream>>>(x, lnfg, lnfb, hf);
  bsplit_kernel<1><<<sLM, blk, 0, stream>>>(lmw, bsL, VV, 0, 32);
  gemm_kernel<1,false><<<gl, blk, 0, stream>>>(hf, CC, nullptr, 0, bsL,
      lmb, nullptr, out, CC, VV, 0, 0, 32, 0, 16, 0);
}

// Round 13
// 6806.322 us; speedup vs baseline: 8.0797x; 1.0891x over previous
//
#include <hip/hip_runtime.h>

#define LL 6
#define BB 8
#define TT 1024
#define CC 1024
#define HH 16
#define HS 64
#define VV 4096
#define BT (BB*TT)

typedef __attribute__((ext_vector_type(4))) float f32x4;
typedef __attribute__((ext_vector_type(8))) short bf16x8;

__device__ __forceinline__ float bf2f(unsigned short u) {
  union { unsigned int u; float f; } v; v.u = ((unsigned int)u) << 16; return v.f;
}
__device__ __forceinline__ unsigned short rne16(float f) {
  unsigned u = __float_as_uint(f);
  return (unsigned short)((u + 0x7fffu + ((u >> 16) & 1u)) >> 16);
}
__device__ __forceinline__ void gld16(const uint4* g, uint4* l) {
  __builtin_amdgcn_global_load_lds(
      (const __attribute__((address_space(1))) void*)g,
      (__attribute__((address_space(3))) void*)l, 16, 0, 0);
}

// ---------------- embedding ----------------
__global__ __launch_bounds__(256) void embed_kernel(
    const int* __restrict__ idx, const float* __restrict__ tok,
    const float* __restrict__ pos, float* __restrict__ x) {
  int bt = blockIdx.x;
  int t = bt & (TT - 1);
  int id = idx[bt];
  float4 te = reinterpret_cast<const float4*>(tok)[(size_t)id * (CC/4) + threadIdx.x];
  float4 pe = reinterpret_cast<const float4*>(pos)[(size_t)t * (CC/4) + threadIdx.x];
  float4 r; r.x = te.x+pe.x; r.y = te.y+pe.y; r.z = te.z+pe.z; r.w = te.w+pe.w;
  reinterpret_cast<float4*>(x)[(size_t)bt * (CC/4) + threadIdx.x] = r;
}

// ---------------- layernorm fp32->fp32 (R4-proven) ----------------
__global__ __launch_bounds__(256) void ln32_kernel(
    const float* __restrict__ x, const float* __restrict__ g,
    const float* __restrict__ b, float* __restrict__ out) {
  __shared__ float red[8];
  int row = blockIdx.x, tid = threadIdx.x;
  float4 v = reinterpret_cast<const float4*>(x)[(size_t)row * (CC/4) + tid];
  float s  = v.x+v.y+v.z+v.w;
  float ss = v.x*v.x+v.y*v.y+v.z*v.z+v.w*v.w;
  #pragma unroll
  for (int off = 32; off; off >>= 1) { s += __shfl_xor(s, off); ss += __shfl_xor(ss, off); }
  if ((tid & 63) == 0) { red[tid>>6] = s; red[4+(tid>>6)] = ss; }
  __syncthreads();
  s  = red[0]+red[1]+red[2]+red[3];
  ss = red[4]+red[5]+red[6]+red[7];
  float mu = s * (1.f/CC);
  float rs = rsqrtf(ss*(1.f/CC) - mu*mu + 1e-5f);
  float4 gg = reinterpret_cast<const float4*>(g)[tid];
  float4 bb = reinterpret_cast<const float4*>(b)[tid];
  float4 o;
  o.x = (v.x-mu)*rs*gg.x + bb.x;
  o.y = (v.y-mu)*rs*gg.y + bb.y;
  o.z = (v.z-mu)*rs*gg.z + bb.z;
  o.w = (v.w-mu)*rs*gg.w + bb.w;
  reinterpret_cast<float4*>(out)[(size_t)row * (CC/4) + tid] = o;
}

// ---- split 8 fp32 into 3 truncated-bf16 planes (R7-proven) ----
struct Oct3 { uint4 p0, p1, p2; };
__device__ __forceinline__ unsigned pk2(unsigned lo, unsigned hi) {
  return (lo >> 16) | (hi & 0xffff0000u);
}
__device__ __forceinline__ Oct3 split8(const float* f) {
  unsigned a0[8], a1[8], a2[8];
  #pragma unroll
  for (int e = 0; e < 8; ++e) {
    float v = f[e];
    unsigned u = __float_as_uint(v);
    a0[e] = u;
    float r = v - __uint_as_float(u & 0xffff0000u);
    unsigned ur = __float_as_uint(r);
    a1[e] = ur;
    float r2 = r - __uint_as_float(ur & 0xffff0000u);
    a2[e] = __float_as_uint(r2);
  }
  Oct3 o;
  o.p0 = make_uint4(pk2(a0[0],a0[1]), pk2(a0[2],a0[3]), pk2(a0[4],a0[5]), pk2(a0[6],a0[7]));
  o.p1 = make_uint4(pk2(a1[0],a1[1]), pk2(a1[2],a1[3]), pk2(a1[4],a1[5]), pk2(a1[6],a1[7]));
  o.p2 = make_uint4(pk2(a2[0],a2[1]), pk2(a2[2],a2[3]), pk2(a2[4],a2[5]), pk2(a2[6],a2[7]));
  return o;
}

// ---- split 8 fp32 into 2 RNE bf16 planes (R10-proven) ----
struct Oct2 { uint4 p0, p1; };
__device__ __forceinline__ Oct2 split8_rne2(const float* f) {
  unsigned h0[8], h1[8];
  #pragma unroll
  for (int e = 0; e < 8; ++e) {
    h0[e] = rne16(f[e]);
    float r = f[e] - bf2f((unsigned short)h0[e]);
    h1[e] = rne16(r);
  }
  Oct2 o;
  o.p0 = make_uint4(h0[0]|(h0[1]<<16), h0[2]|(h0[3]<<16), h0[4]|(h0[5]<<16), h0[6]|(h0[7]<<16));
  o.p1 = make_uint4(h1[0]|(h1[1]<<16), h1[2]|(h1[3]<<16), h1[4]|(h1[5]<<16), h1[6]|(h1[7]<<16));
  return o;
}
__device__ __forceinline__ uint4 pack8_rne(const float* f) {
  unsigned h[8];
  #pragma unroll
  for (int e = 0; e < 8; ++e) h[e] = rne16(f[e]);
  return make_uint4(h[0]|(h[1]<<16), h[2]|(h[3]<<16), h[4]|(h[5]<<16), h[6]|(h[7]<<16));
}

// ---------------- A pre-split: fp32 [M x lda] -> NP planes, PRE-SWIZZLED tiles ----
// out[plane][(mt*ktT + kt)*512 + ((c&~7) | ((c&7) ^ ((c>>3)&7)))], c = row*8+sl.
// GEMMs copy linearly (global_load_lds); ds_read uses the swizzled index.
template<int NP>
__global__ __launch_bounds__(256) void asplit_kernel(
    const float* __restrict__ A, int lda, uint4* __restrict__ outp) {
  int mt = blockIdx.x, kt = blockIdx.y;
  size_t aPS = (size_t)gridDim.x * gridDim.y * 512;
  int tid = threadIdx.x;
  #pragma unroll
  for (int i = 0; i < 2; ++i) {
    int c = tid + i * 256;
    int row = c >> 3, sl = c & 7;
    const float4* ap = reinterpret_cast<const float4*>(
        A + (size_t)(mt*64 + row) * lda + kt*64 + sl*8);
    float4 x0 = ap[0], x1 = ap[1];
    float f[8] = {x0.x,x0.y,x0.z,x0.w,x1.x,x1.y,x1.z,x1.w};
    size_t di = ((size_t)(mt * gridDim.y + kt)) * 512
              + ((c & ~7) | ((c & 7) ^ ((c >> 3) & 7)));
    if (NP == 3) {
      Oct3 o = split8(f);
      outp[di] = o.p0; outp[aPS+di] = o.p1; outp[2*aPS+di] = o.p2;
    } else {
      Oct2 o = split8_rne2(f);
      outp[di] = o.p0; outp[aPS+di] = o.p1;
    }
  }
}

// ---------------- B pre-split (R11-proven) ----------------
template<int NP>
__global__ __launch_bounds__(256) void bsplit_kernel(
    const float* __restrict__ Bw, uint4* __restrict__ outp, int ldb,
    int ntile0, int ntTotal) {
  int ntile = ntile0 + blockIdx.x, kt = blockIdx.y;
  size_t planeStride = (size_t)ntTotal * gridDim.y * 1024;
  int tid = threadIdx.x;
  int bcol = tid & 127, bkcg = tid >> 7;
  #pragma unroll
  for (int g = 0; g < 4; ++g) {
    int kc = bkcg*4 + g;
    float f[8];
    #pragma unroll
    for (int j = 0; j < 8; ++j)
      f[j] = Bw[(size_t)(kt*64 + kc*8 + j) * ldb + blockIdx.x*128 + bcol];
    size_t di = (((size_t)ntile * gridDim.y + kt) * 8 + kc) * 128 + bcol;
    if (NP == 3) {
      Oct3 o = split8(f);
      outp[di] = o.p0; outp[planeStride+di] = o.p1; outp[2*planeStride+di] = o.p2;
    } else if (NP == 2) {
      Oct2 o = split8_rne2(f);
      outp[di] = o.p0; outp[planeStride+di] = o.p1;
    } else {
      outp[di] = pack8_rne(f);
    }
  }
}

// ---------------- OLD 64x128 GEMM (kept for QK: NP=3, pre-split A+B) ----------------
template<int NP, bool ASP>
__global__ __launch_bounds__(256) void gemm_kernel(
    const float* __restrict__ A, int lda,
    const uint4* __restrict__ Asp, size_t aPS,
    const uint4* __restrict__ Bs,
    const float* __restrict__ bias, const float* __restrict__ res,
    float* __restrict__ outf, int K, int ldc, int relu,
    int ntile0, int ntTotal, int kt0, int ktTotal, int vtmode) {
  __shared__ uint4 lds_a[NP][64*8];
  __shared__ uint4 lds_b[NP][8*128];
  int tid = threadIdx.x;
  int m0 = blockIdx.y * 64;
  int n0 = blockIdx.x * 128;
  int ntg = ntile0 + blockIdx.x;
  size_t planeStride = (size_t)ntTotal * ktTotal * 1024;
  int lane = tid & 63, wid = tid >> 6;
  int wm = wid >> 1, wn = wid & 1;
  int lr = lane & 15, lk = lane >> 4;
  int bcol = tid & 127, bkcg = tid >> 7;

  f32x4 acc[2][4];
  #pragma unroll
  for (int m = 0; m < 2; ++m)
    #pragma unroll
    for (int n = 0; n < 4; ++n)
      acc[m][n] = (f32x4){0.f, 0.f, 0.f, 0.f};

  for (int k0 = 0; k0 < K; k0 += 64) {
    if (ASP) {
      // pre-swizzled source -> linear copy
      size_t abase = ((size_t)blockIdx.y * (unsigned)(K >> 6) + (k0 >> 6)) * 512;
      #pragma unroll
      for (int p = 0; p < NP; ++p)
        #pragma unroll
        for (int i = 0; i < 2; ++i) {
          int c = tid + i*256;
          lds_a[p][c] = Asp[p*aPS + abase + c];
        }
    } else {
      #pragma unroll
      for (int i = 0; i < 2; ++i) {
        int c = tid + i * 256;
        int row = c >> 3, sl = c & 7;
        const float4* ap = reinterpret_cast<const float4*>(
            A + (size_t)(m0+row)*lda + k0 + sl*8);
        float4 x0 = ap[0], x1 = ap[1];
        float f[8] = {x0.x,x0.y,x0.z,x0.w,x1.x,x1.y,x1.z,x1.w};
        int di = row*8 + (sl ^ (row & 7));
        if (NP == 3) {
          Oct3 o = split8(f);
          lds_a[0][di] = o.p0; lds_a[1][di] = o.p1; lds_a[2][di] = o.p2;
        } else if (NP == 2) {
          Oct2 o = split8_rne2(f);
          lds_a[0][di] = o.p0; lds_a[1][di] = o.p1;
        } else {
          lds_a[0][di] = pack8_rne(f);
        }
      }
    }
    {
      int ktg = kt0 + (k0 >> 6);
      #pragma unroll
      for (int g = 0; g < 4; ++g) {
        int kc = bkcg*4 + g;
        size_t di = (((size_t)ntg * ktTotal + ktg) * 8 + kc) * 128 + bcol;
        lds_b[0][kc*128 + bcol] = Bs[di];
        if (NP >= 2) lds_b[1][kc*128 + bcol] = Bs[planeStride + di];
        if (NP == 3) lds_b[2][kc*128 + bcol] = Bs[2*planeStride + di];
      }
    }
    __syncthreads();
    #pragma unroll
    for (int ks = 0; ks < 2; ++ks) {
      int kc = ks*4 + lk;
      bf16x8 af[NP][2], bfr[NP][4];
      #pragma unroll
      for (int m = 0; m < 2; ++m) {
        int row = wm*32 + m*16 + lr;
        int si = row*8 + (kc ^ (row & 7));
        #pragma unroll
        for (int p = 0; p < NP; ++p)
          af[p][m] = reinterpret_cast<const bf16x8*>(lds_a[p])[si];
      }
      #pragma unroll
      for (int n = 0; n < 4; ++n) {
        int si = kc*128 + wn*64 + n*16 + lr;
        #pragma unroll
        for (int p = 0; p < NP; ++p)
          bfr[p][n] = reinterpret_cast<const bf16x8*>(lds_b[p])[si];
      }
      #pragma unroll
      for (int m = 0; m < 2; ++m)
        #pragma unroll
        for (int n = 0; n < 4; ++n) {
          acc[m][n] = __builtin_amdgcn_mfma_f32_16x16x32_bf16(af[0][m], bfr[0][n], acc[m][n], 0, 0, 0);
          if (NP >= 2) {
            acc[m][n] = __builtin_amdgcn_mfma_f32_16x16x32_bf16(af[0][m], bfr[1][n], acc[m][n], 0, 0, 0);
            acc[m][n] = __builtin_amdgcn_mfma_f32_16x16x32_bf16(af[1][m], bfr[0][n], acc[m][n], 0, 0, 0);
            acc[m][n] = __builtin_amdgcn_mfma_f32_16x16x32_bf16(af[1][m], bfr[1][n], acc[m][n], 0, 0, 0);
          }
          if (NP == 3) {
            acc[m][n] = __builtin_amdgcn_mfma_f32_16x16x32_bf16(af[2][m], bfr[0][n], acc[m][n], 0, 0, 0);
            acc[m][n] = __builtin_amdgcn_mfma_f32_16x16x32_bf16(af[0][m], bfr[2][n], acc[m][n], 0, 0, 0);
          }
        }
    }
    __syncthreads();
  }

  #pragma unroll
  for (int m = 0; m < 2; ++m) {
    #pragma unroll
    for (int n = 0; n < 4; ++n) {
      int col = n0 + wn*64 + n*16 + lr;
      float bv = bias ? bias[col] : 0.f;
      #pragma unroll
      for (int j = 0; j < 4; ++j) {
        int row = m0 + wm*32 + m*16 + lk*4 + j;
        float vv = acc[m][n][j] + bv;
        if (relu) vv = fmaxf(vv, 0.f);
        size_t off = (size_t)row * ldc + col;
        if (res) vv += res[off];
        outf[off] = vv;
      }
    }
  }
  (void)vtmode;
}

// ---------------- NEW 128x128 GEMM, global_load_lds staging (m97 structure) ------
// ASP=true: A pre-split+pre-swizzled -> DMA copy. ASP=false: A fp32, reg split.
// B always pre-split (LDS-linear layout) -> DMA copy.
template<int NP, bool ASP>
__global__ __launch_bounds__(256) void gemm128_kernel(
    const float* __restrict__ A, int lda,
    const uint4* __restrict__ Asp, size_t aPS,
    const uint4* __restrict__ Bs,
    const float* __restrict__ bias, const float* __restrict__ res,
    float* __restrict__ outf, int K, int ldc, int relu,
    int ntile0, int ntTotal, int kt0, int ktTotal, int vtmode) {
  __shared__ uint4 lds_a[NP][1024];
  __shared__ uint4 lds_b[NP][1024];
  int tid = threadIdx.x;
  int by = blockIdx.y;
  int m0 = by * 128;
  int n0 = blockIdx.x * 128;
  int ntg = ntile0 + blockIdx.x;
  size_t bPS = (size_t)ntTotal * ktTotal * 1024;
  int lane = tid & 63, w = tid >> 6;
  int wm = w >> 1, wn = w & 1;
  int lr = lane & 15, lk = lane >> 4;
  int nkt = K >> 6;

  f32x4 acc[4][4];
  #pragma unroll
  for (int m = 0; m < 4; ++m)
    #pragma unroll
    for (int n = 0; n < 4; ++n)
      acc[m][n] = (f32x4){0.f, 0.f, 0.f, 0.f};

  for (int kt = 0; kt < nkt; ++kt) {
    if (ASP) {
      #pragma unroll
      for (int p = 0; p < NP; ++p) {
        const uint4* s0 = Asp + p*aPS + ((size_t)(2*by)   * nkt + kt)*512;
        const uint4* s1 = Asp + p*aPS + ((size_t)(2*by+1) * nkt + kt)*512;
        #pragma unroll
        for (int i = 0; i < 2; ++i) {
          int ch = w*2 + i;                       // 0..7
          gld16(s0 + ch*64 + lane, &lds_a[p][ch*64]);
          gld16(s1 + ch*64 + lane, &lds_a[p][512 + ch*64]);
        }
      }
    } else {
      #pragma unroll
      for (int i = 0; i < 4; ++i) {
        int c = tid + i * 256;                    // 0..1023
        int row = c >> 3, sl = c & 7;
        const float4* ap = reinterpret_cast<const float4*>(
            A + (size_t)(m0+row)*lda + kt*64 + sl*8);
        float4 x0 = ap[0], x1 = ap[1];
        float f[8] = {x0.x,x0.y,x0.z,x0.w,x1.x,x1.y,x1.z,x1.w};
        int di = (row>>6)*512 + (row&63)*8 + (sl ^ (row & 7));
        if (NP == 2) {
          Oct2 o = split8_rne2(f);
          lds_a[0][di] = o.p0; lds_a[1][di] = o.p1;
        } else {
          lds_a[0][di] = pack8_rne(f);
        }
      }
    }
    {
      int ktg = kt0 + kt;
      #pragma unroll
      for (int p = 0; p < NP; ++p) {
        const uint4* sb = Bs + p*bPS + ((size_t)ntg * ktTotal + ktg)*1024;
        #pragma unroll
        for (int i = 0; i < 4; ++i) {
          int ch = w*4 + i;                       // 0..15
          gld16(sb + ch*64 + lane, &lds_b[p][ch*64]);
        }
      }
    }
    __syncthreads();
    #pragma unroll
    for (int ks = 0; ks < 2; ++ks) {
      int kc = ks*4 + lk;
      bf16x8 af[NP][4], bfr[NP][4];
      #pragma unroll
      for (int m = 0; m < 4; ++m) {
        int row = wm*64 + m*16 + lr;
        int si = (row>>6)*512 + (row&63)*8 + (kc ^ (row & 7));
        #pragma unroll
        for (int p = 0; p < NP; ++p)
          af[p][m] = reinterpret_cast<const bf16x8*>(lds_a[p])[si];
      }
      #pragma unroll
      for (int n = 0; n < 4; ++n) {
        int si = kc*128 + wn*64 + n*16 + lr;
        #pragma unroll
        for (int p = 0; p < NP; ++p)
          bfr[p][n] = reinterpret_cast<const bf16x8*>(lds_b[p])[si];
      }
      #pragma unroll
      for (int m = 0; m < 4; ++m)
        #pragma unroll
        for (int n = 0; n < 4; ++n) {
          acc[m][n] = __builtin_amdgcn_mfma_f32_16x16x32_bf16(af[0][m], bfr[0][n], acc[m][n], 0, 0, 0);
          if (NP == 2) {
            acc[m][n] = __builtin_amdgcn_mfma_f32_16x16x32_bf16(af[0][m], bfr[1][n], acc[m][n], 0, 0, 0);
            acc[m][n] = __builtin_amdgcn_mfma_f32_16x16x32_bf16(af[1][m], bfr[0][n], acc[m][n], 0, 0, 0);
            acc[m][n] = __builtin_amdgcn_mfma_f32_16x16x32_bf16(af[1][m], bfr[1][n], acc[m][n], 0, 0, 0);
          }
        }
    }
    __syncthreads();
  }

  if (vtmode) {
    #pragma unroll
    for (int m = 0; m < 4; ++m) {
      int t0 = m0 + wm*64 + m*16 + lk*4;
      int bq = t0 >> 10, tb = t0 & (TT-1);
      #pragma unroll
      for (int n = 0; n < 4; ++n) {
        int col = n0 + wn*64 + n*16 + lr;
        float4 val;
        val.x = acc[m][n][0]; val.y = acc[m][n][1];
        val.z = acc[m][n][2]; val.w = acc[m][n][3];
        *reinterpret_cast<float4*>(
            outf + (((size_t)(bq*HH + (col>>6)))*HS + (col&63))*TT + tb) = val;
      }
    }
  } else {
    #pragma unroll
    for (int m = 0; m < 4; ++m) {
      #pragma unroll
      for (int n = 0; n < 4; ++n) {
        int col = n0 + wn*64 + n*16 + lr;
        float bv = bias ? bias[col] : 0.f;
        #pragma unroll
        for (int j = 0; j < 4; ++j) {
          int row = m0 + wm*64 + m*16 + lk*4 + j;
          float vv = acc[m][n][j] + bv;
          if (relu) vv = fmaxf(vv, 0.f);
          size_t off = (size_t)row * ldc + col;
          if (res) vv += res[off];
          outf[off] = vv;
        }
      }
    }
  }
}

// ---------------- MFMA flash attention (R9-proven; qk-combined addressing) ------
__global__ __launch_bounds__(256) void attn_mfma_kernel(
    float* __restrict__ qk, const float* __restrict__ vt) {
  __shared__ uint4 K_lds[3][64*8];
  __shared__ uint4 V_lds[2][8*66];
  __shared__ unsigned P_lds[64*68];
  int tid = threadIdx.x, lane = tid & 63, w = tid >> 6;
  int rid = blockIdx.x;
  int qt = rid & 15, hh = (rid >> 4) & 15, b = rid >> 8;
  int lr = lane & 15, lk = lane >> 4;
  const size_t tok0 = (size_t)b * TT;

  bf16x8 qa[2][3];
  {
    const float* qp = qk + (tok0 + qt*64 + w*16 + lr) * 2048 + hh*HS;
    #pragma unroll
    for (int ks = 0; ks < 2; ++ks) {
      const float4* p4 = reinterpret_cast<const float4*>(qp + ks*32 + lk*8);
      float4 a = p4[0], c = p4[1];
      float f[8] = {a.x,a.y,a.z,a.w,c.x,c.y,c.z,c.w};
      Oct3 ot = split8(f);
      qa[ks][0] = *reinterpret_cast<bf16x8*>(&ot.p0);
      qa[ks][1] = *reinterpret_cast<bf16x8*>(&ot.p1);
      qa[ks][2] = *reinterpret_cast<bf16x8*>(&ot.p2);
    }
  }

  float mrow[4] = {-3.0e38f,-3.0e38f,-3.0e38f,-3.0e38f};
  float lrow[4] = {0.f,0.f,0.f,0.f};
  f32x4 oac[4];
  #pragma unroll
  for (int n = 0; n < 4; ++n) oac[n] = (f32x4){0.f,0.f,0.f,0.f};

  for (int kt = 0; kt <= qt; ++kt) {
    __syncthreads();
    #pragma unroll
    for (int pp = 0; pp < 2; ++pp) {
      int c = tid + pp*256;
      int r = c >> 3, sl = c & 7;
      const float4* kp = reinterpret_cast<const float4*>(
          qk + (tok0 + kt*64 + r) * 2048 + 1024 + hh*HS + sl*8);
      float4 x0 = kp[0], x1 = kp[1];
      float f[8] = {x0.x,x0.y,x0.z,x0.w,x1.x,x1.y,x1.z,x1.w};
      Oct3 ot = split8(f);
      int di = r*8 + (sl ^ (r & 7));
      K_lds[0][di] = ot.p0; K_lds[1][di] = ot.p1; K_lds[2][di] = ot.p2;
    }
    #pragma unroll
    for (int pp = 0; pp < 2; ++pp) {
      int c = tid + pp*256;
      int kc = c & 7, d = c >> 3;
      const float4* vp = reinterpret_cast<const float4*>(
          vt + (((size_t)(b*HH+hh)*HS + d))*TT + kt*64 + kc*8);
      float4 x0 = vp[0], x1 = vp[1];
      float f[8] = {x0.x,x0.y,x0.z,x0.w,x1.x,x1.y,x1.z,x1.w};
      Oct2 ot = split8_rne2(f);
      int di = (kc ^ (d & 7))*66 + d;
      V_lds[0][di] = ot.p0; V_lds[1][di] = ot.p1;
    }
    __syncthreads();

    f32x4 sfr[4];
    #pragma unroll
    for (int nf = 0; nf < 4; ++nf) sfr[nf] = (f32x4){0.f,0.f,0.f,0.f};
    #pragma unroll
    for (int ks = 0; ks < 2; ++ks) {
      int kc = ks*4 + lk;
      #pragma unroll
      for (int nf = 0; nf < 4; ++nf) {
        int row = nf*16 + lr;
        int si = row*8 + (kc ^ (row & 7));
        bf16x8 k0 = *reinterpret_cast<const bf16x8*>(&K_lds[0][si]);
        bf16x8 k1 = *reinterpret_cast<const bf16x8*>(&K_lds[1][si]);
        bf16x8 k2 = *reinterpret_cast<const bf16x8*>(&K_lds[2][si]);
        sfr[nf] = __builtin_amdgcn_mfma_f32_16x16x32_bf16(qa[ks][0], k0, sfr[nf], 0,0,0);
        sfr[nf] = __builtin_amdgcn_mfma_f32_16x16x32_bf16(qa[ks][0], k1, sfr[nf], 0,0,0);
        sfr[nf] = __builtin_amdgcn_mfma_f32_16x16x32_bf16(qa[ks][1], k0, sfr[nf], 0,0,0);
        sfr[nf] = __builtin_amdgcn_mfma_f32_16x16x32_bf16(qa[ks][1], k1, sfr[nf], 0,0,0);
        sfr[nf] = __builtin_amdgcn_mfma_f32_16x16x32_bf16(qa[ks][2], k0, sfr[nf], 0,0,0);
        sfr[nf] = __builtin_amdgcn_mfma_f32_16x16x32_bf16(qa[ks][0], k2, sfr[nf], 0,0,0);
      }
    }
    #pragma unroll
    for (int nf = 0; nf < 4; ++nf)
      #pragma unroll
      for (int j = 0; j < 4; ++j) {
        float s = sfr[nf][j] * 8.0f;
        if (kt == qt && (nf*16 + lr) > (w*16 + lk*4 + j)) s = -3.0e38f;
        sfr[nf][j] = s;
      }
    float alpha[4], tsum[4];
    #pragma unroll
    for (int j = 0; j < 4; ++j) {
      float mx = fmaxf(fmaxf(sfr[0][j], sfr[1][j]), fmaxf(sfr[2][j], sfr[3][j]));
      mx = fmaxf(mx, __shfl_xor(mx, 1));
      mx = fmaxf(mx, __shfl_xor(mx, 2));
      mx = fmaxf(mx, __shfl_xor(mx, 4));
      mx = fmaxf(mx, __shfl_xor(mx, 8));
      float mnew = fmaxf(mrow[j], mx);
      alpha[j] = __expf(mrow[j] - mnew);
      mrow[j] = mnew;
      tsum[j] = 0.f;
    }
    #pragma unroll
    for (int nf = 0; nf < 4; ++nf)
      #pragma unroll
      for (int j = 0; j < 4; ++j) {
        float p = __expf(sfr[nf][j] - mrow[j]);
        tsum[j] += p;
        unsigned u = __float_as_uint(p);
        float r = p - __uint_as_float(u & 0xffff0000u);
        unsigned pw = (u & 0xffff0000u) | (__float_as_uint(r) >> 16);
        int qrow = w*16 + lk*4 + j;
        int kcol = nf*16 + lr;
        P_lds[qrow*68 + (((kcol>>3) ^ (qrow & 7)))*8 + (kcol & 7)] = pw;
      }
    #pragma unroll
    for (int j = 0; j < 4; ++j) {
      float ts = tsum[j];
      ts += __shfl_xor(ts, 1);
      ts += __shfl_xor(ts, 2);
      ts += __shfl_xor(ts, 4);
      ts += __shfl_xor(ts, 8);
      lrow[j] = lrow[j]*alpha[j] + ts;
      oac[0][j] *= alpha[j]; oac[1][j] *= alpha[j];
      oac[2][j] *= alpha[j]; oac[3][j] *= alpha[j];
    }
    __syncthreads();

    #pragma unroll
    for (int ks = 0; ks < 2; ++ks) {
      int kc = ks*4 + lk;
      int prow = w*16 + lr;
      const uint4* pp4 = reinterpret_cast<const uint4*>(
          &P_lds[prow*68 + ((kc ^ (prow & 7)))*8]);
      uint4 pw0 = pp4[0], pw1 = pp4[1];
      uint4 phu, plu;
      phu.x = (pw0.x>>16) | (pw0.y & 0xffff0000u);
      phu.y = (pw0.z>>16) | (pw0.w & 0xffff0000u);
      phu.z = (pw1.x>>16) | (pw1.y & 0xffff0000u);
      phu.w = (pw1.z>>16) | (pw1.w & 0xffff0000u);
      plu.x = (pw0.x & 0xffffu) | (pw0.y << 16);
      plu.y = (pw0.z & 0xffffu) | (pw0.w << 16);
      plu.z = (pw1.x & 0xffffu) | (pw1.y << 16);
      plu.w = (pw1.z & 0xffffu) | (pw1.w << 16);
      bf16x8 ph = *reinterpret_cast<bf16x8*>(&phu);
      bf16x8 pl = *reinterpret_cast<bf16x8*>(&plu);
      #pragma unroll
      for (int nf2 = 0; nf2 < 4; ++nf2) {
        int d = nf2*16 + lr;
        int di = (kc ^ (d & 7))*66 + d;
        bf16x8 vh = *reinterpret_cast<const bf16x8*>(&V_lds[0][di]);
        bf16x8 vl = *reinterpret_cast<const bf16x8*>(&V_lds[1][di]);
        oac[nf2] = __builtin_amdgcn_mfma_f32_16x16x32_bf16(ph, vh, oac[nf2], 0,0,0);
        oac[nf2] = __builtin_amdgcn_mfma_f32_16x16x32_bf16(ph, vl, oac[nf2], 0,0,0);
        oac[nf2] = __builtin_amdgcn_mfma_f32_16x16x32_bf16(pl, vh, oac[nf2], 0,0,0);
      }
    }
  }

  #pragma unroll
  for (int j = 0; j < 4; ++j) {
    float inv = 1.0f / lrow[j];
    float* op = qk + (tok0 + qt*64 + w*16 + lk*4 + j) * 2048 + hh*HS;
    #pragma unroll
    for (int nf2 = 0; nf2 < 4; ++nf2)
      op[nf2*16 + lr] = oac[nf2][j] * inv;
  }
}

extern "C" void kernel_launch(void* const* d_in, const int* in_sizes, int n_in,
                              void* d_out, int out_size, void* d_ws, size_t ws_size,
                              hipStream_t stream) {
  const int*   idx  = (const int*)d_in[0];
  const float* tok  = (const float*)d_in[1];
  const float* pos  = (const float*)d_in[2];
  const float* Wq   = (const float*)d_in[3];
  const float* Wk   = (const float*)d_in[4];
  const float* Wv   = (const float*)d_in[5];
  const float* Wo   = (const float*)d_in[6];
  const float* bo   = (const float*)d_in[7];
  const float* ln1g = (const float*)d_in[8];
  const float* ln1b = (const float*)d_in[9];
  const float* ln2g = (const float*)d_in[10];
  const float* ln2b = (const float*)d_in[11];
  const float* W1   = (const float*)d_in[12];
  const float* b1   = (const float*)d_in[13];
  const float* W2   = (const float*)d_in[14];
  const float* b2   = (const float*)d_in[15];
  const float* lnfg = (const float*)d_in[16];
  const float* lnfb = (const float*)d_in[17];
  const float* lmw  = (const float*)d_in[18];
  const float* lmb  = (const float*)d_in[19];
  float* out = (float*)d_out;

  // d_out: x[0,32M) | h/vt[32,64M) | qk (8192x2048) / a1 [64,128M)
  // ws (64 MB, time-shared; liveness checked, same as R12):
  char* ob = (char*)d_out;
  float* x  = (float*)ob;
  float* h  = (float*)(ob + ((size_t)32<<20));
  float* vt = h;
  float* qk = (float*)(ob + ((size_t)64<<20));
  float* a1 = (float*)(ob + ((size_t)64<<20));
  char* wsb = (char*)d_ws;
  uint4* aspH  = (uint4*)wsb;
  uint4* bsQK  = (uint4*)(wsb + ((size_t)48<<20));
  uint4* bsV   = (uint4*)(wsb + ((size_t)60<<20));
  uint4* aspH2 = (uint4*)wsb;
  uint4* bsO   = (uint4*)(wsb + ((size_t)32<<20));
  uint4* aspH3 = (uint4*)wsb;
  uint4* bsW1  = (uint4*)(wsb + ((size_t)32<<20));
  uint4* bsW2  = (uint4*)(wsb + ((size_t)48<<20));
  float* hf    = (float*)wsb;
  uint4* bsL   = (uint4*)(wsb + ((size_t)32<<20));
  const size_t aPSh = (size_t)128 * 16 * 512;   // uint4 per A plane (16 MB)

  dim3 blk(256);
  dim3 gQK(16, 128);            // old kernel, BM=64
  dim3 gV(8, 64), gO(8, 64);    // new kernel, BM=128
  dim3 gW1(16, 64), gW2(8, 64), gL(32, 64);
  dim3 sA(128, 16), s8(8, 16), sW1(32, 16), sW2(8, 64), sLM(32, 16);

  embed_kernel<<<BT, blk, 0, stream>>>(idx, tok, pos, x);
  for (int l = 0; l < LL; ++l) {
    const float* Wq_l = Wq + (size_t)l*CC*CC;
    const float* Wk_l = Wk + (size_t)l*CC*CC;
    const float* Wv_l = Wv + (size_t)l*CC*CC;
    const float* Wo_l = Wo + (size_t)l*CC*CC;
    const float* W1_l = W1 + (size_t)l*CC*4*CC;
    const float* W2_l = W2 + (size_t)l*4*CC*CC;
    ln32_kernel<<<BT, blk, 0, stream>>>(x, ln1g + (size_t)l*CC, ln1b + (size_t)l*CC, h);
    asplit_kernel<3><<<sA, blk, 0, stream>>>(h, CC, aspH);
    bsplit_kernel<3><<<s8, blk, 0, stream>>>(Wq_l, bsQK, CC, 0, 16);
    bsplit_kernel<3><<<s8, blk, 0, stream>>>(Wk_l, bsQK, CC, 8, 16);
    bsplit_kernel<2><<<s8, blk, 0, stream>>>(Wv_l, bsV, CC, 0, 8);
    gemm_kernel<3,true><<<gQK, blk, 0, stream>>>(nullptr, 0, aspH, aPSh, bsQK,
        nullptr, nullptr, qk, CC, 2048, 0, 0, 16, 0, 16, 0);
    gemm128_kernel<2,true><<<gV, blk, 0, stream>>>(nullptr, 0, aspH, aPSh, bsV,
        nullptr, nullptr, vt, CC, CC, 0, 0, 8, 0, 16, 1);
    attn_mfma_kernel<<<BB*HH*16, blk, 0, stream>>>(qk, vt);
    asplit_kernel<2><<<sA, blk, 0, stream>>>(qk, 2048, aspH2);
    bsplit_kernel<2><<<s8, blk, 0, stream>>>(Wo_l, bsO, CC, 0, 8);
    gemm128_kernel<2,true><<<gO, blk, 0, stream>>>(nullptr, 0, aspH2, aPSh, bsO,
        bo + (size_t)l*CC, x, x, CC, CC, 0, 0, 8, 0, 16, 0);
    ln32_kernel<<<BT, blk, 0, stream>>>(x, ln2g + (size_t)l*CC, ln2b + (size_t)l*CC, h);
    asplit_kernel<2><<<sA, blk, 0, stream>>>(h, CC, aspH3);
    bsplit_kernel<2><<<sW1, blk, 0, stream>>>(W1_l, bsW1, 4*CC, 0, 32);
    bsplit_kernel<2><<<sW2, blk, 0, stream>>>(W2_l, bsW2, CC, 0, 8);
    gemm128_kernel<2,true><<<gW1, blk, 0, stream>>>(nullptr, 0, aspH3, aPSh, bsW1,
        b1 + (size_t)l*4*CC, nullptr, a1, CC, 2048, 1, 0, 32, 0, 16, 0);
    gemm128_kernel<2,false><<<gW2, blk, 0, stream>>>(a1, 2048, nullptr, 0, bsW2,
        b2 + (size_t)l*CC, x, x, 2048, CC, 0, 0, 8, 0, 64, 0);
    gemm128_kernel<2,true><<<gW1, blk, 0, stream>>>(nullptr, 0, aspH3, aPSh, bsW1,
        b1 + (size_t)l*4*CC + 2048, nullptr, a1, CC, 2048, 1, 16, 32, 0, 16, 0);
    gemm128_kernel<2,false><<<gW2, blk, 0, stream>>>(a1, 2048, nullptr, 0, bsW2,
        nullptr, x, x, 2048, CC, 0, 0, 8, 32, 64, 0);
  }
  ln32_kernel<<<BT, blk, 0, stream>>>(x, lnfg, lnfb, hf);
  bsplit_kernel<1><<<sLM, blk, 0, stream>>>(lmw, bsL, VV, 0, 32);
  gemm128_kernel<1,false><<<gL, blk, 0, stream>>>(hf, CC, nullptr, 0, bsL,
      lmb, nullptr, out, CC, VV, 0, 0, 32, 0, 16, 0);
}

// Round 14
// 6418.506 us; speedup vs baseline: 8.5678x; 1.0604x over previous
//
#include <hip/hip_runtime.h>

#define LL 6
#define BB 8
#define TT 1024
#define CC 1024
#define HH 16
#define HS 64
#define VV 4096
#define BT (BB*TT)

typedef __attribute__((ext_vector_type(4))) float f32x4;
typedef __attribute__((ext_vector_type(8))) short bf16x8;

__device__ __forceinline__ float bf2f(unsigned short u) {
  union { unsigned int u; float f; } v; v.u = ((unsigned int)u) << 16; return v.f;
}
__device__ __forceinline__ unsigned short rne16(float f) {
  unsigned u = __float_as_uint(f);
  return (unsigned short)((u + 0x7fffu + ((u >> 16) & 1u)) >> 16);
}
__device__ __forceinline__ void gld16(const uint4* g, uint4* l) {
  __builtin_amdgcn_global_load_lds(
      (const __attribute__((address_space(1))) void*)g,
      (__attribute__((address_space(3))) void*)l, 16, 0, 0);
}

// ---------------- embedding ----------------
__global__ __launch_bounds__(256) void embed_kernel(
    const int* __restrict__ idx, const float* __restrict__ tok,
    const float* __restrict__ pos, float* __restrict__ x) {
  int bt = blockIdx.x;
  int t = bt & (TT - 1);
  int id = idx[bt];
  float4 te = reinterpret_cast<const float4*>(tok)[(size_t)id * (CC/4) + threadIdx.x];
  float4 pe = reinterpret_cast<const float4*>(pos)[(size_t)t * (CC/4) + threadIdx.x];
  float4 r; r.x = te.x+pe.x; r.y = te.y+pe.y; r.z = te.z+pe.z; r.w = te.w+pe.w;
  reinterpret_cast<float4*>(x)[(size_t)bt * (CC/4) + threadIdx.x] = r;
}

// ---------------- layernorm fp32->fp32 (R4-proven) ----------------
__global__ __launch_bounds__(256) void ln32_kernel(
    const float* __restrict__ x, const float* __restrict__ g,
    const float* __restrict__ b, float* __restrict__ out) {
  __shared__ float red[8];
  int row = blockIdx.x, tid = threadIdx.x;
  float4 v = reinterpret_cast<const float4*>(x)[(size_t)row * (CC/4) + tid];
  float s  = v.x+v.y+v.z+v.w;
  float ss = v.x*v.x+v.y*v.y+v.z*v.z+v.w*v.w;
  #pragma unroll
  for (int off = 32; off; off >>= 1) { s += __shfl_xor(s, off); ss += __shfl_xor(ss, off); }
  if ((tid & 63) == 0) { red[tid>>6] = s; red[4+(tid>>6)] = ss; }
  __syncthreads();
  s  = red[0]+red[1]+red[2]+red[3];
  ss = red[4]+red[5]+red[6]+red[7];
  float mu = s * (1.f/CC);
  float rs = rsqrtf(ss*(1.f/CC) - mu*mu + 1e-5f);
  float4 gg = reinterpret_cast<const float4*>(g)[tid];
  float4 bb = reinterpret_cast<const float4*>(b)[tid];
  float4 o;
  o.x = (v.x-mu)*rs*gg.x + bb.x;
  o.y = (v.y-mu)*rs*gg.y + bb.y;
  o.z = (v.z-mu)*rs*gg.z + bb.z;
  o.w = (v.w-mu)*rs*gg.w + bb.w;
  reinterpret_cast<float4*>(out)[(size_t)row * (CC/4) + tid] = o;
}

// ---- split 8 fp32 into 3 truncated-bf16 planes (R7-proven) ----
struct Oct3 { uint4 p0, p1, p2; };
__device__ __forceinline__ unsigned pk2(unsigned lo, unsigned hi) {
  return (lo >> 16) | (hi & 0xffff0000u);
}
__device__ __forceinline__ Oct3 split8(const float* f) {
  unsigned a0[8], a1[8], a2[8];
  #pragma unroll
  for (int e = 0; e < 8; ++e) {
    float v = f[e];
    unsigned u = __float_as_uint(v);
    a0[e] = u;
    float r = v - __uint_as_float(u & 0xffff0000u);
    unsigned ur = __float_as_uint(r);
    a1[e] = ur;
    float r2 = r - __uint_as_float(ur & 0xffff0000u);
    a2[e] = __float_as_uint(r2);
  }
  Oct3 o;
  o.p0 = make_uint4(pk2(a0[0],a0[1]), pk2(a0[2],a0[3]), pk2(a0[4],a0[5]), pk2(a0[6],a0[7]));
  o.p1 = make_uint4(pk2(a1[0],a1[1]), pk2(a1[2],a1[3]), pk2(a1[4],a1[5]), pk2(a1[6],a1[7]));
  o.p2 = make_uint4(pk2(a2[0],a2[1]), pk2(a2[2],a2[3]), pk2(a2[4],a2[5]), pk2(a2[6],a2[7]));
  return o;
}

// ---- split 8 fp32 into 2 RNE bf16 planes (R10-proven) ----
struct Oct2 { uint4 p0, p1; };
__device__ __forceinline__ Oct2 split8_rne2(const float* f) {
  unsigned h0[8], h1[8];
  #pragma unroll
  for (int e = 0; e < 8; ++e) {
    h0[e] = rne16(f[e]);
    float r = f[e] - bf2f((unsigned short)h0[e]);
    h1[e] = rne16(r);
  }
  Oct2 o;
  o.p0 = make_uint4(h0[0]|(h0[1]<<16), h0[2]|(h0[3]<<16), h0[4]|(h0[5]<<16), h0[6]|(h0[7]<<16));
  o.p1 = make_uint4(h1[0]|(h1[1]<<16), h1[2]|(h1[3]<<16), h1[4]|(h1[5]<<16), h1[6]|(h1[7]<<16));
  return o;
}
__device__ __forceinline__ uint4 pack8_rne(const float* f) {
  unsigned h[8];
  #pragma unroll
  for (int e = 0; e < 8; ++e) h[e] = rne16(f[e]);
  return make_uint4(h[0]|(h[1]<<16), h[2]|(h[3]<<16), h[4]|(h[5]<<16), h[6]|(h[7]<<16));
}

// ---------------- A pre-split (R12-proven; pre-swizzled tiles) ----------------
template<int NP>
__global__ __launch_bounds__(256) void asplit_kernel(
    const float* __restrict__ A, int lda, uint4* __restrict__ outp) {
  int mt = blockIdx.x, kt = blockIdx.y;
  size_t aPS = (size_t)gridDim.x * gridDim.y * 512;
  int tid = threadIdx.x;
  #pragma unroll
  for (int i = 0; i < 2; ++i) {
    int c = tid + i * 256;
    int row = c >> 3, sl = c & 7;
    const float4* ap = reinterpret_cast<const float4*>(
        A + (size_t)(mt*64 + row) * lda + kt*64 + sl*8);
    float4 x0 = ap[0], x1 = ap[1];
    float f[8] = {x0.x,x0.y,x0.z,x0.w,x1.x,x1.y,x1.z,x1.w};
    size_t di = ((size_t)(mt * gridDim.y + kt)) * 512
              + ((c & ~7) | ((c & 7) ^ ((c >> 3) & 7)));
    if (NP == 3) {
      Oct3 o = split8(f);
      outp[di] = o.p0; outp[aPS+di] = o.p1; outp[2*aPS+di] = o.p2;
    } else {
      Oct2 o = split8_rne2(f);
      outp[di] = o.p0; outp[aPS+di] = o.p1;
    }
  }
}

// ---------------- B pre-split (R11-proven) ----------------
template<int NP>
__global__ __launch_bounds__(256) void bsplit_kernel(
    const float* __restrict__ Bw, uint4* __restrict__ outp, int ldb,
    int ntile0, int ntTotal) {
  int ntile = ntile0 + blockIdx.x, kt = blockIdx.y;
  size_t planeStride = (size_t)ntTotal * gridDim.y * 1024;
  int tid = threadIdx.x;
  int bcol = tid & 127, bkcg = tid >> 7;
  #pragma unroll
  for (int g = 0; g < 4; ++g) {
    int kc = bkcg*4 + g;
    float f[8];
    #pragma unroll
    for (int j = 0; j < 8; ++j)
      f[j] = Bw[(size_t)(kt*64 + kc*8 + j) * ldb + blockIdx.x*128 + bcol];
    size_t di = (((size_t)ntile * gridDim.y + kt) * 8 + kc) * 128 + bcol;
    if (NP == 3) {
      Oct3 o = split8(f);
      outp[di] = o.p0; outp[planeStride+di] = o.p1; outp[2*planeStride+di] = o.p2;
    } else if (NP == 2) {
      Oct2 o = split8_rne2(f);
      outp[di] = o.p0; outp[planeStride+di] = o.p1;
    } else {
      outp[di] = pack8_rne(f);
    }
  }
}

// ---------------- K pre-split: qk K-half -> 3-plane attn-ready tiles ----------------
// tile = ((b*HH+hh)*16 + kt); within tile: uint4 at r*8 + (sl ^ (r&7)).
__global__ __launch_bounds__(256) void ksplit_kernel(
    const float* __restrict__ qk, uint4* __restrict__ Kp) {
  int tile = blockIdx.x;
  int kt = tile & 15, hh = (tile >> 4) & 15, b = tile >> 8;
  const size_t KPS = (size_t)2048 * 512;
  int tid = threadIdx.x;
  #pragma unroll
  for (int i = 0; i < 2; ++i) {
    int c = tid + i*256;
    int r = c >> 3, sl = c & 7;
    const float4* kp = reinterpret_cast<const float4*>(
        qk + ((size_t)(b*TT + kt*64 + r))*2048 + 1024 + hh*HS + sl*8);
    float4 x0 = kp[0], x1 = kp[1];
    float f[8] = {x0.x,x0.y,x0.z,x0.w,x1.x,x1.y,x1.z,x1.w};
    Oct3 ot = split8(f);
    size_t di = (size_t)tile*512 + r*8 + (sl ^ (r & 7));
    Kp[di] = ot.p0; Kp[KPS+di] = ot.p1; Kp[2*KPS+di] = ot.p2;
  }
}

// ---------------- OLD 64x128 GEMM (QK only: NP=3, pre-split A+B, DMA staging) ----
template<int NP, bool ASP>
__global__ __launch_bounds__(256) void gemm_kernel(
    const float* __restrict__ A, int lda,
    const uint4* __restrict__ Asp, size_t aPS,
    const uint4* __restrict__ Bs,
    const float* __restrict__ bias, const float* __restrict__ res,
    float* __restrict__ outf, int K, int ldc, int relu,
    int ntile0, int ntTotal, int kt0, int ktTotal, int vtmode) {
  __shared__ uint4 lds_a[NP][64*8];
  __shared__ uint4 lds_b[NP][8*128];
  int tid = threadIdx.x;
  int m0 = blockIdx.y * 64;
  int n0 = blockIdx.x * 128;
  int ntg = ntile0 + blockIdx.x;
  size_t planeStride = (size_t)ntTotal * ktTotal * 1024;
  int lane = tid & 63, wid = tid >> 6;
  int wm = wid >> 1, wn = wid & 1;
  int lr = lane & 15, lk = lane >> 4;

  f32x4 acc[2][4];
  #pragma unroll
  for (int m = 0; m < 2; ++m)
    #pragma unroll
    for (int n = 0; n < 4; ++n)
      acc[m][n] = (f32x4){0.f, 0.f, 0.f, 0.f};

  for (int k0 = 0; k0 < K; k0 += 64) {
    // A: pre-split + pre-swizzled -> DMA linear copy (512 uint4 per plane)
    {
      size_t abase = ((size_t)blockIdx.y * (unsigned)(K >> 6) + (k0 >> 6)) * 512;
      #pragma unroll
      for (int p = 0; p < NP; ++p)
        #pragma unroll
        for (int i = 0; i < 2; ++i) {
          int ch = i*4 + wid;
          gld16(Asp + p*aPS + abase + ch*64 + lane, &lds_a[p][ch*64]);
        }
    }
    // B: pre-split LDS-linear -> DMA copy (1024 uint4 per plane)
    {
      int ktg = kt0 + (k0 >> 6);
      size_t bbase = ((size_t)ntg * ktTotal + ktg) * 1024;
      #pragma unroll
      for (int p = 0; p < NP; ++p)
        #pragma unroll
        for (int i = 0; i < 4; ++i) {
          int ch = i*4 + wid;
          gld16(Bs + p*planeStride + bbase + ch*64 + lane, &lds_b[p][ch*64]);
        }
    }
    __syncthreads();
    #pragma unroll
    for (int ks = 0; ks < 2; ++ks) {
      int kc = ks*4 + lk;
      bf16x8 af[NP][2], bfr[NP][4];
      #pragma unroll
      for (int m = 0; m < 2; ++m) {
        int row = wm*32 + m*16 + lr;
        int si = row*8 + (kc ^ (row & 7));
        #pragma unroll
        for (int p = 0; p < NP; ++p)
          af[p][m] = reinterpret_cast<const bf16x8*>(lds_a[p])[si];
      }
      #pragma unroll
      for (int n = 0; n < 4; ++n) {
        int si = kc*128 + wn*64 + n*16 + lr;
        #pragma unroll
        for (int p = 0; p < NP; ++p)
          bfr[p][n] = reinterpret_cast<const bf16x8*>(lds_b[p])[si];
      }
      #pragma unroll
      for (int m = 0; m < 2; ++m)
        #pragma unroll
        for (int n = 0; n < 4; ++n) {
          acc[m][n] = __builtin_amdgcn_mfma_f32_16x16x32_bf16(af[0][m], bfr[0][n], acc[m][n], 0, 0, 0);
          if (NP >= 2) {
            acc[m][n] = __builtin_amdgcn_mfma_f32_16x16x32_bf16(af[0][m], bfr[1][n], acc[m][n], 0, 0, 0);
            acc[m][n] = __builtin_amdgcn_mfma_f32_16x16x32_bf16(af[1][m], bfr[0][n], acc[m][n], 0, 0, 0);
            acc[m][n] = __builtin_amdgcn_mfma_f32_16x16x32_bf16(af[1][m], bfr[1][n], acc[m][n], 0, 0, 0);
          }
          if (NP == 3) {
            acc[m][n] = __builtin_amdgcn_mfma_f32_16x16x32_bf16(af[2][m], bfr[0][n], acc[m][n], 0, 0, 0);
            acc[m][n] = __builtin_amdgcn_mfma_f32_16x16x32_bf16(af[0][m], bfr[2][n], acc[m][n], 0, 0, 0);
          }
        }
    }
    __syncthreads();
  }

  #pragma unroll
  for (int m = 0; m < 2; ++m) {
    #pragma unroll
    for (int n = 0; n < 4; ++n) {
      int col = n0 + wn*64 + n*16 + lr;
      float bv = bias ? bias[col] : 0.f;
      #pragma unroll
      for (int j = 0; j < 4; ++j) {
        int row = m0 + wm*32 + m*16 + lk*4 + j;
        float vv = acc[m][n][j] + bv;
        if (relu) vv = fmaxf(vv, 0.f);
        size_t off = (size_t)row * ldc + col;
        if (res) vv += res[off];
        outf[off] = vv;
      }
    }
  }
  (void)A; (void)lda; (void)vtmode;
}

// ---------------- 128x128 GEMM, global_load_lds staging (R13-proven) ------
// vtmode=1 (V projection): epilogue writes 2-plane bf16 V tiles in the
// attention's LDS-ready layout: tile=((b*HH+h)*16+kt), uint4 vi = kc*64 +
// ((d ^ (kc<<1)) & 63) holding 8 tokens' bf16 at dim d. outf = plane0 base;
// plane1 at +16MB.
template<int NP, bool ASP>
__global__ __launch_bounds__(256) void gemm128_kernel(
    const float* __restrict__ A, int lda,
    const uint4* __restrict__ Asp, size_t aPS,
    const uint4* __restrict__ Bs,
    const float* __restrict__ bias, const float* __restrict__ res,
    float* __restrict__ outf, int K, int ldc, int relu,
    int ntile0, int ntTotal, int kt0, int ktTotal, int vtmode) {
  __shared__ uint4 lds_a[NP][1024];
  __shared__ uint4 lds_b[NP][1024];
  int tid = threadIdx.x;
  int by = blockIdx.y;
  int m0 = by * 128;
  int n0 = blockIdx.x * 128;
  int ntg = ntile0 + blockIdx.x;
  size_t bPS = (size_t)ntTotal * ktTotal * 1024;
  int lane = tid & 63, w = tid >> 6;
  int wm = w >> 1, wn = w & 1;
  int lr = lane & 15, lk = lane >> 4;
  int nkt = K >> 6;

  f32x4 acc[4][4];
  #pragma unroll
  for (int m = 0; m < 4; ++m)
    #pragma unroll
    for (int n = 0; n < 4; ++n)
      acc[m][n] = (f32x4){0.f, 0.f, 0.f, 0.f};

  for (int kt = 0; kt < nkt; ++kt) {
    if (ASP) {
      #pragma unroll
      for (int p = 0; p < NP; ++p) {
        const uint4* s0 = Asp + p*aPS + ((size_t)(2*by)   * nkt + kt)*512;
        const uint4* s1 = Asp + p*aPS + ((size_t)(2*by+1) * nkt + kt)*512;
        #pragma unroll
        for (int i = 0; i < 2; ++i) {
          int ch = w*2 + i;
          gld16(s0 + ch*64 + lane, &lds_a[p][ch*64]);
          gld16(s1 + ch*64 + lane, &lds_a[p][512 + ch*64]);
        }
      }
    } else {
      #pragma unroll
      for (int i = 0; i < 4; ++i) {
        int c = tid + i * 256;
        int row = c >> 3, sl = c & 7;
        const float4* ap = reinterpret_cast<const float4*>(
            A + (size_t)(m0+row)*lda + kt*64 + sl*8);
        float4 x0 = ap[0], x1 = ap[1];
        float f[8] = {x0.x,x0.y,x0.z,x0.w,x1.x,x1.y,x1.z,x1.w};
        int di = (row>>6)*512 + (row&63)*8 + (sl ^ (row & 7));
        if (NP == 2) {
          Oct2 o = split8_rne2(f);
          lds_a[0][di] = o.p0; lds_a[1][di] = o.p1;
        } else {
          lds_a[0][di] = pack8_rne(f);
        }
      }
    }
    {
      int ktg = kt0 + kt;
      #pragma unroll
      for (int p = 0; p < NP; ++p) {
        const uint4* sb = Bs + p*bPS + ((size_t)ntg * ktTotal + ktg)*1024;
        #pragma unroll
        for (int i = 0; i < 4; ++i) {
          int ch = w*4 + i;
          gld16(sb + ch*64 + lane, &lds_b[p][ch*64]);
        }
      }
    }
    __syncthreads();
    #pragma unroll
    for (int ks = 0; ks < 2; ++ks) {
      int kc = ks*4 + lk;
      bf16x8 af[NP][4], bfr[NP][4];
      #pragma unroll
      for (int m = 0; m < 4; ++m) {
        int row = wm*64 + m*16 + lr;
        int si = (row>>6)*512 + (row&63)*8 + (kc ^ (row & 7));
        #pragma unroll
        for (int p = 0; p < NP; ++p)
          af[p][m] = reinterpret_cast<const bf16x8*>(lds_a[p])[si];
      }
      #pragma unroll
      for (int n = 0; n < 4; ++n) {
        int si = kc*128 + wn*64 + n*16 + lr;
        #pragma unroll
        for (int p = 0; p < NP; ++p)
          bfr[p][n] = reinterpret_cast<const bf16x8*>(lds_b[p])[si];
      }
      #pragma unroll
      for (int m = 0; m < 4; ++m)
        #pragma unroll
        for (int n = 0; n < 4; ++n) {
          acc[m][n] = __builtin_amdgcn_mfma_f32_16x16x32_bf16(af[0][m], bfr[0][n], acc[m][n], 0, 0, 0);
          if (NP == 2) {
            acc[m][n] = __builtin_amdgcn_mfma_f32_16x16x32_bf16(af[0][m], bfr[1][n], acc[m][n], 0, 0, 0);
            acc[m][n] = __builtin_amdgcn_mfma_f32_16x16x32_bf16(af[1][m], bfr[0][n], acc[m][n], 0, 0, 0);
            acc[m][n] = __builtin_amdgcn_mfma_f32_16x16x32_bf16(af[1][m], bfr[1][n], acc[m][n], 0, 0, 0);
          }
        }
    }
    __syncthreads();
  }

  if (vtmode) {
    // write V as 2-plane bf16 in attn tile layout
    char* vb = (char*)outf;
    const size_t VPSb = (size_t)2048 * 512 * 16;   // 16 MB plane stride
    #pragma unroll
    for (int m = 0; m < 4; ++m) {
      int row = m0 + wm*64 + m*16 + lk*4;          // token of j=0
      int bq = row >> 10;
      int t  = row & (TT-1);
      int ktile = t >> 6, r = t & 63;
      int kc = r >> 3, toct0 = r & 7;              // 0 or 4
      #pragma unroll
      for (int n = 0; n < 4; ++n) {
        int col = n0 + wn*64 + n*16 + lr;
        int hh2 = col >> 6, d = col & 63;
        int tile = (bq*HH + hh2)*16 + ktile;
        int vi = kc*64 + ((d ^ (kc<<1)) & 63);
        unsigned p0[4], p1[4];
        #pragma unroll
        for (int j = 0; j < 4; ++j) {
          float v = acc[m][n][j];
          p0[j] = rne16(v);
          p1[j] = rne16(v - bf2f((unsigned short)p0[j]));
        }
        uint2 w0 = make_uint2(p0[0]|(p0[1]<<16), p0[2]|(p0[3]<<16));
        uint2 w1 = make_uint2(p1[0]|(p1[1]<<16), p1[2]|(p1[3]<<16));
        char* base = vb + ((size_t)tile*512 + vi)*16 + toct0*2;
        *reinterpret_cast<uint2*>(base) = w0;
        *reinterpret_cast<uint2*>(base + VPSb) = w1;
      }
    }
  } else {
    #pragma unroll
    for (int m = 0; m < 4; ++m) {
      #pragma unroll
      for (int n = 0; n < 4; ++n) {
        int col = n0 + wn*64 + n*16 + lr;
        float bv = bias ? bias[col] : 0.f;
        #pragma unroll
        for (int j = 0; j < 4; ++j) {
          int row = m0 + wm*64 + m*16 + lk*4 + j;
          float vv = acc[m][n][j] + bv;
          if (relu) vv = fmaxf(vv, 0.f);
          size_t off = (size_t)row * ldc + col;
          if (res) vv += res[off];
          outf[off] = vv;
        }
      }
    }
  }
}

// ---------------- MFMA flash attention: K/V pre-split, DMA staging ----------------
__global__ __launch_bounds__(256) void attn_mfma_kernel(
    float* __restrict__ qk, const uint4* __restrict__ Kp,
    const uint4* __restrict__ Vp) {
  __shared__ uint4 K_lds[3][512];
  __shared__ uint4 V_lds[2][512];
  __shared__ unsigned P_lds[64*68];
  const size_t KPS = (size_t)2048 * 512;
  const size_t VPS = (size_t)2048 * 512;
  int tid = threadIdx.x, lane = tid & 63, w = tid >> 6;
  int rid = blockIdx.x;
  int qt = rid & 15, hh = (rid >> 4) & 15, b = rid >> 8;
  int lr = lane & 15, lk = lane >> 4;
  const size_t tok0 = (size_t)b * TT;

  bf16x8 qa[2][3];
  {
    const float* qp = qk + (tok0 + qt*64 + w*16 + lr) * 2048 + hh*HS;
    #pragma unroll
    for (int ks = 0; ks < 2; ++ks) {
      const float4* p4 = reinterpret_cast<const float4*>(qp + ks*32 + lk*8);
      float4 a = p4[0], c = p4[1];
      float f[8] = {a.x,a.y,a.z,a.w,c.x,c.y,c.z,c.w};
      Oct3 ot = split8(f);
      qa[ks][0] = *reinterpret_cast<bf16x8*>(&ot.p0);
      qa[ks][1] = *reinterpret_cast<bf16x8*>(&ot.p1);
      qa[ks][2] = *reinterpret_cast<bf16x8*>(&ot.p2);
    }
  }

  float mrow[4] = {-3.0e38f,-3.0e38f,-3.0e38f,-3.0e38f};
  float lrow[4] = {0.f,0.f,0.f,0.f};
  f32x4 oac[4];
  #pragma unroll
  for (int n = 0; n < 4; ++n) oac[n] = (f32x4){0.f,0.f,0.f,0.f};

  for (int kt = 0; kt <= qt; ++kt) {
    __syncthreads();
    // stage K (3 planes) + V (2 planes): pure DMA
    {
      int tile = ((b*HH + hh)*16 + kt);
      const uint4* ksrc = Kp + (size_t)tile*512;
      #pragma unroll
      for (int p = 0; p < 3; ++p)
        #pragma unroll
        for (int i = 0; i < 2; ++i) {
          int ch = w*2 + i;
          gld16(ksrc + p*KPS + ch*64 + lane, &K_lds[p][ch*64]);
        }
      const uint4* vsrc = Vp + (size_t)tile*512;
      #pragma unroll
      for (int p = 0; p < 2; ++p)
        #pragma unroll
        for (int i = 0; i < 2; ++i) {
          int ch = w*2 + i;
          gld16(vsrc + p*VPS + ch*64 + lane, &V_lds[p][ch*64]);
        }
    }
    __syncthreads();

    f32x4 sfr[4];
    #pragma unroll
    for (int nf = 0; nf < 4; ++nf) sfr[nf] = (f32x4){0.f,0.f,0.f,0.f};
    #pragma unroll
    for (int ks = 0; ks < 2; ++ks) {
      int kc = ks*4 + lk;
      #pragma unroll
      for (int nf = 0; nf < 4; ++nf) {
        int row = nf*16 + lr;
        int si = row*8 + (kc ^ (row & 7));
        bf16x8 k0 = *reinterpret_cast<const bf16x8*>(&K_lds[0][si]);
        bf16x8 k1 = *reinterpret_cast<const bf16x8*>(&K_lds[1][si]);
        bf16x8 k2 = *reinterpret_cast<const bf16x8*>(&K_lds[2][si]);
        sfr[nf] = __builtin_amdgcn_mfma_f32_16x16x32_bf16(qa[ks][0], k0, sfr[nf], 0,0,0);
        sfr[nf] = __builtin_amdgcn_mfma_f32_16x16x32_bf16(qa[ks][0], k1, sfr[nf], 0,0,0);
        sfr[nf] = __builtin_amdgcn_mfma_f32_16x16x32_bf16(qa[ks][1], k0, sfr[nf], 0,0,0);
        sfr[nf] = __builtin_amdgcn_mfma_f32_16x16x32_bf16(qa[ks][1], k1, sfr[nf], 0,0,0);
        sfr[nf] = __builtin_amdgcn_mfma_f32_16x16x32_bf16(qa[ks][2], k0, sfr[nf], 0,0,0);
        sfr[nf] = __builtin_amdgcn_mfma_f32_16x16x32_bf16(qa[ks][0], k2, sfr[nf], 0,0,0);
      }
    }
    #pragma unroll
    for (int nf = 0; nf < 4; ++nf)
      #pragma unroll
      for (int j = 0; j < 4; ++j) {
        float s = sfr[nf][j] * 8.0f;
        if (kt == qt && (nf*16 + lr) > (w*16 + lk*4 + j)) s = -3.0e38f;
        sfr[nf][j] = s;
      }
    float alpha[4], tsum[4];
    #pragma unroll
    for (int j = 0; j < 4; ++j) {
      float mx = fmaxf(fmaxf(sfr[0][j], sfr[1][j]), fmaxf(sfr[2][j], sfr[3][j]));
      mx = fmaxf(mx, __shfl_xor(mx, 1));
      mx = fmaxf(mx, __shfl_xor(mx, 2));
      mx = fmaxf(mx, __shfl_xor(mx, 4));
      mx = fmaxf(mx, __shfl_xor(mx, 8));
      float mnew = fmaxf(mrow[j], mx);
      alpha[j] = __expf(mrow[j] - mnew);
      mrow[j] = mnew;
      tsum[j] = 0.f;
    }
    #pragma unroll
    for (int nf = 0; nf < 4; ++nf)
      #pragma unroll
      for (int j = 0; j < 4; ++j) {
        float p = __expf(sfr[nf][j] - mrow[j]);
        tsum[j] += p;
        unsigned u = __float_as_uint(p);
        float r = p - __uint_as_float(u & 0xffff0000u);
        unsigned pw = (u & 0xffff0000u) | (__float_as_uint(r) >> 16);
        int qrow = w*16 + lk*4 + j;
        int kcol = nf*16 + lr;
        P_lds[qrow*68 + (((kcol>>3) ^ (qrow & 7)))*8 + (kcol & 7)] = pw;
      }
    #pragma unroll
    for (int j = 0; j < 4; ++j) {
      float ts = tsum[j];
      ts += __shfl_xor(ts, 1);
      ts += __shfl_xor(ts, 2);
      ts += __shfl_xor(ts, 4);
      ts += __shfl_xor(ts, 8);
      lrow[j] = lrow[j]*alpha[j] + ts;
      oac[0][j] *= alpha[j]; oac[1][j] *= alpha[j];
      oac[2][j] *= alpha[j]; oac[3][j] *= alpha[j];
    }
    __syncthreads();

    #pragma unroll
    for (int ks = 0; ks < 2; ++ks) {
      int kc = ks*4 + lk;
      int prow = w*16 + lr;
      const uint4* pp4 = reinterpret_cast<const uint4*>(
          &P_lds[prow*68 + ((kc ^ (prow & 7)))*8]);
      uint4 pw0 = pp4[0], pw1 = pp4[1];
      uint4 phu, plu;
      phu.x = (pw0.x>>16) | (pw0.y & 0xffff0000u);
      phu.y = (pw0.z>>16) | (pw0.w & 0xffff0000u);
      phu.z = (pw1.x>>16) | (pw1.y & 0xffff0000u);
      phu.w = (pw1.z>>16) | (pw1.w & 0xffff0000u);
      plu.x = (pw0.x & 0xffffu) | (pw0.y << 16);
      plu.y = (pw0.z & 0xffffu) | (pw0.w << 16);
      plu.z = (pw1.x & 0xffffu) | (pw1.y << 16);
      plu.w = (pw1.z & 0xffffu) | (pw1.w << 16);
      bf16x8 ph = *reinterpret_cast<bf16x8*>(&phu);
      bf16x8 pl = *reinterpret_cast<bf16x8*>(&plu);
      #pragma unroll
      for (int nf2 = 0; nf2 < 4; ++nf2) {
        int d = nf2*16 + lr;
        int vi = kc*64 + ((d ^ (kc<<1)) & 63);
        bf16x8 vh = *reinterpret_cast<const bf16x8*>(&V_lds[0][vi]);
        bf16x8 vl = *reinterpret_cast<const bf16x8*>(&V_lds[1][vi]);
        oac[nf2] = __builtin_amdgcn_mfma_f32_16x16x32_bf16(ph, vh, oac[nf2], 0,0,0);
        oac[nf2] = __builtin_amdgcn_mfma_f32_16x16x32_bf16(ph, vl, oac[nf2], 0,0,0);
        oac[nf2] = __builtin_amdgcn_mfma_f32_16x16x32_bf16(pl, vh, oac[nf2], 0,0,0);
      }
    }
  }

  #pragma unroll
  for (int j = 0; j < 4; ++j) {
    float inv = 1.0f / lrow[j];
    float* op = qk + (tok0 + qt*64 + w*16 + lk*4 + j) * 2048 + hh*HS;
    #pragma unroll
    for (int nf2 = 0; nf2 < 4; ++nf2)
      op[nf2*16 + lr] = oac[nf2][j] * inv;
  }
}

extern "C" void kernel_launch(void* const* d_in, const int* in_sizes, int n_in,
                              void* d_out, int out_size, void* d_ws, size_t ws_size,
                              hipStream_t stream) {
  const int*   idx  = (const int*)d_in[0];
  const float* tok  = (const float*)d_in[1];
  const float* pos  = (const float*)d_in[2];
  const float* Wq   = (const float*)d_in[3];
  const float* Wk   = (const float*)d_in[4];
  const float* Wv   = (const float*)d_in[5];
  const float* Wo   = (const float*)d_in[6];
  const float* bo   = (const float*)d_in[7];
  const float* ln1g = (const float*)d_in[8];
  const float* ln1b = (const float*)d_in[9];
  const float* ln2g = (const float*)d_in[10];
  const float* ln2b = (const float*)d_in[11];
  const float* W1   = (const float*)d_in[12];
  const float* b1   = (const float*)d_in[13];
  const float* W2   = (const float*)d_in[14];
  const float* b2   = (const float*)d_in[15];
  const float* lnfg = (const float*)d_in[16];
  const float* lnfb = (const float*)d_in[17];
  const float* lmw  = (const float*)d_in[18];
  const float* lmb  = (const float*)d_in[19];
  float* out = (float*)d_out;

  // d_out: x[0,32M) | h[32,64M) (ln out; later V planes 2x16M) | qk/a1 [64,128M)
  // ws (64 MB, time-shared; liveness checked):
  //  phase A: aspH (3pl) [0,48) | bsQK [48,60) | bsV [60,64)
  //           then (aspH dead after V gemm) Kp (3pl) [0,48) via ksplit
  //  phase B: aspH2 [0,32) | bsO [32,36)
  //  phase C: aspH3 [0,32) | bsW1 [32,48) | bsW2 [48,64)
  //  final:   hf [0,32) | bsL [32,40)
  char* ob = (char*)d_out;
  float* x  = (float*)ob;
  float* h  = (float*)(ob + ((size_t)32<<20));
  float* vplanes = (float*)(ob + ((size_t)32<<20));  // 2 x 16MB bf16 planes
  float* qk = (float*)(ob + ((size_t)64<<20));
  float* a1 = (float*)(ob + ((size_t)64<<20));
  char* wsb = (char*)d_ws;
  uint4* aspH  = (uint4*)wsb;
  uint4* bsQK  = (uint4*)(wsb + ((size_t)48<<20));
  uint4* bsV   = (uint4*)(wsb + ((size_t)60<<20));
  uint4* Kp    = (uint4*)wsb;
  uint4* aspH2 = (uint4*)wsb;
  uint4* bsO   = (uint4*)(wsb + ((size_t)32<<20));
  uint4* aspH3 = (uint4*)wsb;
  uint4* bsW1  = (uint4*)(wsb + ((size_t)32<<20));
  uint4* bsW2  = (uint4*)(wsb + ((size_t)48<<20));
  float* hf    = (float*)wsb;
  uint4* bsL   = (uint4*)(wsb + ((size_t)32<<20));
  const size_t aPSh = (size_t)128 * 16 * 512;

  dim3 blk(256);
  dim3 gQK(16, 128);
  dim3 gV(8, 64), gO(8, 64);
  dim3 gW1(16, 64), gW2(8, 64), gL(32, 64);
  dim3 sA(128, 16), s8(8, 16), sW1(32, 16), sW2(8, 64), sLM(32, 16);

  embed_kernel<<<BT, blk, 0, stream>>>(idx, tok, pos, x);
  for (int l = 0; l < LL; ++l) {
    const float* Wq_l = Wq + (size_t)l*CC*CC;
    const float* Wk_l = Wk + (size_t)l*CC*CC;
    const float* Wv_l = Wv + (size_t)l*CC*CC;
    const float* Wo_l = Wo + (size_t)l*CC*CC;
    const float* W1_l = W1 + (size_t)l*CC*4*CC;
    const float* W2_l = W2 + (size_t)l*4*CC*CC;
    ln32_kernel<<<BT, blk, 0, stream>>>(x, ln1g + (size_t)l*CC, ln1b + (size_t)l*CC, h);
    asplit_kernel<3><<<sA, blk, 0, stream>>>(h, CC, aspH);
    bsplit_kernel<3><<<s8, blk, 0, stream>>>(Wq_l, bsQK, CC, 0, 16);
    bsplit_kernel<3><<<s8, blk, 0, stream>>>(Wk_l, bsQK, CC, 8, 16);
    bsplit_kernel<2><<<s8, blk, 0, stream>>>(Wv_l, bsV, CC, 0, 8);
    gemm_kernel<3,true><<<gQK, blk, 0, stream>>>(nullptr, 0, aspH, aPSh, bsQK,
        nullptr, nullptr, qk, CC, 2048, 0, 0, 16, 0, 16, 0);
    gemm128_kernel<2,true><<<gV, blk, 0, stream>>>(nullptr, 0, aspH, aPSh, bsV,
        nullptr, nullptr, vplanes, CC, CC, 0, 0, 8, 0, 16, 1);
    ksplit_kernel<<<2048, blk, 0, stream>>>(qk, Kp);
    attn_mfma_kernel<<<BB*HH*16, blk, 0, stream>>>(qk, Kp, (const uint4*)vplanes);
    asplit_kernel<2><<<sA, blk, 0, stream>>>(qk, 2048, aspH2);
    bsplit_kernel<2><<<s8, blk, 0, stream>>>(Wo_l, bsO, CC, 0, 8);
    gemm128_kernel<2,true><<<gO, blk, 0, stream>>>(nullptr, 0, aspH2, aPSh, bsO,
        bo + (size_t)l*CC, x, x, CC, CC, 0, 0, 8, 0, 16, 0);
    ln32_kernel<<<BT, blk, 0, stream>>>(x, ln2g + (size_t)l*CC, ln2b + (size_t)l*CC, h);
    asplit_kernel<2><<<sA, blk, 0, stream>>>(h, CC, aspH3);
    bsplit_kernel<2><<<sW1, blk, 0, stream>>>(W1_l, bsW1, 4*CC, 0, 32);
    bsplit_kernel<2><<<sW2, blk, 0, stream>>>(W2_l, bsW2, CC, 0, 8);
    gemm128_kernel<2,true><<<gW1, blk, 0, stream>>>(nullptr, 0, aspH3, aPSh, bsW1,
        b1 + (size_t)l*4*CC, nullptr, a1, CC, 2048, 1, 0, 32, 0, 16, 0);
    gemm128_kernel<2,false><<<gW2, blk, 0, stream>>>(a1, 2048, nullptr, 0, bsW2,
        b2 + (size_t)l*CC, x, x, 2048, CC, 0, 0, 8, 0, 64, 0);
    gemm128_kernel<2,true><<<gW1, blk, 0, stream>>>(nullptr, 0, aspH3, aPSh, bsW1,
        b1 + (size_t)l*4*CC + 2048, nullptr, a1, CC, 2048, 1, 16, 32, 0, 16, 0);
    gemm128_kernel<2,false><<<gW2, blk, 0, stream>>>(a1, 2048, nullptr, 0, bsW2,
        nullptr, x, x, 2048, CC, 0, 0, 8, 32, 64, 0);
  }
  ln32_kernel<<<BT, blk, 0, stream>>>(x, lnfg, lnfb, hf);
  bsplit_kernel<1><<<sLM, blk, 0, stream>>>(lmw, bsL, VV, 0, 32);
  gemm128_kernel<1,false><<<gL, blk, 0, stream>>>(hf, CC, nullptr, 0, bsL,
      lmb, nullptr, out, CC, VV, 0, 0, 32, 0, 16, 0);
}

// Round 15
// 6080.488 us; speedup vs baseline: 9.0441x; 1.0556x over previous
//
#include <hip/hip_runtime.h>

#define LL 6
#define BB 8
#define TT 1024
#define CC 1024
#define HH 16
#define HS 64
#define VV 4096
#define BT (BB*TT)

typedef __attribute__((ext_vector_type(4))) float f32x4;
typedef __attribute__((ext_vector_type(8))) short bf16x8;

__device__ __forceinline__ float bf2f(unsigned short u) {
  union { unsigned int u; float f; } v; v.u = ((unsigned int)u) << 16; return v.f;
}
__device__ __forceinline__ unsigned short rne16(float f) {
  unsigned u = __float_as_uint(f);
  return (unsigned short)((u + 0x7fffu + ((u >> 16) & 1u)) >> 16);
}
__device__ __forceinline__ void gld16(const uint4* g, uint4* l) {
  __builtin_amdgcn_global_load_lds(
      (const __attribute__((address_space(1))) void*)g,
      (__attribute__((address_space(3))) void*)l, 16, 0, 0);
}

// ---------------- embedding ----------------
__global__ __launch_bounds__(256) void embed_kernel(
    const int* __restrict__ idx, const float* __restrict__ tok,
    const float* __restrict__ pos, float* __restrict__ x) {
  int bt = blockIdx.x;
  int t = bt & (TT - 1);
  int id = idx[bt];
  float4 te = reinterpret_cast<const float4*>(tok)[(size_t)id * (CC/4) + threadIdx.x];
  float4 pe = reinterpret_cast<const float4*>(pos)[(size_t)t * (CC/4) + threadIdx.x];
  float4 r; r.x = te.x+pe.x; r.y = te.y+pe.y; r.z = te.z+pe.z; r.w = te.w+pe.w;
  reinterpret_cast<float4*>(x)[(size_t)bt * (CC/4) + threadIdx.x] = r;
}

// ---- splits ----
struct Oct3 { uint4 p0, p1, p2; };
__device__ __forceinline__ unsigned pk2(unsigned lo, unsigned hi) {
  return (lo >> 16) | (hi & 0xffff0000u);
}
__device__ __forceinline__ Oct3 split8(const float* f) {
  unsigned a0[8], a1[8], a2[8];
  #pragma unroll
  for (int e = 0; e < 8; ++e) {
    float v = f[e];
    unsigned u = __float_as_uint(v);
    a0[e] = u;
    float r = v - __uint_as_float(u & 0xffff0000u);
    unsigned ur = __float_as_uint(r);
    a1[e] = ur;
    float r2 = r - __uint_as_float(ur & 0xffff0000u);
    a2[e] = __float_as_uint(r2);
  }
  Oct3 o;
  o.p0 = make_uint4(pk2(a0[0],a0[1]), pk2(a0[2],a0[3]), pk2(a0[4],a0[5]), pk2(a0[6],a0[7]));
  o.p1 = make_uint4(pk2(a1[0],a1[1]), pk2(a1[2],a1[3]), pk2(a1[4],a1[5]), pk2(a1[6],a1[7]));
  o.p2 = make_uint4(pk2(a2[0],a2[1]), pk2(a2[2],a2[3]), pk2(a2[4],a2[5]), pk2(a2[6],a2[7]));
  return o;
}
struct Oct2 { uint4 p0, p1; };
__device__ __forceinline__ Oct2 split8_rne2(const float* f) {
  unsigned h0[8], h1[8];
  #pragma unroll
  for (int e = 0; e < 8; ++e) {
    h0[e] = rne16(f[e]);
    float r = f[e] - bf2f((unsigned short)h0[e]);
    h1[e] = rne16(r);
  }
  Oct2 o;
  o.p0 = make_uint4(h0[0]|(h0[1]<<16), h0[2]|(h0[3]<<16), h0[4]|(h0[5]<<16), h0[6]|(h0[7]<<16));
  o.p1 = make_uint4(h1[0]|(h1[1]<<16), h1[2]|(h1[3]<<16), h1[4]|(h1[5]<<16), h1[6]|(h1[7]<<16));
  return o;
}
__device__ __forceinline__ uint4 pack8_rne(const float* f) {
  unsigned h[8];
  #pragma unroll
  for (int e = 0; e < 8; ++e) h[e] = rne16(f[e]);
  return make_uint4(h[0]|(h[1]<<16), h[2]|(h[3]<<16), h[4]|(h[5]<<16), h[6]|(h[7]<<16));
}

// ---------------- layernorm fp32->fp32 (final LN only) ----------------
__global__ __launch_bounds__(256) void ln32_kernel(
    const float* __restrict__ x, const float* __restrict__ g,
    const float* __restrict__ b, float* __restrict__ out) {
  __shared__ float red[8];
  int row = blockIdx.x, tid = threadIdx.x;
  float4 v = reinterpret_cast<const float4*>(x)[(size_t)row * (CC/4) + tid];
  float s  = v.x+v.y+v.z+v.w;
  float ss = v.x*v.x+v.y*v.y+v.z*v.z+v.w*v.w;
  #pragma unroll
  for (int off = 32; off; off >>= 1) { s += __shfl_xor(s, off); ss += __shfl_xor(ss, off); }
  if ((tid & 63) == 0) { red[tid>>6] = s; red[4+(tid>>6)] = ss; }
  __syncthreads();
  s  = red[0]+red[1]+red[2]+red[3];
  ss = red[4]+red[5]+red[6]+red[7];
  float mu = s * (1.f/CC);
  float rs = rsqrtf(ss*(1.f/CC) - mu*mu + 1e-5f);
  float4 gg = reinterpret_cast<const float4*>(g)[tid];
  float4 bb = reinterpret_cast<const float4*>(b)[tid];
  float4 o;
  o.x = (v.x-mu)*rs*gg.x + bb.x;
  o.y = (v.y-mu)*rs*gg.y + bb.y;
  o.z = (v.z-mu)*rs*gg.z + bb.z;
  o.w = (v.w-mu)*rs*gg.w + bb.w;
  reinterpret_cast<float4*>(out)[(size_t)row * (CC/4) + tid] = o;
}

// ---------------- FUSED layernorm + A-presplit (pre-swizzled tile layout) --------
template<int NP>
__global__ __launch_bounds__(256) void lnsplit_kernel(
    const float* __restrict__ x, const float* __restrict__ g,
    const float* __restrict__ b, uint4* __restrict__ outp) {
  __shared__ float red[8];
  __shared__ float rowbuf[1024];
  int row = blockIdx.x, tid = threadIdx.x;
  float4 v = reinterpret_cast<const float4*>(x)[(size_t)row * (CC/4) + tid];
  float s  = v.x+v.y+v.z+v.w;
  float ss = v.x*v.x+v.y*v.y+v.z*v.z+v.w*v.w;
  #pragma unroll
  for (int off = 32; off; off >>= 1) { s += __shfl_xor(s, off); ss += __shfl_xor(ss, off); }
  if ((tid & 63) == 0) { red[tid>>6] = s; red[4+(tid>>6)] = ss; }
  __syncthreads();
  s  = red[0]+red[1]+red[2]+red[3];
  ss = red[4]+red[5]+red[6]+red[7];
  float mu = s * (1.f/CC);
  float rs = rsqrtf(ss*(1.f/CC) - mu*mu + 1e-5f);
  float4 gg = reinterpret_cast<const float4*>(g)[tid];
  float4 bb = reinterpret_cast<const float4*>(b)[tid];
  float4 o;
  o.x = (v.x-mu)*rs*gg.x + bb.x;
  o.y = (v.y-mu)*rs*gg.y + bb.y;
  o.z = (v.z-mu)*rs*gg.z + bb.z;
  o.w = (v.w-mu)*rs*gg.w + bb.w;
  *reinterpret_cast<float4*>(&rowbuf[tid*4]) = o;
  __syncthreads();
  if (tid < 128) {
    const size_t aPS = (size_t)128 * 16 * 512;
    int kt = tid >> 3, sl = tid & 7;
    int r = row & 63, mt = row >> 6;
    float f[8];
    #pragma unroll
    for (int e = 0; e < 8; ++e) f[e] = rowbuf[tid*8 + e];
    size_t di = ((size_t)(mt*16 + kt))*512 + r*8 + (sl ^ (r & 7));
    if (NP == 3) {
      Oct3 ot = split8(f);
      outp[di] = ot.p0; outp[aPS+di] = ot.p1; outp[2*aPS+di] = ot.p2;
    } else {
      Oct2 ot = split8_rne2(f);
      outp[di] = ot.p0; outp[aPS+di] = ot.p1;
    }
  }
}

// ---------------- A pre-split (kept for attn-out -> Wo path) ----------------
template<int NP>
__global__ __launch_bounds__(256) void asplit_kernel(
    const float* __restrict__ A, int lda, uint4* __restrict__ outp) {
  int mt = blockIdx.x, kt = blockIdx.y;
  size_t aPS = (size_t)gridDim.x * gridDim.y * 512;
  int tid = threadIdx.x;
  #pragma unroll
  for (int i = 0; i < 2; ++i) {
    int c = tid + i * 256;
    int row = c >> 3, sl = c & 7;
    const float4* ap = reinterpret_cast<const float4*>(
        A + (size_t)(mt*64 + row) * lda + kt*64 + sl*8);
    float4 x0 = ap[0], x1 = ap[1];
    float f[8] = {x0.x,x0.y,x0.z,x0.w,x1.x,x1.y,x1.z,x1.w};
    size_t di = ((size_t)(mt * gridDim.y + kt)) * 512
              + ((c & ~7) | ((c & 7) ^ ((c >> 3) & 7)));
    if (NP == 3) {
      Oct3 o = split8(f);
      outp[di] = o.p0; outp[aPS+di] = o.p1; outp[2*aPS+di] = o.p2;
    } else {
      Oct2 o = split8_rne2(f);
      outp[di] = o.p0; outp[aPS+di] = o.p1;
    }
  }
}

// ---------------- B pre-split (R11-proven) ----------------
template<int NP>
__global__ __launch_bounds__(256) void bsplit_kernel(
    const float* __restrict__ Bw, uint4* __restrict__ outp, int ldb,
    int ntile0, int ntTotal) {
  int ntile = ntile0 + blockIdx.x, kt = blockIdx.y;
  size_t planeStride = (size_t)ntTotal * gridDim.y * 1024;
  int tid = threadIdx.x;
  int bcol = tid & 127, bkcg = tid >> 7;
  #pragma unroll
  for (int g = 0; g < 4; ++g) {
    int kc = bkcg*4 + g;
    float f[8];
    #pragma unroll
    for (int j = 0; j < 8; ++j)
      f[j] = Bw[(size_t)(kt*64 + kc*8 + j) * ldb + blockIdx.x*128 + bcol];
    size_t di = (((size_t)ntile * gridDim.y + kt) * 8 + kc) * 128 + bcol;
    if (NP == 3) {
      Oct3 o = split8(f);
      outp[di] = o.p0; outp[planeStride+di] = o.p1; outp[2*planeStride+di] = o.p2;
    } else if (NP == 2) {
      Oct2 o = split8_rne2(f);
      outp[di] = o.p0; outp[planeStride+di] = o.p1;
    } else {
      outp[di] = pack8_rne(f);
    }
  }
}

// ---------------- K pre-split (R14-proven) ----------------
__global__ __launch_bounds__(256) void ksplit_kernel(
    const float* __restrict__ qk, uint4* __restrict__ Kp) {
  int tile = blockIdx.x;
  int kt = tile & 15, hh = (tile >> 4) & 15, b = tile >> 8;
  const size_t KPS = (size_t)2048 * 512;
  int tid = threadIdx.x;
  #pragma unroll
  for (int i = 0; i < 2; ++i) {
    int c = tid + i*256;
    int r = c >> 3, sl = c & 7;
    const float4* kp = reinterpret_cast<const float4*>(
        qk + ((size_t)(b*TT + kt*64 + r))*2048 + 1024 + hh*HS + sl*8);
    float4 x0 = kp[0], x1 = kp[1];
    float f[8] = {x0.x,x0.y,x0.z,x0.w,x1.x,x1.y,x1.z,x1.w};
    Oct3 ot = split8(f);
    size_t di = (size_t)tile*512 + r*8 + (sl ^ (r & 7));
    Kp[di] = ot.p0; Kp[KPS+di] = ot.p1; Kp[2*KPS+di] = ot.p2;
  }
}

// ---------------- OLD 64x128 GEMM (QK only: NP=3, DMA staging) ----------------
template<int NP, bool ASP>
__global__ __launch_bounds__(256) void gemm_kernel(
    const float* __restrict__ A, int lda,
    const uint4* __restrict__ Asp, size_t aPS,
    const uint4* __restrict__ Bs,
    const float* __restrict__ bias, const float* __restrict__ res,
    float* __restrict__ outf, int K, int ldc, int relu,
    int ntile0, int ntTotal, int kt0, int ktTotal, int vtmode) {
  __shared__ uint4 lds_a[NP][64*8];
  __shared__ uint4 lds_b[NP][8*128];
  int tid = threadIdx.x;
  int m0 = blockIdx.y * 64;
  int n0 = blockIdx.x * 128;
  int ntg = ntile0 + blockIdx.x;
  size_t planeStride = (size_t)ntTotal * ktTotal * 1024;
  int lane = tid & 63, wid = tid >> 6;
  int wm = wid >> 1, wn = wid & 1;
  int lr = lane & 15, lk = lane >> 4;

  f32x4 acc[2][4];
  #pragma unroll
  for (int m = 0; m < 2; ++m)
    #pragma unroll
    for (int n = 0; n < 4; ++n)
      acc[m][n] = (f32x4){0.f, 0.f, 0.f, 0.f};

  for (int k0 = 0; k0 < K; k0 += 64) {
    {
      size_t abase = ((size_t)blockIdx.y * (unsigned)(K >> 6) + (k0 >> 6)) * 512;
      #pragma unroll
      for (int p = 0; p < NP; ++p)
        #pragma unroll
        for (int i = 0; i < 2; ++i) {
          int ch = i*4 + wid;
          gld16(Asp + p*aPS + abase + ch*64 + lane, &lds_a[p][ch*64]);
        }
    }
    {
      int ktg = kt0 + (k0 >> 6);
      size_t bbase = ((size_t)ntg * ktTotal + ktg) * 1024;
      #pragma unroll
      for (int p = 0; p < NP; ++p)
        #pragma unroll
        for (int i = 0; i < 4; ++i) {
          int ch = i*4 + wid;
          gld16(Bs + p*planeStride + bbase + ch*64 + lane, &lds_b[p][ch*64]);
        }
    }
    __syncthreads();
    #pragma unroll
    for (int ks = 0; ks < 2; ++ks) {
      int kc = ks*4 + lk;
      bf16x8 af[NP][2], bfr[NP][4];
      #pragma unroll
      for (int m = 0; m < 2; ++m) {
        int row = wm*32 + m*16 + lr;
        int si = row*8 + (kc ^ (row & 7));
        #pragma unroll
        for (int p = 0; p < NP; ++p)
          af[p][m] = reinterpret_cast<const bf16x8*>(lds_a[p])[si];
      }
      #pragma unroll
      for (int n = 0; n < 4; ++n) {
        int si = kc*128 + wn*64 + n*16 + lr;
        #pragma unroll
        for (int p = 0; p < NP; ++p)
          bfr[p][n] = reinterpret_cast<const bf16x8*>(lds_b[p])[si];
      }
      #pragma unroll
      for (int m = 0; m < 2; ++m)
        #pragma unroll
        for (int n = 0; n < 4; ++n) {
          acc[m][n] = __builtin_amdgcn_mfma_f32_16x16x32_bf16(af[0][m], bfr[0][n], acc[m][n], 0, 0, 0);
          if (NP >= 2) {
            acc[m][n] = __builtin_amdgcn_mfma_f32_16x16x32_bf16(af[0][m], bfr[1][n], acc[m][n], 0, 0, 0);
            acc[m][n] = __builtin_amdgcn_mfma_f32_16x16x32_bf16(af[1][m], bfr[0][n], acc[m][n], 0, 0, 0);
            acc[m][n] = __builtin_amdgcn_mfma_f32_16x16x32_bf16(af[1][m], bfr[1][n], acc[m][n], 0, 0, 0);
          }
          if (NP == 3) {
            acc[m][n] = __builtin_amdgcn_mfma_f32_16x16x32_bf16(af[2][m], bfr[0][n], acc[m][n], 0, 0, 0);
            acc[m][n] = __builtin_amdgcn_mfma_f32_16x16x32_bf16(af[0][m], bfr[2][n], acc[m][n], 0, 0, 0);
          }
        }
    }
    __syncthreads();
  }

  #pragma unroll
  for (int m = 0; m < 2; ++m) {
    #pragma unroll
    for (int n = 0; n < 4; ++n) {
      int col = n0 + wn*64 + n*16 + lr;
      float bv = bias ? bias[col] : 0.f;
      #pragma unroll
      for (int j = 0; j < 4; ++j) {
        int row = m0 + wm*32 + m*16 + lk*4 + j;
        float vv = acc[m][n][j] + bv;
        if (relu) vv = fmaxf(vv, 0.f);
        size_t off = (size_t)row * ldc + col;
        if (res) vv += res[off];
        outf[off] = vv;
      }
    }
  }
  (void)A; (void)lda; (void)vtmode;
}

// ---------------- 128x128 GEMM, global_load_lds staging ------
// vtmode: 0=normal, 1=V-plane epilogue (attn layout), 2=a1 2-plane epilogue
// (bias+relu, LDS bounce, pre-swizzled A-tile layout; outf = plane0 base).
template<int NP, bool ASP>
__global__ __launch_bounds__(256) void gemm128_kernel(
    const float* __restrict__ A, int lda,
    const uint4* __restrict__ Asp, size_t aPS,
    const uint4* __restrict__ Bs,
    const float* __restrict__ bias, const float* __restrict__ res,
    float* __restrict__ outf, int K, int ldc, int relu,
    int ntile0, int ntTotal, int kt0, int ktTotal, int vtmode) {
  __shared__ uint4 lds_all[NP*2048];
  uint4* lds_a = lds_all;
  uint4* lds_b = lds_all + NP*1024;
  int tid = threadIdx.x;
  int by = blockIdx.y;
  int m0 = by * 128;
  int n0 = blockIdx.x * 128;
  int ntg = ntile0 + blockIdx.x;
  size_t bPS = (size_t)ntTotal * ktTotal * 1024;
  int lane = tid & 63, w = tid >> 6;
  int wm = w >> 1, wn = w & 1;
  int lr = lane & 15, lk = lane >> 4;
  int nkt = K >> 6;

  f32x4 acc[4][4];
  #pragma unroll
  for (int m = 0; m < 4; ++m)
    #pragma unroll
    for (int n = 0; n < 4; ++n)
      acc[m][n] = (f32x4){0.f, 0.f, 0.f, 0.f};

  for (int kt = 0; kt < nkt; ++kt) {
    if (ASP) {
      #pragma unroll
      for (int p = 0; p < NP; ++p) {
        const uint4* s0 = Asp + p*aPS + ((size_t)(2*by)   * nkt + kt)*512;
        const uint4* s1 = Asp + p*aPS + ((size_t)(2*by+1) * nkt + kt)*512;
        #pragma unroll
        for (int i = 0; i < 2; ++i) {
          int ch = w*2 + i;
          gld16(s0 + ch*64 + lane, &lds_a[p*1024 + ch*64]);
          gld16(s1 + ch*64 + lane, &lds_a[p*1024 + 512 + ch*64]);
        }
      }
    } else {
      #pragma unroll
      for (int i = 0; i < 4; ++i) {
        int c = tid + i * 256;
        int row = c >> 3, sl = c & 7;
        const float4* ap = reinterpret_cast<const float4*>(
            A + (size_t)(m0+row)*lda + kt*64 + sl*8);
        float4 x0 = ap[0], x1 = ap[1];
        float f[8] = {x0.x,x0.y,x0.z,x0.w,x1.x,x1.y,x1.z,x1.w};
        int di = (row>>6)*512 + (row&63)*8 + (sl ^ (row & 7));
        if (NP == 2) {
          Oct2 o = split8_rne2(f);
          lds_a[di] = o.p0; lds_a[1024 + di] = o.p1;
        } else {
          lds_a[di] = pack8_rne(f);
        }
      }
    }
    {
      int ktg = kt0 + kt;
      #pragma unroll
      for (int p = 0; p < NP; ++p) {
        const uint4* sb = Bs + p*bPS + ((size_t)ntg * ktTotal + ktg)*1024;
        #pragma unroll
        for (int i = 0; i < 4; ++i) {
          int ch = w*4 + i;
          gld16(sb + ch*64 + lane, &lds_b[p*1024 + ch*64]);
        }
      }
    }
    __syncthreads();
    #pragma unroll
    for (int ks = 0; ks < 2; ++ks) {
      int kc = ks*4 + lk;
      bf16x8 af[NP][4], bfr[NP][4];
      #pragma unroll
      for (int m = 0; m < 4; ++m) {
        int row = wm*64 + m*16 + lr;
        int si = (row>>6)*512 + (row&63)*8 + (kc ^ (row & 7));
        #pragma unroll
        for (int p = 0; p < NP; ++p)
          af[p][m] = reinterpret_cast<const bf16x8*>(lds_a + p*1024)[si];
      }
      #pragma unroll
      for (int n = 0; n < 4; ++n) {
        int si = kc*128 + wn*64 + n*16 + lr;
        #pragma unroll
        for (int p = 0; p < NP; ++p)
          bfr[p][n] = reinterpret_cast<const bf16x8*>(lds_b + p*1024)[si];
      }
      #pragma unroll
      for (int m = 0; m < 4; ++m)
        #pragma unroll
        for (int n = 0; n < 4; ++n) {
          acc[m][n] = __builtin_amdgcn_mfma_f32_16x16x32_bf16(af[0][m], bfr[0][n], acc[m][n], 0, 0, 0);
          if (NP == 2) {
            acc[m][n] = __builtin_amdgcn_mfma_f32_16x16x32_bf16(af[0][m], bfr[1][n], acc[m][n], 0, 0, 0);
            acc[m][n] = __builtin_amdgcn_mfma_f32_16x16x32_bf16(af[1][m], bfr[0][n], acc[m][n], 0, 0, 0);
            acc[m][n] = __builtin_amdgcn_mfma_f32_16x16x32_bf16(af[1][m], bfr[1][n], acc[m][n], 0, 0, 0);
          }
        }
    }
    __syncthreads();
  }

  if (vtmode == 1) {
    char* vb = (char*)outf;
    const size_t VPSb = (size_t)2048 * 512 * 16;
    #pragma unroll
    for (int m = 0; m < 4; ++m) {
      int row = m0 + wm*64 + m*16 + lk*4;
      int bq = row >> 10;
      int t  = row & (TT-1);
      int ktile = t >> 6, r = t & 63;
      int kc = r >> 3, toct0 = r & 7;
      #pragma unroll
      for (int n = 0; n < 4; ++n) {
        int col = n0 + wn*64 + n*16 + lr;
        int hh2 = col >> 6, d = col & 63;
        int tile = (bq*HH + hh2)*16 + ktile;
        int vi = kc*64 + ((d ^ (kc<<1)) & 63);
        unsigned p0[4], p1[4];
        #pragma unroll
        for (int j = 0; j < 4; ++j) {
          float v = acc[m][n][j];
          p0[j] = rne16(v);
          p1[j] = rne16(v - bf2f((unsigned short)p0[j]));
        }
        uint2 w0 = make_uint2(p0[0]|(p0[1]<<16), p0[2]|(p0[3]<<16));
        uint2 w1 = make_uint2(p1[0]|(p1[1]<<16), p1[2]|(p1[3]<<16));
        char* base = vb + ((size_t)tile*512 + vi)*16 + toct0*2;
        *reinterpret_cast<uint2*>(base) = w0;
        *reinterpret_cast<uint2*>(base + VPSb) = w1;
      }
    }
  } else if (vtmode == 2) {
    // a1 2-plane epilogue: bias + relu, LDS bounce, split, tiled write
    float* bounce = (float*)lds_all;     // 64KB for NP=2 -> 128x128 fp32
    #pragma unroll
    for (int m = 0; m < 4; ++m)
      #pragma unroll
      for (int n = 0; n < 4; ++n) {
        int cl = wn*64 + n*16 + lr;
        float bv = bias[n0 + cl];
        #pragma unroll
        for (int j = 0; j < 4; ++j) {
          int rl = wm*64 + m*16 + lk*4 + j;
          bounce[rl*128 + cl] = fmaxf(acc[m][n][j] + bv, 0.f);
        }
      }
    __syncthreads();
    uint4* a1p = (uint4*)outf;
    const size_t aPSa = (size_t)128 * 32 * 512;
    #pragma unroll
    for (int i = 0; i < 8; ++i) {
      int ot = tid + i*256;              // 0..2047
      int r = ot >> 4, o = ot & 15;
      float f[8];
      #pragma unroll
      for (int e = 0; e < 8; ++e) f[e] = bounce[r*128 + o*8 + e];
      Oct2 o2 = split8_rne2(f);
      int mt = 2*by + (r>>6), rs = r & 63;
      int ktg = (n0 >> 6) + (o >> 3), sl = o & 7;
      size_t di = ((size_t)(mt*32 + ktg))*512 + rs*8 + (sl ^ (rs & 7));
      a1p[di] = o2.p0; a1p[aPSa + di] = o2.p1;
    }
  } else {
    #pragma unroll
    for (int m = 0; m < 4; ++m) {
      #pragma unroll
      for (int n = 0; n < 4; ++n) {
        int col = n0 + wn*64 + n*16 + lr;
        float bv = bias ? bias[col] : 0.f;
        #pragma unroll
        for (int j = 0; j < 4; ++j) {
          int row = m0 + wm*64 + m*16 + lk*4 + j;
          float vv = acc[m][n][j] + bv;
          if (relu) vv = fmaxf(vv, 0.f);
          size_t off = (size_t)row * ldc + col;
          if (res) vv += res[off];
          outf[off] = vv;
        }
      }
    }
  }
}

// ---------------- MFMA flash attention (R14-proven, unchanged) ----------------
__global__ __launch_bounds__(256) void attn_mfma_kernel(
    float* __restrict__ qk, const uint4* __restrict__ Kp,
    const uint4* __restrict__ Vp) {
  __shared__ uint4 K_lds[3][512];
  __shared__ uint4 V_lds[2][512];
  __shared__ unsigned P_lds[64*68];
  const size_t KPS = (size_t)2048 * 512;
  const size_t VPS = (size_t)2048 * 512;
  int tid = threadIdx.x, lane = tid & 63, w = tid >> 6;
  int rid = blockIdx.x;
  int qt = rid & 15, hh = (rid >> 4) & 15, b = rid >> 8;
  int lr = lane & 15, lk = lane >> 4;
  const size_t tok0 = (size_t)b * TT;

  bf16x8 qa[2][3];
  {
    const float* qp = qk + (tok0 + qt*64 + w*16 + lr) * 2048 + hh*HS;
    #pragma unroll
    for (int ks = 0; ks < 2; ++ks) {
      const float4* p4 = reinterpret_cast<const float4*>(qp + ks*32 + lk*8);
      float4 a = p4[0], c = p4[1];
      float f[8] = {a.x,a.y,a.z,a.w,c.x,c.y,c.z,c.w};
      Oct3 ot = split8(f);
      qa[ks][0] = *reinterpret_cast<bf16x8*>(&ot.p0);
      qa[ks][1] = *reinterpret_cast<bf16x8*>(&ot.p1);
      qa[ks][2] = *reinterpret_cast<bf16x8*>(&ot.p2);
    }
  }

  float mrow[4] = {-3.0e38f,-3.0e38f,-3.0e38f,-3.0e38f};
  float lrow[4] = {0.f,0.f,0.f,0.f};
  f32x4 oac[4];
  #pragma unroll
  for (int n = 0; n < 4; ++n) oac[n] = (f32x4){0.f,0.f,0.f,0.f};

  for (int kt = 0; kt <= qt; ++kt) {
    __syncthreads();
    {
      int tile = ((b*HH + hh)*16 + kt);
      const uint4* ksrc = Kp + (size_t)tile*512;
      #pragma unroll
      for (int p = 0; p < 3; ++p)
        #pragma unroll
        for (int i = 0; i < 2; ++i) {
          int ch = w*2 + i;
          gld16(ksrc + p*KPS + ch*64 + lane, &K_lds[p][ch*64]);
        }
      const uint4* vsrc = Vp + (size_t)tile*512;
      #pragma unroll
      for (int p = 0; p < 2; ++p)
        #pragma unroll
        for (int i = 0; i < 2; ++i) {
          int ch = w*2 + i;
          gld16(vsrc + p*VPS + ch*64 + lane, &V_lds[p][ch*64]);
        }
    }
    __syncthreads();

    f32x4 sfr[4];
    #pragma unroll
    for (int nf = 0; nf < 4; ++nf) sfr[nf] = (f32x4){0.f,0.f,0.f,0.f};
    #pragma unroll
    for (int ks = 0; ks < 2; ++ks) {
      int kc = ks*4 + lk;
      #pragma unroll
      for (int nf = 0; nf < 4; ++nf) {
        int row = nf*16 + lr;
        int si = row*8 + (kc ^ (row & 7));
        bf16x8 k0 = *reinterpret_cast<const bf16x8*>(&K_lds[0][si]);
        bf16x8 k1 = *reinterpret_cast<const bf16x8*>(&K_lds[1][si]);
        bf16x8 k2 = *reinterpret_cast<const bf16x8*>(&K_lds[2][si]);
        sfr[nf] = __builtin_amdgcn_mfma_f32_16x16x32_bf16(qa[ks][0], k0, sfr[nf], 0,0,0);
        sfr[nf] = __builtin_amdgcn_mfma_f32_16x16x32_bf16(qa[ks][0], k1, sfr[nf], 0,0,0);
        sfr[nf] = __builtin_amdgcn_mfma_f32_16x16x32_bf16(qa[ks][1], k0, sfr[nf], 0,0,0);
        sfr[nf] = __builtin_amdgcn_mfma_f32_16x16x32_bf16(qa[ks][1], k1, sfr[nf], 0,0,0);
        sfr[nf] = __builtin_amdgcn_mfma_f32_16x16x32_bf16(qa[ks][2], k0, sfr[nf], 0,0,0);
        sfr[nf] = __builtin_amdgcn_mfma_f32_16x16x32_bf16(qa[ks][0], k2, sfr[nf], 0,0,0);
      }
    }
    #pragma unroll
    for (int nf = 0; nf < 4; ++nf)
      #pragma unroll
      for (int j = 0; j < 4; ++j) {
        float s = sfr[nf][j] * 8.0f;
        if (kt == qt && (nf*16 + lr) > (w*16 + lk*4 + j)) s = -3.0e38f;
        sfr[nf][j] = s;
      }
    float alpha[4], tsum[4];
    #pragma unroll
    for (int j = 0; j < 4; ++j) {
      float mx = fmaxf(fmaxf(sfr[0][j], sfr[1][j]), fmaxf(sfr[2][j], sfr[3][j]));
      mx = fmaxf(mx, __shfl_xor(mx, 1));
      mx = fmaxf(mx, __shfl_xor(mx, 2));
      mx = fmaxf(mx, __shfl_xor(mx, 4));
      mx = fmaxf(mx, __shfl_xor(mx, 8));
      float mnew = fmaxf(mrow[j], mx);
      alpha[j] = __expf(mrow[j] - mnew);
      mrow[j] = mnew;
      tsum[j] = 0.f;
    }
    #pragma unroll
    for (int nf = 0; nf < 4; ++nf)
      #pragma unroll
      for (int j = 0; j < 4; ++j) {
        float p = __expf(sfr[nf][j] - mrow[j]);
        tsum[j] += p;
        unsigned u = __float_as_uint(p);
        float r = p - __uint_as_float(u & 0xffff0000u);
        unsigned pw = (u & 0xffff0000u) | (__float_as_uint(r) >> 16);
        int qrow = w*16 + lk*4 + j;
        int kcol = nf*16 + lr;
        P_lds[qrow*68 + (((kcol>>3) ^ (qrow & 7)))*8 + (kcol & 7)] = pw;
      }
    #pragma unroll
    for (int j = 0; j < 4; ++j) {
      float ts = tsum[j];
      ts += __shfl_xor(ts, 1);
      ts += __shfl_xor(ts, 2);
      ts += __shfl_xor(ts, 4);
      ts += __shfl_xor(ts, 8);
      lrow[j] = lrow[j]*alpha[j] + ts;
      oac[0][j] *= alpha[j]; oac[1][j] *= alpha[j];
      oac[2][j] *= alpha[j]; oac[3][j] *= alpha[j];
    }
    __syncthreads();

    #pragma unroll
    for (int ks = 0; ks < 2; ++ks) {
      int kc = ks*4 + lk;
      int prow = w*16 + lr;
      const uint4* pp4 = reinterpret_cast<const uint4*>(
          &P_lds[prow*68 + ((kc ^ (prow & 7)))*8]);
      uint4 pw0 = pp4[0], pw1 = pp4[1];
      uint4 phu, plu;
      phu.x = (pw0.x>>16) | (pw0.y & 0xffff0000u);
      phu.y = (pw0.z>>16) | (pw0.w & 0xffff0000u);
      phu.z = (pw1.x>>16) | (pw1.y & 0xffff0000u);
      phu.w = (pw1.z>>16) | (pw1.w & 0xffff0000u);
      plu.x = (pw0.x & 0xffffu) | (pw0.y << 16);
      plu.y = (pw0.z & 0xffffu) | (pw0.w << 16);
      plu.z = (pw1.x & 0xffffu) | (pw1.y << 16);
      plu.w = (pw1.z & 0xffffu) | (pw1.w << 16);
      bf16x8 ph = *reinterpret_cast<bf16x8*>(&phu);
      bf16x8 pl = *reinterpret_cast<bf16x8*>(&plu);
      #pragma unroll
      for (int nf2 = 0; nf2 < 4; ++nf2) {
        int d = nf2*16 + lr;
        int vi = kc*64 + ((d ^ (kc<<1)) & 63);
        bf16x8 vh = *reinterpret_cast<const bf16x8*>(&V_lds[0][vi]);
        bf16x8 vl = *reinterpret_cast<const bf16x8*>(&V_lds[1][vi]);
        oac[nf2] = __builtin_amdgcn_mfma_f32_16x16x32_bf16(ph, vh, oac[nf2], 0,0,0);
        oac[nf2] = __builtin_amdgcn_mfma_f32_16x16x32_bf16(ph, vl, oac[nf2], 0,0,0);
        oac[nf2] = __builtin_amdgcn_mfma_f32_16x16x32_bf16(pl, vh, oac[nf2], 0,0,0);
      }
    }
  }

  #pragma unroll
  for (int j = 0; j < 4; ++j) {
    float inv = 1.0f / lrow[j];
    float* op = qk + (tok0 + qt*64 + w*16 + lk*4 + j) * 2048 + hh*HS;
    #pragma unroll
    for (int nf2 = 0; nf2 < 4; ++nf2)
      op[nf2*16 + lr] = oac[nf2][j] * inv;
  }
}

extern "C" void kernel_launch(void* const* d_in, const int* in_sizes, int n_in,
                              void* d_out, int out_size, void* d_ws, size_t ws_size,
                              hipStream_t stream) {
  const int*   idx  = (const int*)d_in[0];
  const float* tok  = (const float*)d_in[1];
  const float* pos  = (const float*)d_in[2];
  const float* Wq   = (const float*)d_in[3];
  const float* Wk   = (const float*)d_in[4];
  const float* Wv   = (const float*)d_in[5];
  const float* Wo   = (const float*)d_in[6];
  const float* bo   = (const float*)d_in[7];
  const float* ln1g = (const float*)d_in[8];
  const float* ln1b = (const float*)d_in[9];
  const float* ln2g = (const float*)d_in[10];
  const float* ln2b = (const float*)d_in[11];
  const float* W1   = (const float*)d_in[12];
  const float* b1   = (const float*)d_in[13];
  const float* W2   = (const float*)d_in[14];
  const float* b2   = (const float*)d_in[15];
  const float* lnfg = (const float*)d_in[16];
  const float* lnfb = (const float*)d_in[17];
  const float* lmw  = (const float*)d_in[18];
  const float* lmb  = (const float*)d_in[19];
  float* out = (float*)d_out;

  // d_out: x[0,32M) | vplanes[32,64M) | qk [64,128M) -> a1 planes [64,96),[96,128)
  // ws (64 MB, time-shared; liveness checked):
  //  phase A: aspH (3pl) [0,48) | bsQK [48,60) | bsV [60,64)
  //           then (aspH dead after V gemm) Kp (3pl) [0,48) via ksplit
  //  phase B: aspH2 [0,32) (over dead Kp, after attn) | bsO [32,36)
  //  phase C: aspH3 [0,32) | bsW1 [32,48) | bsW2 [48,64)
  //  final:   hf [0,32) | bsL [32,40)
  char* ob = (char*)d_out;
  float* x  = (float*)ob;
  float* vplanes = (float*)(ob + ((size_t)32<<20));
  float* qk = (float*)(ob + ((size_t)64<<20));
  float* a1p = (float*)(ob + ((size_t)64<<20));   // 2 x 32MB planes
  char* wsb = (char*)d_ws;
  uint4* aspH  = (uint4*)wsb;
  uint4* bsQK  = (uint4*)(wsb + ((size_t)48<<20));
  uint4* bsV   = (uint4*)(wsb + ((size_t)60<<20));
  uint4* Kp    = (uint4*)wsb;
  uint4* aspH2 = (uint4*)wsb;
  uint4* bsO   = (uint4*)(wsb + ((size_t)32<<20));
  uint4* aspH3 = (uint4*)wsb;
  uint4* bsW1  = (uint4*)(wsb + ((size_t)32<<20));
  uint4* bsW2  = (uint4*)(wsb + ((size_t)48<<20));
  float* hf    = (float*)wsb;
  uint4* bsL   = (uint4*)(wsb + ((size_t)32<<20));
  const size_t aPSh = (size_t)128 * 16 * 512;   // A planes for K=1024
  const size_t aPSa = (size_t)128 * 32 * 512;   // a1 planes (K=2048)

  dim3 blk(256);
  dim3 gQK(16, 128);
  dim3 gV(8, 64), gO(8, 64);
  dim3 gW1(16, 64), gW2(8, 64), gL(32, 64);
  dim3 sA(128, 16), s8(8, 16), sW1(32, 16), sW2(8, 64), sLM(32, 16);

  embed_kernel<<<BT, blk, 0, stream>>>(idx, tok, pos, x);
  for (int l = 0; l < LL; ++l) {
    const float* Wq_l = Wq + (size_t)l*CC*CC;
    const float* Wk_l = Wk + (size_t)l*CC*CC;
    const float* Wv_l = Wv + (size_t)l*CC*CC;
    const float* Wo_l = Wo + (size_t)l*CC*CC;
    const float* W1_l = W1 + (size_t)l*CC*4*CC;
    const float* W2_l = W2 + (size_t)l*4*CC*CC;
    lnsplit_kernel<3><<<BT, blk, 0, stream>>>(x, ln1g + (size_t)l*CC, ln1b + (size_t)l*CC, aspH);
    bsplit_kernel<3><<<s8, blk, 0, stream>>>(Wq_l, bsQK, CC, 0, 16);
    bsplit_kernel<3><<<s8, blk, 0, stream>>>(Wk_l, bsQK, CC, 8, 16);
    bsplit_kernel<2><<<s8, blk, 0, stream>>>(Wv_l, bsV, CC, 0, 8);
    gemm_kernel<3,true><<<gQK, blk, 0, stream>>>(nullptr, 0, aspH, aPSh, bsQK,
        nullptr, nullptr, qk, CC, 2048, 0, 0, 16, 0, 16, 0);
    gemm128_kernel<2,true><<<gV, blk, 0, stream>>>(nullptr, 0, aspH, aPSh, bsV,
        nullptr, nullptr, vplanes, CC, CC, 0, 0, 8, 0, 16, 1);
    ksplit_kernel<<<2048, blk, 0, stream>>>(qk, Kp);
    attn_mfma_kernel<<<BB*HH*16, blk, 0, stream>>>(qk, Kp, (const uint4*)vplanes);
    asplit_kernel<2><<<sA, blk, 0, stream>>>(qk, 2048, aspH2);
    bsplit_kernel<2><<<s8, blk, 0, stream>>>(Wo_l, bsO, CC, 0, 8);
    gemm128_kernel<2,true><<<gO, blk, 0, stream>>>(nullptr, 0, aspH2, aPSh, bsO,
        bo + (size_t)l*CC, x, x, CC, CC, 0, 0, 8, 0, 16, 0);
    lnsplit_kernel<2><<<BT, blk, 0, stream>>>(x, ln2g + (size_t)l*CC, ln2b + (size_t)l*CC, aspH3);
    bsplit_kernel<2><<<sW1, blk, 0, stream>>>(W1_l, bsW1, 4*CC, 0, 32);
    bsplit_kernel<2><<<sW2, blk, 0, stream>>>(W2_l, bsW2, CC, 0, 8);
    gemm128_kernel<2,true><<<gW1, blk, 0, stream>>>(nullptr, 0, aspH3, aPSh, bsW1,
        b1 + (size_t)l*4*CC, nullptr, a1p, CC, 2048, 1, 0, 32, 0, 16, 2);
    gemm128_kernel<2,true><<<gW2, blk, 0, stream>>>(nullptr, 0, (const uint4*)a1p, aPSa, bsW2,
        b2 + (size_t)l*CC, x, x, 2048, CC, 0, 0, 8, 0, 64, 0);
    gemm128_kernel<2,true><<<gW1, blk, 0, stream>>>(nullptr, 0, aspH3, aPSh, bsW1,
        b1 + (size_t)l*4*CC + 2048, nullptr, a1p, CC, 2048, 1, 16, 32, 0, 16, 2);
    gemm128_kernel<2,true><<<gW2, blk, 0, stream>>>(nullptr, 0, (const uint4*)a1p, aPSa, bsW2,
        nullptr, x, x, 2048, CC, 0, 0, 8, 32, 64, 0);
  }
  ln32_kernel<<<BT, blk, 0, stream>>>(x, lnfg, lnfb, hf);
  bsplit_kernel<1><<<sLM, blk, 0, stream>>>(lmw, bsL, VV, 0, 32);
  gemm128_kernel<1,false><<<gL, blk, 0, stream>>>(hf, CC, nullptr, 0, bsL,
      lmb, nullptr, out, CC, VV, 0, 0, 32, 0, 16, 0);
}

// Round 16
// 5724.601 us; speedup vs baseline: 9.6064x; 1.0622x over previous
//
#include <hip/hip_runtime.h>

#define LL 6
#define BB 8
#define TT 1024
#define CC 1024
#define HH 16
#define HS 64
#define VV 4096
#define BT (BB*TT)

typedef __attribute__((ext_vector_type(4))) float f32x4;
typedef __attribute__((ext_vector_type(8))) short bf16x8;

__device__ __forceinline__ float bf2f(unsigned short u) {
  union { unsigned int u; float f; } v; v.u = ((unsigned int)u) << 16; return v.f;
}
__device__ __forceinline__ unsigned short rne16(float f) {
  unsigned u = __float_as_uint(f);
  return (unsigned short)((u + 0x7fffu + ((u >> 16) & 1u)) >> 16);
}
__device__ __forceinline__ void gld16(const uint4* g, uint4* l) {
  __builtin_amdgcn_global_load_lds(
      (const __attribute__((address_space(1))) void*)g,
      (__attribute__((address_space(3))) void*)l, 16, 0, 0);
}

// ---------------- embedding ----------------
__global__ __launch_bounds__(256) void embed_kernel(
    const int* __restrict__ idx, const float* __restrict__ tok,
    const float* __restrict__ pos, float* __restrict__ x) {
  int bt = blockIdx.x;
  int t = bt & (TT - 1);
  int id = idx[bt];
  float4 te = reinterpret_cast<const float4*>(tok)[(size_t)id * (CC/4) + threadIdx.x];
  float4 pe = reinterpret_cast<const float4*>(pos)[(size_t)t * (CC/4) + threadIdx.x];
  float4 r; r.x = te.x+pe.x; r.y = te.y+pe.y; r.z = te.z+pe.z; r.w = te.w+pe.w;
  reinterpret_cast<float4*>(x)[(size_t)bt * (CC/4) + threadIdx.x] = r;
}

// ---- splits ----
struct Oct3 { uint4 p0, p1, p2; };
__device__ __forceinline__ unsigned pk2(unsigned lo, unsigned hi) {
  return (lo >> 16) | (hi & 0xffff0000u);
}
__device__ __forceinline__ Oct3 split8(const float* f) {
  unsigned a0[8], a1[8], a2[8];
  #pragma unroll
  for (int e = 0; e < 8; ++e) {
    float v = f[e];
    unsigned u = __float_as_uint(v);
    a0[e] = u;
    float r = v - __uint_as_float(u & 0xffff0000u);
    unsigned ur = __float_as_uint(r);
    a1[e] = ur;
    float r2 = r - __uint_as_float(ur & 0xffff0000u);
    a2[e] = __float_as_uint(r2);
  }
  Oct3 o;
  o.p0 = make_uint4(pk2(a0[0],a0[1]), pk2(a0[2],a0[3]), pk2(a0[4],a0[5]), pk2(a0[6],a0[7]));
  o.p1 = make_uint4(pk2(a1[0],a1[1]), pk2(a1[2],a1[3]), pk2(a1[4],a1[5]), pk2(a1[6],a1[7]));
  o.p2 = make_uint4(pk2(a2[0],a2[1]), pk2(a2[2],a2[3]), pk2(a2[4],a2[5]), pk2(a2[6],a2[7]));
  return o;
}
struct Oct2 { uint4 p0, p1; };
__device__ __forceinline__ Oct2 split8_rne2(const float* f) {
  unsigned h0[8], h1[8];
  #pragma unroll
  for (int e = 0; e < 8; ++e) {
    h0[e] = rne16(f[e]);
    float r = f[e] - bf2f((unsigned short)h0[e]);
    h1[e] = rne16(r);
  }
  Oct2 o;
  o.p0 = make_uint4(h0[0]|(h0[1]<<16), h0[2]|(h0[3]<<16), h0[4]|(h0[5]<<16), h0[6]|(h0[7]<<16));
  o.p1 = make_uint4(h1[0]|(h1[1]<<16), h1[2]|(h1[3]<<16), h1[4]|(h1[5]<<16), h1[6]|(h1[7]<<16));
  return o;
}
__device__ __forceinline__ uint4 pack8_rne(const float* f) {
  unsigned h[8];
  #pragma unroll
  for (int e = 0; e < 8; ++e) h[e] = rne16(f[e]);
  return make_uint4(h[0]|(h[1]<<16), h[2]|(h[3]<<16), h[4]|(h[5]<<16), h[6]|(h[7]<<16));
}

// ---------------- layernorm fp32->fp32 (final LN only) ----------------
__global__ __launch_bounds__(256) void ln32_kernel(
    const float* __restrict__ x, const float* __restrict__ g,
    const float* __restrict__ b, float* __restrict__ out) {
  __shared__ float red[8];
  int row = blockIdx.x, tid = threadIdx.x;
  float4 v = reinterpret_cast<const float4*>(x)[(size_t)row * (CC/4) + tid];
  float s  = v.x+v.y+v.z+v.w;
  float ss = v.x*v.x+v.y*v.y+v.z*v.z+v.w*v.w;
  #pragma unroll
  for (int off = 32; off; off >>= 1) { s += __shfl_xor(s, off); ss += __shfl_xor(ss, off); }
  if ((tid & 63) == 0) { red[tid>>6] = s; red[4+(tid>>6)] = ss; }
  __syncthreads();
  s  = red[0]+red[1]+red[2]+red[3];
  ss = red[4]+red[5]+red[6]+red[7];
  float mu = s * (1.f/CC);
  float rs = rsqrtf(ss*(1.f/CC) - mu*mu + 1e-5f);
  float4 gg = reinterpret_cast<const float4*>(g)[tid];
  float4 bb = reinterpret_cast<const float4*>(b)[tid];
  float4 o;
  o.x = (v.x-mu)*rs*gg.x + bb.x;
  o.y = (v.y-mu)*rs*gg.y + bb.y;
  o.z = (v.z-mu)*rs*gg.z + bb.z;
  o.w = (v.w-mu)*rs*gg.w + bb.w;
  reinterpret_cast<float4*>(out)[(size_t)row * (CC/4) + tid] = o;
}

// ---------------- FUSED layernorm + A-presplit (pre-swizzled tile layout) --------
template<int NP>
__global__ __launch_bounds__(256) void lnsplit_kernel(
    const float* __restrict__ x, const float* __restrict__ g,
    const float* __restrict__ b, uint4* __restrict__ outp) {
  __shared__ float red[8];
  __shared__ float rowbuf[1024];
  int row = blockIdx.x, tid = threadIdx.x;
  float4 v = reinterpret_cast<const float4*>(x)[(size_t)row * (CC/4) + tid];
  float s  = v.x+v.y+v.z+v.w;
  float ss = v.x*v.x+v.y*v.y+v.z*v.z+v.w*v.w;
  #pragma unroll
  for (int off = 32; off; off >>= 1) { s += __shfl_xor(s, off); ss += __shfl_xor(ss, off); }
  if ((tid & 63) == 0) { red[tid>>6] = s; red[4+(tid>>6)] = ss; }
  __syncthreads();
  s  = red[0]+red[1]+red[2]+red[3];
  ss = red[4]+red[5]+red[6]+red[7];
  float mu = s * (1.f/CC);
  float rs = rsqrtf(ss*(1.f/CC) - mu*mu + 1e-5f);
  float4 gg = reinterpret_cast<const float4*>(g)[tid];
  float4 bb = reinterpret_cast<const float4*>(b)[tid];
  float4 o;
  o.x = (v.x-mu)*rs*gg.x + bb.x;
  o.y = (v.y-mu)*rs*gg.y + bb.y;
  o.z = (v.z-mu)*rs*gg.z + bb.z;
  o.w = (v.w-mu)*rs*gg.w + bb.w;
  *reinterpret_cast<float4*>(&rowbuf[tid*4]) = o;
  __syncthreads();
  if (tid < 128) {
    const size_t aPS = (size_t)128 * 16 * 512;
    int kt = tid >> 3, sl = tid & 7;
    int r = row & 63, mt = row >> 6;
    float f[8];
    #pragma unroll
    for (int e = 0; e < 8; ++e) f[e] = rowbuf[tid*8 + e];
    size_t di = ((size_t)(mt*16 + kt))*512 + r*8 + (sl ^ (r & 7));
    if (NP == 3) {
      Oct3 ot = split8(f);
      outp[di] = ot.p0; outp[aPS+di] = ot.p1; outp[2*aPS+di] = ot.p2;
    } else {
      Oct2 ot = split8_rne2(f);
      outp[di] = ot.p0; outp[aPS+di] = ot.p1;
    }
  }
}

// ---------------- A pre-split (attn-out -> Wo path) ----------------
template<int NP>
__global__ __launch_bounds__(256) void asplit_kernel(
    const float* __restrict__ A, int lda, uint4* __restrict__ outp) {
  int mt = blockIdx.x, kt = blockIdx.y;
  size_t aPS = (size_t)gridDim.x * gridDim.y * 512;
  int tid = threadIdx.x;
  #pragma unroll
  for (int i = 0; i < 2; ++i) {
    int c = tid + i * 256;
    int row = c >> 3, sl = c & 7;
    const float4* ap = reinterpret_cast<const float4*>(
        A + (size_t)(mt*64 + row) * lda + kt*64 + sl*8);
    float4 x0 = ap[0], x1 = ap[1];
    float f[8] = {x0.x,x0.y,x0.z,x0.w,x1.x,x1.y,x1.z,x1.w};
    size_t di = ((size_t)(mt * gridDim.y + kt)) * 512
              + ((c & ~7) | ((c & 7) ^ ((c >> 3) & 7)));
    if (NP == 3) {
      Oct3 o = split8(f);
      outp[di] = o.p0; outp[aPS+di] = o.p1; outp[2*aPS+di] = o.p2;
    } else {
      Oct2 o = split8_rne2(f);
      outp[di] = o.p0; outp[aPS+di] = o.p1;
    }
  }
}

// ---------------- B pre-split (R11-proven) ----------------
template<int NP>
__global__ __launch_bounds__(256) void bsplit_kernel(
    const float* __restrict__ Bw, uint4* __restrict__ outp, int ldb,
    int ntile0, int ntTotal) {
  int ntile = ntile0 + blockIdx.x, kt = blockIdx.y;
  size_t planeStride = (size_t)ntTotal * gridDim.y * 1024;
  int tid = threadIdx.x;
  int bcol = tid & 127, bkcg = tid >> 7;
  #pragma unroll
  for (int g = 0; g < 4; ++g) {
    int kc = bkcg*4 + g;
    float f[8];
    #pragma unroll
    for (int j = 0; j < 8; ++j)
      f[j] = Bw[(size_t)(kt*64 + kc*8 + j) * ldb + blockIdx.x*128 + bcol];
    size_t di = (((size_t)ntile * gridDim.y + kt) * 8 + kc) * 128 + bcol;
    if (NP == 3) {
      Oct3 o = split8(f);
      outp[di] = o.p0; outp[planeStride+di] = o.p1; outp[2*planeStride+di] = o.p2;
    } else if (NP == 2) {
      Oct2 o = split8_rne2(f);
      outp[di] = o.p0; outp[planeStride+di] = o.p1;
    } else {
      outp[di] = pack8_rne(f);
    }
  }
}

// ---------------- K pre-split (R14-proven) ----------------
__global__ __launch_bounds__(256) void ksplit_kernel(
    const float* __restrict__ qk, uint4* __restrict__ Kp) {
  int tile = blockIdx.x;
  int kt = tile & 15, hh = (tile >> 4) & 15, b = tile >> 8;
  const size_t KPS = (size_t)2048 * 512;
  int tid = threadIdx.x;
  #pragma unroll
  for (int i = 0; i < 2; ++i) {
    int c = tid + i*256;
    int r = c >> 3, sl = c & 7;
    const float4* kp = reinterpret_cast<const float4*>(
        qk + ((size_t)(b*TT + kt*64 + r))*2048 + 1024 + hh*HS + sl*8);
    float4 x0 = kp[0], x1 = kp[1];
    float f[8] = {x0.x,x0.y,x0.z,x0.w,x1.x,x1.y,x1.z,x1.w};
    Oct3 ot = split8(f);
    size_t di = (size_t)tile*512 + r*8 + (sl ^ (r & 7));
    Kp[di] = ot.p0; Kp[KPS+di] = ot.p1; Kp[2*KPS+di] = ot.p2;
  }
}

// ---------------- OLD 64x128 GEMM (QK only: NP=3, DMA staging) ----------------
template<int NP, bool ASP>
__global__ __launch_bounds__(256) void gemm_kernel(
    const float* __restrict__ A, int lda,
    const uint4* __restrict__ Asp, size_t aPS,
    const uint4* __restrict__ Bs,
    const float* __restrict__ bias, const float* __restrict__ res,
    float* __restrict__ outf, int K, int ldc, int relu,
    int ntile0, int ntTotal, int kt0, int ktTotal, int vtmode) {
  __shared__ uint4 lds_a[NP][64*8];
  __shared__ uint4 lds_b[NP][8*128];
  int tid = threadIdx.x;
  int m0 = blockIdx.y * 64;
  int n0 = blockIdx.x * 128;
  int ntg = ntile0 + blockIdx.x;
  size_t planeStride = (size_t)ntTotal * ktTotal * 1024;
  int lane = tid & 63, wid = tid >> 6;
  int wm = wid >> 1, wn = wid & 1;
  int lr = lane & 15, lk = lane >> 4;

  f32x4 acc[2][4];
  #pragma unroll
  for (int m = 0; m < 2; ++m)
    #pragma unroll
    for (int n = 0; n < 4; ++n)
      acc[m][n] = (f32x4){0.f, 0.f, 0.f, 0.f};

  for (int k0 = 0; k0 < K; k0 += 64) {
    {
      size_t abase = ((size_t)blockIdx.y * (unsigned)(K >> 6) + (k0 >> 6)) * 512;
      #pragma unroll
      for (int p = 0; p < NP; ++p)
        #pragma unroll
        for (int i = 0; i < 2; ++i) {
          int ch = i*4 + wid;
          gld16(Asp + p*aPS + abase + ch*64 + lane, &lds_a[p][ch*64]);
        }
    }
    {
      int ktg = kt0 + (k0 >> 6);
      size_t bbase = ((size_t)ntg * ktTotal + ktg) * 1024;
      #pragma unroll
      for (int p = 0; p < NP; ++p)
        #pragma unroll
        for (int i = 0; i < 4; ++i) {
          int ch = i*4 + wid;
          gld16(Bs + p*planeStride + bbase + ch*64 + lane, &lds_b[p][ch*64]);
        }
    }
    __syncthreads();
    #pragma unroll
    for (int ks = 0; ks < 2; ++ks) {
      int kc = ks*4 + lk;
      bf16x8 af[NP][2], bfr[NP][4];
      #pragma unroll
      for (int m = 0; m < 2; ++m) {
        int row = wm*32 + m*16 + lr;
        int si = row*8 + (kc ^ (row & 7));
        #pragma unroll
        for (int p = 0; p < NP; ++p)
          af[p][m] = reinterpret_cast<const bf16x8*>(lds_a[p])[si];
      }
      #pragma unroll
      for (int n = 0; n < 4; ++n) {
        int si = kc*128 + wn*64 + n*16 + lr;
        #pragma unroll
        for (int p = 0; p < NP; ++p)
          bfr[p][n] = reinterpret_cast<const bf16x8*>(lds_b[p])[si];
      }
      #pragma unroll
      for (int m = 0; m < 2; ++m)
        #pragma unroll
        for (int n = 0; n < 4; ++n) {
          acc[m][n] = __builtin_amdgcn_mfma_f32_16x16x32_bf16(af[0][m], bfr[0][n], acc[m][n], 0, 0, 0);
          if (NP >= 2) {
            acc[m][n] = __builtin_amdgcn_mfma_f32_16x16x32_bf16(af[0][m], bfr[1][n], acc[m][n], 0, 0, 0);
            acc[m][n] = __builtin_amdgcn_mfma_f32_16x16x32_bf16(af[1][m], bfr[0][n], acc[m][n], 0, 0, 0);
            acc[m][n] = __builtin_amdgcn_mfma_f32_16x16x32_bf16(af[1][m], bfr[1][n], acc[m][n], 0, 0, 0);
          }
          if (NP == 3) {
            acc[m][n] = __builtin_amdgcn_mfma_f32_16x16x32_bf16(af[2][m], bfr[0][n], acc[m][n], 0, 0, 0);
            acc[m][n] = __builtin_amdgcn_mfma_f32_16x16x32_bf16(af[0][m], bfr[2][n], acc[m][n], 0, 0, 0);
          }
        }
    }
    __syncthreads();
  }

  #pragma unroll
  for (int m = 0; m < 2; ++m) {
    #pragma unroll
    for (int n = 0; n < 4; ++n) {
      int col = n0 + wn*64 + n*16 + lr;
      float bv = bias ? bias[col] : 0.f;
      #pragma unroll
      for (int j = 0; j < 4; ++j) {
        int row = m0 + wm*32 + m*16 + lk*4 + j;
        float vv = acc[m][n][j] + bv;
        if (relu) vv = fmaxf(vv, 0.f);
        size_t off = (size_t)row * ldc + col;
        if (res) vv += res[off];
        outf[off] = vv;
      }
    }
  }
  (void)A; (void)lda; (void)vtmode;
}

// ---------------- 128x128 GEMM, global_load_lds staging ------
// NP=2 now uses the 3-MFMA combo (a1*b1 dropped; ~2^-16 rel, zero-mean).
// vtmode: 0=normal, 1=V-plane epilogue, 2=a1 2-plane epilogue.
template<int NP, bool ASP>
__global__ __launch_bounds__(256) void gemm128_kernel(
    const float* __restrict__ A, int lda,
    const uint4* __restrict__ Asp, size_t aPS,
    const uint4* __restrict__ Bs,
    const float* __restrict__ bias, const float* __restrict__ res,
    float* __restrict__ outf, int K, int ldc, int relu,
    int ntile0, int ntTotal, int kt0, int ktTotal, int vtmode) {
  __shared__ uint4 lds_all[NP*2048];
  uint4* lds_a = lds_all;
  uint4* lds_b = lds_all + NP*1024;
  int tid = threadIdx.x;
  int by = blockIdx.y;
  int m0 = by * 128;
  int n0 = blockIdx.x * 128;
  int ntg = ntile0 + blockIdx.x;
  size_t bPS = (size_t)ntTotal * ktTotal * 1024;
  int lane = tid & 63, w = tid >> 6;
  int wm = w >> 1, wn = w & 1;
  int lr = lane & 15, lk = lane >> 4;
  int nkt = K >> 6;

  f32x4 acc[4][4];
  #pragma unroll
  for (int m = 0; m < 4; ++m)
    #pragma unroll
    for (int n = 0; n < 4; ++n)
      acc[m][n] = (f32x4){0.f, 0.f, 0.f, 0.f};

  for (int kt = 0; kt < nkt; ++kt) {
    if (ASP) {
      #pragma unroll
      for (int p = 0; p < NP; ++p) {
        const uint4* s0 = Asp + p*aPS + ((size_t)(2*by)   * nkt + kt)*512;
        const uint4* s1 = Asp + p*aPS + ((size_t)(2*by+1) * nkt + kt)*512;
        #pragma unroll
        for (int i = 0; i < 2; ++i) {
          int ch = w*2 + i;
          gld16(s0 + ch*64 + lane, &lds_a[p*1024 + ch*64]);
          gld16(s1 + ch*64 + lane, &lds_a[p*1024 + 512 + ch*64]);
        }
      }
    } else {
      #pragma unroll
      for (int i = 0; i < 4; ++i) {
        int c = tid + i * 256;
        int row = c >> 3, sl = c & 7;
        const float4* ap = reinterpret_cast<const float4*>(
            A + (size_t)(m0+row)*lda + kt*64 + sl*8);
        float4 x0 = ap[0], x1 = ap[1];
        float f[8] = {x0.x,x0.y,x0.z,x0.w,x1.x,x1.y,x1.z,x1.w};
        int di = (row>>6)*512 + (row&63)*8 + (sl ^ (row & 7));
        if (NP == 2) {
          Oct2 o = split8_rne2(f);
          lds_a[di] = o.p0; lds_a[1024 + di] = o.p1;
        } else {
          lds_a[di] = pack8_rne(f);
        }
      }
    }
    {
      int ktg = kt0 + kt;
      #pragma unroll
      for (int p = 0; p < NP; ++p) {
        const uint4* sb = Bs + p*bPS + ((size_t)ntg * ktTotal + ktg)*1024;
        #pragma unroll
        for (int i = 0; i < 4; ++i) {
          int ch = w*4 + i;
          gld16(sb + ch*64 + lane, &lds_b[p*1024 + ch*64]);
        }
      }
    }
    __syncthreads();
    #pragma unroll
    for (int ks = 0; ks < 2; ++ks) {
      int kc = ks*4 + lk;
      bf16x8 af[NP][4], bfr[NP][4];
      #pragma unroll
      for (int m = 0; m < 4; ++m) {
        int row = wm*64 + m*16 + lr;
        int si = (row>>6)*512 + (row&63)*8 + (kc ^ (row & 7));
        #pragma unroll
        for (int p = 0; p < NP; ++p)
          af[p][m] = reinterpret_cast<const bf16x8*>(lds_a + p*1024)[si];
      }
      #pragma unroll
      for (int n = 0; n < 4; ++n) {
        int si = kc*128 + wn*64 + n*16 + lr;
        #pragma unroll
        for (int p = 0; p < NP; ++p)
          bfr[p][n] = reinterpret_cast<const bf16x8*>(lds_b + p*1024)[si];
      }
      #pragma unroll
      for (int m = 0; m < 4; ++m)
        #pragma unroll
        for (int n = 0; n < 4; ++n) {
          acc[m][n] = __builtin_amdgcn_mfma_f32_16x16x32_bf16(af[0][m], bfr[0][n], acc[m][n], 0, 0, 0);
          if (NP == 2) {
            acc[m][n] = __builtin_amdgcn_mfma_f32_16x16x32_bf16(af[0][m], bfr[1][n], acc[m][n], 0, 0, 0);
            acc[m][n] = __builtin_amdgcn_mfma_f32_16x16x32_bf16(af[1][m], bfr[0][n], acc[m][n], 0, 0, 0);
            // a1*b1 dropped: ~2^-16 rel, zero-mean (RNE residuals)
          }
        }
    }
    __syncthreads();
  }

  if (vtmode == 1) {
    char* vb = (char*)outf;
    const size_t VPSb = (size_t)2048 * 512 * 16;
    #pragma unroll
    for (int m = 0; m < 4; ++m) {
      int row = m0 + wm*64 + m*16 + lk*4;
      int bq = row >> 10;
      int t  = row & (TT-1);
      int ktile = t >> 6, r = t & 63;
      int kc = r >> 3, toct0 = r & 7;
      #pragma unroll
      for (int n = 0; n < 4; ++n) {
        int col = n0 + wn*64 + n*16 + lr;
        int hh2 = col >> 6, d = col & 63;
        int tile = (bq*HH + hh2)*16 + ktile;
        int vi = kc*64 + ((d ^ (kc<<1)) & 63);
        unsigned p0[4], p1[4];
        #pragma unroll
        for (int j = 0; j < 4; ++j) {
          float v = acc[m][n][j];
          p0[j] = rne16(v);
          p1[j] = rne16(v - bf2f((unsigned short)p0[j]));
        }
        uint2 w0 = make_uint2(p0[0]|(p0[1]<<16), p0[2]|(p0[3]<<16));
        uint2 w1 = make_uint2(p1[0]|(p1[1]<<16), p1[2]|(p1[3]<<16));
        char* base = vb + ((size_t)tile*512 + vi)*16 + toct0*2;
        *reinterpret_cast<uint2*>(base) = w0;
        *reinterpret_cast<uint2*>(base + VPSb) = w1;
      }
    }
  } else if (vtmode == 2) {
    float* bounce = (float*)lds_all;
    #pragma unroll
    for (int m = 0; m < 4; ++m)
      #pragma unroll
      for (int n = 0; n < 4; ++n) {
        int cl = wn*64 + n*16 + lr;
        float bv = bias[n0 + cl];
        #pragma unroll
        for (int j = 0; j < 4; ++j) {
          int rl = wm*64 + m*16 + lk*4 + j;
          bounce[rl*128 + cl] = fmaxf(acc[m][n][j] + bv, 0.f);
        }
      }
    __syncthreads();
    uint4* a1p = (uint4*)outf;
    const size_t aPSa = (size_t)128 * 32 * 512;
    #pragma unroll
    for (int i = 0; i < 8; ++i) {
      int ot = tid + i*256;
      int r = ot >> 4, o = ot & 15;
      float f[8];
      #pragma unroll
      for (int e = 0; e < 8; ++e) f[e] = bounce[r*128 + o*8 + e];
      Oct2 o2 = split8_rne2(f);
      int mt = 2*by + (r>>6), rs = r & 63;
      int ktg = (n0 >> 6) + (o >> 3), sl = o & 7;
      size_t di = ((size_t)(mt*32 + ktg))*512 + rs*8 + (sl ^ (rs & 7));
      a1p[di] = o2.p0; a1p[aPSa + di] = o2.p1;
    }
  } else {
    #pragma unroll
    for (int m = 0; m < 4; ++m) {
      #pragma unroll
      for (int n = 0; n < 4; ++n) {
        int col = n0 + wn*64 + n*16 + lr;
        float bv = bias ? bias[col] : 0.f;
        #pragma unroll
        for (int j = 0; j < 4; ++j) {
          int row = m0 + wm*64 + m*16 + lk*4 + j;
          float vv = acc[m][n][j] + bv;
          if (relu) vv = fmaxf(vv, 0.f);
          size_t off = (size_t)row * ldc + col;
          if (res) vv += res[off];
          outf[off] = vv;
        }
      }
    }
  }
}

// ---------------- MFMA flash attention (R14-proven, unchanged) ----------------
__global__ __launch_bounds__(256) void attn_mfma_kernel(
    float* __restrict__ qk, const uint4* __restrict__ Kp,
    const uint4* __restrict__ Vp) {
  __shared__ uint4 K_lds[3][512];
  __shared__ uint4 V_lds[2][512];
  __shared__ unsigned P_lds[64*68];
  const size_t KPS = (size_t)2048 * 512;
  const size_t VPS = (size_t)2048 * 512;
  int tid = threadIdx.x, lane = tid & 63, w = tid >> 6;
  int rid = blockIdx.x;
  int qt = rid & 15, hh = (rid >> 4) & 15, b = rid >> 8;
  int lr = lane & 15, lk = lane >> 4;
  const size_t tok0 = (size_t)b * TT;

  bf16x8 qa[2][3];
  {
    const float* qp = qk + (tok0 + qt*64 + w*16 + lr) * 2048 + hh*HS;
    #pragma unroll
    for (int ks = 0; ks < 2; ++ks) {
      const float4* p4 = reinterpret_cast<const float4*>(qp + ks*32 + lk*8);
      float4 a = p4[0], c = p4[1];
      float f[8] = {a.x,a.y,a.z,a.w,c.x,c.y,c.z,c.w};
      Oct3 ot = split8(f);
      qa[ks][0] = *reinterpret_cast<bf16x8*>(&ot.p0);
      qa[ks][1] = *reinterpret_cast<bf16x8*>(&ot.p1);
      qa[ks][2] = *reinterpret_cast<bf16x8*>(&ot.p2);
    }
  }

  float mrow[4] = {-3.0e38f,-3.0e38f,-3.0e38f,-3.0e38f};
  float lrow[4] = {0.f,0.f,0.f,0.f};
  f32x4 oac[4];
  #pragma unroll
  for (int n = 0; n < 4; ++n) oac[n] = (f32x4){0.f,0.f,0.f,0.f};

  for (int kt = 0; kt <= qt; ++kt) {
    __syncthreads();
    {
      int tile = ((b*HH + hh)*16 + kt);
      const uint4* ksrc = Kp + (size_t)tile*512;
      #pragma unroll
      for (int p = 0; p < 3; ++p)
        #pragma unroll
        for (int i = 0; i < 2; ++i) {
          int ch = w*2 + i;
          gld16(ksrc + p*KPS + ch*64 + lane, &K_lds[p][ch*64]);
        }
      const uint4* vsrc = Vp + (size_t)tile*512;
      #pragma unroll
      for (int p = 0; p < 2; ++p)
        #pragma unroll
        for (int i = 0; i < 2; ++i) {
          int ch = w*2 + i;
          gld16(vsrc + p*VPS + ch*64 + lane, &V_lds[p][ch*64]);
        }
    }
    __syncthreads();

    f32x4 sfr[4];
    #pragma unroll
    for (int nf = 0; nf < 4; ++nf) sfr[nf] = (f32x4){0.f,0.f,0.f,0.f};
    #pragma unroll
    for (int ks = 0; ks < 2; ++ks) {
      int kc = ks*4 + lk;
      #pragma unroll
      for (int nf = 0; nf < 4; ++nf) {
        int row = nf*16 + lr;
        int si = row*8 + (kc ^ (row & 7));
        bf16x8 k0 = *reinterpret_cast<const bf16x8*>(&K_lds[0][si]);
        bf16x8 k1 = *reinterpret_cast<const bf16x8*>(&K_lds[1][si]);
        bf16x8 k2 = *reinterpret_cast<const bf16x8*>(&K_lds[2][si]);
        sfr[nf] = __builtin_amdgcn_mfma_f32_16x16x32_bf16(qa[ks][0], k0, sfr[nf], 0,0,0);
        sfr[nf] = __builtin_amdgcn_mfma_f32_16x16x32_bf16(qa[ks][0], k1, sfr[nf], 0,0,0);
        sfr[nf] = __builtin_amdgcn_mfma_f32_16x16x32_bf16(qa[ks][1], k0, sfr[nf], 0,0,0);
        sfr[nf] = __builtin_amdgcn_mfma_f32_16x16x32_bf16(qa[ks][1], k1, sfr[nf], 0,0,0);
        sfr[nf] = __builtin_amdgcn_mfma_f32_16x16x32_bf16(qa[ks][2], k0, sfr[nf], 0,0,0);
        sfr[nf] = __builtin_amdgcn_mfma_f32_16x16x32_bf16(qa[ks][0], k2, sfr[nf], 0,0,0);
      }
    }
    #pragma unroll
    for (int nf = 0; nf < 4; ++nf)
      #pragma unroll
      for (int j = 0; j < 4; ++j) {
        float s = sfr[nf][j] * 8.0f;
        if (kt == qt && (nf*16 + lr) > (w*16 + lk*4 + j)) s = -3.0e38f;
        sfr[nf][j] = s;
      }
    float alpha[4], tsum[4];
    #pragma unroll
    for (int j = 0; j < 4; ++j) {
      float mx = fmaxf(fmaxf(sfr[0][j], sfr[1][j]), fmaxf(sfr[2][j], sfr[3][j]));
      mx = fmaxf(mx, __shfl_xor(mx, 1));
      mx = fmaxf(mx, __shfl_xor(mx, 2));
      mx = fmaxf(mx, __shfl_xor(mx, 4));
      mx = fmaxf(mx, __shfl_xor(mx, 8));
      float mnew = fmaxf(mrow[j], mx);
      alpha[j] = __expf(mrow[j] - mnew);
      mrow[j] = mnew;
      tsum[j] = 0.f;
    }
    #pragma unroll
    for (int nf = 0; nf < 4; ++nf)
      #pragma unroll
      for (int j = 0; j < 4; ++j) {
        float p = __expf(sfr[nf][j] - mrow[j]);
        tsum[j] += p;
        unsigned u = __float_as_uint(p);
        float r = p - __uint_as_float(u & 0xffff0000u);
        unsigned pw = (u & 0xffff0000u) | (__float_as_uint(r) >> 16);
        int qrow = w*16 + lk*4 + j;
        int kcol = nf*16 + lr;
        P_lds[qrow*68 + (((kcol>>3) ^ (qrow & 7)))*8 + (kcol & 7)] = pw;
      }
    #pragma unroll
    for (int j = 0; j < 4; ++j) {
      float ts = tsum[j];
      ts += __shfl_xor(ts, 1);
      ts += __shfl_xor(ts, 2);
      ts += __shfl_xor(ts, 4);
      ts += __shfl_xor(ts, 8);
      lrow[j] = lrow[j]*alpha[j] + ts;
      oac[0][j] *= alpha[j]; oac[1][j] *= alpha[j];
      oac[2][j] *= alpha[j]; oac[3][j] *= alpha[j];
    }
    __syncthreads();

    #pragma unroll
    for (int ks = 0; ks < 2; ++ks) {
      int kc = ks*4 + lk;
      int prow = w*16 + lr;
      const uint4* pp4 = reinterpret_cast<const uint4*>(
          &P_lds[prow*68 + ((kc ^ (prow & 7)))*8]);
      uint4 pw0 = pp4[0], pw1 = pp4[1];
      uint4 phu, plu;
      phu.x = (pw0.x>>16) | (pw0.y & 0xffff0000u);
      phu.y = (pw0.z>>16) | (pw0.w & 0xffff0000u);
      phu.z = (pw1.x>>16) | (pw1.y & 0xffff0000u);
      phu.w = (pw1.z>>16) | (pw1.w & 0xffff0000u);
      plu.x = (pw0.x & 0xffffu) | (pw0.y << 16);
      plu.y = (pw0.z & 0xffffu) | (pw0.w << 16);
      plu.z = (pw1.x & 0xffffu) | (pw1.y << 16);
      plu.w = (pw1.z & 0xffffu) | (pw1.w << 16);
      bf16x8 ph = *reinterpret_cast<bf16x8*>(&phu);
      bf16x8 pl = *reinterpret_cast<bf16x8*>(&plu);
      #pragma unroll
      for (int nf2 = 0; nf2 < 4; ++nf2) {
        int d = nf2*16 + lr;
        int vi = kc*64 + ((d ^ (kc<<1)) & 63);
        bf16x8 vh = *reinterpret_cast<const bf16x8*>(&V_lds[0][vi]);
        bf16x8 vl = *reinterpret_cast<const bf16x8*>(&V_lds[1][vi]);
        oac[nf2] = __builtin_amdgcn_mfma_f32_16x16x32_bf16(ph, vh, oac[nf2], 0,0,0);
        oac[nf2] = __builtin_amdgcn_mfma_f32_16x16x32_bf16(ph, vl, oac[nf2], 0,0,0);
        oac[nf2] = __builtin_amdgcn_mfma_f32_16x16x32_bf16(pl, vh, oac[nf2], 0,0,0);
      }
    }
  }

  #pragma unroll
  for (int j = 0; j < 4; ++j) {
    float inv = 1.0f / lrow[j];
    float* op = qk + (tok0 + qt*64 + w*16 + lk*4 + j) * 2048 + hh*HS;
    #pragma unroll
    for (int nf2 = 0; nf2 < 4; ++nf2)
      op[nf2*16 + lr] = oac[nf2][j] * inv;
  }
}

extern "C" void kernel_launch(void* const* d_in, const int* in_sizes, int n_in,
                              void* d_out, int out_size, void* d_ws, size_t ws_size,
                              hipStream_t stream) {
  const int*   idx  = (const int*)d_in[0];
  const float* tok  = (const float*)d_in[1];
  const float* pos  = (const float*)d_in[2];
  const float* Wq   = (const float*)d_in[3];
  const float* Wk   = (const float*)d_in[4];
  const float* Wv   = (const float*)d_in[5];
  const float* Wo   = (const float*)d_in[6];
  const float* bo   = (const float*)d_in[7];
  const float* ln1g = (const float*)d_in[8];
  const float* ln1b = (const float*)d_in[9];
  const float* ln2g = (const float*)d_in[10];
  const float* ln2b = (const float*)d_in[11];
  const float* W1   = (const float*)d_in[12];
  const float* b1   = (const float*)d_in[13];
  const float* W2   = (const float*)d_in[14];
  const float* b2   = (const float*)d_in[15];
  const float* lnfg = (const float*)d_in[16];
  const float* lnfb = (const float*)d_in[17];
  const float* lmw  = (const float*)d_in[18];
  const float* lmb  = (const float*)d_in[19];
  float* out = (float*)d_out;

  // d_out: x[0,32M) | vplanes[32,64M) | qk [64,128M) -> a1 planes [64,96),[96,128)
  // ws (64 MB, time-shared; liveness checked, same as R15)
  char* ob = (char*)d_out;
  float* x  = (float*)ob;
  float* vplanes = (float*)(ob + ((size_t)32<<20));
  float* qk = (float*)(ob + ((size_t)64<<20));
  float* a1p = (float*)(ob + ((size_t)64<<20));
  char* wsb = (char*)d_ws;
  uint4* aspH  = (uint4*)wsb;
  uint4* bsQK  = (uint4*)(wsb + ((size_t)48<<20));
  uint4* bsV   = (uint4*)(wsb + ((size_t)60<<20));
  uint4* Kp    = (uint4*)wsb;
  uint4* aspH2 = (uint4*)wsb;
  uint4* bsO   = (uint4*)(wsb + ((size_t)32<<20));
  uint4* aspH3 = (uint4*)wsb;
  uint4* bsW1  = (uint4*)(wsb + ((size_t)32<<20));
  uint4* bsW2  = (uint4*)(wsb + ((size_t)48<<20));
  float* hf    = (float*)wsb;
  uint4* bsL   = (uint4*)(wsb + ((size_t)32<<20));
  const size_t aPSh = (size_t)128 * 16 * 512;
  const size_t aPSa = (size_t)128 * 32 * 512;

  dim3 blk(256);
  dim3 gQK(16, 128);
  dim3 gV(8, 64), gO(8, 64);
  dim3 gW1(16, 64), gW2(8, 64), gL(32, 64);
  dim3 sA(128, 16), s8(8, 16), sW1(32, 16), sW2(8, 64), sLM(32, 16);

  embed_kernel<<<BT, blk, 0, stream>>>(idx, tok, pos, x);
  for (int l = 0; l < LL; ++l) {
    const float* Wq_l = Wq + (size_t)l*CC*CC;
    const float* Wk_l = Wk + (size_t)l*CC*CC;
    const float* Wv_l = Wv + (size_t)l*CC*CC;
    const float* Wo_l = Wo + (size_t)l*CC*CC;
    const float* W1_l = W1 + (size_t)l*CC*4*CC;
    const float* W2_l = W2 + (size_t)l*4*CC*CC;
    lnsplit_kernel<3><<<BT, blk, 0, stream>>>(x, ln1g + (size_t)l*CC, ln1b + (size_t)l*CC, aspH);
    bsplit_kernel<3><<<s8, blk, 0, stream>>>(Wq_l, bsQK, CC, 0, 16);
    bsplit_kernel<3><<<s8, blk, 0, stream>>>(Wk_l, bsQK, CC, 8, 16);
    bsplit_kernel<2><<<s8, blk, 0, stream>>>(Wv_l, bsV, CC, 0, 8);
    gemm_kernel<3,true><<<gQK, blk, 0, stream>>>(nullptr, 0, aspH, aPSh, bsQK,
        nullptr, nullptr, qk, CC, 2048, 0, 0, 16, 0, 16, 0);
    gemm128_kernel<2,true><<<gV, blk, 0, stream>>>(nullptr, 0, aspH, aPSh, bsV,
        nullptr, nullptr, vplanes, CC, CC, 0, 0, 8, 0, 16, 1);
    ksplit_kernel<<<2048, blk, 0, stream>>>(qk, Kp);
    attn_mfma_kernel<<<BB*HH*16, blk, 0, stream>>>(qk, Kp, (const uint4*)vplanes);
    asplit_kernel<2><<<sA, blk, 0, stream>>>(qk, 2048, aspH2);
    bsplit_kernel<2><<<s8, blk, 0, stream>>>(Wo_l, bsO, CC, 0, 8);
    gemm128_kernel<2,true><<<gO, blk, 0, stream>>>(nullptr, 0, aspH2, aPSh, bsO,
        bo + (size_t)l*CC, x, x, CC, CC, 0, 0, 8, 0, 16, 0);
    lnsplit_kernel<2><<<BT, blk, 0, stream>>>(x, ln2g + (size_t)l*CC, ln2b + (size_t)l*CC, aspH3);
    bsplit_kernel<2><<<sW1, blk, 0, stream>>>(W1_l, bsW1, 4*CC, 0, 32);
    bsplit_kernel<2><<<sW2, blk, 0, stream>>>(W2_l, bsW2, CC, 0, 8);
    gemm128_kernel<2,true><<<gW1, blk, 0, stream>>>(nullptr, 0, aspH3, aPSh, bsW1,
        b1 + (size_t)l*4*CC, nullptr, a1p, CC, 2048, 1, 0, 32, 0, 16, 2);
    gemm128_kernel<2,true><<<gW2, blk, 0, stream>>>(nullptr, 0, (const uint4*)a1p, aPSa, bsW2,
        b2 + (size_t)l*CC, x, x, 2048, CC, 0, 0, 8, 0, 64, 0);
    gemm128_kernel<2,true><<<gW1, blk, 0, stream>>>(nullptr, 0, aspH3, aPSh, bsW1,
        b1 + (size_t)l*4*CC + 2048, nullptr, a1p, CC, 2048, 1, 16, 32, 0, 16, 2);
    gemm128_kernel<2,true><<<gW2, blk, 0, stream>>>(nullptr, 0, (const uint4*)a1p, aPSa, bsW2,
        nullptr, x, x, 2048, CC, 0, 0, 8, 32, 64, 0);
  }
  ln32_kernel<<<BT, blk, 0, stream>>>(x, lnfg, lnfb, hf);
  bsplit_kernel<1><<<sLM, blk, 0, stream>>>(lmw, bsL, VV, 0, 32);
  gemm128_kernel<1,false><<<gL, blk, 0, stream>>>(hf, CC, nullptr, 0, bsL,
      lmb, nullptr, out, CC, VV, 0, 0, 32, 0, 16, 0);
}

// Round 17
// 5099.047 us; speedup vs baseline: 10.7849x; 1.1227x over previous
//
#include <hip/hip_runtime.h>

#define LL 6
#define BB 8
#define TT 1024
#define CC 1024
#define HH 16
#define HS 64
#define VV 4096
#define BT (BB*TT)

typedef __attribute__((ext_vector_type(4))) float f32x4;
typedef __attribute__((ext_vector_type(8))) short bf16x8;

__device__ __forceinline__ float bf2f(unsigned short u) {
  union { unsigned int u; float f; } v; v.u = ((unsigned int)u) << 16; return v.f;
}
__device__ __forceinline__ unsigned short rne16(float f) {
  unsigned u = __float_as_uint(f);
  return (unsigned short)((u + 0x7fffu + ((u >> 16) & 1u)) >> 16);
}
__device__ __forceinline__ void gld16(const uint4* g, uint4* l) {
  __builtin_amdgcn_global_load_lds(
      (const __attribute__((address_space(1))) void*)g,
      (__attribute__((address_space(3))) void*)l, 16, 0, 0);
}

// ---------------- embedding ----------------
__global__ __launch_bounds__(256) void embed_kernel(
    const int* __restrict__ idx, const float* __restrict__ tok,
    const float* __restrict__ pos, float* __restrict__ x) {
  int bt = blockIdx.x;
  int t = bt & (TT - 1);
  int id = idx[bt];
  float4 te = reinterpret_cast<const float4*>(tok)[(size_t)id * (CC/4) + threadIdx.x];
  float4 pe = reinterpret_cast<const float4*>(pos)[(size_t)t * (CC/4) + threadIdx.x];
  float4 r; r.x = te.x+pe.x; r.y = te.y+pe.y; r.z = te.z+pe.z; r.w = te.w+pe.w;
  reinterpret_cast<float4*>(x)[(size_t)bt * (CC/4) + threadIdx.x] = r;
}

// ---- splits ----
struct Oct3 { uint4 p0, p1, p2; };
__device__ __forceinline__ unsigned pk2(unsigned lo, unsigned hi) {
  return (lo >> 16) | (hi & 0xffff0000u);
}
__device__ __forceinline__ Oct3 split8(const float* f) {
  unsigned a0[8], a1[8], a2[8];
  #pragma unroll
  for (int e = 0; e < 8; ++e) {
    float v = f[e];
    unsigned u = __float_as_uint(v);
    a0[e] = u;
    float r = v - __uint_as_float(u & 0xffff0000u);
    unsigned ur = __float_as_uint(r);
    a1[e] = ur;
    float r2 = r - __uint_as_float(ur & 0xffff0000u);
    a2[e] = __float_as_uint(r2);
  }
  Oct3 o;
  o.p0 = make_uint4(pk2(a0[0],a0[1]), pk2(a0[2],a0[3]), pk2(a0[4],a0[5]), pk2(a0[6],a0[7]));
  o.p1 = make_uint4(pk2(a1[0],a1[1]), pk2(a1[2],a1[3]), pk2(a1[4],a1[5]), pk2(a1[6],a1[7]));
  o.p2 = make_uint4(pk2(a2[0],a2[1]), pk2(a2[2],a2[3]), pk2(a2[4],a2[5]), pk2(a2[6],a2[7]));
  return o;
}
struct Oct2 { uint4 p0, p1; };
__device__ __forceinline__ Oct2 split8_rne2(const float* f) {
  unsigned h0[8], h1[8];
  #pragma unroll
  for (int e = 0; e < 8; ++e) {
    h0[e] = rne16(f[e]);
    float r = f[e] - bf2f((unsigned short)h0[e]);
    h1[e] = rne16(r);
  }
  Oct2 o;
  o.p0 = make_uint4(h0[0]|(h0[1]<<16), h0[2]|(h0[3]<<16), h0[4]|(h0[5]<<16), h0[6]|(h0[7]<<16));
  o.p1 = make_uint4(h1[0]|(h1[1]<<16), h1[2]|(h1[3]<<16), h1[4]|(h1[5]<<16), h1[6]|(h1[7]<<16));
  return o;
}
__device__ __forceinline__ uint4 pack8_rne(const float* f) {
  unsigned h[8];
  #pragma unroll
  for (int e = 0; e < 8; ++e) h[e] = rne16(f[e]);
  return make_uint4(h[0]|(h[1]<<16), h[2]|(h[3]<<16), h[4]|(h[5]<<16), h[6]|(h[7]<<16));
}

// ---------------- layernorm fp32->fp32 (final LN only) ----------------
__global__ __launch_bounds__(256) void ln32_kernel(
    const float* __restrict__ x, const float* __restrict__ g,
    const float* __restrict__ b, float* __restrict__ out) {
  __shared__ float red[8];
  int row = blockIdx.x, tid = threadIdx.x;
  float4 v = reinterpret_cast<const float4*>(x)[(size_t)row * (CC/4) + tid];
  float s  = v.x+v.y+v.z+v.w;
  float ss = v.x*v.x+v.y*v.y+v.z*v.z+v.w*v.w;
  #pragma unroll
  for (int off = 32; off; off >>= 1) { s += __shfl_xor(s, off); ss += __shfl_xor(ss, off); }
  if ((tid & 63) == 0) { red[tid>>6] = s; red[4+(tid>>6)] = ss; }
  __syncthreads();
  s  = red[0]+red[1]+red[2]+red[3];
  ss = red[4]+red[5]+red[6]+red[7];
  float mu = s * (1.f/CC);
  float rs = rsqrtf(ss*(1.f/CC) - mu*mu + 1e-5f);
  float4 gg = reinterpret_cast<const float4*>(g)[tid];
  float4 bb = reinterpret_cast<const float4*>(b)[tid];
  float4 o;
  o.x = (v.x-mu)*rs*gg.x + bb.x;
  o.y = (v.y-mu)*rs*gg.y + bb.y;
  o.z = (v.z-mu)*rs*gg.z + bb.z;
  o.w = (v.w-mu)*rs*gg.w + bb.w;
  reinterpret_cast<float4*>(out)[(size_t)row * (CC/4) + tid] = o;
}

// ---------------- FUSED layernorm + A-presplit (2-plane RNE, pre-swizzled) -------
__global__ __launch_bounds__(256) void lnsplit_kernel(
    const float* __restrict__ x, const float* __restrict__ g,
    const float* __restrict__ b, uint4* __restrict__ outp) {
  __shared__ float red[8];
  __shared__ float rowbuf[1024];
  int row = blockIdx.x, tid = threadIdx.x;
  float4 v = reinterpret_cast<const float4*>(x)[(size_t)row * (CC/4) + tid];
  float s  = v.x+v.y+v.z+v.w;
  float ss = v.x*v.x+v.y*v.y+v.z*v.z+v.w*v.w;
  #pragma unroll
  for (int off = 32; off; off >>= 1) { s += __shfl_xor(s, off); ss += __shfl_xor(ss, off); }
  if ((tid & 63) == 0) { red[tid>>6] = s; red[4+(tid>>6)] = ss; }
  __syncthreads();
  s  = red[0]+red[1]+red[2]+red[3];
  ss = red[4]+red[5]+red[6]+red[7];
  float mu = s * (1.f/CC);
  float rs = rsqrtf(ss*(1.f/CC) - mu*mu + 1e-5f);
  float4 gg = reinterpret_cast<const float4*>(g)[tid];
  float4 bb = reinterpret_cast<const float4*>(b)[tid];
  float4 o;
  o.x = (v.x-mu)*rs*gg.x + bb.x;
  o.y = (v.y-mu)*rs*gg.y + bb.y;
  o.z = (v.z-mu)*rs*gg.z + bb.z;
  o.w = (v.w-mu)*rs*gg.w + bb.w;
  *reinterpret_cast<float4*>(&rowbuf[tid*4]) = o;
  __syncthreads();
  if (tid < 128) {
    const size_t aPS = (size_t)128 * 16 * 512;
    int kt = tid >> 3, sl = tid & 7;
    int r = row & 63, mt = row >> 6;
    float f[8];
    #pragma unroll
    for (int e = 0; e < 8; ++e) f[e] = rowbuf[tid*8 + e];
    size_t di = ((size_t)(mt*16 + kt))*512 + r*8 + (sl ^ (r & 7));
    Oct2 ot = split8_rne2(f);
    outp[di] = ot.p0; outp[aPS+di] = ot.p1;
  }
}

// ---------------- B pre-split ----------------
template<int NP>
__global__ __launch_bounds__(256) void bsplit_kernel(
    const float* __restrict__ Bw, uint4* __restrict__ outp, int ldb,
    int ntile0, int ntTotal) {
  int ntile = ntile0 + blockIdx.x, kt = blockIdx.y;
  size_t planeStride = (size_t)ntTotal * gridDim.y * 1024;
  int tid = threadIdx.x;
  int bcol = tid & 127, bkcg = tid >> 7;
  #pragma unroll
  for (int g = 0; g < 4; ++g) {
    int kc = bkcg*4 + g;
    float f[8];
    #pragma unroll
    for (int j = 0; j < 8; ++j)
      f[j] = Bw[(size_t)(kt*64 + kc*8 + j) * ldb + blockIdx.x*128 + bcol];
    size_t di = (((size_t)ntile * gridDim.y + kt) * 8 + kc) * 128 + bcol;
    if (NP == 2) {
      Oct2 o = split8_rne2(f);
      outp[di] = o.p0; outp[planeStride+di] = o.p1;
    } else {
      outp[di] = pack8_rne(f);
    }
  }
}

// ---------------- 128x128 GEMM, global_load_lds staging ------
// NM: MFMA count for NP=2 (3 = drop a1b1, 4 = full).
// vtmode: 0=normal, 1=V-plane epilogue, 2=a1 2-plane epilogue,
//         3=QK: ntg<8 -> fp32 q (ldc), ntg>=8 -> K 2-plane attn-tile epilogue.
template<int NP, bool ASP, int NM>
__global__ __launch_bounds__(256) void gemm128_kernel(
    const float* __restrict__ A, int lda,
    const uint4* __restrict__ Asp, size_t aPS,
    const uint4* __restrict__ Bs,
    const float* __restrict__ bias, const float* __restrict__ res,
    float* __restrict__ outf, int K, int ldc, int relu,
    int ntile0, int ntTotal, int kt0, int ktTotal, int vtmode,
    uint4* __restrict__ kout) {
  __shared__ uint4 lds_all[NP*2048];
  uint4* lds_a = lds_all;
  uint4* lds_b = lds_all + NP*1024;
  int tid = threadIdx.x;
  int by = blockIdx.y;
  int m0 = by * 128;
  int n0 = blockIdx.x * 128;
  int ntg = ntile0 + blockIdx.x;
  size_t bPS = (size_t)ntTotal * ktTotal * 1024;
  int lane = tid & 63, w = tid >> 6;
  int wm = w >> 1, wn = w & 1;
  int lr = lane & 15, lk = lane >> 4;
  int nkt = K >> 6;

  f32x4 acc[4][4];
  #pragma unroll
  for (int m = 0; m < 4; ++m)
    #pragma unroll
    for (int n = 0; n < 4; ++n)
      acc[m][n] = (f32x4){0.f, 0.f, 0.f, 0.f};

  for (int kt = 0; kt < nkt; ++kt) {
    if (ASP) {
      #pragma unroll
      for (int p = 0; p < NP; ++p) {
        const uint4* s0 = Asp + p*aPS + ((size_t)(2*by)   * nkt + kt)*512;
        const uint4* s1 = Asp + p*aPS + ((size_t)(2*by+1) * nkt + kt)*512;
        #pragma unroll
        for (int i = 0; i < 2; ++i) {
          int ch = w*2 + i;
          gld16(s0 + ch*64 + lane, &lds_a[p*1024 + ch*64]);
          gld16(s1 + ch*64 + lane, &lds_a[p*1024 + 512 + ch*64]);
        }
      }
    } else {
      #pragma unroll
      for (int i = 0; i < 4; ++i) {
        int c = tid + i * 256;
        int row = c >> 3, sl = c & 7;
        const float4* ap = reinterpret_cast<const float4*>(
            A + (size_t)(m0+row)*lda + kt*64 + sl*8);
        float4 x0 = ap[0], x1 = ap[1];
        float f[8] = {x0.x,x0.y,x0.z,x0.w,x1.x,x1.y,x1.z,x1.w};
        int di = (row>>6)*512 + (row&63)*8 + (sl ^ (row & 7));
        if (NP == 2) {
          Oct2 o = split8_rne2(f);
          lds_a[di] = o.p0; lds_a[1024 + di] = o.p1;
        } else {
          lds_a[di] = pack8_rne(f);
        }
      }
    }
    {
      int ktg = kt0 + kt;
      #pragma unroll
      for (int p = 0; p < NP; ++p) {
        const uint4* sb = Bs + p*bPS + ((size_t)ntg * ktTotal + ktg)*1024;
        #pragma unroll
        for (int i = 0; i < 4; ++i) {
          int ch = w*4 + i;
          gld16(sb + ch*64 + lane, &lds_b[p*1024 + ch*64]);
        }
      }
    }
    __syncthreads();
    #pragma unroll
    for (int ks = 0; ks < 2; ++ks) {
      int kc = ks*4 + lk;
      bf16x8 af[NP][4], bfr[NP][4];
      #pragma unroll
      for (int m = 0; m < 4; ++m) {
        int row = wm*64 + m*16 + lr;
        int si = (row>>6)*512 + (row&63)*8 + (kc ^ (row & 7));
        #pragma unroll
        for (int p = 0; p < NP; ++p)
          af[p][m] = reinterpret_cast<const bf16x8*>(lds_a + p*1024)[si];
      }
      #pragma unroll
      for (int n = 0; n < 4; ++n) {
        int si = kc*128 + wn*64 + n*16 + lr;
        #pragma unroll
        for (int p = 0; p < NP; ++p)
          bfr[p][n] = reinterpret_cast<const bf16x8*>(lds_b + p*1024)[si];
      }
      #pragma unroll
      for (int m = 0; m < 4; ++m)
        #pragma unroll
        for (int n = 0; n < 4; ++n) {
          acc[m][n] = __builtin_amdgcn_mfma_f32_16x16x32_bf16(af[0][m], bfr[0][n], acc[m][n], 0, 0, 0);
          if (NP == 2) {
            acc[m][n] = __builtin_amdgcn_mfma_f32_16x16x32_bf16(af[0][m], bfr[1][n], acc[m][n], 0, 0, 0);
            acc[m][n] = __builtin_amdgcn_mfma_f32_16x16x32_bf16(af[1][m], bfr[0][n], acc[m][n], 0, 0, 0);
            if (NM == 4)
              acc[m][n] = __builtin_amdgcn_mfma_f32_16x16x32_bf16(af[1][m], bfr[1][n], acc[m][n], 0, 0, 0);
          }
        }
    }
    __syncthreads();
  }

  if (vtmode == 1) {
    char* vb = (char*)outf;
    const size_t VPSb = (size_t)2048 * 512 * 16;
    #pragma unroll
    for (int m = 0; m < 4; ++m) {
      int row = m0 + wm*64 + m*16 + lk*4;
      int bq = row >> 10;
      int t  = row & (TT-1);
      int ktile = t >> 6, r = t & 63;
      int kc = r >> 3, toct0 = r & 7;
      #pragma unroll
      for (int n = 0; n < 4; ++n) {
        int col = n0 + wn*64 + n*16 + lr;
        int hh2 = col >> 6, d = col & 63;
        int tile = (bq*HH + hh2)*16 + ktile;
        int vi = kc*64 + ((d ^ (kc<<1)) & 63);
        unsigned p0[4], p1[4];
        #pragma unroll
        for (int j = 0; j < 4; ++j) {
          float v = acc[m][n][j];
          p0[j] = rne16(v);
          p1[j] = rne16(v - bf2f((unsigned short)p0[j]));
        }
        uint2 w0 = make_uint2(p0[0]|(p0[1]<<16), p0[2]|(p0[3]<<16));
        uint2 w1 = make_uint2(p1[0]|(p1[1]<<16), p1[2]|(p1[3]<<16));
        char* base = vb + ((size_t)tile*512 + vi)*16 + toct0*2;
        *reinterpret_cast<uint2*>(base) = w0;
        *reinterpret_cast<uint2*>(base + VPSb) = w1;
      }
    }
  } else if (vtmode == 2) {
    float* bounce = (float*)lds_all;
    #pragma unroll
    for (int m = 0; m < 4; ++m)
      #pragma unroll
      for (int n = 0; n < 4; ++n) {
        int cl = wn*64 + n*16 + lr;
        float bv = bias[n0 + cl];
        #pragma unroll
        for (int j = 0; j < 4; ++j) {
          int rl = wm*64 + m*16 + lk*4 + j;
          bounce[rl*128 + cl] = fmaxf(acc[m][n][j] + bv, 0.f);
        }
      }
    __syncthreads();
    uint4* a1p = (uint4*)outf;
    const size_t aPSa = (size_t)128 * 32 * 512;
    #pragma unroll
    for (int i = 0; i < 8; ++i) {
      int ot = tid + i*256;
      int r = ot >> 4, o = ot & 15;
      float f[8];
      #pragma unroll
      for (int e = 0; e < 8; ++e) f[e] = bounce[r*128 + o*8 + e];
      Oct2 o2 = split8_rne2(f);
      int mt = 2*by + (r>>6), rs = r & 63;
      int ktg = (n0 >> 6) + (o >> 3), sl = o & 7;
      size_t di = ((size_t)(mt*32 + ktg))*512 + rs*8 + (sl ^ (rs & 7));
      a1p[di] = o2.p0; a1p[aPSa + di] = o2.p1;
    }
  } else if (vtmode == 3 && ntg >= 8) {
    // K projection -> 2-plane RNE attn tiles
    float* bounce = (float*)lds_all;      // 128 x 128 fp32 = 64KB
    #pragma unroll
    for (int m = 0; m < 4; ++m)
      #pragma unroll
      for (int n = 0; n < 4; ++n) {
        int cl = wn*64 + n*16 + lr;
        #pragma unroll
        for (int j = 0; j < 4; ++j) {
          int rl = wm*64 + m*16 + lk*4 + j;
          bounce[rl*128 + cl] = acc[m][n][j];
        }
      }
    __syncthreads();
    const size_t KPSC = (size_t)2048 * 512;
    int bq = m0 >> 10;
    int kt0tok = (m0 & 1023) >> 6;
    int hh0 = (ntg - 8) * 2;
    #pragma unroll
    for (int i = 0; i < 8; ++i) {
      int u = tid + i*256;
      int r = u >> 4, oct = u & 15;
      int head = oct >> 3, sl = oct & 7;
      float f[8];
      #pragma unroll
      for (int e = 0; e < 8; ++e) f[e] = bounce[r*128 + head*64 + sl*8 + e];
      Oct2 o = split8_rne2(f);
      int rk = r & 63;
      int tile = (bq*HH + hh0 + head)*16 + kt0tok + (r >> 6);
      size_t di = (size_t)tile*512 + rk*8 + (sl ^ (rk & 7));
      kout[di] = o.p0; kout[KPSC + di] = o.p1;
    }
  } else {
    #pragma unroll
    for (int m = 0; m < 4; ++m) {
      #pragma unroll
      for (int n = 0; n < 4; ++n) {
        int col = n0 + wn*64 + n*16 + lr;
        float bv = bias ? bias[col] : 0.f;
        #pragma unroll
        for (int j = 0; j < 4; ++j) {
          int row = m0 + wm*64 + m*16 + lk*4 + j;
          float vv = acc[m][n][j] + bv;
          if (relu) vv = fmaxf(vv, 0.f);
          size_t off = (size_t)row * ldc + col;
          if (res) vv += res[off];
          outf[off] = vv;
        }
      }
    }
  }
}

// ---------------- MFMA flash attention: K 2-plane, 5-MFMA QK, fused A-out --------
__global__ __launch_bounds__(256) void attn_mfma_kernel(
    const float* __restrict__ qf, const uint4* __restrict__ Kp,
    const uint4* __restrict__ Vp, uint4* __restrict__ aout) {
  __shared__ uint4 K_lds[2][512];
  __shared__ uint4 V_lds[2][512];
  __shared__ unsigned P_lds[64*68];
  const size_t KPS = (size_t)2048 * 512;
  const size_t VPS = (size_t)2048 * 512;
  const size_t APS = (size_t)128 * 16 * 512;
  int tid = threadIdx.x, lane = tid & 63, w = tid >> 6;
  int rid = blockIdx.x;
  int qt = 15 - (rid & 15), hh = (rid >> 4) & 15, b = rid >> 8;
  int lr = lane & 15, lk = lane >> 4;
  const size_t tok0 = (size_t)b * TT;

  // Q -> 3-plane trunc frags (from fp32 q, compact ldq=1024)
  bf16x8 qa[2][3];
  {
    const float* qp = qf + (tok0 + qt*64 + w*16 + lr) * 1024 + hh*HS;
    #pragma unroll
    for (int ks = 0; ks < 2; ++ks) {
      const float4* p4 = reinterpret_cast<const float4*>(qp + ks*32 + lk*8);
      float4 a = p4[0], c = p4[1];
      float f[8] = {a.x,a.y,a.z,a.w,c.x,c.y,c.z,c.w};
      Oct3 ot = split8(f);
      qa[ks][0] = *reinterpret_cast<bf16x8*>(&ot.p0);
      qa[ks][1] = *reinterpret_cast<bf16x8*>(&ot.p1);
      qa[ks][2] = *reinterpret_cast<bf16x8*>(&ot.p2);
    }
  }

  float mrow[4] = {-3.0e38f,-3.0e38f,-3.0e38f,-3.0e38f};
  float lrow[4] = {0.f,0.f,0.f,0.f};
  f32x4 oac[4];
  #pragma unroll
  for (int n = 0; n < 4; ++n) oac[n] = (f32x4){0.f,0.f,0.f,0.f};

  for (int kt = 0; kt <= qt; ++kt) {
    __syncthreads();
    {
      int tile = ((b*HH + hh)*16 + kt);
      const uint4* ksrc = Kp + (size_t)tile*512;
      #pragma unroll
      for (int p = 0; p < 2; ++p)
        #pragma unroll
        for (int i = 0; i < 2; ++i) {
          int ch = w*2 + i;
          gld16(ksrc + p*KPS + ch*64 + lane, &K_lds[p][ch*64]);
        }
      const uint4* vsrc = Vp + (size_t)tile*512;
      #pragma unroll
      for (int p = 0; p < 2; ++p)
        #pragma unroll
        for (int i = 0; i < 2; ++i) {
          int ch = w*2 + i;
          gld16(vsrc + p*VPS + ch*64 + lane, &V_lds[p][ch*64]);
        }
    }
    __syncthreads();

    f32x4 sfr[4];
    #pragma unroll
    for (int nf = 0; nf < 4; ++nf) sfr[nf] = (f32x4){0.f,0.f,0.f,0.f};
    #pragma unroll
    for (int ks = 0; ks < 2; ++ks) {
      int kc = ks*4 + lk;
      #pragma unroll
      for (int nf = 0; nf < 4; ++nf) {
        int row = nf*16 + lr;
        int si = row*8 + (kc ^ (row & 7));
        bf16x8 k0 = *reinterpret_cast<const bf16x8*>(&K_lds[0][si]);
        bf16x8 k1 = *reinterpret_cast<const bf16x8*>(&K_lds[1][si]);
        sfr[nf] = __builtin_amdgcn_mfma_f32_16x16x32_bf16(qa[ks][0], k0, sfr[nf], 0,0,0);
        sfr[nf] = __builtin_amdgcn_mfma_f32_16x16x32_bf16(qa[ks][0], k1, sfr[nf], 0,0,0);
        sfr[nf] = __builtin_amdgcn_mfma_f32_16x16x32_bf16(qa[ks][1], k0, sfr[nf], 0,0,0);
        sfr[nf] = __builtin_amdgcn_mfma_f32_16x16x32_bf16(qa[ks][1], k1, sfr[nf], 0,0,0);
        sfr[nf] = __builtin_amdgcn_mfma_f32_16x16x32_bf16(qa[ks][2], k0, sfr[nf], 0,0,0);
      }
    }
    #pragma unroll
    for (int nf = 0; nf < 4; ++nf)
      #pragma unroll
      for (int j = 0; j < 4; ++j) {
        float s = sfr[nf][j] * 8.0f;
        if (kt == qt && (nf*16 + lr) > (w*16 + lk*4 + j)) s = -3.0e38f;
        sfr[nf][j] = s;
      }
    float alpha[4], tsum[4];
    #pragma unroll
    for (int j = 0; j < 4; ++j) {
      float mx = fmaxf(fmaxf(sfr[0][j], sfr[1][j]), fmaxf(sfr[2][j], sfr[3][j]));
      mx = fmaxf(mx, __shfl_xor(mx, 1));
      mx = fmaxf(mx, __shfl_xor(mx, 2));
      mx = fmaxf(mx, __shfl_xor(mx, 4));
      mx = fmaxf(mx, __shfl_xor(mx, 8));
      float mnew = fmaxf(mrow[j], mx);
      alpha[j] = __expf(mrow[j] - mnew);
      mrow[j] = mnew;
      tsum[j] = 0.f;
    }
    #pragma unroll
    for (int nf = 0; nf < 4; ++nf)
      #pragma unroll
      for (int j = 0; j < 4; ++j) {
        float p = __expf(sfr[nf][j] - mrow[j]);
        tsum[j] += p;
        unsigned u = __float_as_uint(p);
        float r = p - __uint_as_float(u & 0xffff0000u);
        unsigned pw = (u & 0xffff0000u) | (__float_as_uint(r) >> 16);
        int qrow = w*16 + lk*4 + j;
        int kcol = nf*16 + lr;
        P_lds[qrow*68 + (((kcol>>3) ^ (qrow & 7)))*8 + (kcol & 7)] = pw;
      }
    #pragma unroll
    for (int j = 0; j < 4; ++j) {
      float ts = tsum[j];
      ts += __shfl_xor(ts, 1);
      ts += __shfl_xor(ts, 2);
      ts += __shfl_xor(ts, 4);
      ts += __shfl_xor(ts, 8);
      lrow[j] = lrow[j]*alpha[j] + ts;
      oac[0][j] *= alpha[j]; oac[1][j] *= alpha[j];
      oac[2][j] *= alpha[j]; oac[3][j] *= alpha[j];
    }
    __syncthreads();

    #pragma unroll
    for (int ks = 0; ks < 2; ++ks) {
      int kc = ks*4 + lk;
      int prow = w*16 + lr;
      const uint4* pp4 = reinterpret_cast<const uint4*>(
          &P_lds[prow*68 + ((kc ^ (prow & 7)))*8]);
      uint4 pw0 = pp4[0], pw1 = pp4[1];
      uint4 phu, plu;
      phu.x = (pw0.x>>16) | (pw0.y & 0xffff0000u);
      phu.y = (pw0.z>>16) | (pw0.w & 0xffff0000u);
      phu.z = (pw1.x>>16) | (pw1.y & 0xffff0000u);
      phu.w = (pw1.z>>16) | (pw1.w & 0xffff0000u);
      plu.x = (pw0.x & 0xffffu) | (pw0.y << 16);
      plu.y = (pw0.z & 0xffffu) | (pw0.w << 16);
      plu.z = (pw1.x & 0xffffu) | (pw1.y << 16);
      plu.w = (pw1.z & 0xffffu) | (pw1.w << 16);
      bf16x8 ph = *reinterpret_cast<bf16x8*>(&phu);
      bf16x8 pl = *reinterpret_cast<bf16x8*>(&plu);
      #pragma unroll
      for (int nf2 = 0; nf2 < 4; ++nf2) {
        int d = nf2*16 + lr;
        int vi = kc*64 + ((d ^ (kc<<1)) & 63);
        bf16x8 vh = *reinterpret_cast<const bf16x8*>(&V_lds[0][vi]);
        bf16x8 vl = *reinterpret_cast<const bf16x8*>(&V_lds[1][vi]);
        oac[nf2] = __builtin_amdgcn_mfma_f32_16x16x32_bf16(ph, vh, oac[nf2], 0,0,0);
        oac[nf2] = __builtin_amdgcn_mfma_f32_16x16x32_bf16(ph, vl, oac[nf2], 0,0,0);
        oac[nf2] = __builtin_amdgcn_mfma_f32_16x16x32_bf16(pl, vh, oac[nf2], 0,0,0);
      }
    }
  }

  // fused epilogue: O -> 2-plane A-tiles for the Wo gemm (P_lds reused as bounce)
  __syncthreads();
  float* Pf = (float*)P_lds;
  #pragma unroll
  for (int j = 0; j < 4; ++j) {
    float inv = 1.0f / lrow[j];
    #pragma unroll
    for (int nf2 = 0; nf2 < 4; ++nf2)
      Pf[(w*16 + lk*4 + j)*68 + nf2*16 + lr] = oac[nf2][j] * inv;
  }
  __syncthreads();
  int mtkt = (b*16 + qt)*16 + hh;
  #pragma unroll
  for (int i = 0; i < 2; ++i) {
    int u = tid + i*256;
    int r = u >> 3, sl = u & 7;
    float f[8];
    #pragma unroll
    for (int e = 0; e < 8; ++e) f[e] = Pf[r*68 + sl*8 + e];
    Oct2 o = split8_rne2(f);
    size_t di = (size_t)mtkt*512 + r*8 + (sl ^ (r & 7));
    aout[di] = o.p0; aout[APS + di] = o.p1;
  }
}

extern "C" void kernel_launch(void* const* d_in, const int* in_sizes, int n_in,
                              void* d_out, int out_size, void* d_ws, size_t ws_size,
                              hipStream_t stream) {
  const int*   idx  = (const int*)d_in[0];
  const float* tok  = (const float*)d_in[1];
  const float* pos  = (const float*)d_in[2];
  const float* Wq   = (const float*)d_in[3];
  const float* Wk   = (const float*)d_in[4];
  const float* Wv   = (const float*)d_in[5];
  const float* Wo   = (const float*)d_in[6];
  const float* bo   = (const float*)d_in[7];
  const float* ln1g = (const float*)d_in[8];
  const float* ln1b = (const float*)d_in[9];
  const float* ln2g = (const float*)d_in[10];
  const float* ln2b = (const float*)d_in[11];
  const float* W1   = (const float*)d_in[12];
  const float* b1   = (const float*)d_in[13];
  const float* W2   = (const float*)d_in[14];
  const float* b2   = (const float*)d_in[15];
  const float* lnfg = (const float*)d_in[16];
  const float* lnfb = (const float*)d_in[17];
  const float* lmw  = (const float*)d_in[18];
  const float* lmb  = (const float*)d_in[19];
  float* out = (float*)d_out;

  // d_out: x[0,32M) | vplanes[32,64M) | qf[64,96M) | Kp 2pl [96,128M);
  //        a1p reuses [64,128M) during MLP. Logits overwrite all at end.
  // ws: aspH[0,32) | bsQK[32,40) | bsV[40,44) | bsO[44,48)
  //     aspH2 (attn out) -> [0,32) after aspH dead; aspH3 [0,32);
  //     bsW1 [32,48) | bsW2 [48,64); final: hf[0,32) | bsL[32,40).
  char* ob = (char*)d_out;
  float* x  = (float*)ob;
  float* vplanes = (float*)(ob + ((size_t)32<<20));
  float* qf = (float*)(ob + ((size_t)64<<20));
  uint4* Kp = (uint4*)(ob + ((size_t)96<<20));
  float* a1p = (float*)(ob + ((size_t)64<<20));
  char* wsb = (char*)d_ws;
  uint4* aspH  = (uint4*)wsb;
  uint4* bsQK  = (uint4*)(wsb + ((size_t)32<<20));
  uint4* bsV   = (uint4*)(wsb + ((size_t)40<<20));
  uint4* bsO   = (uint4*)(wsb + ((size_t)44<<20));
  uint4* aspH2 = (uint4*)wsb;
  uint4* aspH3 = (uint4*)wsb;
  uint4* bsW1  = (uint4*)(wsb + ((size_t)32<<20));
  uint4* bsW2  = (uint4*)(wsb + ((size_t)48<<20));
  float* hf    = (float*)wsb;
  uint4* bsL   = (uint4*)(wsb + ((size_t)32<<20));
  const size_t aPSh = (size_t)128 * 16 * 512;
  const size_t aPSa = (size_t)128 * 32 * 512;

  dim3 blk(256);
  dim3 gQK(16, 64), gV(8, 64), gO(8, 64);
  dim3 gW1(16, 64), gW2(8, 64), gL(32, 64);
  dim3 s8(8, 16), sW1(32, 16), sW2(8, 64), sLM(32, 16);

  embed_kernel<<<BT, blk, 0, stream>>>(idx, tok, pos, x);
  for (int l = 0; l < LL; ++l) {
    const float* Wq_l = Wq + (size_t)l*CC*CC;
    const float* Wk_l = Wk + (size_t)l*CC*CC;
    const float* Wv_l = Wv + (size_t)l*CC*CC;
    const float* Wo_l = Wo + (size_t)l*CC*CC;
    const float* W1_l = W1 + (size_t)l*CC*4*CC;
    const float* W2_l = W2 + (size_t)l*4*CC*CC;
    lnsplit_kernel<<<BT, blk, 0, stream>>>(x, ln1g + (size_t)l*CC, ln1b + (size_t)l*CC, aspH);
    bsplit_kernel<2><<<s8, blk, 0, stream>>>(Wq_l, bsQK, CC, 0, 16);
    bsplit_kernel<2><<<s8, blk, 0, stream>>>(Wk_l, bsQK, CC, 8, 16);
    bsplit_kernel<2><<<s8, blk, 0, stream>>>(Wv_l, bsV, CC, 0, 8);
    bsplit_kernel<2><<<s8, blk, 0, stream>>>(Wo_l, bsO, CC, 0, 8);
    gemm128_kernel<2,true,4><<<gQK, blk, 0, stream>>>(nullptr, 0, aspH, aPSh, bsQK,
        nullptr, nullptr, qf, CC, 1024, 0, 0, 16, 0, 16, 3, Kp);
    gemm128_kernel<2,true,3><<<gV, blk, 0, stream>>>(nullptr, 0, aspH, aPSh, bsV,
        nullptr, nullptr, vplanes, CC, CC, 0, 0, 8, 0, 16, 1, nullptr);
    attn_mfma_kernel<<<BB*HH*16, blk, 0, stream>>>(qf, Kp, (const uint4*)vplanes, aspH2);
    gemm128_kernel<2,true,3><<<gO, blk, 0, stream>>>(nullptr, 0, aspH2, aPSh, bsO,
        bo + (size_t)l*CC, x, x, CC, CC, 0, 0, 8, 0, 16, 0, nullptr);
    lnsplit_kernel<<<BT, blk, 0, stream>>>(x, ln2g + (size_t)l*CC, ln2b + (size_t)l*CC, aspH3);
    bsplit_kernel<2><<<sW1, blk, 0, stream>>>(W1_l, bsW1, 4*CC, 0, 32);
    bsplit_kernel<2><<<sW2, blk, 0, stream>>>(W2_l, bsW2, CC, 0, 8);
    gemm128_kernel<2,true,3><<<gW1, blk, 0, stream>>>(nullptr, 0, aspH3, aPSh, bsW1,
        b1 + (size_t)l*4*CC, nullptr, a1p, CC, 2048, 1, 0, 32, 0, 16, 2, nullptr);
    gemm128_kernel<2,true,3><<<gW2, blk, 0, stream>>>(nullptr, 0, (const uint4*)a1p, aPSa, bsW2,
        b2 + (size_t)l*CC, x, x, 2048, CC, 0, 0, 8, 0, 64, 0, nullptr);
    gemm128_kernel<2,true,3><<<gW1, blk, 0, stream>>>(nullptr, 0, aspH3, aPSh, bsW1,
        b1 + (size_t)l*4*CC + 2048, nullptr, a1p, CC, 2048, 1, 16, 32, 0, 16, 2, nullptr);
    gemm128_kernel<2,true,3><<<gW2, blk, 0, stream>>>(nullptr, 0, (const uint4*)a1p, aPSa, bsW2,
        nullptr, x, x, 2048, CC, 0, 0, 8, 32, 64, 0, nullptr);
  }
  ln32_kernel<<<BT, blk, 0, stream>>>(x, lnfg, lnfb, hf);
  bsplit_kernel<1><<<sLM, blk, 0, stream>>>(lmw, bsL, VV, 0, 32);
  gemm128_kernel<1,false,1><<<gL, blk, 0, stream>>>(hf, CC, nullptr, 0, bsL,
      lmb, nullptr, out, CC, VV, 0, 0, 32, 0, 16, 0, nullptr);
}

// Round 18
// 4719.771 us; speedup vs baseline: 11.6516x; 1.0804x over previous
//
#include <hip/hip_runtime.h>

#define LL 6
#define BB 8
#define TT 1024
#define CC 1024
#define HH 16
#define HS 64
#define VV 4096
#define BT (BB*TT)

typedef __attribute__((ext_vector_type(4))) float f32x4;
typedef __attribute__((ext_vector_type(8))) short bf16x8;

__device__ __forceinline__ float bf2f(unsigned short u) {
  union { unsigned int u; float f; } v; v.u = ((unsigned int)u) << 16; return v.f;
}
__device__ __forceinline__ unsigned short rne16(float f) {
  unsigned u = __float_as_uint(f);
  return (unsigned short)((u + 0x7fffu + ((u >> 16) & 1u)) >> 16);
}
__device__ __forceinline__ void gld16(const uint4* g, uint4* l) {
  __builtin_amdgcn_global_load_lds(
      (const __attribute__((address_space(1))) void*)g,
      (__attribute__((address_space(3))) void*)l, 16, 0, 0);
}

// ---------------- embedding ----------------
__global__ __launch_bounds__(256) void embed_kernel(
    const int* __restrict__ idx, const float* __restrict__ tok,
    const float* __restrict__ pos, float* __restrict__ x) {
  int bt = blockIdx.x;
  int t = bt & (TT - 1);
  int id = idx[bt];
  float4 te = reinterpret_cast<const float4*>(tok)[(size_t)id * (CC/4) + threadIdx.x];
  float4 pe = reinterpret_cast<const float4*>(pos)[(size_t)t * (CC/4) + threadIdx.x];
  float4 r; r.x = te.x+pe.x; r.y = te.y+pe.y; r.z = te.z+pe.z; r.w = te.w+pe.w;
  reinterpret_cast<float4*>(x)[(size_t)bt * (CC/4) + threadIdx.x] = r;
}

// ---- splits ----
struct Oct3 { uint4 p0, p1, p2; };
__device__ __forceinline__ unsigned pk2(unsigned lo, unsigned hi) {
  return (lo >> 16) | (hi & 0xffff0000u);
}
__device__ __forceinline__ Oct3 split8(const float* f) {
  unsigned a0[8], a1[8], a2[8];
  #pragma unroll
  for (int e = 0; e < 8; ++e) {
    float v = f[e];
    unsigned u = __float_as_uint(v);
    a0[e] = u;
    float r = v - __uint_as_float(u & 0xffff0000u);
    unsigned ur = __float_as_uint(r);
    a1[e] = ur;
    float r2 = r - __uint_as_float(ur & 0xffff0000u);
    a2[e] = __float_as_uint(r2);
  }
  Oct3 o;
  o.p0 = make_uint4(pk2(a0[0],a0[1]), pk2(a0[2],a0[3]), pk2(a0[4],a0[5]), pk2(a0[6],a0[7]));
  o.p1 = make_uint4(pk2(a1[0],a1[1]), pk2(a1[2],a1[3]), pk2(a1[4],a1[5]), pk2(a1[6],a1[7]));
  o.p2 = make_uint4(pk2(a2[0],a2[1]), pk2(a2[2],a2[3]), pk2(a2[4],a2[5]), pk2(a2[6],a2[7]));
  return o;
}
struct Oct2 { uint4 p0, p1; };
__device__ __forceinline__ Oct2 split8_rne2(const float* f) {
  unsigned h0[8], h1[8];
  #pragma unroll
  for (int e = 0; e < 8; ++e) {
    h0[e] = rne16(f[e]);
    float r = f[e] - bf2f((unsigned short)h0[e]);
    h1[e] = rne16(r);
  }
  Oct2 o;
  o.p0 = make_uint4(h0[0]|(h0[1]<<16), h0[2]|(h0[3]<<16), h0[4]|(h0[5]<<16), h0[6]|(h0[7]<<16));
  o.p1 = make_uint4(h1[0]|(h1[1]<<16), h1[2]|(h1[3]<<16), h1[4]|(h1[5]<<16), h1[6]|(h1[7]<<16));
  return o;
}
__device__ __forceinline__ uint4 pack8_rne(const float* f) {
  unsigned h[8];
  #pragma unroll
  for (int e = 0; e < 8; ++e) h[e] = rne16(f[e]);
  return make_uint4(h[0]|(h[1]<<16), h[2]|(h[3]<<16), h[4]|(h[5]<<16), h[6]|(h[7]<<16));
}

// ---------------- layernorm fp32->fp32 (final LN only) ----------------
__global__ __launch_bounds__(256) void ln32_kernel(
    const float* __restrict__ x, const float* __restrict__ g,
    const float* __restrict__ b, float* __restrict__ out) {
  __shared__ float red[8];
  int row = blockIdx.x, tid = threadIdx.x;
  float4 v = reinterpret_cast<const float4*>(x)[(size_t)row * (CC/4) + tid];
  float s  = v.x+v.y+v.z+v.w;
  float ss = v.x*v.x+v.y*v.y+v.z*v.z+v.w*v.w;
  #pragma unroll
  for (int off = 32; off; off >>= 1) { s += __shfl_xor(s, off); ss += __shfl_xor(ss, off); }
  if ((tid & 63) == 0) { red[tid>>6] = s; red[4+(tid>>6)] = ss; }
  __syncthreads();
  s  = red[0]+red[1]+red[2]+red[3];
  ss = red[4]+red[5]+red[6]+red[7];
  float mu = s * (1.f/CC);
  float rs = rsqrtf(ss*(1.f/CC) - mu*mu + 1e-5f);
  float4 gg = reinterpret_cast<const float4*>(g)[tid];
  float4 bb = reinterpret_cast<const float4*>(b)[tid];
  float4 o;
  o.x = (v.x-mu)*rs*gg.x + bb.x;
  o.y = (v.y-mu)*rs*gg.y + bb.y;
  o.z = (v.z-mu)*rs*gg.z + bb.z;
  o.w = (v.w-mu)*rs*gg.w + bb.w;
  reinterpret_cast<float4*>(out)[(size_t)row * (CC/4) + tid] = o;
}

// ---------------- FUSED layernorm + A-presplit (2-plane RNE, pre-swizzled) -------
__global__ __launch_bounds__(256) void lnsplit_kernel(
    const float* __restrict__ x, const float* __restrict__ g,
    const float* __restrict__ b, uint4* __restrict__ outp) {
  __shared__ float red[8];
  __shared__ float rowbuf[1024];
  int row = blockIdx.x, tid = threadIdx.x;
  float4 v = reinterpret_cast<const float4*>(x)[(size_t)row * (CC/4) + tid];
  float s  = v.x+v.y+v.z+v.w;
  float ss = v.x*v.x+v.y*v.y+v.z*v.z+v.w*v.w;
  #pragma unroll
  for (int off = 32; off; off >>= 1) { s += __shfl_xor(s, off); ss += __shfl_xor(ss, off); }
  if ((tid & 63) == 0) { red[tid>>6] = s; red[4+(tid>>6)] = ss; }
  __syncthreads();
  s  = red[0]+red[1]+red[2]+red[3];
  ss = red[4]+red[5]+red[6]+red[7];
  float mu = s * (1.f/CC);
  float rs = rsqrtf(ss*(1.f/CC) - mu*mu + 1e-5f);
  float4 gg = reinterpret_cast<const float4*>(g)[tid];
  float4 bb = reinterpret_cast<const float4*>(b)[tid];
  float4 o;
  o.x = (v.x-mu)*rs*gg.x + bb.x;
  o.y = (v.y-mu)*rs*gg.y + bb.y;
  o.z = (v.z-mu)*rs*gg.z + bb.z;
  o.w = (v.w-mu)*rs*gg.w + bb.w;
  *reinterpret_cast<float4*>(&rowbuf[tid*4]) = o;
  __syncthreads();
  if (tid < 128) {
    const size_t aPS = (size_t)128 * 16 * 512;
    int kt = tid >> 3, sl = tid & 7;
    int r = row & 63, mt = row >> 6;
    float f[8];
    #pragma unroll
    for (int e = 0; e < 8; ++e) f[e] = rowbuf[tid*8 + e];
    size_t di = ((size_t)(mt*16 + kt))*512 + r*8 + (sl ^ (r & 7));
    Oct2 ot = split8_rne2(f);
    outp[di] = ot.p0; outp[aPS+di] = ot.p1;
  }
}

// ---------------- fused B pre-split for Wq/Wk/Wv/Wo (one dispatch) ----------------
__global__ __launch_bounds__(256) void bsplit4_kernel(
    const float* __restrict__ Wq, const float* __restrict__ Wk,
    const float* __restrict__ Wv, const float* __restrict__ Wo,
    uint4* __restrict__ bsQK, uint4* __restrict__ bsV, uint4* __restrict__ bsO) {
  int z = blockIdx.z;
  const float* Bw = (z == 0) ? Wq : (z == 1) ? Wk : (z == 2) ? Wv : Wo;
  uint4* outp = (z <= 1) ? bsQK : (z == 2) ? bsV : bsO;
  int ntile0 = (z == 1) ? 8 : 0;
  int ntTotal = (z <= 1) ? 16 : 8;
  int ntile = ntile0 + blockIdx.x, kt = blockIdx.y;
  size_t planeStride = (size_t)ntTotal * 16 * 1024;
  int tid = threadIdx.x;
  int bcol = tid & 127, bkcg = tid >> 7;
  #pragma unroll
  for (int g = 0; g < 4; ++g) {
    int kc = bkcg*4 + g;
    float f[8];
    #pragma unroll
    for (int j = 0; j < 8; ++j)
      f[j] = Bw[(size_t)(kt*64 + kc*8 + j) * CC + blockIdx.x*128 + bcol];
    size_t di = (((size_t)ntile * 16 + kt) * 8 + kc) * 128 + bcol;
    Oct2 o = split8_rne2(f);
    outp[di] = o.p0; outp[planeStride+di] = o.p1;
  }
}

// ---------------- B pre-split (W1/W2/logits) ----------------
template<int NP>
__global__ __launch_bounds__(256) void bsplit_kernel(
    const float* __restrict__ Bw, uint4* __restrict__ outp, int ldb,
    int ntile0, int ntTotal) {
  int ntile = ntile0 + blockIdx.x, kt = blockIdx.y;
  size_t planeStride = (size_t)ntTotal * gridDim.y * 1024;
  int tid = threadIdx.x;
  int bcol = tid & 127, bkcg = tid >> 7;
  #pragma unroll
  for (int g = 0; g < 4; ++g) {
    int kc = bkcg*4 + g;
    float f[8];
    #pragma unroll
    for (int j = 0; j < 8; ++j)
      f[j] = Bw[(size_t)(kt*64 + kc*8 + j) * ldb + blockIdx.x*128 + bcol];
    size_t di = (((size_t)ntile * gridDim.y + kt) * 8 + kc) * 128 + bcol;
    if (NP == 2) {
      Oct2 o = split8_rne2(f);
      outp[di] = o.p0; outp[planeStride+di] = o.p1;
    } else {
      outp[di] = pack8_rne(f);
    }
  }
}

// ---------------- 128x128 GEMM, global_load_lds staging (R17-proven) ------
template<int NP, bool ASP, int NM>
__global__ __launch_bounds__(256) void gemm128_kernel(
    const float* __restrict__ A, int lda,
    const uint4* __restrict__ Asp, size_t aPS,
    const uint4* __restrict__ Bs,
    const float* __restrict__ bias, const float* __restrict__ res,
    float* __restrict__ outf, int K, int ldc, int relu,
    int ntile0, int ntTotal, int kt0, int ktTotal, int vtmode,
    uint4* __restrict__ kout) {
  __shared__ uint4 lds_all[NP*2048];
  uint4* lds_a = lds_all;
  uint4* lds_b = lds_all + NP*1024;
  int tid = threadIdx.x;
  int by = blockIdx.y;
  int m0 = by * 128;
  int n0 = blockIdx.x * 128;
  int ntg = ntile0 + blockIdx.x;
  size_t bPS = (size_t)ntTotal * ktTotal * 1024;
  int lane = tid & 63, w = tid >> 6;
  int wm = w >> 1, wn = w & 1;
  int lr = lane & 15, lk = lane >> 4;
  int nkt = K >> 6;

  f32x4 acc[4][4];
  #pragma unroll
  for (int m = 0; m < 4; ++m)
    #pragma unroll
    for (int n = 0; n < 4; ++n)
      acc[m][n] = (f32x4){0.f, 0.f, 0.f, 0.f};

  for (int kt = 0; kt < nkt; ++kt) {
    if (ASP) {
      #pragma unroll
      for (int p = 0; p < NP; ++p) {
        const uint4* s0 = Asp + p*aPS + ((size_t)(2*by)   * nkt + kt)*512;
        const uint4* s1 = Asp + p*aPS + ((size_t)(2*by+1) * nkt + kt)*512;
        #pragma unroll
        for (int i = 0; i < 2; ++i) {
          int ch = w*2 + i;
          gld16(s0 + ch*64 + lane, &lds_a[p*1024 + ch*64]);
          gld16(s1 + ch*64 + lane, &lds_a[p*1024 + 512 + ch*64]);
        }
      }
    } else {
      #pragma unroll
      for (int i = 0; i < 4; ++i) {
        int c = tid + i * 256;
        int row = c >> 3, sl = c & 7;
        const float4* ap = reinterpret_cast<const float4*>(
            A + (size_t)(m0+row)*lda + kt*64 + sl*8);
        float4 x0 = ap[0], x1 = ap[1];
        float f[8] = {x0.x,x0.y,x0.z,x0.w,x1.x,x1.y,x1.z,x1.w};
        int di = (row>>6)*512 + (row&63)*8 + (sl ^ (row & 7));
        if (NP == 2) {
          Oct2 o = split8_rne2(f);
          lds_a[di] = o.p0; lds_a[1024 + di] = o.p1;
        } else {
          lds_a[di] = pack8_rne(f);
        }
      }
    }
    {
      int ktg = kt0 + kt;
      #pragma unroll
      for (int p = 0; p < NP; ++p) {
        const uint4* sb = Bs + p*bPS + ((size_t)ntg * ktTotal + ktg)*1024;
        #pragma unroll
        for (int i = 0; i < 4; ++i) {
          int ch = w*4 + i;
          gld16(sb + ch*64 + lane, &lds_b[p*1024 + ch*64]);
        }
      }
    }
    __syncthreads();
    #pragma unroll
    for (int ks = 0; ks < 2; ++ks) {
      int kc = ks*4 + lk;
      bf16x8 af[NP][4], bfr[NP][4];
      #pragma unroll
      for (int m = 0; m < 4; ++m) {
        int row = wm*64 + m*16 + lr;
        int si = (row>>6)*512 + (row&63)*8 + (kc ^ (row & 7));
        #pragma unroll
        for (int p = 0; p < NP; ++p)
          af[p][m] = reinterpret_cast<const bf16x8*>(lds_a + p*1024)[si];
      }
      #pragma unroll
      for (int n = 0; n < 4; ++n) {
        int si = kc*128 + wn*64 + n*16 + lr;
        #pragma unroll
        for (int p = 0; p < NP; ++p)
          bfr[p][n] = reinterpret_cast<const bf16x8*>(lds_b + p*1024)[si];
      }
      #pragma unroll
      for (int m = 0; m < 4; ++m)
        #pragma unroll
        for (int n = 0; n < 4; ++n) {
          acc[m][n] = __builtin_amdgcn_mfma_f32_16x16x32_bf16(af[0][m], bfr[0][n], acc[m][n], 0, 0, 0);
          if (NP == 2) {
            acc[m][n] = __builtin_amdgcn_mfma_f32_16x16x32_bf16(af[0][m], bfr[1][n], acc[m][n], 0, 0, 0);
            acc[m][n] = __builtin_amdgcn_mfma_f32_16x16x32_bf16(af[1][m], bfr[0][n], acc[m][n], 0, 0, 0);
            if (NM == 4)
              acc[m][n] = __builtin_amdgcn_mfma_f32_16x16x32_bf16(af[1][m], bfr[1][n], acc[m][n], 0, 0, 0);
          }
        }
    }
    __syncthreads();
  }

  if (vtmode == 1) {
    char* vb = (char*)outf;
    const size_t VPSb = (size_t)2048 * 512 * 16;
    #pragma unroll
    for (int m = 0; m < 4; ++m) {
      int row = m0 + wm*64 + m*16 + lk*4;
      int bq = row >> 10;
      int t  = row & (TT-1);
      int ktile = t >> 6, r = t & 63;
      int kc = r >> 3, toct0 = r & 7;
      #pragma unroll
      for (int n = 0; n < 4; ++n) {
        int col = n0 + wn*64 + n*16 + lr;
        int hh2 = col >> 6, d = col & 63;
        int tile = (bq*HH + hh2)*16 + ktile;
        int vi = kc*64 + ((d ^ (kc<<1)) & 63);
        unsigned p0[4], p1[4];
        #pragma unroll
        for (int j = 0; j < 4; ++j) {
          float v = acc[m][n][j];
          p0[j] = rne16(v);
          p1[j] = rne16(v - bf2f((unsigned short)p0[j]));
        }
        uint2 w0 = make_uint2(p0[0]|(p0[1]<<16), p0[2]|(p0[3]<<16));
        uint2 w1 = make_uint2(p1[0]|(p1[1]<<16), p1[2]|(p1[3]<<16));
        char* base = vb + ((size_t)tile*512 + vi)*16 + toct0*2;
        *reinterpret_cast<uint2*>(base) = w0;
        *reinterpret_cast<uint2*>(base + VPSb) = w1;
      }
    }
  } else if (vtmode == 2) {
    float* bounce = (float*)lds_all;
    #pragma unroll
    for (int m = 0; m < 4; ++m)
      #pragma unroll
      for (int n = 0; n < 4; ++n) {
        int cl = wn*64 + n*16 + lr;
        float bv = bias[n0 + cl];
        #pragma unroll
        for (int j = 0; j < 4; ++j) {
          int rl = wm*64 + m*16 + lk*4 + j;
          bounce[rl*128 + cl] = fmaxf(acc[m][n][j] + bv, 0.f);
        }
      }
    __syncthreads();
    uint4* a1p = (uint4*)outf;
    const size_t aPSa = (size_t)128 * 32 * 512;
    #pragma unroll
    for (int i = 0; i < 8; ++i) {
      int ot = tid + i*256;
      int r = ot >> 4, o = ot & 15;
      float f[8];
      #pragma unroll
      for (int e = 0; e < 8; ++e) f[e] = bounce[r*128 + o*8 + e];
      Oct2 o2 = split8_rne2(f);
      int mt = 2*by + (r>>6), rs = r & 63;
      int ktg = (n0 >> 6) + (o >> 3), sl = o & 7;
      size_t di = ((size_t)(mt*32 + ktg))*512 + rs*8 + (sl ^ (rs & 7));
      a1p[di] = o2.p0; a1p[aPSa + di] = o2.p1;
    }
  } else if (vtmode == 3 && ntg >= 8) {
    float* bounce = (float*)lds_all;
    #pragma unroll
    for (int m = 0; m < 4; ++m)
      #pragma unroll
      for (int n = 0; n < 4; ++n) {
        int cl = wn*64 + n*16 + lr;
        #pragma unroll
        for (int j = 0; j < 4; ++j) {
          int rl = wm*64 + m*16 + lk*4 + j;
          bounce[rl*128 + cl] = acc[m][n][j];
        }
      }
    __syncthreads();
    const size_t KPSC = (size_t)2048 * 512;
    int bq = m0 >> 10;
    int kt0tok = (m0 & 1023) >> 6;
    int hh0 = (ntg - 8) * 2;
    #pragma unroll
    for (int i = 0; i < 8; ++i) {
      int u = tid + i*256;
      int r = u >> 4, oct = u & 15;
      int head = oct >> 3, sl = oct & 7;
      float f[8];
      #pragma unroll
      for (int e = 0; e < 8; ++e) f[e] = bounce[r*128 + head*64 + sl*8 + e];
      Oct2 o = split8_rne2(f);
      int rk = r & 63;
      int tile = (bq*HH + hh0 + head)*16 + kt0tok + (r >> 6);
      size_t di = (size_t)tile*512 + rk*8 + (sl ^ (rk & 7));
      kout[di] = o.p0; kout[KPSC + di] = o.p1;
    }
  } else {
    #pragma unroll
    for (int m = 0; m < 4; ++m) {
      #pragma unroll
      for (int n = 0; n < 4; ++n) {
        int col = n0 + wn*64 + n*16 + lr;
        float bv = bias ? bias[col] : 0.f;
        #pragma unroll
        for (int j = 0; j < 4; ++j) {
          int row = m0 + wm*64 + m*16 + lk*4 + j;
          float vv = acc[m][n][j] + bv;
          if (relu) vv = fmaxf(vv, 0.f);
          size_t off = (size_t)row * ldc + col;
          if (res) vv += res[off];
          outf[off] = vv;
        }
      }
    }
  }
}

// ---------------- MFMA flash attention: XCD-grouped, Q 2-plane, 3-MFMA QK -------
__global__ __launch_bounds__(256) void attn_mfma_kernel(
    const float* __restrict__ qf, const uint4* __restrict__ Kp,
    const uint4* __restrict__ Vp, uint4* __restrict__ aout) {
  __shared__ uint4 K_lds[2][512];
  __shared__ uint4 V_lds[2][512];
  __shared__ unsigned P_lds[64*68];
  const size_t KPS = (size_t)2048 * 512;
  const size_t VPS = (size_t)2048 * 512;
  const size_t APS = (size_t)128 * 16 * 512;
  int tid = threadIdx.x, lane = tid & 63, w = tid >> 6;
  // XCD-grouped bijective map: all 16 qt-blocks of one (b,h) share i%8
  int i = blockIdx.x;
  int xcd = i & 7, qm = (i >> 3) & 15, ghi = i >> 7;
  int g = ghi*8 + xcd;
  int b = g >> 4, hh = g & 15, qt = 15 - qm;
  int lr = lane & 15, lk = lane >> 4;
  const size_t tok0 = (size_t)b * TT;

  // Q -> 2-plane RNE frags (from fp32 q, compact ldq=1024)
  bf16x8 qa[2][2];
  {
    const float* qp = qf + (tok0 + qt*64 + w*16 + lr) * 1024 + hh*HS;
    #pragma unroll
    for (int ks = 0; ks < 2; ++ks) {
      const float4* p4 = reinterpret_cast<const float4*>(qp + ks*32 + lk*8);
      float4 a = p4[0], c = p4[1];
      float f[8] = {a.x,a.y,a.z,a.w,c.x,c.y,c.z,c.w};
      Oct2 ot = split8_rne2(f);
      qa[ks][0] = *reinterpret_cast<bf16x8*>(&ot.p0);
      qa[ks][1] = *reinterpret_cast<bf16x8*>(&ot.p1);
    }
  }

  float mrow[4] = {-3.0e38f,-3.0e38f,-3.0e38f,-3.0e38f};
  float lrow[4] = {0.f,0.f,0.f,0.f};
  f32x4 oac[4];
  #pragma unroll
  for (int n = 0; n < 4; ++n) oac[n] = (f32x4){0.f,0.f,0.f,0.f};

  for (int kt = 0; kt <= qt; ++kt) {
    __syncthreads();
    {
      int tile = ((b*HH + hh)*16 + kt);
      const uint4* ksrc = Kp + (size_t)tile*512;
      #pragma unroll
      for (int p = 0; p < 2; ++p)
        #pragma unroll
        for (int i2 = 0; i2 < 2; ++i2) {
          int ch = w*2 + i2;
          gld16(ksrc + p*KPS + ch*64 + lane, &K_lds[p][ch*64]);
        }
      const uint4* vsrc = Vp + (size_t)tile*512;
      #pragma unroll
      for (int p = 0; p < 2; ++p)
        #pragma unroll
        for (int i2 = 0; i2 < 2; ++i2) {
          int ch = w*2 + i2;
          gld16(vsrc + p*VPS + ch*64 + lane, &V_lds[p][ch*64]);
        }
    }
    __syncthreads();

    f32x4 sfr[4];
    #pragma unroll
    for (int nf = 0; nf < 4; ++nf) sfr[nf] = (f32x4){0.f,0.f,0.f,0.f};
    #pragma unroll
    for (int ks = 0; ks < 2; ++ks) {
      int kc = ks*4 + lk;
      #pragma unroll
      for (int nf = 0; nf < 4; ++nf) {
        int row = nf*16 + lr;
        int si = row*8 + (kc ^ (row & 7));
        bf16x8 k0 = *reinterpret_cast<const bf16x8*>(&K_lds[0][si]);
        bf16x8 k1 = *reinterpret_cast<const bf16x8*>(&K_lds[1][si]);
        sfr[nf] = __builtin_amdgcn_mfma_f32_16x16x32_bf16(qa[ks][0], k0, sfr[nf], 0,0,0);
        sfr[nf] = __builtin_amdgcn_mfma_f32_16x16x32_bf16(qa[ks][0], k1, sfr[nf], 0,0,0);
        sfr[nf] = __builtin_amdgcn_mfma_f32_16x16x32_bf16(qa[ks][1], k0, sfr[nf], 0,0,0);
      }
    }
    #pragma unroll
    for (int nf = 0; nf < 4; ++nf)
      #pragma unroll
      for (int j = 0; j < 4; ++j) {
        float s = sfr[nf][j] * 8.0f;
        if (kt == qt && (nf*16 + lr) > (w*16 + lk*4 + j)) s = -3.0e38f;
        sfr[nf][j] = s;
      }
    float alpha[4], tsum[4];
    #pragma unroll
    for (int j = 0; j < 4; ++j) {
      float mx = fmaxf(fmaxf(sfr[0][j], sfr[1][j]), fmaxf(sfr[2][j], sfr[3][j]));
      mx = fmaxf(mx, __shfl_xor(mx, 1));
      mx = fmaxf(mx, __shfl_xor(mx, 2));
      mx = fmaxf(mx, __shfl_xor(mx, 4));
      mx = fmaxf(mx, __shfl_xor(mx, 8));
      float mnew = fmaxf(mrow[j], mx);
      alpha[j] = __expf(mrow[j] - mnew);
      mrow[j] = mnew;
      tsum[j] = 0.f;
    }
    #pragma unroll
    for (int nf = 0; nf < 4; ++nf)
      #pragma unroll
      for (int j = 0; j < 4; ++j) {
        float p = __expf(sfr[nf][j] - mrow[j]);
        tsum[j] += p;
        unsigned u = __float_as_uint(p);
        float r = p - __uint_as_float(u & 0xffff0000u);
        unsigned pw = (u & 0xffff0000u) | (__float_as_uint(r) >> 16);
        int qrow = w*16 + lk*4 + j;
        int kcol = nf*16 + lr;
        P_lds[qrow*68 + (((kcol>>3) ^ (qrow & 7)))*8 + (kcol & 7)] = pw;
      }
    #pragma unroll
    for (int j = 0; j < 4; ++j) {
      float ts = tsum[j];
      ts += __shfl_xor(ts, 1);
      ts += __shfl_xor(ts, 2);
      ts += __shfl_xor(ts, 4);
      ts += __shfl_xor(ts, 8);
      lrow[j] = lrow[j]*alpha[j] + ts;
      oac[0][j] *= alpha[j]; oac[1][j] *= alpha[j];
      oac[2][j] *= alpha[j]; oac[3][j] *= alpha[j];
    }
    __syncthreads();

    #pragma unroll
    for (int ks = 0; ks < 2; ++ks) {
      int kc = ks*4 + lk;
      int prow = w*16 + lr;
      const uint4* pp4 = reinterpret_cast<const uint4*>(
          &P_lds[prow*68 + ((kc ^ (prow & 7)))*8]);
      uint4 pw0 = pp4[0], pw1 = pp4[1];
      uint4 phu, plu;
      phu.x = (pw0.x>>16) | (pw0.y & 0xffff0000u);
      phu.y = (pw0.z>>16) | (pw0.w & 0xffff0000u);
      phu.z = (pw1.x>>16) | (pw1.y & 0xffff0000u);
      phu.w = (pw1.z>>16) | (pw1.w & 0xffff0000u);
      plu.x = (pw0.x & 0xffffu) | (pw0.y << 16);
      plu.y = (pw0.z & 0xffffu) | (pw0.w << 16);
      plu.z = (pw1.x & 0xffffu) | (pw1.y << 16);
      plu.w = (pw1.z & 0xffffu) | (pw1.w << 16);
      bf16x8 ph = *reinterpret_cast<bf16x8*>(&phu);
      bf16x8 pl = *reinterpret_cast<bf16x8*>(&plu);
      #pragma unroll
      for (int nf2 = 0; nf2 < 4; ++nf2) {
        int d = nf2*16 + lr;
        int vi = kc*64 + ((d ^ (kc<<1)) & 63);
        bf16x8 vh = *reinterpret_cast<const bf16x8*>(&V_lds[0][vi]);
        bf16x8 vl = *reinterpret_cast<const bf16x8*>(&V_lds[1][vi]);
        oac[nf2] = __builtin_amdgcn_mfma_f32_16x16x32_bf16(ph, vh, oac[nf2], 0,0,0);
        oac[nf2] = __builtin_amdgcn_mfma_f32_16x16x32_bf16(ph, vl, oac[nf2], 0,0,0);
        oac[nf2] = __builtin_amdgcn_mfma_f32_16x16x32_bf16(pl, vh, oac[nf2], 0,0,0);
      }
    }
  }

  // fused epilogue: O -> 2-plane A-tiles for the Wo gemm
  __syncthreads();
  float* Pf = (float*)P_lds;
  #pragma unroll
  for (int j = 0; j < 4; ++j) {
    float inv = 1.0f / lrow[j];
    #pragma unroll
    for (int nf2 = 0; nf2 < 4; ++nf2)
      Pf[(w*16 + lk*4 + j)*68 + nf2*16 + lr] = oac[nf2][j] * inv;
  }
  __syncthreads();
  int mtkt = (b*16 + qt)*16 + hh;
  #pragma unroll
  for (int i2 = 0; i2 < 2; ++i2) {
    int u = tid + i2*256;
    int r = u >> 3, sl = u & 7;
    float f[8];
    #pragma unroll
    for (int e = 0; e < 8; ++e) f[e] = Pf[r*68 + sl*8 + e];
    Oct2 o = split8_rne2(f);
    size_t di = (size_t)mtkt*512 + r*8 + (sl ^ (r & 7));
    aout[di] = o.p0; aout[APS + di] = o.p1;
  }
}

extern "C" void kernel_launch(void* const* d_in, const int* in_sizes, int n_in,
                              void* d_out, int out_size, void* d_ws, size_t ws_size,
                              hipStream_t stream) {
  const int*   idx  = (const int*)d_in[0];
  const float* tok  = (const float*)d_in[1];
  const float* pos  = (const float*)d_in[2];
  const float* Wq   = (const float*)d_in[3];
  const float* Wk   = (const float*)d_in[4];
  const float* Wv   = (const float*)d_in[5];
  const float* Wo   = (const float*)d_in[6];
  const float* bo   = (const float*)d_in[7];
  const float* ln1g = (const float*)d_in[8];
  const float* ln1b = (const float*)d_in[9];
  const float* ln2g = (const float*)d_in[10];
  const float* ln2b = (const float*)d_in[11];
  const float* W1   = (const float*)d_in[12];
  const float* b1   = (const float*)d_in[13];
  const float* W2   = (const float*)d_in[14];
  const float* b2   = (const float*)d_in[15];
  const float* lnfg = (const float*)d_in[16];
  const float* lnfb = (const float*)d_in[17];
  const float* lmw  = (const float*)d_in[18];
  const float* lmb  = (const float*)d_in[19];
  float* out = (float*)d_out;

  // d_out: x[0,32M) | vplanes[32,64M) | qf[64,96M) | Kp 2pl [96,128M);
  //        a1p reuses [64,128M) during MLP. Logits overwrite all at end.
  // ws: aspH[0,32) | bsQK[32,40) | bsV[40,44) | bsO[44,48)
  //     aspH2 (attn out) [0,32); aspH3 [0,32); bsW1 [32,48) | bsW2 [48,64);
  //     final: hf[0,32) | bsL[32,40).
  char* ob = (char*)d_out;
  float* x  = (float*)ob;
  float* vplanes = (float*)(ob + ((size_t)32<<20));
  float* qf = (float*)(ob + ((size_t)64<<20));
  uint4* Kp = (uint4*)(ob + ((size_t)96<<20));
  float* a1p = (float*)(ob + ((size_t)64<<20));
  char* wsb = (char*)d_ws;
  uint4* aspH  = (uint4*)wsb;
  uint4* bsQK  = (uint4*)(wsb + ((size_t)32<<20));
  uint4* bsV   = (uint4*)(wsb + ((size_t)40<<20));
  uint4* bsO   = (uint4*)(wsb + ((size_t)44<<20));
  uint4* aspH2 = (uint4*)wsb;
  uint4* aspH3 = (uint4*)wsb;
  uint4* bsW1  = (uint4*)(wsb + ((size_t)32<<20));
  uint4* bsW2  = (uint4*)(wsb + ((size_t)48<<20));
  float* hf    = (float*)wsb;
  uint4* bsL   = (uint4*)(wsb + ((size_t)32<<20));
  const size_t aPSh = (size_t)128 * 16 * 512;
  const size_t aPSa = (size_t)128 * 32 * 512;

  dim3 blk(256);
  dim3 gQK(16, 64), gV(8, 64), gO(8, 64);
  dim3 gW1(16, 64), gW2(8, 64), gL(32, 64);
  dim3 s4(8, 16, 4), sW1(32, 16), sW2(8, 64), sLM(32, 16);

  embed_kernel<<<BT, blk, 0, stream>>>(idx, tok, pos, x);
  for (int l = 0; l < LL; ++l) {
    const float* Wq_l = Wq + (size_t)l*CC*CC;
    const float* Wk_l = Wk + (size_t)l*CC*CC;
    const float* Wv_l = Wv + (size_t)l*CC*CC;
    const float* Wo_l = Wo + (size_t)l*CC*CC;
    const float* W1_l = W1 + (size_t)l*CC*4*CC;
    const float* W2_l = W2 + (size_t)l*4*CC*CC;
    lnsplit_kernel<<<BT, blk, 0, stream>>>(x, ln1g + (size_t)l*CC, ln1b + (size_t)l*CC, aspH);
    bsplit4_kernel<<<s4, blk, 0, stream>>>(Wq_l, Wk_l, Wv_l, Wo_l, bsQK, bsV, bsO);
    gemm128_kernel<2,true,4><<<gQK, blk, 0, stream>>>(nullptr, 0, aspH, aPSh, bsQK,
        nullptr, nullptr, qf, CC, 1024, 0, 0, 16, 0, 16, 3, Kp);
    gemm128_kernel<2,true,3><<<gV, blk, 0, stream>>>(nullptr, 0, aspH, aPSh, bsV,
        nullptr, nullptr, vplanes, CC, CC, 0, 0, 8, 0, 16, 1, nullptr);
    attn_mfma_kernel<<<BB*HH*16, blk, 0, stream>>>(qf, Kp, (const uint4*)vplanes, aspH2);
    gemm128_kernel<2,true,3><<<gO, blk, 0, stream>>>(nullptr, 0, aspH2, aPSh, bsO,
        bo + (size_t)l*CC, x, x, CC, CC, 0, 0, 8, 0, 16, 0, nullptr);
    lnsplit_kernel<<<BT, blk, 0, stream>>>(x, ln2g + (size_t)l*CC, ln2b + (size_t)l*CC, aspH3);
    bsplit_kernel<2><<<sW1, blk, 0, stream>>>(W1_l, bsW1, 4*CC, 0, 32);
    bsplit_kernel<2><<<sW2, blk, 0, stream>>>(W2_l, bsW2, CC, 0, 8);
    gemm128_kernel<2,true,3><<<gW1, blk, 0, stream>>>(nullptr, 0, aspH3, aPSh, bsW1,
        b1 + (size_t)l*4*CC, nullptr, a1p, CC, 2048, 1, 0, 32, 0, 16, 2, nullptr);
    gemm128_kernel<2,true,3><<<gW2, blk, 0, stream>>>(nullptr, 0, (const uint4*)a1p, aPSa, bsW2,
        b2 + (size_t)l*CC, x, x, 2048, CC, 0, 0, 8, 0, 64, 0, nullptr);
    gemm128_kernel<2,true,3><<<gW1, blk, 0, stream>>>(nullptr, 0, aspH3, aPSh, bsW1,
        b1 + (size_t)l*4*CC + 2048, nullptr, a1p, CC, 2048, 1, 16, 32, 0, 16, 2, nullptr);
    gemm128_kernel<2,true,3><<<gW2, blk, 0, stream>>>(nullptr, 0, (const uint4*)a1p, aPSa, bsW2,
        nullptr, x, x, 2048, CC, 0, 0, 8, 32, 64, 0, nullptr);
  }
  ln32_kernel<<<BT, blk, 0, stream>>>(x, lnfg, lnfb, hf);
  bsplit_kernel<1><<<sLM, blk, 0, stream>>>(lmw, bsL, VV, 0, 32);
  gemm128_kernel<1,false,1><<<gL, blk, 0, stream>>>(hf, CC, nullptr, 0, bsL,
      lmb, nullptr, out, CC, VV, 0, 0, 32, 0, 16, 0, nullptr);
}

// Round 19
// 4392.312 us; speedup vs baseline: 12.5202x; 1.0746x over previous
//
#include <hip/hip_runtime.h>

#define LL 6
#define BB 8
#define TT 1024
#define CC 1024
#define HH 16
#define HS 64
#define VV 4096
#define BT (BB*TT)

typedef __attribute__((ext_vector_type(4))) float f32x4;
typedef __attribute__((ext_vector_type(8))) short bf16x8;

__device__ __forceinline__ float bf2f(unsigned short u) {
  union { unsigned int u; float f; } v; v.u = ((unsigned int)u) << 16; return v.f;
}
__device__ __forceinline__ unsigned short rne16(float f) {
  unsigned u = __float_as_uint(f);
  return (unsigned short)((u + 0x7fffu + ((u >> 16) & 1u)) >> 16);
}
__device__ __forceinline__ void gld16(const uint4* g, uint4* l) {
  __builtin_amdgcn_global_load_lds(
      (const __attribute__((address_space(1))) void*)g,
      (__attribute__((address_space(3))) void*)l, 16, 0, 0);
}

// ---------------- embedding ----------------
__global__ __launch_bounds__(256) void embed_kernel(
    const int* __restrict__ idx, const float* __restrict__ tok,
    const float* __restrict__ pos, float* __restrict__ x) {
  int bt = blockIdx.x;
  int t = bt & (TT - 1);
  int id = idx[bt];
  float4 te = reinterpret_cast<const float4*>(tok)[(size_t)id * (CC/4) + threadIdx.x];
  float4 pe = reinterpret_cast<const float4*>(pos)[(size_t)t * (CC/4) + threadIdx.x];
  float4 r; r.x = te.x+pe.x; r.y = te.y+pe.y; r.z = te.z+pe.z; r.w = te.w+pe.w;
  reinterpret_cast<float4*>(x)[(size_t)bt * (CC/4) + threadIdx.x] = r;
}

// ---- splits ----
struct Oct2 { uint4 p0, p1; };
__device__ __forceinline__ Oct2 split8_rne2(const float* f) {
  unsigned h0[8], h1[8];
  #pragma unroll
  for (int e = 0; e < 8; ++e) {
    h0[e] = rne16(f[e]);
    float r = f[e] - bf2f((unsigned short)h0[e]);
    h1[e] = rne16(r);
  }
  Oct2 o;
  o.p0 = make_uint4(h0[0]|(h0[1]<<16), h0[2]|(h0[3]<<16), h0[4]|(h0[5]<<16), h0[6]|(h0[7]<<16));
  o.p1 = make_uint4(h1[0]|(h1[1]<<16), h1[2]|(h1[3]<<16), h1[4]|(h1[5]<<16), h1[6]|(h1[7]<<16));
  return o;
}
__device__ __forceinline__ uint4 pack8_rne(const float* f) {
  unsigned h[8];
  #pragma unroll
  for (int e = 0; e < 8; ++e) h[e] = rne16(f[e]);
  return make_uint4(h[0]|(h[1]<<16), h[2]|(h[3]<<16), h[4]|(h[5]<<16), h[6]|(h[7]<<16));
}

// ---------------- FUSED layernorm + A-presplit (2-plane RNE, pre-swizzled) -------
__global__ __launch_bounds__(256) void lnsplit_kernel(
    const float* __restrict__ x, const float* __restrict__ g,
    const float* __restrict__ b, uint4* __restrict__ outp) {
  __shared__ float red[8];
  __shared__ float rowbuf[1024];
  int row = blockIdx.x, tid = threadIdx.x;
  float4 v = reinterpret_cast<const float4*>(x)[(size_t)row * (CC/4) + tid];
  float s  = v.x+v.y+v.z+v.w;
  float ss = v.x*v.x+v.y*v.y+v.z*v.z+v.w*v.w;
  #pragma unroll
  for (int off = 32; off; off >>= 1) { s += __shfl_xor(s, off); ss += __shfl_xor(ss, off); }
  if ((tid & 63) == 0) { red[tid>>6] = s; red[4+(tid>>6)] = ss; }
  __syncthreads();
  s  = red[0]+red[1]+red[2]+red[3];
  ss = red[4]+red[5]+red[6]+red[7];
  float mu = s * (1.f/CC);
  float rs = rsqrtf(ss*(1.f/CC) - mu*mu + 1e-5f);
  float4 gg = reinterpret_cast<const float4*>(g)[tid];
  float4 bb = reinterpret_cast<const float4*>(b)[tid];
  float4 o;
  o.x = (v.x-mu)*rs*gg.x + bb.x;
  o.y = (v.y-mu)*rs*gg.y + bb.y;
  o.z = (v.z-mu)*rs*gg.z + bb.z;
  o.w = (v.w-mu)*rs*gg.w + bb.w;
  *reinterpret_cast<float4*>(&rowbuf[tid*4]) = o;
  __syncthreads();
  if (tid < 128) {
    const size_t aPS = (size_t)128 * 16 * 512;
    int kt = tid >> 3, sl = tid & 7;
    int r = row & 63, mt = row >> 6;
    float f[8];
    #pragma unroll
    for (int e = 0; e < 8; ++e) f[e] = rowbuf[tid*8 + e];
    size_t di = ((size_t)(mt*16 + kt))*512 + r*8 + (sl ^ (r & 7));
    Oct2 ot = split8_rne2(f);
    outp[di] = ot.p0; outp[aPS+di] = ot.p1;
  }
}

// ---------------- FUSED layernorm + 1-plane presplit (final LN / logits) ---------
__global__ __launch_bounds__(256) void lnsplit1_kernel(
    const float* __restrict__ x, const float* __restrict__ g,
    const float* __restrict__ b, uint4* __restrict__ outp) {
  __shared__ float red[8];
  __shared__ float rowbuf[1024];
  int row = blockIdx.x, tid = threadIdx.x;
  float4 v = reinterpret_cast<const float4*>(x)[(size_t)row * (CC/4) + tid];
  float s  = v.x+v.y+v.z+v.w;
  float ss = v.x*v.x+v.y*v.y+v.z*v.z+v.w*v.w;
  #pragma unroll
  for (int off = 32; off; off >>= 1) { s += __shfl_xor(s, off); ss += __shfl_xor(ss, off); }
  if ((tid & 63) == 0) { red[tid>>6] = s; red[4+(tid>>6)] = ss; }
  __syncthreads();
  s  = red[0]+red[1]+red[2]+red[3];
  ss = red[4]+red[5]+red[6]+red[7];
  float mu = s * (1.f/CC);
  float rs = rsqrtf(ss*(1.f/CC) - mu*mu + 1e-5f);
  float4 gg = reinterpret_cast<const float4*>(g)[tid];
  float4 bb = reinterpret_cast<const float4*>(b)[tid];
  float4 o;
  o.x = (v.x-mu)*rs*gg.x + bb.x;
  o.y = (v.y-mu)*rs*gg.y + bb.y;
  o.z = (v.z-mu)*rs*gg.z + bb.z;
  o.w = (v.w-mu)*rs*gg.w + bb.w;
  *reinterpret_cast<float4*>(&rowbuf[tid*4]) = o;
  __syncthreads();
  if (tid < 128) {
    int kt = tid >> 3, sl = tid & 7;
    int r = row & 63, mt = row >> 6;
    float f[8];
    #pragma unroll
    for (int e = 0; e < 8; ++e) f[e] = rowbuf[tid*8 + e];
    size_t di = ((size_t)(mt*16 + kt))*512 + r*8 + (sl ^ (r & 7));
    outp[di] = pack8_rne(f);
  }
}

// ---------------- fused B pre-split for Wq/Wk/Wv/Wo (one dispatch) ----------------
__global__ __launch_bounds__(256) void bsplit4_kernel(
    const float* __restrict__ Wq, const float* __restrict__ Wk,
    const float* __restrict__ Wv, const float* __restrict__ Wo,
    uint4* __restrict__ bsQK, uint4* __restrict__ bsV, uint4* __restrict__ bsO) {
  int z = blockIdx.z;
  const float* Bw = (z == 0) ? Wq : (z == 1) ? Wk : (z == 2) ? Wv : Wo;
  uint4* outp = (z <= 1) ? bsQK : (z == 2) ? bsV : bsO;
  int ntile0 = (z == 1) ? 8 : 0;
  int ntTotal = (z <= 1) ? 16 : 8;
  int ntile = ntile0 + blockIdx.x, kt = blockIdx.y;
  size_t planeStride = (size_t)ntTotal * 16 * 1024;
  int tid = threadIdx.x;
  int bcol = tid & 127, bkcg = tid >> 7;
  #pragma unroll
  for (int g = 0; g < 4; ++g) {
    int kc = bkcg*4 + g;
    float f[8];
    #pragma unroll
    for (int j = 0; j < 8; ++j)
      f[j] = Bw[(size_t)(kt*64 + kc*8 + j) * CC + blockIdx.x*128 + bcol];
    size_t di = (((size_t)ntile * 16 + kt) * 8 + kc) * 128 + bcol;
    Oct2 o = split8_rne2(f);
    outp[di] = o.p0; outp[planeStride+di] = o.p1;
  }
}

// ---------------- B pre-split (W1/W2/logits) ----------------
template<int NP>
__global__ __launch_bounds__(256) void bsplit_kernel(
    const float* __restrict__ Bw, uint4* __restrict__ outp, int ldb,
    int ntile0, int ntTotal) {
  int ntile = ntile0 + blockIdx.x, kt = blockIdx.y;
  size_t planeStride = (size_t)ntTotal * gridDim.y * 1024;
  int tid = threadIdx.x;
  int bcol = tid & 127, bkcg = tid >> 7;
  #pragma unroll
  for (int g = 0; g < 4; ++g) {
    int kc = bkcg*4 + g;
    float f[8];
    #pragma unroll
    for (int j = 0; j < 8; ++j)
      f[j] = Bw[(size_t)(kt*64 + kc*8 + j) * ldb + blockIdx.x*128 + bcol];
    size_t di = (((size_t)ntile * gridDim.y + kt) * 8 + kc) * 128 + bcol;
    if (NP == 2) {
      Oct2 o = split8_rne2(f);
      outp[di] = o.p0; outp[planeStride+di] = o.p1;
    } else {
      outp[di] = pack8_rne(f);
    }
  }
}

// ---------------- 128x128 GEMM, global_load_lds staging, XCD-grouped grid -------
// Block remap: by == XCD (mod 8) -> A-panel (shared across bx) stays in one L2.
template<int NP, bool ASP, int NM>
__global__ __launch_bounds__(256) void gemm128_kernel(
    const float* __restrict__ A, int lda,
    const uint4* __restrict__ Asp, size_t aPS,
    const uint4* __restrict__ Bs,
    const float* __restrict__ bias, const float* __restrict__ res,
    float* __restrict__ outf, int K, int ldc, int relu,
    int ntile0, int ntTotal, int kt0, int ktTotal, int vtmode,
    uint4* __restrict__ kout) {
  __shared__ uint4 lds_all[NP*2048];
  uint4* lds_a = lds_all;
  uint4* lds_b = lds_all + NP*1024;
  int tid = threadIdx.x;
  // XCD-grouped bijective remap (requires gridDim.y % 8 == 0)
  int NYd8 = gridDim.y >> 3;
  int li = blockIdx.x + gridDim.x * blockIdx.y;
  int xcd = li & 7, j = li >> 3;
  int by = xcd + 8 * (j % NYd8);
  int bx = j / NYd8;
  int m0 = by * 128;
  int n0 = bx * 128;
  int ntg = ntile0 + bx;
  size_t bPS = (size_t)ntTotal * ktTotal * 1024;
  int lane = tid & 63, w = tid >> 6;
  int wm = w >> 1, wn = w & 1;
  int lr = lane & 15, lk = lane >> 4;
  int nkt = K >> 6;

  f32x4 acc[4][4];
  #pragma unroll
  for (int m = 0; m < 4; ++m)
    #pragma unroll
    for (int n = 0; n < 4; ++n)
      acc[m][n] = (f32x4){0.f, 0.f, 0.f, 0.f};

  for (int kt = 0; kt < nkt; ++kt) {
    if (ASP) {
      #pragma unroll
      for (int p = 0; p < NP; ++p) {
        const uint4* s0 = Asp + p*aPS + ((size_t)(2*by)   * nkt + kt)*512;
        const uint4* s1 = Asp + p*aPS + ((size_t)(2*by+1) * nkt + kt)*512;
        #pragma unroll
        for (int i = 0; i < 2; ++i) {
          int ch = w*2 + i;
          gld16(s0 + ch*64 + lane, &lds_a[p*1024 + ch*64]);
          gld16(s1 + ch*64 + lane, &lds_a[p*1024 + 512 + ch*64]);
        }
      }
    } else {
      #pragma unroll
      for (int i = 0; i < 4; ++i) {
        int c = tid + i * 256;
        int row = c >> 3, sl = c & 7;
        const float4* ap = reinterpret_cast<const float4*>(
            A + (size_t)(m0+row)*lda + kt*64 + sl*8);
        float4 x0 = ap[0], x1 = ap[1];
        float f[8] = {x0.x,x0.y,x0.z,x0.w,x1.x,x1.y,x1.z,x1.w};
        int di = (row>>6)*512 + (row&63)*8 + (sl ^ (row & 7));
        if (NP == 2) {
          Oct2 o = split8_rne2(f);
          lds_a[di] = o.p0; lds_a[1024 + di] = o.p1;
        } else {
          lds_a[di] = pack8_rne(f);
        }
      }
    }
    {
      int ktg = kt0 + kt;
      #pragma unroll
      for (int p = 0; p < NP; ++p) {
        const uint4* sb = Bs + p*bPS + ((size_t)ntg * ktTotal + ktg)*1024;
        #pragma unroll
        for (int i = 0; i < 4; ++i) {
          int ch = w*4 + i;
          gld16(sb + ch*64 + lane, &lds_b[p*1024 + ch*64]);
        }
      }
    }
    __syncthreads();
    #pragma unroll
    for (int ks = 0; ks < 2; ++ks) {
      int kc = ks*4 + lk;
      bf16x8 af[NP][4], bfr[NP][4];
      #pragma unroll
      for (int m = 0; m < 4; ++m) {
        int row = wm*64 + m*16 + lr;
        int si = (row>>6)*512 + (row&63)*8 + (kc ^ (row & 7));
        #pragma unroll
        for (int p = 0; p < NP; ++p)
          af[p][m] = reinterpret_cast<const bf16x8*>(lds_a + p*1024)[si];
      }
      #pragma unroll
      for (int n = 0; n < 4; ++n) {
        int si = kc*128 + wn*64 + n*16 + lr;
        #pragma unroll
        for (int p = 0; p < NP; ++p)
          bfr[p][n] = reinterpret_cast<const bf16x8*>(lds_b + p*1024)[si];
      }
      #pragma unroll
      for (int m = 0; m < 4; ++m)
        #pragma unroll
        for (int n = 0; n < 4; ++n) {
          acc[m][n] = __builtin_amdgcn_mfma_f32_16x16x32_bf16(af[0][m], bfr[0][n], acc[m][n], 0, 0, 0);
          if (NP == 2) {
            acc[m][n] = __builtin_amdgcn_mfma_f32_16x16x32_bf16(af[0][m], bfr[1][n], acc[m][n], 0, 0, 0);
            acc[m][n] = __builtin_amdgcn_mfma_f32_16x16x32_bf16(af[1][m], bfr[0][n], acc[m][n], 0, 0, 0);
            if (NM == 4)
              acc[m][n] = __builtin_amdgcn_mfma_f32_16x16x32_bf16(af[1][m], bfr[1][n], acc[m][n], 0, 0, 0);
          }
        }
    }
    __syncthreads();
  }

  if (vtmode == 1) {
    char* vb = (char*)outf;
    const size_t VPSb = (size_t)2048 * 512 * 16;
    #pragma unroll
    for (int m = 0; m < 4; ++m) {
      int row = m0 + wm*64 + m*16 + lk*4;
      int bq = row >> 10;
      int t  = row & (TT-1);
      int ktile = t >> 6, r = t & 63;
      int kc = r >> 3, toct0 = r & 7;
      #pragma unroll
      for (int n = 0; n < 4; ++n) {
        int col = n0 + wn*64 + n*16 + lr;
        int hh2 = col >> 6, d = col & 63;
        int tile = (bq*HH + hh2)*16 + ktile;
        int vi = kc*64 + ((d ^ (kc<<1)) & 63);
        unsigned p0[4], p1[4];
        #pragma unroll
        for (int j2 = 0; j2 < 4; ++j2) {
          float v = acc[m][n][j2];
          p0[j2] = rne16(v);
          p1[j2] = rne16(v - bf2f((unsigned short)p0[j2]));
        }
        uint2 w0 = make_uint2(p0[0]|(p0[1]<<16), p0[2]|(p0[3]<<16));
        uint2 w1 = make_uint2(p1[0]|(p1[1]<<16), p1[2]|(p1[3]<<16));
        char* base = vb + ((size_t)tile*512 + vi)*16 + toct0*2;
        *reinterpret_cast<uint2*>(base) = w0;
        *reinterpret_cast<uint2*>(base + VPSb) = w1;
      }
    }
  } else if (vtmode == 2) {
    float* bounce = (float*)lds_all;
    #pragma unroll
    for (int m = 0; m < 4; ++m)
      #pragma unroll
      for (int n = 0; n < 4; ++n) {
        int cl = wn*64 + n*16 + lr;
        float bv = bias[n0 + cl];
        #pragma unroll
        for (int j2 = 0; j2 < 4; ++j2) {
          int rl = wm*64 + m*16 + lk*4 + j2;
          bounce[rl*128 + cl] = fmaxf(acc[m][n][j2] + bv, 0.f);
        }
      }
    __syncthreads();
    uint4* a1p = (uint4*)outf;
    const size_t aPSa = (size_t)128 * 32 * 512;
    #pragma unroll
    for (int i = 0; i < 8; ++i) {
      int ot = tid + i*256;
      int r = ot >> 4, o = ot & 15;
      float f[8];
      #pragma unroll
      for (int e = 0; e < 8; ++e) f[e] = bounce[r*128 + o*8 + e];
      Oct2 o2 = split8_rne2(f);
      int mt = 2*by + (r>>6), rs = r & 63;
      int ktg = (n0 >> 6) + (o >> 3), sl = o & 7;
      size_t di = ((size_t)(mt*32 + ktg))*512 + rs*8 + (sl ^ (rs & 7));
      a1p[di] = o2.p0; a1p[aPSa + di] = o2.p1;
    }
  } else if (vtmode == 3 && ntg >= 8) {
    float* bounce = (float*)lds_all;
    #pragma unroll
    for (int m = 0; m < 4; ++m)
      #pragma unroll
      for (int n = 0; n < 4; ++n) {
        int cl = wn*64 + n*16 + lr;
        #pragma unroll
        for (int j2 = 0; j2 < 4; ++j2) {
          int rl = wm*64 + m*16 + lk*4 + j2;
          bounce[rl*128 + cl] = acc[m][n][j2];
        }
      }
    __syncthreads();
    const size_t KPSC = (size_t)2048 * 512;
    int bq = m0 >> 10;
    int kt0tok = (m0 & 1023) >> 6;
    int hh0 = (ntg - 8) * 2;
    #pragma unroll
    for (int i = 0; i < 8; ++i) {
      int u = tid + i*256;
      int r = u >> 4, oct = u & 15;
      int head = oct >> 3, sl = oct & 7;
      float f[8];
      #pragma unroll
      for (int e = 0; e < 8; ++e) f[e] = bounce[r*128 + head*64 + sl*8 + e];
      Oct2 o = split8_rne2(f);
      int rk = r & 63;
      int tile = (bq*HH + hh0 + head)*16 + kt0tok + (r >> 6);
      size_t di = (size_t)tile*512 + rk*8 + (sl ^ (rk & 7));
      kout[di] = o.p0; kout[KPSC + di] = o.p1;
    }
  } else {
    #pragma unroll
    for (int m = 0; m < 4; ++m) {
      #pragma unroll
      for (int n = 0; n < 4; ++n) {
        int col = n0 + wn*64 + n*16 + lr;
        float bv = bias ? bias[col] : 0.f;
        #pragma unroll
        for (int j2 = 0; j2 < 4; ++j2) {
          int row = m0 + wm*64 + m*16 + lk*4 + j2;
          float vv = acc[m][n][j2] + bv;
          if (relu) vv = fmaxf(vv, 0.f);
          size_t off = (size_t)row * ldc + col;
          if (res) vv += res[off];
          outf[off] = vv;
        }
      }
    }
  }
}

// ---------------- MFMA flash attention (R18-proven, unchanged) -------
__global__ __launch_bounds__(256) void attn_mfma_kernel(
    const float* __restrict__ qf, const uint4* __restrict__ Kp,
    const uint4* __restrict__ Vp, uint4* __restrict__ aout) {
  __shared__ uint4 K_lds[2][512];
  __shared__ uint4 V_lds[2][512];
  __shared__ unsigned P_lds[64*68];
  const size_t KPS = (size_t)2048 * 512;
  const size_t VPS = (size_t)2048 * 512;
  const size_t APS = (size_t)128 * 16 * 512;
  int tid = threadIdx.x, lane = tid & 63, w = tid >> 6;
  int i = blockIdx.x;
  int xcd = i & 7, qm = (i >> 3) & 15, ghi = i >> 7;
  int g = ghi*8 + xcd;
  int b = g >> 4, hh = g & 15, qt = 15 - qm;
  int lr = lane & 15, lk = lane >> 4;
  const size_t tok0 = (size_t)b * TT;

  bf16x8 qa[2][2];
  {
    const float* qp = qf + (tok0 + qt*64 + w*16 + lr) * 1024 + hh*HS;
    #pragma unroll
    for (int ks = 0; ks < 2; ++ks) {
      const float4* p4 = reinterpret_cast<const float4*>(qp + ks*32 + lk*8);
      float4 a = p4[0], c = p4[1];
      float f[8] = {a.x,a.y,a.z,a.w,c.x,c.y,c.z,c.w};
      Oct2 ot = split8_rne2(f);
      qa[ks][0] = *reinterpret_cast<bf16x8*>(&ot.p0);
      qa[ks][1] = *reinterpret_cast<bf16x8*>(&ot.p1);
    }
  }

  float mrow[4] = {-3.0e38f,-3.0e38f,-3.0e38f,-3.0e38f};
  float lrow[4] = {0.f,0.f,0.f,0.f};
  f32x4 oac[4];
  #pragma unroll
  for (int n = 0; n < 4; ++n) oac[n] = (f32x4){0.f,0.f,0.f,0.f};

  for (int kt = 0; kt <= qt; ++kt) {
    __syncthreads();
    {
      int tile = ((b*HH + hh)*16 + kt);
      const uint4* ksrc = Kp + (size_t)tile*512;
      #pragma unroll
      for (int p = 0; p < 2; ++p)
        #pragma unroll
        for (int i2 = 0; i2 < 2; ++i2) {
          int ch = w*2 + i2;
          gld16(ksrc + p*KPS + ch*64 + lane, &K_lds[p][ch*64]);
        }
      const uint4* vsrc = Vp + (size_t)tile*512;
      #pragma unroll
      for (int p = 0; p < 2; ++p)
        #pragma unroll
        for (int i2 = 0; i2 < 2; ++i2) {
          int ch = w*2 + i2;
          gld16(vsrc + p*VPS + ch*64 + lane, &V_lds[p][ch*64]);
        }
    }
    __syncthreads();

    f32x4 sfr[4];
    #pragma unroll
    for (int nf = 0; nf < 4; ++nf) sfr[nf] = (f32x4){0.f,0.f,0.f,0.f};
    #pragma unroll
    for (int ks = 0; ks < 2; ++ks) {
      int kc = ks*4 + lk;
      #pragma unroll
      for (int nf = 0; nf < 4; ++nf) {
        int row = nf*16 + lr;
        int si = row*8 + (kc ^ (row & 7));
        bf16x8 k0 = *reinterpret_cast<const bf16x8*>(&K_lds[0][si]);
        bf16x8 k1 = *reinterpret_cast<const bf16x8*>(&K_lds[1][si]);
        sfr[nf] = __builtin_amdgcn_mfma_f32_16x16x32_bf16(qa[ks][0], k0, sfr[nf], 0,0,0);
        sfr[nf] = __builtin_amdgcn_mfma_f32_16x16x32_bf16(qa[ks][0], k1, sfr[nf], 0,0,0);
        sfr[nf] = __builtin_amdgcn_mfma_f32_16x16x32_bf16(qa[ks][1], k0, sfr[nf], 0,0,0);
      }
    }
    #pragma unroll
    for (int nf = 0; nf < 4; ++nf)
      #pragma unroll
      for (int j = 0; j < 4; ++j) {
        float s = sfr[nf][j] * 8.0f;
        if (kt == qt && (nf*16 + lr) > (w*16 + lk*4 + j)) s = -3.0e38f;
        sfr[nf][j] = s;
      }
    float alpha[4], tsum[4];
    #pragma unroll
    for (int j = 0; j < 4; ++j) {
      float mx = fmaxf(fmaxf(sfr[0][j], sfr[1][j]), fmaxf(sfr[2][j], sfr[3][j]));
      mx = fmaxf(mx, __shfl_xor(mx, 1));
      mx = fmaxf(mx, __shfl_xor(mx, 2));
      mx = fmaxf(mx, __shfl_xor(mx, 4));
      mx = fmaxf(mx, __shfl_xor(mx, 8));
      float mnew = fmaxf(mrow[j], mx);
      alpha[j] = __expf(mrow[j] - mnew);
      mrow[j] = mnew;
      tsum[j] = 0.f;
    }
    #pragma unroll
    for (int nf = 0; nf < 4; ++nf)
      #pragma unroll
      for (int j = 0; j < 4; ++j) {
        float p = __expf(sfr[nf][j] - mrow[j]);
        tsum[j] += p;
        unsigned u = __float_as_uint(p);
        float r = p - __uint_as_float(u & 0xffff0000u);
        unsigned pw = (u & 0xffff0000u) | (__float_as_uint(r) >> 16);
        int qrow = w*16 + lk*4 + j;
        int kcol = nf*16 + lr;
        P_lds[qrow*68 + (((kcol>>3) ^ (qrow & 7)))*8 + (kcol & 7)] = pw;
      }
    #pragma unroll
    for (int j = 0; j < 4; ++j) {
      float ts = tsum[j];
      ts += __shfl_xor(ts, 1);
      ts += __shfl_xor(ts, 2);
      ts += __shfl_xor(ts, 4);
      ts += __shfl_xor(ts, 8);
      lrow[j] = lrow[j]*alpha[j] + ts;
      oac[0][j] *= alpha[j]; oac[1][j] *= alpha[j];
      oac[2][j] *= alpha[j]; oac[3][j] *= alpha[j];
    }
    __syncthreads();

    #pragma unroll
    for (int ks = 0; ks < 2; ++ks) {
      int kc = ks*4 + lk;
      int prow = w*16 + lr;
      const uint4* pp4 = reinterpret_cast<const uint4*>(
          &P_lds[prow*68 + ((kc ^ (prow & 7)))*8]);
      uint4 pw0 = pp4[0], pw1 = pp4[1];
      uint4 phu, plu;
      phu.x = (pw0.x>>16) | (pw0.y & 0xffff0000u);
      phu.y = (pw0.z>>16) | (pw0.w & 0xffff0000u);
      phu.z = (pw1.x>>16) | (pw1.y & 0xffff0000u);
      phu.w = (pw1.z>>16) | (pw1.w & 0xffff0000u);
      plu.x = (pw0.x & 0xffffu) | (pw0.y << 16);
      plu.y = (pw0.z & 0xffffu) | (pw0.w << 16);
      plu.z = (pw1.x & 0xffffu) | (pw1.y << 16);
      plu.w = (pw1.z & 0xffffu) | (pw1.w << 16);
      bf16x8 ph = *reinterpret_cast<bf16x8*>(&phu);
      bf16x8 pl = *reinterpret_cast<bf16x8*>(&plu);
      #pragma unroll
      for (int nf2 = 0; nf2 < 4; ++nf2) {
        int d = nf2*16 + lr;
        int vi = kc*64 + ((d ^ (kc<<1)) & 63);
        bf16x8 vh = *reinterpret_cast<const bf16x8*>(&V_lds[0][vi]);
        bf16x8 vl = *reinterpret_cast<const bf16x8*>(&V_lds[1][vi]);
        oac[nf2] = __builtin_amdgcn_mfma_f32_16x16x32_bf16(ph, vh, oac[nf2], 0,0,0);
        oac[nf2] = __builtin_amdgcn_mfma_f32_16x16x32_bf16(ph, vl, oac[nf2], 0,0,0);
        oac[nf2] = __builtin_amdgcn_mfma_f32_16x16x32_bf16(pl, vh, oac[nf2], 0,0,0);
      }
    }
  }

  __syncthreads();
  float* Pf = (float*)P_lds;
  #pragma unroll
  for (int j = 0; j < 4; ++j) {
    float inv = 1.0f / lrow[j];
    #pragma unroll
    for (int nf2 = 0; nf2 < 4; ++nf2)
      Pf[(w*16 + lk*4 + j)*68 + nf2*16 + lr] = oac[nf2][j] * inv;
  }
  __syncthreads();
  int mtkt = (b*16 + qt)*16 + hh;
  #pragma unroll
  for (int i2 = 0; i2 < 2; ++i2) {
    int u = tid + i2*256;
    int r = u >> 3, sl = u & 7;
    float f[8];
    #pragma unroll
    for (int e = 0; e < 8; ++e) f[e] = Pf[r*68 + sl*8 + e];
    Oct2 o = split8_rne2(f);
    size_t di = (size_t)mtkt*512 + r*8 + (sl ^ (r & 7));
    aout[di] = o.p0; aout[APS + di] = o.p1;
  }
}

extern "C" void kernel_launch(void* const* d_in, const int* in_sizes, int n_in,
                              void* d_out, int out_size, void* d_ws, size_t ws_size,
                              hipStream_t stream) {
  const int*   idx  = (const int*)d_in[0];
  const float* tok  = (const float*)d_in[1];
  const float* pos  = (const float*)d_in[2];
  const float* Wq   = (const float*)d_in[3];
  const float* Wk   = (const float*)d_in[4];
  const float* Wv   = (const float*)d_in[5];
  const float* Wo   = (const float*)d_in[6];
  const float* bo   = (const float*)d_in[7];
  const float* ln1g = (const float*)d_in[8];
  const float* ln1b = (const float*)d_in[9];
  const float* ln2g = (const float*)d_in[10];
  const float* ln2b = (const float*)d_in[11];
  const float* W1   = (const float*)d_in[12];
  const float* b1   = (const float*)d_in[13];
  const float* W2   = (const float*)d_in[14];
  const float* b2   = (const float*)d_in[15];
  const float* lnfg = (const float*)d_in[16];
  const float* lnfb = (const float*)d_in[17];
  const float* lmw  = (const float*)d_in[18];
  const float* lmb  = (const float*)d_in[19];
  float* out = (float*)d_out;

  // d_out: x[0,32M) | vplanes[32,64M) | qf[64,96M) | Kp 2pl [96,128M);
  //        a1p reuses [64,128M) during MLP. Logits overwrite all at end.
  // ws: aspH[0,32) | bsQK[32,40) | bsV[40,44) | bsO[44,48)
  //     aspH2 (attn out) [0,32); aspH3 [0,32); bsW1 [32,48) | bsW2 [48,64);
  //     final: hfp 1-plane [0,16) | bsL[32,40).
  char* ob = (char*)d_out;
  float* x  = (float*)ob;
  float* vplanes = (float*)(ob + ((size_t)32<<20));
  float* qf = (float*)(ob + ((size_t)64<<20));
  uint4* Kp = (uint4*)(ob + ((size_t)96<<20));
  float* a1p = (float*)(ob + ((size_t)64<<20));
  char* wsb = (char*)d_ws;
  uint4* aspH  = (uint4*)wsb;
  uint4* bsQK  = (uint4*)(wsb + ((size_t)32<<20));
  uint4* bsV   = (uint4*)(wsb + ((size_t)40<<20));
  uint4* bsO   = (uint4*)(wsb + ((size_t)44<<20));
  uint4* aspH2 = (uint4*)wsb;
  uint4* aspH3 = (uint4*)wsb;
  uint4* bsW1  = (uint4*)(wsb + ((size_t)32<<20));
  uint4* bsW2  = (uint4*)(wsb + ((size_t)48<<20));
  uint4* hfp   = (uint4*)wsb;
  uint4* bsL   = (uint4*)(wsb + ((size_t)32<<20));
  const size_t aPSh = (size_t)128 * 16 * 512;
  const size_t aPSa = (size_t)128 * 32 * 512;

  dim3 blk(256);
  dim3 gQK(16, 64), gV(8, 64), gO(8, 64);
  dim3 gW1(16, 64), gW2(8, 64), gL(32, 64);
  dim3 s4(8, 16, 4), sW1(32, 16), sW2(8, 64), sLM(32, 16);

  embed_kernel<<<BT, blk, 0, stream>>>(idx, tok, pos, x);
  for (int l = 0; l < LL; ++l) {
    const float* Wq_l = Wq + (size_t)l*CC*CC;
    const float* Wk_l = Wk + (size_t)l*CC*CC;
    const float* Wv_l = Wv + (size_t)l*CC*CC;
    const float* Wo_l = Wo + (size_t)l*CC*CC;
    const float* W1_l = W1 + (size_t)l*CC*4*CC;
    const float* W2_l = W2 + (size_t)l*4*CC*CC;
    lnsplit_kernel<<<BT, blk, 0, stream>>>(x, ln1g + (size_t)l*CC, ln1b + (size_t)l*CC, aspH);
    bsplit4_kernel<<<s4, blk, 0, stream>>>(Wq_l, Wk_l, Wv_l, Wo_l, bsQK, bsV, bsO);
    gemm128_kernel<2,true,4><<<gQK, blk, 0, stream>>>(nullptr, 0, aspH, aPSh, bsQK,
        nullptr, nullptr, qf, CC, 1024, 0, 0, 16, 0, 16, 3, Kp);
    gemm128_kernel<2,true,3><<<gV, blk, 0, stream>>>(nullptr, 0, aspH, aPSh, bsV,
        nullptr, nullptr, vplanes, CC, CC, 0, 0, 8, 0, 16, 1, nullptr);
    attn_mfma_kernel<<<BB*HH*16, blk, 0, stream>>>(qf, Kp, (const uint4*)vplanes, aspH2);
    gemm128_kernel<2,true,3><<<gO, blk, 0, stream>>>(nullptr, 0, aspH2, aPSh, bsO,
        bo + (size_t)l*CC, x, x, CC, CC, 0, 0, 8, 0, 16, 0, nullptr);
    lnsplit_kernel<<<BT, blk, 0, stream>>>(x, ln2g + (size_t)l*CC, ln2b + (size_t)l*CC, aspH3);
    bsplit_kernel<2><<<sW1, blk, 0, stream>>>(W1_l, bsW1, 4*CC, 0, 32);
    bsplit_kernel<2><<<sW2, blk, 0, stream>>>(W2_l, bsW2, CC, 0, 8);
    gemm128_kernel<2,true,3><<<gW1, blk, 0, stream>>>(nullptr, 0, aspH3, aPSh, bsW1,
        b1 + (size_t)l*4*CC, nullptr, a1p, CC, 2048, 1, 0, 32, 0, 16, 2, nullptr);
    gemm128_kernel<2,true,3><<<gW2, blk, 0, stream>>>(nullptr, 0, (const uint4*)a1p, aPSa, bsW2,
        b2 + (size_t)l*CC, x, x, 2048, CC, 0, 0, 8, 0, 64, 0, nullptr);
    gemm128_kernel<2,true,3><<<gW1, blk, 0, stream>>>(nullptr, 0, aspH3, aPSh, bsW1,
        b1 + (size_t)l*4*CC + 2048, nullptr, a1p, CC, 2048, 1, 16, 32, 0, 16, 2, nullptr);
    gemm128_kernel<2,true,3><<<gW2, blk, 0, stream>>>(nullptr, 0, (const uint4*)a1p, aPSa, bsW2,
        nullptr, x, x, 2048, CC, 0, 0, 8, 32, 64, 0, nullptr);
  }
  lnsplit1_kernel<<<BT, blk, 0, stream>>>(x, lnfg, lnfb, hfp);
  bsplit_kernel<1><<<sLM, blk, 0, stream>>>(lmw, bsL, VV, 0, 32);
  gemm128_kernel<1,true,1><<<gL, blk, 0, stream>>>(nullptr, 0, hfp, aPSh, bsL,
      lmb, nullptr, out, CC, VV, 0, 0, 32, 0, 16, 0, nullptr);
}

// Round 20
// 4270.656 us; speedup vs baseline: 12.8769x; 1.0285x over previous
//
#include <hip/hip_runtime.h>

#define LL 6
#define BB 8
#define TT 1024
#define CC 1024
#define HH 16
#define HS 64
#define VV 4096
#define BT (BB*TT)

typedef __attribute__((ext_vector_type(4))) float f32x4;
typedef __attribute__((ext_vector_type(8))) short bf16x8;

// raw barrier: lgkm-drain only (keeps global_load_lds in flight across it)
#define RAWBAR() do { \
  asm volatile("s_waitcnt lgkmcnt(0)" ::: "memory"); \
  __builtin_amdgcn_s_barrier(); \
  __builtin_amdgcn_sched_barrier(0); \
} while (0)

__device__ __forceinline__ float bf2f(unsigned short u) {
  union { unsigned int u; float f; } v; v.u = ((unsigned int)u) << 16; return v.f;
}
__device__ __forceinline__ unsigned short rne16(float f) {
  unsigned u = __float_as_uint(f);
  return (unsigned short)((u + 0x7fffu + ((u >> 16) & 1u)) >> 16);
}
__device__ __forceinline__ void gld16(const uint4* g, uint4* l) {
  __builtin_amdgcn_global_load_lds(
      (const __attribute__((address_space(1))) void*)g,
      (__attribute__((address_space(3))) void*)l, 16, 0, 0);
}

// ---------------- embedding ----------------
__global__ __launch_bounds__(256) void embed_kernel(
    const int* __restrict__ idx, const float* __restrict__ tok,
    const float* __restrict__ pos, float* __restrict__ x) {
  int bt = blockIdx.x;
  int t = bt & (TT - 1);
  int id = idx[bt];
  float4 te = reinterpret_cast<const float4*>(tok)[(size_t)id * (CC/4) + threadIdx.x];
  float4 pe = reinterpret_cast<const float4*>(pos)[(size_t)t * (CC/4) + threadIdx.x];
  float4 r; r.x = te.x+pe.x; r.y = te.y+pe.y; r.z = te.z+pe.z; r.w = te.w+pe.w;
  reinterpret_cast<float4*>(x)[(size_t)bt * (CC/4) + threadIdx.x] = r;
}

// ---- splits ----
struct Oct2 { uint4 p0, p1; };
__device__ __forceinline__ Oct2 split8_rne2(const float* f) {
  unsigned h0[8], h1[8];
  #pragma unroll
  for (int e = 0; e < 8; ++e) {
    h0[e] = rne16(f[e]);
    float r = f[e] - bf2f((unsigned short)h0[e]);
    h1[e] = rne16(r);
  }
  Oct2 o;
  o.p0 = make_uint4(h0[0]|(h0[1]<<16), h0[2]|(h0[3]<<16), h0[4]|(h0[5]<<16), h0[6]|(h0[7]<<16));
  o.p1 = make_uint4(h1[0]|(h1[1]<<16), h1[2]|(h1[3]<<16), h1[4]|(h1[5]<<16), h1[6]|(h1[7]<<16));
  return o;
}
__device__ __forceinline__ uint4 pack8_rne(const float* f) {
  unsigned h[8];
  #pragma unroll
  for (int e = 0; e < 8; ++e) h[e] = rne16(f[e]);
  return make_uint4(h[0]|(h[1]<<16), h[2]|(h[3]<<16), h[4]|(h[5]<<16), h[6]|(h[7]<<16));
}

// ---------------- FUSED layernorm + A-presplit (2-plane RNE, pre-swizzled) -------
__global__ __launch_bounds__(256) void lnsplit_kernel(
    const float* __restrict__ x, const float* __restrict__ g,
    const float* __restrict__ b, uint4* __restrict__ outp) {
  __shared__ float red[8];
  __shared__ float rowbuf[1024];
  int row = blockIdx.x, tid = threadIdx.x;
  float4 v = reinterpret_cast<const float4*>(x)[(size_t)row * (CC/4) + tid];
  float s  = v.x+v.y+v.z+v.w;
  float ss = v.x*v.x+v.y*v.y+v.z*v.z+v.w*v.w;
  #pragma unroll
  for (int off = 32; off; off >>= 1) { s += __shfl_xor(s, off); ss += __shfl_xor(ss, off); }
  if ((tid & 63) == 0) { red[tid>>6] = s; red[4+(tid>>6)] = ss; }
  __syncthreads();
  s  = red[0]+red[1]+red[2]+red[3];
  ss = red[4]+red[5]+red[6]+red[7];
  float mu = s * (1.f/CC);
  float rs = rsqrtf(ss*(1.f/CC) - mu*mu + 1e-5f);
  float4 gg = reinterpret_cast<const float4*>(g)[tid];
  float4 bb = reinterpret_cast<const float4*>(b)[tid];
  float4 o;
  o.x = (v.x-mu)*rs*gg.x + bb.x;
  o.y = (v.y-mu)*rs*gg.y + bb.y;
  o.z = (v.z-mu)*rs*gg.z + bb.z;
  o.w = (v.w-mu)*rs*gg.w + bb.w;
  *reinterpret_cast<float4*>(&rowbuf[tid*4]) = o;
  __syncthreads();
  if (tid < 128) {
    const size_t aPS = (size_t)128 * 16 * 512;
    int kt = tid >> 3, sl = tid & 7;
    int r = row & 63, mt = row >> 6;
    float f[8];
    #pragma unroll
    for (int e = 0; e < 8; ++e) f[e] = rowbuf[tid*8 + e];
    size_t di = ((size_t)(mt*16 + kt))*512 + r*8 + (sl ^ (r & 7));
    Oct2 ot = split8_rne2(f);
    outp[di] = ot.p0; outp[aPS+di] = ot.p1;
  }
}

// ---------------- FUSED layernorm + 1-plane presplit (final LN / logits) ---------
__global__ __launch_bounds__(256) void lnsplit1_kernel(
    const float* __restrict__ x, const float* __restrict__ g,
    const float* __restrict__ b, uint4* __restrict__ outp) {
  __shared__ float red[8];
  __shared__ float rowbuf[1024];
  int row = blockIdx.x, tid = threadIdx.x;
  float4 v = reinterpret_cast<const float4*>(x)[(size_t)row * (CC/4) + tid];
  float s  = v.x+v.y+v.z+v.w;
  float ss = v.x*v.x+v.y*v.y+v.z*v.z+v.w*v.w;
  #pragma unroll
  for (int off = 32; off; off >>= 1) { s += __shfl_xor(s, off); ss += __shfl_xor(ss, off); }
  if ((tid & 63) == 0) { red[tid>>6] = s; red[4+(tid>>6)] = ss; }
  __syncthreads();
  s  = red[0]+red[1]+red[2]+red[3];
  ss = red[4]+red[5]+red[6]+red[7];
  float mu = s * (1.f/CC);
  float rs = rsqrtf(ss*(1.f/CC) - mu*mu + 1e-5f);
  float4 gg = reinterpret_cast<const float4*>(g)[tid];
  float4 bb = reinterpret_cast<const float4*>(b)[tid];
  float4 o;
  o.x = (v.x-mu)*rs*gg.x + bb.x;
  o.y = (v.y-mu)*rs*gg.y + bb.y;
  o.z = (v.z-mu)*rs*gg.z + bb.z;
  o.w = (v.w-mu)*rs*gg.w + bb.w;
  *reinterpret_cast<float4*>(&rowbuf[tid*4]) = o;
  __syncthreads();
  if (tid < 128) {
    int kt = tid >> 3, sl = tid & 7;
    int r = row & 63, mt = row >> 6;
    float f[8];
    #pragma unroll
    for (int e = 0; e < 8; ++e) f[e] = rowbuf[tid*8 + e];
    size_t di = ((size_t)(mt*16 + kt))*512 + r*8 + (sl ^ (r & 7));
    outp[di] = pack8_rne(f);
  }
}

// ---------------- fused B pre-split for Wq/Wk/Wv/Wo (one dispatch) ----------------
__global__ __launch_bounds__(256) void bsplit4_kernel(
    const float* __restrict__ Wq, const float* __restrict__ Wk,
    const float* __restrict__ Wv, const float* __restrict__ Wo,
    uint4* __restrict__ bsQK, uint4* __restrict__ bsV, uint4* __restrict__ bsO) {
  int z = blockIdx.z;
  const float* Bw = (z == 0) ? Wq : (z == 1) ? Wk : (z == 2) ? Wv : Wo;
  uint4* outp = (z <= 1) ? bsQK : (z == 2) ? bsV : bsO;
  int ntile0 = (z == 1) ? 8 : 0;
  int ntTotal = (z <= 1) ? 16 : 8;
  int ntile = ntile0 + blockIdx.x, kt = blockIdx.y;
  size_t planeStride = (size_t)ntTotal * 16 * 1024;
  int tid = threadIdx.x;
  int bcol = tid & 127, bkcg = tid >> 7;
  #pragma unroll
  for (int g = 0; g < 4; ++g) {
    int kc = bkcg*4 + g;
    float f[8];
    #pragma unroll
    for (int j = 0; j < 8; ++j)
      f[j] = Bw[(size_t)(kt*64 + kc*8 + j) * CC + blockIdx.x*128 + bcol];
    size_t di = (((size_t)ntile * 16 + kt) * 8 + kc) * 128 + bcol;
    Oct2 o = split8_rne2(f);
    outp[di] = o.p0; outp[planeStride+di] = o.p1;
  }
}

// ---------------- B pre-split (W1/W2/logits) ----------------
template<int NP>
__global__ __launch_bounds__(256) void bsplit_kernel(
    const float* __restrict__ Bw, uint4* __restrict__ outp, int ldb,
    int ntile0, int ntTotal) {
  int ntile = ntile0 + blockIdx.x, kt = blockIdx.y;
  size_t planeStride = (size_t)ntTotal * gridDim.y * 1024;
  int tid = threadIdx.x;
  int bcol = tid & 127, bkcg = tid >> 7;
  #pragma unroll
  for (int g = 0; g < 4; ++g) {
    int kc = bkcg*4 + g;
    float f[8];
    #pragma unroll
    for (int j = 0; j < 8; ++j)
      f[j] = Bw[(size_t)(kt*64 + kc*8 + j) * ldb + blockIdx.x*128 + bcol];
    size_t di = (((size_t)ntile * gridDim.y + kt) * 8 + kc) * 128 + bcol;
    if (NP == 2) {
      Oct2 o = split8_rne2(f);
      outp[di] = o.p0; outp[planeStride+di] = o.p1;
    } else {
      outp[di] = pack8_rne(f);
    }
  }
}

// ---------------- 128x128 GEMM, global_load_lds staging, XCD-grouped grid -------
template<int NP, bool ASP, int NM>
__global__ __launch_bounds__(256) void gemm128_kernel(
    const float* __restrict__ A, int lda,
    const uint4* __restrict__ Asp, size_t aPS,
    const uint4* __restrict__ Bs,
    const float* __restrict__ bias, const float* __restrict__ res,
    float* __restrict__ outf, int K, int ldc, int relu,
    int ntile0, int ntTotal, int kt0, int ktTotal, int vtmode,
    uint4* __restrict__ kout) {
  __shared__ uint4 lds_all[NP*2048];
  uint4* lds_a = lds_all;
  uint4* lds_b = lds_all + NP*1024;
  int tid = threadIdx.x;
  int NYd8 = gridDim.y >> 3;
  int li = blockIdx.x + gridDim.x * blockIdx.y;
  int xcd = li & 7, j = li >> 3;
  int by = xcd + 8 * (j % NYd8);
  int bx = j / NYd8;
  int m0 = by * 128;
  int n0 = bx * 128;
  int ntg = ntile0 + bx;
  size_t bPS = (size_t)ntTotal * ktTotal * 1024;
  int lane = tid & 63, w = tid >> 6;
  int wm = w >> 1, wn = w & 1;
  int lr = lane & 15, lk = lane >> 4;
  int nkt = K >> 6;

  f32x4 acc[4][4];
  #pragma unroll
  for (int m = 0; m < 4; ++m)
    #pragma unroll
    for (int n = 0; n < 4; ++n)
      acc[m][n] = (f32x4){0.f, 0.f, 0.f, 0.f};

  for (int kt = 0; kt < nkt; ++kt) {
    if (ASP) {
      #pragma unroll
      for (int p = 0; p < NP; ++p) {
        const uint4* s0 = Asp + p*aPS + ((size_t)(2*by)   * nkt + kt)*512;
        const uint4* s1 = Asp + p*aPS + ((size_t)(2*by+1) * nkt + kt)*512;
        #pragma unroll
        for (int i = 0; i < 2; ++i) {
          int ch = w*2 + i;
          gld16(s0 + ch*64 + lane, &lds_a[p*1024 + ch*64]);
          gld16(s1 + ch*64 + lane, &lds_a[p*1024 + 512 + ch*64]);
        }
      }
    } else {
      #pragma unroll
      for (int i = 0; i < 4; ++i) {
        int c = tid + i * 256;
        int row = c >> 3, sl = c & 7;
        const float4* ap = reinterpret_cast<const float4*>(
            A + (size_t)(m0+row)*lda + kt*64 + sl*8);
        float4 x0 = ap[0], x1 = ap[1];
        float f[8] = {x0.x,x0.y,x0.z,x0.w,x1.x,x1.y,x1.z,x1.w};
        int di = (row>>6)*512 + (row&63)*8 + (sl ^ (row & 7));
        if (NP == 2) {
          Oct2 o = split8_rne2(f);
          lds_a[di] = o.p0; lds_a[1024 + di] = o.p1;
        } else {
          lds_a[di] = pack8_rne(f);
        }
      }
    }
    {
      int ktg = kt0 + kt;
      #pragma unroll
      for (int p = 0; p < NP; ++p) {
        const uint4* sb = Bs + p*bPS + ((size_t)ntg * ktTotal + ktg)*1024;
        #pragma unroll
        for (int i = 0; i < 4; ++i) {
          int ch = w*4 + i;
          gld16(sb + ch*64 + lane, &lds_b[p*1024 + ch*64]);
        }
      }
    }
    __syncthreads();
    #pragma unroll
    for (int ks = 0; ks < 2; ++ks) {
      int kc = ks*4 + lk;
      bf16x8 af[NP][4], bfr[NP][4];
      #pragma unroll
      for (int m = 0; m < 4; ++m) {
        int row = wm*64 + m*16 + lr;
        int si = (row>>6)*512 + (row&63)*8 + (kc ^ (row & 7));
        #pragma unroll
        for (int p = 0; p < NP; ++p)
          af[p][m] = reinterpret_cast<const bf16x8*>(lds_a + p*1024)[si];
      }
      #pragma unroll
      for (int n = 0; n < 4; ++n) {
        int si = kc*128 + wn*64 + n*16 + lr;
        #pragma unroll
        for (int p = 0; p < NP; ++p)
          bfr[p][n] = reinterpret_cast<const bf16x8*>(lds_b + p*1024)[si];
      }
      #pragma unroll
      for (int m = 0; m < 4; ++m)
        #pragma unroll
        for (int n = 0; n < 4; ++n) {
          acc[m][n] = __builtin_amdgcn_mfma_f32_16x16x32_bf16(af[0][m], bfr[0][n], acc[m][n], 0, 0, 0);
          if (NP == 2) {
            acc[m][n] = __builtin_amdgcn_mfma_f32_16x16x32_bf16(af[0][m], bfr[1][n], acc[m][n], 0, 0, 0);
            acc[m][n] = __builtin_amdgcn_mfma_f32_16x16x32_bf16(af[1][m], bfr[0][n], acc[m][n], 0, 0, 0);
            if (NM == 4)
              acc[m][n] = __builtin_amdgcn_mfma_f32_16x16x32_bf16(af[1][m], bfr[1][n], acc[m][n], 0, 0, 0);
          }
        }
    }
    __syncthreads();
  }

  if (vtmode == 1) {
    char* vb = (char*)outf;
    const size_t VPSb = (size_t)2048 * 512 * 16;
    #pragma unroll
    for (int m = 0; m < 4; ++m) {
      int row = m0 + wm*64 + m*16 + lk*4;
      int bq = row >> 10;
      int t  = row & (TT-1);
      int ktile = t >> 6, r = t & 63;
      int kc = r >> 3, toct0 = r & 7;
      #pragma unroll
      for (int n = 0; n < 4; ++n) {
        int col = n0 + wn*64 + n*16 + lr;
        int hh2 = col >> 6, d = col & 63;
        int tile = (bq*HH + hh2)*16 + ktile;
        int vi = kc*64 + ((d ^ (kc<<1)) & 63);
        unsigned p0[4], p1[4];
        #pragma unroll
        for (int j2 = 0; j2 < 4; ++j2) {
          float v = acc[m][n][j2];
          p0[j2] = rne16(v);
          p1[j2] = rne16(v - bf2f((unsigned short)p0[j2]));
        }
        uint2 w0 = make_uint2(p0[0]|(p0[1]<<16), p0[2]|(p0[3]<<16));
        uint2 w1 = make_uint2(p1[0]|(p1[1]<<16), p1[2]|(p1[3]<<16));
        char* base = vb + ((size_t)tile*512 + vi)*16 + toct0*2;
        *reinterpret_cast<uint2*>(base) = w0;
        *reinterpret_cast<uint2*>(base + VPSb) = w1;
      }
    }
  } else if (vtmode == 2) {
    float* bounce = (float*)lds_all;
    #pragma unroll
    for (int m = 0; m < 4; ++m)
      #pragma unroll
      for (int n = 0; n < 4; ++n) {
        int cl = wn*64 + n*16 + lr;
        float bv = bias[n0 + cl];
        #pragma unroll
        for (int j2 = 0; j2 < 4; ++j2) {
          int rl = wm*64 + m*16 + lk*4 + j2;
          bounce[rl*128 + cl] = fmaxf(acc[m][n][j2] + bv, 0.f);
        }
      }
    __syncthreads();
    uint4* a1p = (uint4*)outf;
    const size_t aPSa = (size_t)128 * 32 * 512;
    #pragma unroll
    for (int i = 0; i < 8; ++i) {
      int ot = tid + i*256;
      int r = ot >> 4, o = ot & 15;
      float f[8];
      #pragma unroll
      for (int e = 0; e < 8; ++e) f[e] = bounce[r*128 + o*8 + e];
      Oct2 o2 = split8_rne2(f);
      int mt = 2*by + (r>>6), rs = r & 63;
      int ktg = (n0 >> 6) + (o >> 3), sl = o & 7;
      size_t di = ((size_t)(mt*32 + ktg))*512 + rs*8 + (sl ^ (rs & 7));
      a1p[di] = o2.p0; a1p[aPSa + di] = o2.p1;
    }
  } else if (vtmode == 3 && ntg >= 8) {
    float* bounce = (float*)lds_all;
    #pragma unroll
    for (int m = 0; m < 4; ++m)
      #pragma unroll
      for (int n = 0; n < 4; ++n) {
        int cl = wn*64 + n*16 + lr;
        #pragma unroll
        for (int j2 = 0; j2 < 4; ++j2) {
          int rl = wm*64 + m*16 + lk*4 + j2;
          bounce[rl*128 + cl] = acc[m][n][j2];
        }
      }
    __syncthreads();
    const size_t KPSC = (size_t)2048 * 512;
    int bq = m0 >> 10;
    int kt0tok = (m0 & 1023) >> 6;
    int hh0 = (ntg - 8) * 2;
    #pragma unroll
    for (int i = 0; i < 8; ++i) {
      int u = tid + i*256;
      int r = u >> 4, oct = u & 15;
      int head = oct >> 3, sl = oct & 7;
      float f[8];
      #pragma unroll
      for (int e = 0; e < 8; ++e) f[e] = bounce[r*128 + head*64 + sl*8 + e];
      Oct2 o = split8_rne2(f);
      int rk = r & 63;
      int tile = (bq*HH + hh0 + head)*16 + kt0tok + (r >> 6);
      size_t di = (size_t)tile*512 + rk*8 + (sl ^ (rk & 7));
      kout[di] = o.p0; kout[KPSC + di] = o.p1;
    }
  } else {
    #pragma unroll
    for (int m = 0; m < 4; ++m) {
      #pragma unroll
      for (int n = 0; n < 4; ++n) {
        int col = n0 + wn*64 + n*16 + lr;
        float bv = bias ? bias[col] : 0.f;
        #pragma unroll
        for (int j2 = 0; j2 < 4; ++j2) {
          int row = m0 + wm*64 + m*16 + lk*4 + j2;
          float vv = acc[m][n][j2] + bv;
          if (relu) vv = fmaxf(vv, 0.f);
          size_t off = (size_t)row * ldc + col;
          if (res) vv += res[off];
          outf[off] = vv;
        }
      }
    }
  }
}

// ---------------- MFMA flash attention: pipelined K-prefetch, raw barriers -------
__global__ __launch_bounds__(256) void attn_mfma_kernel(
    const float* __restrict__ qf, const uint4* __restrict__ Kp,
    const uint4* __restrict__ Vp, uint4* __restrict__ aout) {
  __shared__ uint4 K_lds[2][512];
  __shared__ uint4 V_lds[2][512];
  __shared__ unsigned P_lds[64*68];
  const size_t KPS = (size_t)2048 * 512;
  const size_t VPS = (size_t)2048 * 512;
  const size_t APS = (size_t)128 * 16 * 512;
  int tid = threadIdx.x, lane = tid & 63, w = tid >> 6;
  int i = blockIdx.x;
  int xcd = i & 7, qm = (i >> 3) & 15, ghi = i >> 7;
  int g = ghi*8 + xcd;
  int b = g >> 4, hh = g & 15, qt = 15 - qm;
  int lr = lane & 15, lk = lane >> 4;
  const size_t tok0 = (size_t)b * TT;
  const int tbase = (b*HH + hh)*16;

  bf16x8 qa[2][2];
  {
    const float* qp = qf + (tok0 + qt*64 + w*16 + lr) * 1024 + hh*HS;
    #pragma unroll
    for (int ks = 0; ks < 2; ++ks) {
      const float4* p4 = reinterpret_cast<const float4*>(qp + ks*32 + lk*8);
      float4 a = p4[0], c = p4[1];
      float f[8] = {a.x,a.y,a.z,a.w,c.x,c.y,c.z,c.w};
      Oct2 ot = split8_rne2(f);
      qa[ks][0] = *reinterpret_cast<bf16x8*>(&ot.p0);
      qa[ks][1] = *reinterpret_cast<bf16x8*>(&ot.p1);
    }
  }

  float mrow[4] = {-3.0e38f,-3.0e38f,-3.0e38f,-3.0e38f};
  float lrow[4] = {0.f,0.f,0.f,0.f};
  f32x4 oac[4];
  #pragma unroll
  for (int n = 0; n < 4; ++n) oac[n] = (f32x4){0.f,0.f,0.f,0.f};

  // prologue: stage K(0), V(0)
  {
    const uint4* ksrc = Kp + (size_t)tbase*512;
    const uint4* vsrc = Vp + (size_t)tbase*512;
    #pragma unroll
    for (int p = 0; p < 2; ++p)
      #pragma unroll
      for (int i2 = 0; i2 < 2; ++i2) {
        int ch = w*2 + i2;
        gld16(ksrc + p*KPS + ch*64 + lane, &K_lds[p][ch*64]);
        gld16(vsrc + p*VPS + ch*64 + lane, &V_lds[p][ch*64]);
      }
  }

  for (int kt = 0; kt <= qt; ++kt) {
    __syncthreads();   // drains staged K(kt),V(kt); orders P overwrite vs prev PV

    // ---- QK (reads K_lds) ----
    f32x4 sfr[4];
    #pragma unroll
    for (int nf = 0; nf < 4; ++nf) sfr[nf] = (f32x4){0.f,0.f,0.f,0.f};
    #pragma unroll
    for (int ks = 0; ks < 2; ++ks) {
      int kc = ks*4 + lk;
      #pragma unroll
      for (int nf = 0; nf < 4; ++nf) {
        int row = nf*16 + lr;
        int si = row*8 + (kc ^ (row & 7));
        bf16x8 k0 = *reinterpret_cast<const bf16x8*>(&K_lds[0][si]);
        bf16x8 k1 = *reinterpret_cast<const bf16x8*>(&K_lds[1][si]);
        sfr[nf] = __builtin_amdgcn_mfma_f32_16x16x32_bf16(qa[ks][0], k0, sfr[nf], 0,0,0);
        sfr[nf] = __builtin_amdgcn_mfma_f32_16x16x32_bf16(qa[ks][0], k1, sfr[nf], 0,0,0);
        sfr[nf] = __builtin_amdgcn_mfma_f32_16x16x32_bf16(qa[ks][1], k0, sfr[nf], 0,0,0);
      }
    }
    RAWBAR();          // all waves consumed K_lds (lgkm-only; no vmem in flight)

    // prefetch K(kt+1) — lands during softmax + PV, drained at next loop-top
    if (kt < qt) {
      const uint4* ksrc = Kp + (size_t)(tbase + kt + 1)*512;
      #pragma unroll
      for (int p = 0; p < 2; ++p)
        #pragma unroll
        for (int i2 = 0; i2 < 2; ++i2) {
          int ch = w*2 + i2;
          gld16(ksrc + p*KPS + ch*64 + lane, &K_lds[p][ch*64]);
        }
    }

    // ---- mask + online softmax + P write ----
    #pragma unroll
    for (int nf = 0; nf < 4; ++nf)
      #pragma unroll
      for (int j = 0; j < 4; ++j) {
        float s = sfr[nf][j] * 8.0f;
        if (kt == qt && (nf*16 + lr) > (w*16 + lk*4 + j)) s = -3.0e38f;
        sfr[nf][j] = s;
      }
    float alpha[4], tsum[4];
    #pragma unroll
    for (int j = 0; j < 4; ++j) {
      float mx = fmaxf(fmaxf(sfr[0][j], sfr[1][j]), fmaxf(sfr[2][j], sfr[3][j]));
      mx = fmaxf(mx, __shfl_xor(mx, 1));
      mx = fmaxf(mx, __shfl_xor(mx, 2));
      mx = fmaxf(mx, __shfl_xor(mx, 4));
      mx = fmaxf(mx, __shfl_xor(mx, 8));
      float mnew = fmaxf(mrow[j], mx);
      alpha[j] = __expf(mrow[j] - mnew);
      mrow[j] = mnew;
      tsum[j] = 0.f;
    }
    #pragma unroll
    for (int nf = 0; nf < 4; ++nf)
      #pragma unroll
      for (int j = 0; j < 4; ++j) {
        float p = __expf(sfr[nf][j] - mrow[j]);
        tsum[j] += p;
        unsigned u = __float_as_uint(p);
        float r = p - __uint_as_float(u & 0xffff0000u);
        unsigned pw = (u & 0xffff0000u) | (__float_as_uint(r) >> 16);
        int qrow = w*16 + lk*4 + j;
        int kcol = nf*16 + lr;
        P_lds[qrow*68 + (((kcol>>3) ^ (qrow & 7)))*8 + (kcol & 7)] = pw;
      }
    #pragma unroll
    for (int j = 0; j < 4; ++j) {
      float ts = tsum[j];
      ts += __shfl_xor(ts, 1);
      ts += __shfl_xor(ts, 2);
      ts += __shfl_xor(ts, 4);
      ts += __shfl_xor(ts, 8);
      lrow[j] = lrow[j]*alpha[j] + ts;
      oac[0][j] *= alpha[j]; oac[1][j] *= alpha[j];
      oac[2][j] *= alpha[j]; oac[3][j] *= alpha[j];
    }
    RAWBAR();          // P visible (lgkm-only: K(kt+1) stays in flight)

    // ---- PV (reads V_lds + P_lds) ----
    #pragma unroll
    for (int ks = 0; ks < 2; ++ks) {
      int kc = ks*4 + lk;
      int prow = w*16 + lr;
      const uint4* pp4 = reinterpret_cast<const uint4*>(
          &P_lds[prow*68 + ((kc ^ (prow & 7)))*8]);
      uint4 pw0 = pp4[0], pw1 = pp4[1];
      uint4 phu, plu;
      phu.x = (pw0.x>>16) | (pw0.y & 0xffff0000u);
      phu.y = (pw0.z>>16) | (pw0.w & 0xffff0000u);
      phu.z = (pw1.x>>16) | (pw1.y & 0xffff0000u);
      phu.w = (pw1.z>>16) | (pw1.w & 0xffff0000u);
      plu.x = (pw0.x & 0xffffu) | (pw0.y << 16);
      plu.y = (pw0.z & 0xffffu) | (pw0.w << 16);
      plu.z = (pw1.x & 0xffffu) | (pw1.y << 16);
      plu.w = (pw1.z & 0xffffu) | (pw1.w << 16);
      bf16x8 ph = *reinterpret_cast<bf16x8*>(&phu);
      bf16x8 pl = *reinterpret_cast<bf16x8*>(&plu);
      #pragma unroll
      for (int nf2 = 0; nf2 < 4; ++nf2) {
        int d = nf2*16 + lr;
        int vi = kc*64 + ((d ^ (kc<<1)) & 63);
        bf16x8 vh = *reinterpret_cast<const bf16x8*>(&V_lds[0][vi]);
        bf16x8 vl = *reinterpret_cast<const bf16x8*>(&V_lds[1][vi]);
        oac[nf2] = __builtin_amdgcn_mfma_f32_16x16x32_bf16(ph, vh, oac[nf2], 0,0,0);
        oac[nf2] = __builtin_amdgcn_mfma_f32_16x16x32_bf16(ph, vl, oac[nf2], 0,0,0);
        oac[nf2] = __builtin_amdgcn_mfma_f32_16x16x32_bf16(pl, vh, oac[nf2], 0,0,0);
      }
    }
    if (kt < qt) {
      RAWBAR();        // all waves consumed V_lds
      const uint4* vsrc = Vp + (size_t)(tbase + kt + 1)*512;
      #pragma unroll
      for (int p = 0; p < 2; ++p)
        #pragma unroll
        for (int i2 = 0; i2 < 2; ++i2) {
          int ch = w*2 + i2;
          gld16(vsrc + p*VPS + ch*64 + lane, &V_lds[p][ch*64]);
        }
    }
  }

  __syncthreads();
  float* Pf = (float*)P_lds;
  #pragma unroll
  for (int j = 0; j < 4; ++j) {
    float inv = 1.0f / lrow[j];
    #pragma unroll
    for (int nf2 = 0; nf2 < 4; ++nf2)
      Pf[(w*16 + lk*4 + j)*68 + nf2*16 + lr] = oac[nf2][j] * inv;
  }
  __syncthreads();
  int mtkt = (b*16 + qt)*16 + hh;
  #pragma unroll
  for (int i2 = 0; i2 < 2; ++i2) {
    int u = tid + i2*256;
    int r = u >> 3, sl = u & 7;
    float f[8];
    #pragma unroll
    for (int e = 0; e < 8; ++e) f[e] = Pf[r*68 + sl*8 + e];
    Oct2 o = split8_rne2(f);
    size_t di = (size_t)mtkt*512 + r*8 + (sl ^ (r & 7));
    aout[di] = o.p0; aout[APS + di] = o.p1;
  }
}

extern "C" void kernel_launch(void* const* d_in, const int* in_sizes, int n_in,
                              void* d_out, int out_size, void* d_ws, size_t ws_size,
                              hipStream_t stream) {
  const int*   idx  = (const int*)d_in[0];
  const float* tok  = (const float*)d_in[1];
  const float* pos  = (const float*)d_in[2];
  const float* Wq   = (const float*)d_in[3];
  const float* Wk   = (const float*)d_in[4];
  const float* Wv   = (const float*)d_in[5];
  const float* Wo   = (const float*)d_in[6];
  const float* bo   = (const float*)d_in[7];
  const float* ln1g = (const float*)d_in[8];
  const float* ln1b = (const float*)d_in[9];
  const float* ln2g = (const float*)d_in[10];
  const float* ln2b = (const float*)d_in[11];
  const float* W1   = (const float*)d_in[12];
  const float* b1   = (const float*)d_in[13];
  const float* W2   = (const float*)d_in[14];
  const float* b2   = (const float*)d_in[15];
  const float* lnfg = (const float*)d_in[16];
  const float* lnfb = (const float*)d_in[17];
  const float* lmw  = (const float*)d_in[18];
  const float* lmb  = (const float*)d_in[19];
  float* out = (float*)d_out;

  char* ob = (char*)d_out;
  float* x  = (float*)ob;
  float* vplanes = (float*)(ob + ((size_t)32<<20));
  float* qf = (float*)(ob + ((size_t)64<<20));
  uint4* Kp = (uint4*)(ob + ((size_t)96<<20));
  float* a1p = (float*)(ob + ((size_t)64<<20));
  char* wsb = (char*)d_ws;
  uint4* aspH  = (uint4*)wsb;
  uint4* bsQK  = (uint4*)(wsb + ((size_t)32<<20));
  uint4* bsV   = (uint4*)(wsb + ((size_t)40<<20));
  uint4* bsO   = (uint4*)(wsb + ((size_t)44<<20));
  uint4* aspH2 = (uint4*)wsb;
  uint4* aspH3 = (uint4*)wsb;
  uint4* bsW1  = (uint4*)(wsb + ((size_t)32<<20));
  uint4* bsW2  = (uint4*)(wsb + ((size_t)48<<20));
  uint4* hfp   = (uint4*)wsb;
  uint4* bsL   = (uint4*)(wsb + ((size_t)32<<20));
  const size_t aPSh = (size_t)128 * 16 * 512;
  const size_t aPSa = (size_t)128 * 32 * 512;

  dim3 blk(256);
  dim3 gQK(16, 64), gV(8, 64), gO(8, 64);
  dim3 gW1(16, 64), gW2(8, 64), gL(32, 64);
  dim3 s4(8, 16, 4), sW1(32, 16), sW2(8, 64), sLM(32, 16);

  embed_kernel<<<BT, blk, 0, stream>>>(idx, tok, pos, x);
  for (int l = 0; l < LL; ++l) {
    const float* Wq_l = Wq + (size_t)l*CC*CC;
    const float* Wk_l = Wk + (size_t)l*CC*CC;
    const float* Wv_l = Wv + (size_t)l*CC*CC;
    const float* Wo_l = Wo + (size_t)l*CC*CC;
    const float* W1_l = W1 + (size_t)l*CC*4*CC;
    const float* W2_l = W2 + (size_t)l*4*CC*CC;
    lnsplit_kernel<<<BT, blk, 0, stream>>>(x, ln1g + (size_t)l*CC, ln1b + (size_t)l*CC, aspH);
    bsplit4_kernel<<<s4, blk, 0, stream>>>(Wq_l, Wk_l, Wv_l, Wo_l, bsQK, bsV, bsO);
    gemm128_kernel<2,true,3><<<gQK, blk, 0, stream>>>(nullptr, 0, aspH, aPSh, bsQK,
        nullptr, nullptr, qf, CC, 1024, 0, 0, 16, 0, 16, 3, Kp);
    gemm128_kernel<2,true,3><<<gV, blk, 0, stream>>>(nullptr, 0, aspH, aPSh, bsV,
        nullptr, nullptr, vplanes, CC, CC, 0, 0, 8, 0, 16, 1, nullptr);
    attn_mfma_kernel<<<BB*HH*16, blk, 0, stream>>>(qf, Kp, (const uint4*)vplanes, aspH2);
    gemm128_kernel<2,true,3><<<gO, blk, 0, stream>>>(nullptr, 0, aspH2, aPSh, bsO,
        bo + (size_t)l*CC, x, x, CC, CC, 0, 0, 8, 0, 16, 0, nullptr);
    lnsplit_kernel<<<BT, blk, 0, stream>>>(x, ln2g + (size_t)l*CC, ln2b + (size_t)l*CC, aspH3);
    bsplit_kernel<2><<<sW1, blk, 0, stream>>>(W1_l, bsW1, 4*CC, 0, 32);
    bsplit_kernel<2><<<sW2, blk, 0, stream>>>(W2_l, bsW2, CC, 0, 8);
    gemm128_kernel<2,true,3><<<gW1, blk, 0, stream>>>(nullptr, 0, aspH3, aPSh, bsW1,
        b1 + (size_t)l*4*CC, nullptr, a1p, CC, 2048, 1, 0, 32, 0, 16, 2, nullptr);
    gemm128_kernel<2,true,3><<<gW2, blk, 0, stream>>>(nullptr, 0, (const uint4*)a1p, aPSa, bsW2,
        b2 + (size_t)l*CC, x, x, 2048, CC, 0, 0, 8, 0, 64, 0, nullptr);
    gemm128_kernel<2,true,3><<<gW1, blk, 0, stream>>>(nullptr, 0, aspH3, aPSh, bsW1,
        b1 + (size_t)l*4*CC + 2048, nullptr, a1p, CC, 2048, 1, 16, 32, 0, 16, 2, nullptr);
    gemm128_kernel<2,true,3><<<gW2, blk, 0, stream>>>(nullptr, 0, (const uint4*)a1p, aPSa, bsW2,
        nullptr, x, x, 2048, CC, 0, 0, 8, 32, 64, 0, nullptr);
  }
  lnsplit1_kernel<<<BT, blk, 0, stream>>>(x, lnfg, lnfb, hfp);
  bsplit_kernel<1><<<sLM, blk, 0, stream>>>(lmw, bsL, VV, 0, 32);
  gemm128_kernel<1,true,1><<<gL, blk, 0, stream>>>(nullptr, 0, hfp, aPSh, bsL,
      lmb, nullptr, out, CC, VV, 0, 0, 32, 0, 16, 0, nullptr);
}